// Round 3
// baseline (1096.661 us; speedup 1.0000x reference)
//
#include <hip/hip_runtime.h>

typedef unsigned short u16;
typedef unsigned int u32;
typedef __attribute__((ext_vector_type(8))) short short8;
typedef __attribute__((ext_vector_type(4))) float floatx4;

#define E_EDGES 24576
#define EC 12288            // edge chunk
#define N_NODES_C 4096

__device__ __forceinline__ float bf2f(u16 u) {
    union { u32 i; float f; } v; v.i = ((u32)u) << 16; return v.f;
}
__device__ __forceinline__ u16 f2bf(float f) {
    union { float f; u32 i; } v; v.f = f;
    u32 x = v.i;
    u32 r = (x + 0x7fffu + ((x >> 16) & 1u)) >> 16;
    return (u16)r;
}
// packed f32x2 -> bf16x2 in one VALU inst (RNE), no builtin on gfx950 -> inline asm
__device__ __forceinline__ u32 pk_bf16(float a, float b) {
    u32 r;
    asm("v_cvt_pk_bf16_f32 %0, %1, %2" : "=v"(r) : "v"(a), "v"(b));
    return r;
}
__device__ __forceinline__ u32 encf(float f) {
    union { float f; u32 i; } v; v.f = f;
    return (v.i & 0x80000000u) ? ~v.i : (v.i | 0x80000000u);
}
__device__ __forceinline__ float decf(u32 u) {
    union { u32 i; float f; } v;
    v.i = (u & 0x80000000u) ? (u ^ 0x80000000u) : ~u;
    return v.f;
}
// fast transcendentals: v_exp_f32 + v_rcp_f32
__device__ __forceinline__ float sigmoidf_(float x) { return __fdividef(1.f, 1.f + __expf(-x)); }
__device__ __forceinline__ float siluf_(float x) { return x * __fdividef(1.f, 1.f + __expf(-x)); }

// async global->LDS, 16B per lane; LDS dest must be wave-uniform base + lane*16
__device__ __forceinline__ void gld16(const u16* g, u16* l) {
    __builtin_amdgcn_global_load_lds((const __attribute__((address_space(1))) unsigned int*)g,
                                     (__attribute__((address_space(3))) unsigned int*)l, 16, 0, 0);
}

// diagnostic: ws too small -> paint output with 1000 (f32)
__global__ void k_diag(float* __restrict__ out, int n) {
    int i = blockIdx.x * 256 + threadIdx.x;
    if (i < n) out[i] = 1000.0f;
}

// ---------------- weight prep (f32 src -> bf16 transposed) ----------------
__global__ void k_transpose(const float* __restrict__ src, u16* __restrict__ dst, int K, int N) {
    int idx = blockIdx.x * 256 + threadIdx.x;
    if (idx >= K * N) return;
    int k = idx / N, n = idx % N;
    dst[n * K + k] = f2bf(src[idx]);
}
// combined complex weight, pre-transposed. src (K, 2H) f32: wa=cols[0:H), wb=cols[H:2H).
// dst (2H, 2K) bf16: dst[n][k] = k<K ? src[k][n] : (n<H ? -src[k-K][H+n] : src[k-K][n-H])
__global__ void k_combine(const float* __restrict__ src, u16* __restrict__ dst, int K, int H) {
    int total = 4 * K * H;
    int idx = blockIdx.x * 256 + threadIdx.x;
    if (idx >= total) return;
    int n = idx / (2 * K), k = idx % (2 * K);
    float v;
    if (k < K) v = src[k * 2 * H + n];
    else {
        int kk = k - K;
        if (n < H) v = -src[kk * 2 * H + H + n];
        else       v = src[kk * 2 * H + (n - H)];
    }
    dst[idx] = f2bf(v);
}

// pack to_grid (100,19) -> tgP[112][32] bf16; pack from_grid (19,100) -> fgP[32][128] bf16
__global__ void k_packgrid(const float* __restrict__ tg, const float* __restrict__ fg,
                           u16* __restrict__ tgP, u16* __restrict__ fgP) {
    int idx = blockIdx.x * 256 + threadIdx.x;
    if (idx < 112 * 32) {
        int p = idx >> 5, m = idx & 31;
        tgP[idx] = (p < 100 && m < 19) ? f2bf(tg[p * 19 + m]) : (u16)0;
    }
    int j = idx - 112 * 32;
    if (j >= 0 && j < 32 * 128) {
        int m = j >> 7, k = j & 127;
        fgP[j] = (m < 19 && k < 100) ? f2bf(fg[m * 100 + k]) : (u16)0;
    }
}

__global__ void k_init(u32* __restrict__ nmax, float* __restrict__ nsum, int n) {
    int idx = blockIdx.x * 256 + threadIdx.x;
    if (idx < n) { nmax[idx] = 0x007FFFFFu; /* enc(-inf) */ nsum[idx] = 0.f; }
}

// ---------------- CSR build over receivers (static per launch) ----------------
__global__ void k_deg(const int* __restrict__ rcv, u32* __restrict__ deg) {
    int e = blockIdx.x * 256 + threadIdx.x;
    if (e < E_EDGES) atomicAdd(&deg[rcv[e]], 1u);
}
__global__ __launch_bounds__(256) void k_pfx(const u32* __restrict__ deg,
                                             u32* __restrict__ rowstart, u32* __restrict__ cur) {
    __shared__ u32 ps[256];
    int t = threadIdx.x;
    u32 loc[16]; u32 s = 0;
#pragma unroll
    for (int i = 0; i < 16; i++) { loc[i] = s; s += deg[t * 16 + i]; }
    ps[t] = s;
    __syncthreads();
    for (int o = 1; o < 256; o <<= 1) {
        u32 v = (t >= o) ? ps[t - o] : 0u;
        __syncthreads();
        ps[t] += v;
        __syncthreads();
    }
    u32 base = (t == 0) ? 0u : ps[t - 1];
#pragma unroll
    for (int i = 0; i < 16; i++) { u32 v = base + loc[i]; rowstart[t * 16 + i] = v; cur[t * 16 + i] = v; }
}
__global__ void k_fill(const int* __restrict__ rcv, u32* __restrict__ cur, int* __restrict__ elist) {
    int e = blockIdx.x * 256 + threadIdx.x;
    if (e < E_EDGES) { u32 p = atomicAdd(&cur[rcv[e]], 1u); elist[p] = e; }
}

// ---------------- edge embeddings (f32 in -> bf16 A) ----------------
__global__ void k_ee(const float* __restrict__ dist, const int* __restrict__ species,
                     const int* __restrict__ snd, const int* __restrict__ rcv,
                     const float* __restrict__ semb, const float* __restrict__ remb,
                     u16* __restrict__ ee) {
    int idx = blockIdx.x * 256 + threadIdx.x;
    if (idx >= E_EDGES * 192) return;
    int e = idx / 192, c = idx % 192;
    float v;
    if (c < 64)       v = dist[e * 64 + c];
    else if (c < 128) v = semb[species[snd[e]] * 64 + (c - 64)];
    else              v = remb[species[rcv[e]] * 64 + (c - 128)];
    ee[idx] = f2bf(v);
}

// ---------------- GEMM (m97 structure): A (M,K) bf16 rm, BT (N,K) bf16 rm, C (M,N) bf16 ----------------
// global_load_lds staging, unpadded 64B rows. M%128==0, K%32==0; N guarded.
// Explicit s_waitcnt vmcnt(0) before barrier — async LDS-DMA must drain (round-6 race fix).
__global__ __launch_bounds__(256) void k_gemm(
    const u16* __restrict__ A, int lda,
    const u16* __restrict__ BT, int ldb,
    u16* __restrict__ C, int ldc,
    int N, int K,
    const float* __restrict__ bias) {
    __shared__ u16 As[128 * 32];
    __shared__ u16 Bs[128 * 32];
    int tid = threadIdx.x;
    int bm0 = blockIdx.x * 128;
    int bn0 = blockIdx.y * 128;
    int wave = tid >> 6, lane = tid & 63;
    int wm = (wave >> 1) * 64, wn = (wave & 1) * 64;
    int lrow = lane & 15, lk = (lane >> 4) * 8;

    // staging geometry: wave w covers rows w*16 + (lane>>2), 16B chunk (lane&3)
    int srow = (wave << 4) + (lane >> 2);        // 0..63
    int schunk = (lane & 3) << 3;                // u16 offset 0/8/16/24
    const u16* Arow0 = A + (size_t)(bm0 + srow) * lda + schunk;
    const u16* Arow1 = A + (size_t)(bm0 + srow + 64) * lda + schunk;
    int n0 = bn0 + srow;      if (n0 >= N) n0 = N - 1;
    int n1 = bn0 + srow + 64; if (n1 >= N) n1 = N - 1;
    const u16* Brow0 = BT + (size_t)n0 * ldb + schunk;
    const u16* Brow1 = BT + (size_t)n1 * ldb + schunk;
    u16* lA0 = &As[srow * 32 + schunk];
    u16* lA1 = &As[(srow + 64) * 32 + schunk];
    u16* lB0 = &Bs[srow * 32 + schunk];
    u16* lB1 = &Bs[(srow + 64) * 32 + schunk];

    floatx4 acc[4][4];
#pragma unroll
    for (int i = 0; i < 4; i++)
#pragma unroll
        for (int j = 0; j < 4; j++) acc[i][j] = floatx4{0.f, 0.f, 0.f, 0.f};

    for (int k0 = 0; k0 < K; k0 += 32) {
        gld16(Arow0 + k0, lA0);
        gld16(Arow1 + k0, lA1);
        gld16(Brow0 + k0, lB0);
        gld16(Brow1 + k0, lB1);
        asm volatile("s_waitcnt vmcnt(0)" ::: "memory");
        __syncthreads();
        short8 a[4], b[4];
#pragma unroll
        for (int i = 0; i < 4; i++) a[i] = *(const short8*)(&As[(wm + i * 16 + lrow) * 32 + lk]);
#pragma unroll
        for (int j = 0; j < 4; j++) b[j] = *(const short8*)(&Bs[(wn + j * 16 + lrow) * 32 + lk]);
#pragma unroll
        for (int i = 0; i < 4; i++)
#pragma unroll
            for (int j = 0; j < 4; j++)
                acc[i][j] = __builtin_amdgcn_mfma_f32_16x16x32_bf16(a[i], b[j], acc[i][j], 0, 0, 0);
        __syncthreads();
    }

    int q = lane >> 4;
#pragma unroll
    for (int i = 0; i < 4; i++) {
#pragma unroll
        for (int j = 0; j < 4; j++) {
            int col = bn0 + wn + j * 16 + lrow;
            if (col < N) {
                float bv = bias ? bias[col] : 0.f;
#pragma unroll
                for (int r = 0; r < 4; r++) {
                    int row = bm0 + wm + i * 16 + q * 4 + r;
                    C[(size_t)row * ldc + col] = f2bf(acc[i][j][r] + bv);
                }
            }
        }
    }
}

// ---------------- LayerNorm(64) + SiLU (bf16 io, f32 params) ----------------
__global__ __launch_bounds__(256) void k_ln_silu(const u16* __restrict__ in, u16* __restrict__ out,
                                                 const float* __restrict__ g, const float* __restrict__ b) {
    int tid = threadIdx.x;
    int e = blockIdx.x * 4 + (tid >> 6);
    int c = tid & 63;
    float x = bf2f(in[(size_t)e * 64 + c]);
    float s = x, s2 = x * x;
#pragma unroll
    for (int o = 32; o; o >>= 1) { s += __shfl_xor(s, o); s2 += __shfl_xor(s2, o); }
    float mu = s * (1.f / 64.f);
    float var = s2 * (1.f / 64.f) - mu * mu;
    float rs = rsqrtf(var + 1e-5f);
    float y = (x - mu) * rs * g[c] + b[c];
    out[(size_t)e * 64 + c] = f2bf(siluf_(y));
}

// ---------------- rotate: wigner @ concat(nf[snd],nf[rcv]); scale by x_edge; pack A1 (chunked) ----------------
__global__ __launch_bounds__(256) void k_rotate(const float* __restrict__ nf, const float* __restrict__ wig,
                                                const int* __restrict__ snd, const int* __restrict__ rcv,
                                                const u16* __restrict__ xe, u16* __restrict__ A1, int e0) {
    __shared__ float wl[2][475];
    int tid = threadIdx.x;
    for (int i = tid; i < 950; i += 256) {
        int ee = e0 + blockIdx.x * 2 + (i / 475);
        wl[i / 475][i % 475] = wig[(size_t)ee * 475 + (i % 475)];
    }
    __syncthreads();
    int le = tid >> 7, c = tid & 127;
    int el = blockIdx.x * 2 + le;       // chunk-local
    int e = e0 + el;                    // global
    int nd = (c < 64) ? snd[e] : rcv[e];
    int cc = c & 63;
    float msg[25];
#pragma unroll
    for (int k = 0; k < 25; k++) msg[k] = nf[(size_t)nd * 1600 + k * 64 + cc];
    const float* w = wl[le];
    size_t ebase = (size_t)el * 2432;
    size_t xbase = (size_t)el * 1536;
#pragma unroll
    for (int m = 0; m < 19; m++) {
        float r = 0.f;
#pragma unroll
        for (int k = 0; k < 25; k++) r += w[m * 25 + k] * msg[k];
        int a1c, xc;
        if (m < 5)       { a1c = m * 128;               xc = m * 128; }
        else if (m < 9)  { a1c = 640 + (m - 5) * 128;   xc = 640 + (m - 5) * 128; }
        else if (m < 13) { a1c = 1152 + (m - 9) * 128;  xc = 640 + (m - 9) * 128; }
        else if (m < 16) { a1c = 1664 + (m - 13) * 128; xc = 1152 + (m - 13) * 128; }
        else             { a1c = 2048 + (m - 16) * 128; xc = 1152 + (m - 16) * 128; }
        float sc = bf2f(xe[xbase + xc + c]);
        A1[ebase + a1c + c] = f2bf(r * sc);
    }
}

// ---------------- attention logits + segment max ----------------
__global__ __launch_bounds__(256) void k_logits(const u16* __restrict__ Y0, const int* __restrict__ rcv,
                                                const float* __restrict__ g, const float* __restrict__ b,
                                                const float* __restrict__ adot,
                                                float* __restrict__ logits, u32* __restrict__ nmax) {
    int e = blockIdx.x;
    int tid = threadIdx.x;
    int h = tid >> 5, c = tid & 31;
    float x = bf2f(Y0[(size_t)e * 640 + 320 + h * 32 + c]);
    float s = x, s2 = x * x;
#pragma unroll
    for (int o = 16; o; o >>= 1) { s += __shfl_xor(s, o); s2 += __shfl_xor(s2, o); }
    float mu = s * (1.f / 32.f);
    float var = s2 * (1.f / 32.f) - mu * mu;
    float rs = rsqrtf(var + 1e-5f);
    float a = (x - mu) * rs * g[c] + b[c];
    float f = 0.6f * a + 0.4f * a * (2.f * sigmoidf_(a) - 1.f);
    float l = f * adot[h * 32 + c];
#pragma unroll
    for (int o = 16; o; o >>= 1) l += __shfl_xor(l, o);
    if (c == 0) {
        logits[e * 8 + h] = l;
        atomicMax(&nmax[rcv[e] * 8 + h], encf(l));
    }
}

__global__ void k_expsum(const float* __restrict__ logits, const int* __restrict__ rcv,
                         const u32* __restrict__ nmax, float* __restrict__ ealpha, float* __restrict__ nsum) {
    int idx = blockIdx.x * 256 + threadIdx.x;
    if (idx >= E_EDGES * 8) return;
    int e = idx >> 3, h = idx & 7;
    int r = rcv[e];
    float amax = decf(nmax[r * 8 + h]);
    if (!(amax > -1e38f && amax < 1e38f)) amax = 0.f;
    float v = __expf(logits[idx] - amax);
    ealpha[idx] = v;
    atomicAdd(&nsum[r * 8 + h], v);
}

// ---------------- grid round-trip via MFMA ----------------
// LDS: Xs aliased into T1s (Xs fully consumed into registers before T1s written).
// 45KB->35KB => 3 -> 4 blocks/CU.
#define GR_XS_STR 40
#define GR_T1_STR 136
__global__ __launch_bounds__(256) void k_grid_mfma(
    const u16* __restrict__ Y0, const u16* __restrict__ Y1, const u16* __restrict__ Y2,
    const u16* __restrict__ tgP, const u16* __restrict__ fgP, u16* __restrict__ A2) {
    __shared__ u16 T1s[128 * GR_T1_STR];
    u16* Xs = T1s;                       // alias: see barrier discipline below
    int tid = threadIdx.x;
    int e0 = blockIdx.x * 2;
    // stage Xs[ec][m]: thread owns (le, c0-block, m-pair); packed u32 writes
    {
        int mp = tid & 15;                  // m-pair 0..15 -> m = 2mp, 2mp+1
        int c0 = ((tid >> 4) & 7) << 3;     // channel block 0..56
        int le = tid >> 7;                  // local edge 0/1
        int e = e0 + le;
        int m0 = 2 * mp, m1 = m0 + 1;
        uint4 va = {0, 0, 0, 0}, vb = {0, 0, 0, 0};
        if (m0 < 5)       va = *(const uint4*)(&Y0[(size_t)e * 640 + m0 * 64 + c0]);
        else if (m0 < 13) va = *(const uint4*)(&Y1[(size_t)e * 512 + (m0 - 5) * 64 + c0]);
        else if (m0 < 19) va = *(const uint4*)(&Y2[(size_t)e * 384 + (m0 - 13) * 64 + c0]);
        if (m1 < 5)       vb = *(const uint4*)(&Y0[(size_t)e * 640 + m1 * 64 + c0]);
        else if (m1 < 13) vb = *(const uint4*)(&Y1[(size_t)e * 512 + (m1 - 5) * 64 + c0]);
        else if (m1 < 19) vb = *(const uint4*)(&Y2[(size_t)e * 384 + (m1 - 13) * 64 + c0]);
        const u16* pa = (const u16*)&va;
        const u16* pb = (const u16*)&vb;
        int rbase = le * 64 + c0;
#pragma unroll
        for (int j = 0; j < 8; j++) {
            u32 w = (u32)pa[j] | ((u32)pb[j] << 16);
            *(u32*)(&Xs[(rbase + j) * GR_XS_STR + 2 * mp]) = w;
        }
    }
    __syncthreads();
    int wave = tid >> 6, lane = tid & 63;
    int wn = wave << 5;                     // this wave's 32 ec-columns
    int ln = lane & 15, q = lane >> 4;
    // GEMM1 (swapped): A = tgP (p x m), B^T = Xs (ec x m). Out rows = p, cols = ec.
    short8 bx0 = *(const short8*)(&Xs[(wn + ln) * GR_XS_STR + q * 8]);
    short8 bx1 = *(const short8*)(&Xs[(wn + 16 + ln) * GR_XS_STR + q * 8]);
    floatx4 acc1[2][7];
#pragma unroll
    for (int pt = 0; pt < 7; pt++) {
        short8 a = *(const short8*)(&tgP[(size_t)(pt * 16 + ln) * 32 + q * 8]);
        acc1[0][pt] = __builtin_amdgcn_mfma_f32_16x16x32_bf16(a, bx0, floatx4{0.f, 0.f, 0.f, 0.f}, 0, 0, 0);
        acc1[1][pt] = __builtin_amdgcn_mfma_f32_16x16x32_bf16(a, bx1, floatx4{0.f, 0.f, 0.f, 0.f}, 0, 0, 0);
    }
    __syncthreads();    // all Xs reads complete -> safe to overwrite (alias)
    // zero T1s pad cols 112..127 (cols 100..111 are exact zeros from the zeroed tgP rows)
    {
        int row = tid >> 1;
        uint4 z = {0, 0, 0, 0};
        *(uint4*)(&T1s[row * GR_T1_STR + 112 + (tid & 1) * 8]) = z;
    }
    // silu -> T1s[ec][p]: lane holds p = pt*16 + q*4 + r at ec = wn + i*16 + ln -> b64 writes
#pragma unroll
    for (int i = 0; i < 2; i++) {
        u16* dst = &T1s[(wn + i * 16 + ln) * GR_T1_STR + q * 4];
#pragma unroll
        for (int pt = 0; pt < 7; pt++) {
            uint2 pv;
            pv.x = pk_bf16(siluf_(acc1[i][pt][0]), siluf_(acc1[i][pt][1]));
            pv.y = pk_bf16(siluf_(acc1[i][pt][2]), siluf_(acc1[i][pt][3]));
            *(uint2*)(dst + pt * 16) = pv;
        }
    }
    __syncthreads();
    // GEMM2: K=128 (4 steps)
    floatx4 acc2[2][2];
    acc2[0][0] = floatx4{0.f, 0.f, 0.f, 0.f}; acc2[0][1] = floatx4{0.f, 0.f, 0.f, 0.f};
    acc2[1][0] = floatx4{0.f, 0.f, 0.f, 0.f}; acc2[1][1] = floatx4{0.f, 0.f, 0.f, 0.f};
#pragma unroll
    for (int ks = 0; ks < 4; ks++) {
        short8 c0 = *(const short8*)(&T1s[(wn + ln) * GR_T1_STR + ks * 32 + q * 8]);
        short8 c1 = *(const short8*)(&T1s[(wn + 16 + ln) * GR_T1_STR + ks * 32 + q * 8]);
#pragma unroll
        for (int ct = 0; ct < 2; ct++) {
            short8 b = *(const short8*)(&fgP[(size_t)(ct * 16 + ln) * 128 + ks * 32 + q * 8]);
            acc2[0][ct] = __builtin_amdgcn_mfma_f32_16x16x32_bf16(c0, b, acc2[0][ct], 0, 0, 0);
            acc2[1][ct] = __builtin_amdgcn_mfma_f32_16x16x32_bf16(c1, b, acc2[1][ct], 0, 0, 0);
        }
    }
    // direct store: lane holds col m'=ct*16+ln, rows q*4+r -> 4 consecutive c in A2
#pragma unroll
    for (int rt = 0; rt < 2; rt++) {
        int row = wn + rt * 16 + q * 4;
        int e = e0 + (row >> 6), c = row & 63;
#pragma unroll
        for (int ct = 0; ct < 2; ct++) {
            int mp = ct * 16 + ln;
            if (mp >= 1 && mp < 19) {
                uint2 pv;
                pv.x = pk_bf16(acc2[rt][ct][0], acc2[rt][ct][1]);
                pv.y = pk_bf16(acc2[rt][ct][2], acc2[rt][ct][3]);
                *(uint2*)(&A2[(size_t)e * 1216 + mp * 64 + c]) = pv;
            }
        }
    }
    // m=0 gate row
    if (tid < 128) {
        int e = e0 + (tid >> 6), c = tid & 63;
        float gate = bf2f(Y0[(size_t)e * 640 + 576 + c]);
        A2[(size_t)e * 1216 + c] = f2bf(siluf_(gate));
    }
}

// ---------------- gather: attention scale + wigner^T + segment-sum (no atomics) ----------------
// one 128-thread block (2 waves) per node. Wigner rows for a tile of edges are staged
// cooperatively into LDS (padded stride 28 -> aligned float4 reads, 7 LDS ops/row).
// The two waves split the tile's edges; each wave covers all 128 channels (lane, lane+64).
// Partial acc merged through LDS at the end. Two passes over the Z chunks.
#define GT_TS 6
__global__ __launch_bounds__(128) void k_gather(
    const u16* __restrict__ Z0, const u16* __restrict__ Z1, const u16* __restrict__ Z2,
    const float* __restrict__ wig, const float* __restrict__ ealpha, const float* __restrict__ nsum,
    const u32* __restrict__ rowstart, const u32* __restrict__ deg, const int* __restrict__ elist,
    float* __restrict__ node, int e0, int accum) {
    __shared__ float wls[GT_TS * 536];     // [t][m*28+k], k>=25 zero; also merge arena (3216 >= 3200)
    __shared__ int es[GT_TS];
    __shared__ int didAny;
    int n = blockIdx.x;
    int tid = threadIdx.x;
    int wv = tid >> 6, lane = tid & 63;
    int h0 = lane >> 4, h1 = 4 + (lane >> 4);
    float sden0 = __fdividef(1.f, nsum[n * 8 + h0] + 1e-16f);
    float sden1 = __fdividef(1.f, nsum[n * 8 + h1] + 1e-16f);
    float acc0[25], acc1[25];
#pragma unroll
    for (int k = 0; k < 25; k++) { acc0[k] = 0.f; acc1[k] = 0.f; }
    if (tid == 0) didAny = 0;
    u32 lo = rowstart[n], cnt = deg[n];
    for (u32 base = 0; base < cnt; base += GT_TS) {
        int nt = (int)((cnt - base) < GT_TS ? (cnt - base) : GT_TS);
        __syncthreads();                    // protect wls/es reuse across tiles
        if (tid < nt) es[tid] = elist[lo + base + tid];
        __syncthreads();
        for (int t = 0; t < nt; t++) {
            int e = es[t];
            const float* we = wig + (size_t)e * 475;
            for (int i = tid; i < 532; i += 128) {
                int m = i / 28, k = i - m * 28;
                wls[t * 536 + i] = (k < 25) ? we[m * 25 + k] : 0.f;
            }
        }
        __syncthreads();
        for (int t = wv; t < nt; t += 2) {
            int e = es[t];
            int el = e - e0;
            if ((u32)el >= (u32)EC) continue;   // other chunk's pass handles it
            if (lane == 0) didAny = 1;
            float al0 = ealpha[e * 8 + h0] * sden0;
            float al1 = ealpha[e * 8 + h1] * sden1;
            float s0[19], s1[19];
#pragma unroll
            for (int m = 0; m < 19; m++) {
                const u16* zp; int off;
                if (m < 5)       { zp = Z0; off = el * 640 + m * 128; }
                else if (m < 13) { zp = Z1; off = el * 1024 + (m - 5) * 128; }
                else             { zp = Z2; off = el * 768 + (m - 13) * 128; }
                s0[m] = bf2f(zp[(size_t)off + lane]) * al0;
                s1[m] = bf2f(zp[(size_t)off + 64 + lane]) * al1;
            }
            const float* wt = &wls[t * 536];
#pragma unroll
            for (int m = 0; m < 19; m++) {
#pragma unroll
                for (int j = 0; j < 6; j++) {
                    float4 w4 = *(const float4*)(&wt[m * 28 + j * 4]);
                    acc0[j * 4 + 0] = fmaf(w4.x, s0[m], acc0[j * 4 + 0]);
                    acc0[j * 4 + 1] = fmaf(w4.y, s0[m], acc0[j * 4 + 1]);
                    acc0[j * 4 + 2] = fmaf(w4.z, s0[m], acc0[j * 4 + 2]);
                    acc0[j * 4 + 3] = fmaf(w4.w, s0[m], acc0[j * 4 + 3]);
                    acc1[j * 4 + 0] = fmaf(w4.x, s1[m], acc1[j * 4 + 0]);
                    acc1[j * 4 + 1] = fmaf(w4.y, s1[m], acc1[j * 4 + 1]);
                    acc1[j * 4 + 2] = fmaf(w4.z, s1[m], acc1[j * 4 + 2]);
                    acc1[j * 4 + 3] = fmaf(w4.w, s1[m], acc1[j * 4 + 3]);
                }
                float wl_ = wt[m * 28 + 24];
                acc0[24] = fmaf(wl_, s0[m], acc0[24]);
                acc1[24] = fmaf(wl_, s1[m], acc1[24]);
            }
        }
    }
    __syncthreads();
    int any = didAny;                       // block-uniform
    if (accum && !any) return;              // nothing from this chunk -> keep pass-0 values
    // merge: wave1 -> LDS, wave0 adds & writes node
    float* arr = wls;
    if (wv == 1) {
#pragma unroll
        for (int k = 0; k < 25; k++) {
            arr[k * 128 + lane] = acc0[k];
            arr[k * 128 + 64 + lane] = acc1[k];
        }
    }
    __syncthreads();
    if (wv == 0) {
        float* nb = node + (size_t)n * 3200;
        if (accum) {
#pragma unroll
            for (int k = 0; k < 25; k++) {
                nb[k * 128 + lane]      += acc0[k] + arr[k * 128 + lane];
                nb[k * 128 + 64 + lane] += acc1[k] + arr[k * 128 + 64 + lane];
            }
        } else {
#pragma unroll
            for (int k = 0; k < 25; k++) {
                nb[k * 128 + lane]      = acc0[k] + arr[k * 128 + lane];
                nb[k * 128 + 64 + lane] = acc1[k] + arr[k * 128 + 64 + lane];
            }
        }
    }
}

// ---------------- final projection via MFMA ----------------
// grid (32 n-tiles, 25 k). Block: M=128 n-rows, N=64 d, K=128 c.
// A = node (f32, stride 3200) -> bf16 LDS; B = pwTb[l] (64x128 bf16).
#define PJ_STR 136
__global__ __launch_bounds__(256) void k_proj_mfma(
    const float* __restrict__ node, const u16* __restrict__ pwTb,
    const float* __restrict__ pb, float* __restrict__ out) {
    __shared__ u16 As[128 * PJ_STR];
    __shared__ u16 Bs[64 * PJ_STR];
    int tid = threadIdx.x;
    int n0 = blockIdx.x * 128;
    int k = blockIdx.y;
    int l = (int)sqrtf((float)k + 0.5f);
    // stage A: 128 rows x 128 c f32 -> bf16; thread i handles row=i>>5, c0=(i&31)*4
#pragma unroll
    for (int it = 0; it < 16; it++) {
        int i = tid + it * 256;
        int row = i >> 5;
        int c0 = (i & 31) << 2;
        float4 v = *(const float4*)(&node[(size_t)(n0 + row) * 3200 + k * 128 + c0]);
        uint2 pv;
        pv.x = pk_bf16(v.x, v.y);
        pv.y = pk_bf16(v.z, v.w);
        *(uint2*)(&As[row * PJ_STR + c0]) = pv;
    }
    // stage B: 64 rows (d) x 128 c bf16, 16B chunks
    const u16* pw = pwTb + (size_t)l * 8192;
#pragma unroll
    for (int jt = 0; jt < 4; jt++) {
        int j = tid + jt * 256;
        int d = j >> 4;
        int c0 = (j & 15) << 3;
        *(uint4*)(&Bs[d * PJ_STR + c0]) = *(const uint4*)(&pw[d * 128 + c0]);
    }
    __syncthreads();
    int wave = tid >> 6, lane = tid & 63;
    int wr = wave * 32;
    int ln = lane & 15, q = lane >> 4;
    floatx4 acc[2][4];
#pragma unroll
    for (int i = 0; i < 2; i++)
#pragma unroll
        for (int j = 0; j < 4; j++) acc[i][j] = floatx4{0.f, 0.f, 0.f, 0.f};
#pragma unroll
    for (int ks = 0; ks < 4; ks++) {
        short8 a0 = *(const short8*)(&As[(wr + ln) * PJ_STR + ks * 32 + q * 8]);
        short8 a1 = *(const short8*)(&As[(wr + 16 + ln) * PJ_STR + ks * 32 + q * 8]);
#pragma unroll
        for (int j = 0; j < 4; j++) {
            short8 b = *(const short8*)(&Bs[(j * 16 + ln) * PJ_STR + ks * 32 + q * 8]);
            acc[0][j] = __builtin_amdgcn_mfma_f32_16x16x32_bf16(a0, b, acc[0][j], 0, 0, 0);
            acc[1][j] = __builtin_amdgcn_mfma_f32_16x16x32_bf16(a1, b, acc[1][j], 0, 0, 0);
        }
    }
    // epilogue: row=wr+rt*16+q*4+r -> n; col d=j*16+ln; +pb at k==0
#pragma unroll
    for (int rt = 0; rt < 2; rt++)
#pragma unroll
        for (int j = 0; j < 4; j++) {
            int d = j * 16 + ln;
            float bv = (k == 0) ? pb[d] : 0.f;
#pragma unroll
            for (int r = 0; r < 4; r++) {
                int n = n0 + wr + rt * 16 + q * 4 + r;
                out[(size_t)n * 1600 + k * 64 + d] = acc[rt][j][r] + bv;
            }
        }
}

extern "C" void kernel_launch(void* const* d_in, const int* in_sizes, int n_in,
                              void* d_out, int out_size, void* d_ws, size_t ws_size,
                              hipStream_t stream) {
    const float* nf      = (const float*)d_in[0];
    const int* species   = (const int*)d_in[1];
    const float* dist    = (const float*)d_in[2];
    const int* snd       = (const int*)d_in[3];
    const int* rcv       = (const int*)d_in[4];
    const float* wig     = (const float*)d_in[5];
    const float* semb    = (const float*)d_in[6];
    const float* remb    = (const float*)d_in[7];
    const float* rad_w1  = (const float*)d_in[8];
    const float* rad_b1  = (const float*)d_in[9];
    const float* rad_g1  = (const float*)d_in[10];
    const float* rad_be1 = (const float*)d_in[11];
    const float* rad_w2  = (const float*)d_in[12];
    const float* rad_b2  = (const float*)d_in[13];
    const float* rad_g2  = (const float*)d_in[14];
    const float* rad_be2 = (const float*)d_in[15];
    const float* rad_w3  = (const float*)d_in[16];
    const float* rad_b3  = (const float*)d_in[17];
    const float* c1_w0   = (const float*)d_in[18];
    const float* c1_b0   = (const float*)d_in[19];
    const float* c1_wm1  = (const float*)d_in[20];
    const float* c1_wm2  = (const float*)d_in[21];
    const float* aln_g   = (const float*)d_in[22];
    const float* aln_b   = (const float*)d_in[23];
    const float* adot    = (const float*)d_in[24];
    const float* to_grid = (const float*)d_in[25];
    const float* from_grid=(const float*)d_in[26];
    const float* c2_w0   = (const float*)d_in[27];
    const float* c2_b0   = (const float*)d_in[28];
    const float* c2_wm1  = (const float*)d_in[29];
    const float* c2_wm2  = (const float*)d_in[30];
    const float* proj_w  = (const float*)d_in[31];
    const float* proj_b  = (const float*)d_in[32];

    char* ws = (char*)d_ws;
    size_t off = 0;
    auto take = [&](size_t bytes) -> char* {
        char* p = ws + off;
        off += (bytes + 255) & ~(size_t)255;
        return p;
    };
    // fixed section
    u16* w_rad1T  = (u16*)take(64 * 192 * 2);
    u16* w_rad2T  = (u16*)take(64 * 64 * 2);
    u16* w_rad3T  = (u16*)take(1536 * 64 * 2);
    u16* w_c1w0T  = (u16*)take(640 * 640 * 2);
    u16* w_c1m1T  = (u16*)take((size_t)512 * 1024 * 2);
    u16* w_c1m2T  = (u16*)take((size_t)384 * 768 * 2);
    u16* w_c2w0T  = (u16*)take((size_t)640 * 320 * 2);
    u16* w_c2m1T  = (u16*)take((size_t)1024 * 512 * 2);
    u16* w_c2m2T  = (u16*)take((size_t)768 * 384 * 2);
    u16* w_tgP    = (u16*)take(112 * 32 * 2);
    u16* w_fgP    = (u16*)take(32 * 128 * 2);
    u16* w_pwT    = (u16*)take(5 * 8192 * 2);
    float* logits = (float*)take((size_t)E_EDGES * 8 * 4);
    float* ealpha = (float*)take((size_t)E_EDGES * 8 * 4);
    u32* nmax     = (u32*)take((size_t)N_NODES_C * 8 * 4);
    float* nsum   = (float*)take((size_t)N_NODES_C * 8 * 4);
    float* node   = (float*)take((size_t)N_NODES_C * 3200 * 4);
    u16* a_h2     = (u16*)take((size_t)E_EDGES * 64 * 2);
    u32* c_deg    = (u32*)take((size_t)N_NODES_C * 4);
    u32* c_row    = (u32*)take((size_t)N_NODES_C * 4);
    u32* c_cur    = (u32*)take((size_t)N_NODES_C * 4);
    int* c_elist  = (int*)take((size_t)E_EDGES * 4);
    // arena — aliased by phase
    char* arena   = take(173015040);
    if (off > ws_size) {  // diagnostic: paint output so the failure mode is identifiable
        k_diag<<<(out_size + 255) / 256, 256, 0, stream>>>((float*)d_out, out_size);
        return;
    }

    u16* a_ee   = (u16*)(arena + 0);           // radial phase
    u16* a_ypre = (u16*)(arena + 9437184);
    u16* a_h1   = (u16*)(arena + 12582912);
    u16* a_xe   = (u16*)(arena + 0);           // per-chunk (EC,1536); radial staging dead
    u16* a_A1   = (u16*)(arena + 37748736);    // per-chunk (EC,2432)
    u16* a_Y0   = (u16*)(arena + 97517568);    // full (E,640)
    u16* a_Y1   = (u16*)(arena + 128974848);   // full (E,512)
    u16* a_Y2   = (u16*)(arena + 154140672);   // full (E,384) -> arena end
    u16* a_A2   = (u16*)(arena + 0);           // full (E,1216); xe/A1 dead
    u16* a_Z0   = (u16*)(arena + 59768832);    // per-chunk (EC,640)
    u16* a_Z1   = (u16*)(arena + 75497472);    // per-chunk (EC,1024)
    u16* a_Z2   = (u16*)(arena + 100663296);   // per-chunk (EC,768); overlaps dead Y0 region

    // ---- weight prep ----
    k_transpose<<<48, 256, 0, stream>>>(rad_w1, w_rad1T, 192, 64);
    k_transpose<<<16, 256, 0, stream>>>(rad_w2, w_rad2T, 64, 64);
    k_transpose<<<384, 256, 0, stream>>>(rad_w3, w_rad3T, 64, 1536);
    k_transpose<<<1600, 256, 0, stream>>>(c1_w0, w_c1w0T, 640, 640);
    k_transpose<<<800, 256, 0, stream>>>(c2_w0, w_c2w0T, 320, 640);
    k_combine<<<2048, 256, 0, stream>>>(c1_wm1, w_c1m1T, 512, 256);
    k_combine<<<1152, 256, 0, stream>>>(c1_wm2, w_c1m2T, 384, 192);
    k_combine<<<2048, 256, 0, stream>>>(c2_wm1, w_c2m1T, 256, 512);
    k_combine<<<1152, 256, 0, stream>>>(c2_wm2, w_c2m2T, 192, 384);
    k_packgrid<<<30, 256, 0, stream>>>(to_grid, from_grid, w_tgP, w_fgP);
    for (int l = 0; l < 5; l++)
        k_transpose<<<32, 256, 0, stream>>>(proj_w + (size_t)l * 8192, w_pwT + (size_t)l * 8192, 128, 64);
    k_init<<<128, 256, 0, stream>>>(nmax, nsum, N_NODES_C * 8);

    // ---- CSR build (receivers static per launch) ----
    hipMemsetAsync(c_deg, 0, (size_t)N_NODES_C * 4, stream);
    k_deg<<<96, 256, 0, stream>>>(rcv, c_deg);
    k_pfx<<<1, 256, 0, stream>>>(c_deg, c_row, c_cur);
    k_fill<<<96, 256, 0, stream>>>(rcv, c_cur, c_elist);

    // ---- radial MLP (full E) ----
    k_ee<<<(E_EDGES * 192 + 255) / 256, 256, 0, stream>>>(dist, species, snd, rcv, semb, remb, a_ee);
    k_gemm<<<dim3(192, 1), 256, 0, stream>>>(a_ee, 192, w_rad1T, 192, a_ypre, 64, 64, 192, rad_b1);
    k_ln_silu<<<6144, 256, 0, stream>>>(a_ypre, a_h1, rad_g1, rad_be1);
    k_gemm<<<dim3(192, 1), 256, 0, stream>>>(a_h1, 64, w_rad2T, 64, a_ypre, 64, 64, 64, rad_b2);
    k_ln_silu<<<6144, 256, 0, stream>>>(a_ypre, a_h2, rad_g2, rad_be2);

    // ---- chunked: x_edge gemm -> rotate -> conv1 ----
    for (int c = 0; c < 2; c++) {
        int e0 = c * EC;
        k_gemm<<<dim3(96, 12), 256, 0, stream>>>(a_h2 + (size_t)e0 * 64, 64, w_rad3T, 64,
                                                 a_xe, 1536, 1536, 64, rad_b3);
        k_rotate<<<EC / 2, 256, 0, stream>>>(nf, wig, snd, rcv, a_xe, a_A1, e0);
        k_gemm<<<dim3(96, 5), 256, 0, stream>>>(a_A1, 2432, w_c1w0T, 640,
                                                a_Y0 + (size_t)e0 * 640, 640, 640, 640, c1_b0);
        k_gemm<<<dim3(96, 4), 256, 0, stream>>>(a_A1 + 640, 2432, w_c1m1T, 1024,
                                                a_Y1 + (size_t)e0 * 512, 512, 512, 1024, nullptr);
        k_gemm<<<dim3(96, 3), 256, 0, stream>>>(a_A1 + 1664, 2432, w_c1m2T, 768,
                                                a_Y2 + (size_t)e0 * 384, 384, 384, 768, nullptr);
    }

    // ---- attention softmax pieces ----
    k_logits<<<E_EDGES, 256, 0, stream>>>(a_Y0, rcv, aln_g, aln_b, adot, logits, nmax);
    k_expsum<<<(E_EDGES * 8 + 255) / 256, 256, 0, stream>>>(logits, rcv, nmax, ealpha, nsum);

    // ---- grid nonlinearity -> packed A2 (full E, MFMA) ----
    k_grid_mfma<<<E_EDGES / 2, 256, 0, stream>>>(a_Y0, a_Y1, a_Y2, w_tgP, w_fgP, a_A2);

    // ---- chunked: conv2 -> gather (CSR, LDS-staged wigner, no atomics) ----
    for (int c = 0; c < 2; c++) {
        int e0 = c * EC;
        k_gemm<<<dim3(96, 5), 256, 0, stream>>>(a_A2 + (size_t)e0 * 1216, 1216, w_c2w0T, 320,
                                                a_Z0, 640, 640, 320, c2_b0);
        k_gemm<<<dim3(96, 8), 256, 0, stream>>>(a_A2 + (size_t)e0 * 1216 + 320, 1216, w_c2m1T, 512,
                                                a_Z1, 1024, 1024, 512, nullptr);
        k_gemm<<<dim3(96, 6), 256, 0, stream>>>(a_A2 + (size_t)e0 * 1216 + 832, 1216, w_c2m2T, 384,
                                                a_Z2, 768, 768, 384, nullptr);
        k_gather<<<N_NODES_C, 128, 0, stream>>>(a_Z0, a_Z1, a_Z2, wig, ealpha, nsum,
                                                c_row, c_deg, c_elist, node, e0, c);
    }

    // ---- output projection (MFMA) ----
    k_proj_mfma<<<dim3(32, 25), 256, 0, stream>>>(node, w_pwT, proj_b, (float*)d_out);
}

// Round 4
// 1038.063 us; speedup vs baseline: 1.0564x; 1.0564x over previous
//
#include <hip/hip_runtime.h>

typedef unsigned short u16;
typedef unsigned int u32;
typedef __attribute__((ext_vector_type(8))) short short8;
typedef __attribute__((ext_vector_type(4))) float floatx4;

#define E_EDGES 24576
#define EC 12288            // edge chunk
#define N_NODES_C 4096

__device__ __forceinline__ float bf2f(u16 u) {
    union { u32 i; float f; } v; v.i = ((u32)u) << 16; return v.f;
}
__device__ __forceinline__ u16 f2bf(float f) {
    union { float f; u32 i; } v; v.f = f;
    u32 x = v.i;
    u32 r = (x + 0x7fffu + ((x >> 16) & 1u)) >> 16;
    return (u16)r;
}
// packed f32x2 -> bf16x2 in one VALU inst (RNE), no builtin on gfx950 -> inline asm
__device__ __forceinline__ u32 pk_bf16(float a, float b) {
    u32 r;
    asm("v_cvt_pk_bf16_f32 %0, %1, %2" : "=v"(r) : "v"(a), "v"(b));
    return r;
}
__device__ __forceinline__ u32 encf(float f) {
    union { float f; u32 i; } v; v.f = f;
    return (v.i & 0x80000000u) ? ~v.i : (v.i | 0x80000000u);
}
__device__ __forceinline__ float decf(u32 u) {
    union { u32 i; float f; } v;
    v.i = (u & 0x80000000u) ? (u ^ 0x80000000u) : ~u;
    return v.f;
}
// fast transcendentals: v_exp_f32 + v_rcp_f32
__device__ __forceinline__ float sigmoidf_(float x) { return __fdividef(1.f, 1.f + __expf(-x)); }
__device__ __forceinline__ float siluf_(float x) { return x * __fdividef(1.f, 1.f + __expf(-x)); }

// async global->LDS, 16B per lane; LDS dest must be wave-uniform base + lane*16
__device__ __forceinline__ void gld16(const u16* g, u16* l) {
    __builtin_amdgcn_global_load_lds((const __attribute__((address_space(1))) unsigned int*)g,
                                     (__attribute__((address_space(3))) unsigned int*)l, 16, 0, 0);
}

// diagnostic: ws too small -> paint output with 1000 (f32)
__global__ void k_diag(float* __restrict__ out, int n) {
    int i = blockIdx.x * 256 + threadIdx.x;
    if (i < n) out[i] = 1000.0f;
}

// ---------------- weight prep (f32 src -> bf16 transposed) ----------------
__global__ void k_transpose(const float* __restrict__ src, u16* __restrict__ dst, int K, int N) {
    int idx = blockIdx.x * 256 + threadIdx.x;
    if (idx >= K * N) return;
    int k = idx / N, n = idx % N;
    dst[n * K + k] = f2bf(src[idx]);
}
// combined complex weight, pre-transposed. src (K, 2H) f32: wa=cols[0:H), wb=cols[H:2H).
// dst (2H, 2K) bf16: dst[n][k] = k<K ? src[k][n] : (n<H ? -src[k-K][H+n] : src[k-K][n-H])
__global__ void k_combine(const float* __restrict__ src, u16* __restrict__ dst, int K, int H) {
    int total = 4 * K * H;
    int idx = blockIdx.x * 256 + threadIdx.x;
    if (idx >= total) return;
    int n = idx / (2 * K), k = idx % (2 * K);
    float v;
    if (k < K) v = src[k * 2 * H + n];
    else {
        int kk = k - K;
        if (n < H) v = -src[kk * 2 * H + H + n];
        else       v = src[kk * 2 * H + (n - H)];
    }
    dst[idx] = f2bf(v);
}

// pack to_grid (100,19) -> tgP[112][32] bf16; pack from_grid (19,100) -> fgP[32][128] bf16
__global__ void k_packgrid(const float* __restrict__ tg, const float* __restrict__ fg,
                           u16* __restrict__ tgP, u16* __restrict__ fgP) {
    int idx = blockIdx.x * 256 + threadIdx.x;
    if (idx < 112 * 32) {
        int p = idx >> 5, m = idx & 31;
        tgP[idx] = (p < 100 && m < 19) ? f2bf(tg[p * 19 + m]) : (u16)0;
    }
    int j = idx - 112 * 32;
    if (j >= 0 && j < 32 * 128) {
        int m = j >> 7, k = j & 127;
        fgP[j] = (m < 19 && k < 100) ? f2bf(fg[m * 100 + k]) : (u16)0;
    }
}

__global__ void k_init(u32* __restrict__ nmax, float* __restrict__ nsum, int n) {
    int idx = blockIdx.x * 256 + threadIdx.x;
    if (idx < n) { nmax[idx] = 0x007FFFFFu; /* enc(-inf) */ nsum[idx] = 0.f; }
}

// ---------------- CSR build over receivers (static per launch) ----------------
__global__ void k_deg(const int* __restrict__ rcv, u32* __restrict__ deg) {
    int e = blockIdx.x * 256 + threadIdx.x;
    if (e < E_EDGES) atomicAdd(&deg[rcv[e]], 1u);
}
__global__ __launch_bounds__(256) void k_pfx(const u32* __restrict__ deg,
                                             u32* __restrict__ rowstart, u32* __restrict__ cur) {
    __shared__ u32 ps[256];
    int t = threadIdx.x;
    u32 loc[16]; u32 s = 0;
#pragma unroll
    for (int i = 0; i < 16; i++) { loc[i] = s; s += deg[t * 16 + i]; }
    ps[t] = s;
    __syncthreads();
    for (int o = 1; o < 256; o <<= 1) {
        u32 v = (t >= o) ? ps[t - o] : 0u;
        __syncthreads();
        ps[t] += v;
        __syncthreads();
    }
    u32 base = (t == 0) ? 0u : ps[t - 1];
#pragma unroll
    for (int i = 0; i < 16; i++) { u32 v = base + loc[i]; rowstart[t * 16 + i] = v; cur[t * 16 + i] = v; }
}
__global__ void k_fill(const int* __restrict__ rcv, u32* __restrict__ cur, int* __restrict__ elist) {
    int e = blockIdx.x * 256 + threadIdx.x;
    if (e < E_EDGES) { u32 p = atomicAdd(&cur[rcv[e]], 1u); elist[p] = e; }
}

// ---------------- edge embeddings (f32 in -> bf16 A) ----------------
__global__ void k_ee(const float* __restrict__ dist, const int* __restrict__ species,
                     const int* __restrict__ snd, const int* __restrict__ rcv,
                     const float* __restrict__ semb, const float* __restrict__ remb,
                     u16* __restrict__ ee) {
    int idx = blockIdx.x * 256 + threadIdx.x;
    if (idx >= E_EDGES * 192) return;
    int e = idx / 192, c = idx % 192;
    float v;
    if (c < 64)       v = dist[e * 64 + c];
    else if (c < 128) v = semb[species[snd[e]] * 64 + (c - 64)];
    else              v = remb[species[rcv[e]] * 64 + (c - 128)];
    ee[idx] = f2bf(v);
}

// ---------------- GEMM (m97 structure): A (M,K) bf16 rm, BT (N,K) bf16 rm, C (M,N) bf16 ----------------
// global_load_lds staging, unpadded 64B rows. M%128==0, K%32==0; N guarded.
// Explicit s_waitcnt vmcnt(0) before barrier — async LDS-DMA must drain (round-6 race fix).
__global__ __launch_bounds__(256) void k_gemm(
    const u16* __restrict__ A, int lda,
    const u16* __restrict__ BT, int ldb,
    u16* __restrict__ C, int ldc,
    int N, int K,
    const float* __restrict__ bias) {
    __shared__ u16 As[128 * 32];
    __shared__ u16 Bs[128 * 32];
    int tid = threadIdx.x;
    int bm0 = blockIdx.x * 128;
    int bn0 = blockIdx.y * 128;
    int wave = tid >> 6, lane = tid & 63;
    int wm = (wave >> 1) * 64, wn = (wave & 1) * 64;
    int lrow = lane & 15, lk = (lane >> 4) * 8;

    // staging geometry: wave w covers rows w*16 + (lane>>2), 16B chunk (lane&3)
    int srow = (wave << 4) + (lane >> 2);        // 0..63
    int schunk = (lane & 3) << 3;                // u16 offset 0/8/16/24
    const u16* Arow0 = A + (size_t)(bm0 + srow) * lda + schunk;
    const u16* Arow1 = A + (size_t)(bm0 + srow + 64) * lda + schunk;
    int n0 = bn0 + srow;      if (n0 >= N) n0 = N - 1;
    int n1 = bn0 + srow + 64; if (n1 >= N) n1 = N - 1;
    const u16* Brow0 = BT + (size_t)n0 * ldb + schunk;
    const u16* Brow1 = BT + (size_t)n1 * ldb + schunk;
    u16* lA0 = &As[srow * 32 + schunk];
    u16* lA1 = &As[(srow + 64) * 32 + schunk];
    u16* lB0 = &Bs[srow * 32 + schunk];
    u16* lB1 = &Bs[(srow + 64) * 32 + schunk];

    floatx4 acc[4][4];
#pragma unroll
    for (int i = 0; i < 4; i++)
#pragma unroll
        for (int j = 0; j < 4; j++) acc[i][j] = floatx4{0.f, 0.f, 0.f, 0.f};

    for (int k0 = 0; k0 < K; k0 += 32) {
        gld16(Arow0 + k0, lA0);
        gld16(Arow1 + k0, lA1);
        gld16(Brow0 + k0, lB0);
        gld16(Brow1 + k0, lB1);
        asm volatile("s_waitcnt vmcnt(0)" ::: "memory");
        __syncthreads();
        short8 a[4], b[4];
#pragma unroll
        for (int i = 0; i < 4; i++) a[i] = *(const short8*)(&As[(wm + i * 16 + lrow) * 32 + lk]);
#pragma unroll
        for (int j = 0; j < 4; j++) b[j] = *(const short8*)(&Bs[(wn + j * 16 + lrow) * 32 + lk]);
#pragma unroll
        for (int i = 0; i < 4; i++)
#pragma unroll
            for (int j = 0; j < 4; j++)
                acc[i][j] = __builtin_amdgcn_mfma_f32_16x16x32_bf16(a[i], b[j], acc[i][j], 0, 0, 0);
        __syncthreads();
    }

    int q = lane >> 4;
#pragma unroll
    for (int i = 0; i < 4; i++) {
#pragma unroll
        for (int j = 0; j < 4; j++) {
            int col = bn0 + wn + j * 16 + lrow;
            if (col < N) {
                float bv = bias ? bias[col] : 0.f;
#pragma unroll
                for (int r = 0; r < 4; r++) {
                    int row = bm0 + wm + i * 16 + q * 4 + r;
                    C[(size_t)row * ldc + col] = f2bf(acc[i][j][r] + bv);
                }
            }
        }
    }
}

// ---------------- LayerNorm(64) + SiLU (bf16 io, f32 params) ----------------
__global__ __launch_bounds__(256) void k_ln_silu(const u16* __restrict__ in, u16* __restrict__ out,
                                                 const float* __restrict__ g, const float* __restrict__ b) {
    int tid = threadIdx.x;
    int e = blockIdx.x * 4 + (tid >> 6);
    int c = tid & 63;
    float x = bf2f(in[(size_t)e * 64 + c]);
    float s = x, s2 = x * x;
#pragma unroll
    for (int o = 32; o; o >>= 1) { s += __shfl_xor(s, o); s2 += __shfl_xor(s2, o); }
    float mu = s * (1.f / 64.f);
    float var = s2 * (1.f / 64.f) - mu * mu;
    float rs = rsqrtf(var + 1e-5f);
    float y = (x - mu) * rs * g[c] + b[c];
    out[(size_t)e * 64 + c] = f2bf(siluf_(y));
}

// ---------------- rotate: wigner @ concat(nf[snd],nf[rcv]); scale by x_edge; pack A1 (chunked) ----------------
__global__ __launch_bounds__(256) void k_rotate(const float* __restrict__ nf, const float* __restrict__ wig,
                                                const int* __restrict__ snd, const int* __restrict__ rcv,
                                                const u16* __restrict__ xe, u16* __restrict__ A1, int e0) {
    __shared__ float wl[2][475];
    int tid = threadIdx.x;
    for (int i = tid; i < 950; i += 256) {
        int ee = e0 + blockIdx.x * 2 + (i / 475);
        wl[i / 475][i % 475] = wig[(size_t)ee * 475 + (i % 475)];
    }
    __syncthreads();
    int le = tid >> 7, c = tid & 127;
    int el = blockIdx.x * 2 + le;       // chunk-local
    int e = e0 + el;                    // global
    int nd = (c < 64) ? snd[e] : rcv[e];
    int cc = c & 63;
    float msg[25];
#pragma unroll
    for (int k = 0; k < 25; k++) msg[k] = nf[(size_t)nd * 1600 + k * 64 + cc];
    const float* w = wl[le];
    size_t ebase = (size_t)el * 2432;
    size_t xbase = (size_t)el * 1536;
#pragma unroll
    for (int m = 0; m < 19; m++) {
        float r = 0.f;
#pragma unroll
        for (int k = 0; k < 25; k++) r += w[m * 25 + k] * msg[k];
        int a1c, xc;
        if (m < 5)       { a1c = m * 128;               xc = m * 128; }
        else if (m < 9)  { a1c = 640 + (m - 5) * 128;   xc = 640 + (m - 5) * 128; }
        else if (m < 13) { a1c = 1152 + (m - 9) * 128;  xc = 640 + (m - 9) * 128; }
        else if (m < 16) { a1c = 1664 + (m - 13) * 128; xc = 1152 + (m - 13) * 128; }
        else             { a1c = 2048 + (m - 16) * 128; xc = 1152 + (m - 16) * 128; }
        float sc = bf2f(xe[xbase + xc + c]);
        A1[ebase + a1c + c] = f2bf(r * sc);
    }
}

// ---------------- attention logits + segment max ----------------
__global__ __launch_bounds__(256) void k_logits(const u16* __restrict__ Y0, const int* __restrict__ rcv,
                                                const float* __restrict__ g, const float* __restrict__ b,
                                                const float* __restrict__ adot,
                                                float* __restrict__ logits, u32* __restrict__ nmax) {
    int e = blockIdx.x;
    int tid = threadIdx.x;
    int h = tid >> 5, c = tid & 31;
    float x = bf2f(Y0[(size_t)e * 640 + 320 + h * 32 + c]);
    float s = x, s2 = x * x;
#pragma unroll
    for (int o = 16; o; o >>= 1) { s += __shfl_xor(s, o); s2 += __shfl_xor(s2, o); }
    float mu = s * (1.f / 32.f);
    float var = s2 * (1.f / 32.f) - mu * mu;
    float rs = rsqrtf(var + 1e-5f);
    float a = (x - mu) * rs * g[c] + b[c];
    float f = 0.6f * a + 0.4f * a * (2.f * sigmoidf_(a) - 1.f);
    float l = f * adot[h * 32 + c];
#pragma unroll
    for (int o = 16; o; o >>= 1) l += __shfl_xor(l, o);
    if (c == 0) {
        logits[e * 8 + h] = l;
        atomicMax(&nmax[rcv[e] * 8 + h], encf(l));
    }
}

__global__ void k_expsum(const float* __restrict__ logits, const int* __restrict__ rcv,
                         const u32* __restrict__ nmax, float* __restrict__ ealpha, float* __restrict__ nsum) {
    int idx = blockIdx.x * 256 + threadIdx.x;
    if (idx >= E_EDGES * 8) return;
    int e = idx >> 3, h = idx & 7;
    int r = rcv[e];
    float amax = decf(nmax[r * 8 + h]);
    if (!(amax > -1e38f && amax < 1e38f)) amax = 0.f;
    float v = __expf(logits[idx] - amax);
    ealpha[idx] = v;
    atomicAdd(&nsum[r * 8 + h], v);
}

// ---------------- grid round-trip via MFMA ----------------
// LDS: Xs aliased into T1s (Xs fully consumed into registers before T1s written).
#define GR_XS_STR 40
#define GR_T1_STR 136
__global__ __launch_bounds__(256) void k_grid_mfma(
    const u16* __restrict__ Y0, const u16* __restrict__ Y1, const u16* __restrict__ Y2,
    const u16* __restrict__ tgP, const u16* __restrict__ fgP, u16* __restrict__ A2) {
    __shared__ u16 T1s[128 * GR_T1_STR];
    u16* Xs = T1s;                       // alias: see barrier discipline below
    int tid = threadIdx.x;
    int e0 = blockIdx.x * 2;
    // stage Xs[ec][m]: thread owns (le, c0-block, m-pair); packed u32 writes
    {
        int mp = tid & 15;                  // m-pair 0..15 -> m = 2mp, 2mp+1
        int c0 = ((tid >> 4) & 7) << 3;     // channel block 0..56
        int le = tid >> 7;                  // local edge 0/1
        int e = e0 + le;
        int m0 = 2 * mp, m1 = m0 + 1;
        uint4 va = {0, 0, 0, 0}, vb = {0, 0, 0, 0};
        if (m0 < 5)       va = *(const uint4*)(&Y0[(size_t)e * 640 + m0 * 64 + c0]);
        else if (m0 < 13) va = *(const uint4*)(&Y1[(size_t)e * 512 + (m0 - 5) * 64 + c0]);
        else if (m0 < 19) va = *(const uint4*)(&Y2[(size_t)e * 384 + (m0 - 13) * 64 + c0]);
        if (m1 < 5)       vb = *(const uint4*)(&Y0[(size_t)e * 640 + m1 * 64 + c0]);
        else if (m1 < 13) vb = *(const uint4*)(&Y1[(size_t)e * 512 + (m1 - 5) * 64 + c0]);
        else if (m1 < 19) vb = *(const uint4*)(&Y2[(size_t)e * 384 + (m1 - 13) * 64 + c0]);
        const u16* pa = (const u16*)&va;
        const u16* pb = (const u16*)&vb;
        int rbase = le * 64 + c0;
#pragma unroll
        for (int j = 0; j < 8; j++) {
            u32 w = (u32)pa[j] | ((u32)pb[j] << 16);
            *(u32*)(&Xs[(rbase + j) * GR_XS_STR + 2 * mp]) = w;
        }
    }
    __syncthreads();
    int wave = tid >> 6, lane = tid & 63;
    int wn = wave << 5;                     // this wave's 32 ec-columns
    int ln = lane & 15, q = lane >> 4;
    // GEMM1 (swapped): A = tgP (p x m), B^T = Xs (ec x m). Out rows = p, cols = ec.
    short8 bx0 = *(const short8*)(&Xs[(wn + ln) * GR_XS_STR + q * 8]);
    short8 bx1 = *(const short8*)(&Xs[(wn + 16 + ln) * GR_XS_STR + q * 8]);
    floatx4 acc1[2][7];
#pragma unroll
    for (int pt = 0; pt < 7; pt++) {
        short8 a = *(const short8*)(&tgP[(size_t)(pt * 16 + ln) * 32 + q * 8]);
        acc1[0][pt] = __builtin_amdgcn_mfma_f32_16x16x32_bf16(a, bx0, floatx4{0.f, 0.f, 0.f, 0.f}, 0, 0, 0);
        acc1[1][pt] = __builtin_amdgcn_mfma_f32_16x16x32_bf16(a, bx1, floatx4{0.f, 0.f, 0.f, 0.f}, 0, 0, 0);
    }
    __syncthreads();    // all Xs reads complete -> safe to overwrite (alias)
    // zero T1s pad cols 112..127 (cols 100..111 are exact zeros from the zeroed tgP rows)
    {
        int row = tid >> 1;
        uint4 z = {0, 0, 0, 0};
        *(uint4*)(&T1s[row * GR_T1_STR + 112 + (tid & 1) * 8]) = z;
    }
    // silu -> T1s[ec][p]: lane holds p = pt*16 + q*4 + r at ec = wn + i*16 + ln -> b64 writes
#pragma unroll
    for (int i = 0; i < 2; i++) {
        u16* dst = &T1s[(wn + i * 16 + ln) * GR_T1_STR + q * 4];
#pragma unroll
        for (int pt = 0; pt < 7; pt++) {
            uint2 pv;
            pv.x = pk_bf16(siluf_(acc1[i][pt][0]), siluf_(acc1[i][pt][1]));
            pv.y = pk_bf16(siluf_(acc1[i][pt][2]), siluf_(acc1[i][pt][3]));
            *(uint2*)(dst + pt * 16) = pv;
        }
    }
    __syncthreads();
    // GEMM2: K=128 (4 steps)
    floatx4 acc2[2][2];
    acc2[0][0] = floatx4{0.f, 0.f, 0.f, 0.f}; acc2[0][1] = floatx4{0.f, 0.f, 0.f, 0.f};
    acc2[1][0] = floatx4{0.f, 0.f, 0.f, 0.f}; acc2[1][1] = floatx4{0.f, 0.f, 0.f, 0.f};
#pragma unroll
    for (int ks = 0; ks < 4; ks++) {
        short8 c0 = *(const short8*)(&T1s[(wn + ln) * GR_T1_STR + ks * 32 + q * 8]);
        short8 c1 = *(const short8*)(&T1s[(wn + 16 + ln) * GR_T1_STR + ks * 32 + q * 8]);
#pragma unroll
        for (int ct = 0; ct < 2; ct++) {
            short8 b = *(const short8*)(&fgP[(size_t)(ct * 16 + ln) * 128 + ks * 32 + q * 8]);
            acc2[0][ct] = __builtin_amdgcn_mfma_f32_16x16x32_bf16(c0, b, acc2[0][ct], 0, 0, 0);
            acc2[1][ct] = __builtin_amdgcn_mfma_f32_16x16x32_bf16(c1, b, acc2[1][ct], 0, 0, 0);
        }
    }
    // direct store: lane holds col m'=ct*16+ln, rows q*4+r -> 4 consecutive c in A2
#pragma unroll
    for (int rt = 0; rt < 2; rt++) {
        int row = wn + rt * 16 + q * 4;
        int e = e0 + (row >> 6), c = row & 63;
#pragma unroll
        for (int ct = 0; ct < 2; ct++) {
            int mp = ct * 16 + ln;
            if (mp >= 1 && mp < 19) {
                uint2 pv;
                pv.x = pk_bf16(acc2[rt][ct][0], acc2[rt][ct][1]);
                pv.y = pk_bf16(acc2[rt][ct][2], acc2[rt][ct][3]);
                *(uint2*)(&A2[(size_t)e * 1216 + mp * 64 + c]) = pv;
            }
        }
    }
    // m=0 gate row
    if (tid < 128) {
        int e = e0 + (tid >> 6), c = tid & 63;
        float gate = bf2f(Y0[(size_t)e * 640 + 576 + c]);
        A2[(size_t)e * 1216 + c] = f2bf(siluf_(gate));
    }
}

// ---------------- gather: attention scale + wigner^T + segment-sum (no atomics) ----------------
// one 256-thread block per node: 2 edge-slots x 128 channels (4 waves).
// Per-slot edge forced wave-uniform (readfirstlane) -> wigner reads eligible for the
// scalar-load path; no LDS wigner staging. LDS only for the slot merge (12.8 KB).
// Two passes over the Z chunks: pass0 plain-writes node, pass1 accumulates (guarded).
__global__ __launch_bounds__(256) void k_gather(
    const u16* __restrict__ Z0, const u16* __restrict__ Z1, const u16* __restrict__ Z2,
    const float* __restrict__ wig, const float* __restrict__ ealpha, const float* __restrict__ nsum,
    const u32* __restrict__ rowstart, const u32* __restrict__ deg, const int* __restrict__ elist,
    float* __restrict__ node, int e0, int accum) {
    __shared__ float mbuf[3200];
    __shared__ int es_s[2];
    __shared__ int anyf;
    int n = blockIdx.x;
    int tid = threadIdx.x;
    int slot = tid >> 7;            // waves 0,1 -> slot 0; waves 2,3 -> slot 1
    int c = tid & 127;
    int h = c >> 4;
    if (tid == 0) anyf = 0;
    float sden = __fdividef(1.f, nsum[n * 8 + h] + 1e-16f);
    float acc[25];
#pragma unroll
    for (int k = 0; k < 25; k++) acc[k] = 0.f;
    u32 lo = rowstart[n], cnt = deg[n];
    for (u32 base = 0; base < cnt; base += 2) {
        if (tid < 2) es_s[tid] = (base + tid < cnt) ? elist[lo + base + tid] : -1;
        __syncthreads();
        int e = es_s[slot];
        int el = e - e0;
        if (e >= 0 && (u32)el < (u32)EC) {
            e = __builtin_amdgcn_readfirstlane(e);      // wave-uniform -> scalar path
            el = e - e0;
            if ((tid & 63) == 0) anyf = 1;
            float al = ealpha[e * 8 + h] * sden;
            const float* __restrict__ w = wig + (size_t)e * 475;
            float s[19];
#pragma unroll
            for (int m = 0; m < 19; m++) {
                const u16* zp; int off;
                if (m < 5)       { zp = Z0; off = el * 640 + m * 128; }
                else if (m < 13) { zp = Z1; off = el * 1024 + (m - 5) * 128; }
                else             { zp = Z2; off = el * 768 + (m - 13) * 128; }
                s[m] = bf2f(zp[(size_t)off + c]) * al;
            }
#pragma unroll
            for (int m = 0; m < 19; m++)
#pragma unroll
                for (int k = 0; k < 25; k++)
                    acc[k] = fmaf(w[m * 25 + k], s[m], acc[k]);
        }
        __syncthreads();            // protect es_s rewrite next round
    }
    // merge slot1 -> slot0 via LDS, then store/RMW (this block owns node n exclusively)
    if (slot == 1) {
#pragma unroll
        for (int k = 0; k < 25; k++) mbuf[k * 128 + c] = acc[k];
    }
    __syncthreads();
    if (slot == 0) {
        float* nb = node + (size_t)n * 3200 + c;
        if (accum) {
            if (anyf) {
#pragma unroll
                for (int k = 0; k < 25; k++) nb[k * 128] += acc[k] + mbuf[k * 128 + c];
            }
        } else {
#pragma unroll
            for (int k = 0; k < 25; k++) nb[k * 128] = acc[k] + mbuf[k * 128 + c];
        }
    }
}

// ---------------- final projection via MFMA ----------------
// grid (32 n-tiles, 25 k). Block: M=128 n-rows, N=64 d, K=128 c.
// A = node (f32, stride 3200) -> bf16 LDS; B = pwTb[l] (64x128 bf16).
#define PJ_STR 136
__global__ __launch_bounds__(256) void k_proj_mfma(
    const float* __restrict__ node, const u16* __restrict__ pwTb,
    const float* __restrict__ pb, float* __restrict__ out) {
    __shared__ u16 As[128 * PJ_STR];
    __shared__ u16 Bs[64 * PJ_STR];
    int tid = threadIdx.x;
    int n0 = blockIdx.x * 128;
    int k = blockIdx.y;
    int l = (int)sqrtf((float)k + 0.5f);
    // stage A: 128 rows x 128 c f32 -> bf16; thread i handles row=i>>5, c0=(i&31)*4
#pragma unroll
    for (int it = 0; it < 16; it++) {
        int i = tid + it * 256;
        int row = i >> 5;
        int c0 = (i & 31) << 2;
        float4 v = *(const float4*)(&node[(size_t)(n0 + row) * 3200 + k * 128 + c0]);
        uint2 pv;
        pv.x = pk_bf16(v.x, v.y);
        pv.y = pk_bf16(v.z, v.w);
        *(uint2*)(&As[row * PJ_STR + c0]) = pv;
    }
    // stage B: 64 rows (d) x 128 c bf16, 16B chunks
    const u16* pw = pwTb + (size_t)l * 8192;
#pragma unroll
    for (int jt = 0; jt < 4; jt++) {
        int j = tid + jt * 256;
        int d = j >> 4;
        int c0 = (j & 15) << 3;
        *(uint4*)(&Bs[d * PJ_STR + c0]) = *(const uint4*)(&pw[d * 128 + c0]);
    }
    __syncthreads();
    int wave = tid >> 6, lane = tid & 63;
    int wr = wave * 32;
    int ln = lane & 15, q = lane >> 4;
    floatx4 acc[2][4];
#pragma unroll
    for (int i = 0; i < 2; i++)
#pragma unroll
        for (int j = 0; j < 4; j++) acc[i][j] = floatx4{0.f, 0.f, 0.f, 0.f};
#pragma unroll
    for (int ks = 0; ks < 4; ks++) {
        short8 a0 = *(const short8*)(&As[(wr + ln) * PJ_STR + ks * 32 + q * 8]);
        short8 a1 = *(const short8*)(&As[(wr + 16 + ln) * PJ_STR + ks * 32 + q * 8]);
#pragma unroll
        for (int j = 0; j < 4; j++) {
            short8 b = *(const short8*)(&Bs[(j * 16 + ln) * PJ_STR + ks * 32 + q * 8]);
            acc[0][j] = __builtin_amdgcn_mfma_f32_16x16x32_bf16(a0, b, acc[0][j], 0, 0, 0);
            acc[1][j] = __builtin_amdgcn_mfma_f32_16x16x32_bf16(a1, b, acc[1][j], 0, 0, 0);
        }
    }
    // epilogue: row=wr+rt*16+q*4+r -> n; col d=j*16+ln; +pb at k==0
#pragma unroll
    for (int rt = 0; rt < 2; rt++)
#pragma unroll
        for (int j = 0; j < 4; j++) {
            int d = j * 16 + ln;
            float bv = (k == 0) ? pb[d] : 0.f;
#pragma unroll
            for (int r = 0; r < 4; r++) {
                int n = n0 + wr + rt * 16 + q * 4 + r;
                out[(size_t)n * 1600 + k * 64 + d] = acc[rt][j][r] + bv;
            }
        }
}

extern "C" void kernel_launch(void* const* d_in, const int* in_sizes, int n_in,
                              void* d_out, int out_size, void* d_ws, size_t ws_size,
                              hipStream_t stream) {
    const float* nf      = (const float*)d_in[0];
    const int* species   = (const int*)d_in[1];
    const float* dist    = (const float*)d_in[2];
    const int* snd       = (const int*)d_in[3];
    const int* rcv       = (const int*)d_in[4];
    const float* wig     = (const float*)d_in[5];
    const float* semb    = (const float*)d_in[6];
    const float* remb    = (const float*)d_in[7];
    const float* rad_w1  = (const float*)d_in[8];
    const float* rad_b1  = (const float*)d_in[9];
    const float* rad_g1  = (const float*)d_in[10];
    const float* rad_be1 = (const float*)d_in[11];
    const float* rad_w2  = (const float*)d_in[12];
    const float* rad_b2  = (const float*)d_in[13];
    const float* rad_g2  = (const float*)d_in[14];
    const float* rad_be2 = (const float*)d_in[15];
    const float* rad_w3  = (const float*)d_in[16];
    const float* rad_b3  = (const float*)d_in[17];
    const float* c1_w0   = (const float*)d_in[18];
    const float* c1_b0   = (const float*)d_in[19];
    const float* c1_wm1  = (const float*)d_in[20];
    const float* c1_wm2  = (const float*)d_in[21];
    const float* aln_g   = (const float*)d_in[22];
    const float* aln_b   = (const float*)d_in[23];
    const float* adot    = (const float*)d_in[24];
    const float* to_grid = (const float*)d_in[25];
    const float* from_grid=(const float*)d_in[26];
    const float* c2_w0   = (const float*)d_in[27];
    const float* c2_b0   = (const float*)d_in[28];
    const float* c2_wm1  = (const float*)d_in[29];
    const float* c2_wm2  = (const float*)d_in[30];
    const float* proj_w  = (const float*)d_in[31];
    const float* proj_b  = (const float*)d_in[32];

    char* ws = (char*)d_ws;
    size_t off = 0;
    auto take = [&](size_t bytes) -> char* {
        char* p = ws + off;
        off += (bytes + 255) & ~(size_t)255;
        return p;
    };
    // fixed section
    u16* w_rad1T  = (u16*)take(64 * 192 * 2);
    u16* w_rad2T  = (u16*)take(64 * 64 * 2);
    u16* w_rad3T  = (u16*)take(1536 * 64 * 2);
    u16* w_c1w0T  = (u16*)take(640 * 640 * 2);
    u16* w_c1m1T  = (u16*)take((size_t)512 * 1024 * 2);
    u16* w_c1m2T  = (u16*)take((size_t)384 * 768 * 2);
    u16* w_c2w0T  = (u16*)take((size_t)640 * 320 * 2);
    u16* w_c2m1T  = (u16*)take((size_t)1024 * 512 * 2);
    u16* w_c2m2T  = (u16*)take((size_t)768 * 384 * 2);
    u16* w_tgP    = (u16*)take(112 * 32 * 2);
    u16* w_fgP    = (u16*)take(32 * 128 * 2);
    u16* w_pwT    = (u16*)take(5 * 8192 * 2);
    float* logits = (float*)take((size_t)E_EDGES * 8 * 4);
    float* ealpha = (float*)take((size_t)E_EDGES * 8 * 4);
    u32* nmax     = (u32*)take((size_t)N_NODES_C * 8 * 4);
    float* nsum   = (float*)take((size_t)N_NODES_C * 8 * 4);
    float* node   = (float*)take((size_t)N_NODES_C * 3200 * 4);
    u16* a_h2     = (u16*)take((size_t)E_EDGES * 64 * 2);
    u32* c_deg    = (u32*)take((size_t)N_NODES_C * 4);
    u32* c_row    = (u32*)take((size_t)N_NODES_C * 4);
    u32* c_cur    = (u32*)take((size_t)N_NODES_C * 4);
    int* c_elist  = (int*)take((size_t)E_EDGES * 4);
    // arena — aliased by phase
    char* arena   = take(173015040);
    if (off > ws_size) {  // diagnostic: paint output so the failure mode is identifiable
        k_diag<<<(out_size + 255) / 256, 256, 0, stream>>>((float*)d_out, out_size);
        return;
    }

    u16* a_ee   = (u16*)(arena + 0);           // radial phase
    u16* a_ypre = (u16*)(arena + 9437184);
    u16* a_h1   = (u16*)(arena + 12582912);
    u16* a_xe   = (u16*)(arena + 0);           // per-chunk (EC,1536); radial staging dead
    u16* a_A1   = (u16*)(arena + 37748736);    // per-chunk (EC,2432)
    u16* a_Y0   = (u16*)(arena + 97517568);    // full (E,640)
    u16* a_Y1   = (u16*)(arena + 128974848);   // full (E,512)
    u16* a_Y2   = (u16*)(arena + 154140672);   // full (E,384) -> arena end
    u16* a_A2   = (u16*)(arena + 0);           // full (E,1216); xe/A1 dead
    u16* a_Z0   = (u16*)(arena + 59768832);    // per-chunk (EC,640)
    u16* a_Z1   = (u16*)(arena + 75497472);    // per-chunk (EC,1024)
    u16* a_Z2   = (u16*)(arena + 100663296);   // per-chunk (EC,768); overlaps dead Y0 region

    // ---- weight prep ----
    k_transpose<<<48, 256, 0, stream>>>(rad_w1, w_rad1T, 192, 64);
    k_transpose<<<16, 256, 0, stream>>>(rad_w2, w_rad2T, 64, 64);
    k_transpose<<<384, 256, 0, stream>>>(rad_w3, w_rad3T, 64, 1536);
    k_transpose<<<1600, 256, 0, stream>>>(c1_w0, w_c1w0T, 640, 640);
    k_transpose<<<800, 256, 0, stream>>>(c2_w0, w_c2w0T, 320, 640);
    k_combine<<<2048, 256, 0, stream>>>(c1_wm1, w_c1m1T, 512, 256);
    k_combine<<<1152, 256, 0, stream>>>(c1_wm2, w_c1m2T, 384, 192);
    k_combine<<<2048, 256, 0, stream>>>(c2_wm1, w_c2m1T, 256, 512);
    k_combine<<<1152, 256, 0, stream>>>(c2_wm2, w_c2m2T, 192, 384);
    k_packgrid<<<30, 256, 0, stream>>>(to_grid, from_grid, w_tgP, w_fgP);
    for (int l = 0; l < 5; l++)
        k_transpose<<<32, 256, 0, stream>>>(proj_w + (size_t)l * 8192, w_pwT + (size_t)l * 8192, 128, 64);
    k_init<<<128, 256, 0, stream>>>(nmax, nsum, N_NODES_C * 8);

    // ---- CSR build (receivers static per launch) ----
    hipMemsetAsync(c_deg, 0, (size_t)N_NODES_C * 4, stream);
    k_deg<<<96, 256, 0, stream>>>(rcv, c_deg);
    k_pfx<<<1, 256, 0, stream>>>(c_deg, c_row, c_cur);
    k_fill<<<96, 256, 0, stream>>>(rcv, c_cur, c_elist);

    // ---- radial MLP (full E) ----
    k_ee<<<(E_EDGES * 192 + 255) / 256, 256, 0, stream>>>(dist, species, snd, rcv, semb, remb, a_ee);
    k_gemm<<<dim3(192, 1), 256, 0, stream>>>(a_ee, 192, w_rad1T, 192, a_ypre, 64, 64, 192, rad_b1);
    k_ln_silu<<<6144, 256, 0, stream>>>(a_ypre, a_h1, rad_g1, rad_be1);
    k_gemm<<<dim3(192, 1), 256, 0, stream>>>(a_h1, 64, w_rad2T, 64, a_ypre, 64, 64, 64, rad_b2);
    k_ln_silu<<<6144, 256, 0, stream>>>(a_ypre, a_h2, rad_g2, rad_be2);

    // ---- chunked: x_edge gemm -> rotate -> conv1 ----
    for (int c = 0; c < 2; c++) {
        int e0 = c * EC;
        k_gemm<<<dim3(96, 12), 256, 0, stream>>>(a_h2 + (size_t)e0 * 64, 64, w_rad3T, 64,
                                                 a_xe, 1536, 1536, 64, rad_b3);
        k_rotate<<<EC / 2, 256, 0, stream>>>(nf, wig, snd, rcv, a_xe, a_A1, e0);
        k_gemm<<<dim3(96, 5), 256, 0, stream>>>(a_A1, 2432, w_c1w0T, 640,
                                                a_Y0 + (size_t)e0 * 640, 640, 640, 640, c1_b0);
        k_gemm<<<dim3(96, 4), 256, 0, stream>>>(a_A1 + 640, 2432, w_c1m1T, 1024,
                                                a_Y1 + (size_t)e0 * 512, 512, 512, 1024, nullptr);
        k_gemm<<<dim3(96, 3), 256, 0, stream>>>(a_A1 + 1664, 2432, w_c1m2T, 768,
                                                a_Y2 + (size_t)e0 * 384, 384, 384, 768, nullptr);
    }

    // ---- attention softmax pieces ----
    k_logits<<<E_EDGES, 256, 0, stream>>>(a_Y0, rcv, aln_g, aln_b, adot, logits, nmax);
    k_expsum<<<(E_EDGES * 8 + 255) / 256, 256, 0, stream>>>(logits, rcv, nmax, ealpha, nsum);

    // ---- grid nonlinearity -> packed A2 (full E, MFMA) ----
    k_grid_mfma<<<E_EDGES / 2, 256, 0, stream>>>(a_Y0, a_Y1, a_Y2, w_tgP, w_fgP, a_A2);

    // ---- chunked: conv2 -> gather (CSR, scalar-path wigner, no atomics) ----
    for (int c = 0; c < 2; c++) {
        int e0 = c * EC;
        k_gemm<<<dim3(96, 5), 256, 0, stream>>>(a_A2 + (size_t)e0 * 1216, 1216, w_c2w0T, 320,
                                                a_Z0, 640, 640, 320, c2_b0);
        k_gemm<<<dim3(96, 8), 256, 0, stream>>>(a_A2 + (size_t)e0 * 1216 + 320, 1216, w_c2m1T, 512,
                                                a_Z1, 1024, 1024, 512, nullptr);
        k_gemm<<<dim3(96, 6), 256, 0, stream>>>(a_A2 + (size_t)e0 * 1216 + 832, 1216, w_c2m2T, 384,
                                                a_Z2, 768, 768, 384, nullptr);
        k_gather<<<N_NODES_C, 256, 0, stream>>>(a_Z0, a_Z1, a_Z2, wig, ealpha, nsum,
                                                c_row, c_deg, c_elist, node, e0, c);
    }

    // ---- output projection (MFMA) ----
    k_proj_mfma<<<dim3(32, 25), 256, 0, stream>>>(node, w_pwT, proj_b, (float*)d_out);
}

// Round 5
// 1030.972 us; speedup vs baseline: 1.0637x; 1.0069x over previous
//
#include <hip/hip_runtime.h>

typedef unsigned short u16;
typedef unsigned int u32;
typedef __attribute__((ext_vector_type(8))) short short8;
typedef __attribute__((ext_vector_type(4))) float floatx4;

#define E_EDGES 24576
#define EC 12288            // edge chunk
#define N_NODES_C 4096

__device__ __forceinline__ float bf2f(u16 u) {
    union { u32 i; float f; } v; v.i = ((u32)u) << 16; return v.f;
}
__device__ __forceinline__ u16 f2bf(float f) {
    union { float f; u32 i; } v; v.f = f;
    u32 x = v.i;
    u32 r = (x + 0x7fffu + ((x >> 16) & 1u)) >> 16;
    return (u16)r;
}
// packed f32x2 -> bf16x2 in one VALU inst (RNE), no builtin on gfx950 -> inline asm
__device__ __forceinline__ u32 pk_bf16(float a, float b) {
    u32 r;
    asm("v_cvt_pk_bf16_f32 %0, %1, %2" : "=v"(r) : "v"(a), "v"(b));
    return r;
}
__device__ __forceinline__ u32 encf(float f) {
    union { float f; u32 i; } v; v.f = f;
    return (v.i & 0x80000000u) ? ~v.i : (v.i | 0x80000000u);
}
__device__ __forceinline__ float decf(u32 u) {
    union { u32 i; float f; } v;
    v.i = (u & 0x80000000u) ? (u ^ 0x80000000u) : ~u;
    return v.f;
}
// fast transcendentals: v_exp_f32 + v_rcp_f32
__device__ __forceinline__ float sigmoidf_(float x) { return __fdividef(1.f, 1.f + __expf(-x)); }
__device__ __forceinline__ float siluf_(float x) { return x * __fdividef(1.f, 1.f + __expf(-x)); }

// async global->LDS, 16B per lane; LDS dest must be wave-uniform base + lane*16
__device__ __forceinline__ void gld16(const u16* g, u16* l) {
    __builtin_amdgcn_global_load_lds((const __attribute__((address_space(1))) unsigned int*)g,
                                     (__attribute__((address_space(3))) unsigned int*)l, 16, 0, 0);
}

// diagnostic: ws too small -> paint output with 1000 (f32)
__global__ void k_diag(float* __restrict__ out, int n) {
    int i = blockIdx.x * 256 + threadIdx.x;
    if (i < n) out[i] = 1000.0f;
}

// ---------------- weight prep (f32 src -> bf16 transposed) ----------------
__global__ void k_transpose(const float* __restrict__ src, u16* __restrict__ dst, int K, int N) {
    int idx = blockIdx.x * 256 + threadIdx.x;
    if (idx >= K * N) return;
    int k = idx / N, n = idx % N;
    dst[n * K + k] = f2bf(src[idx]);
}
// combined complex weight, pre-transposed. src (K, 2H) f32: wa=cols[0:H), wb=cols[H:2H).
// dst (2H, 2K) bf16: dst[n][k] = k<K ? src[k][n] : (n<H ? -src[k-K][H+n] : src[k-K][n-H])
__global__ void k_combine(const float* __restrict__ src, u16* __restrict__ dst, int K, int H) {
    int total = 4 * K * H;
    int idx = blockIdx.x * 256 + threadIdx.x;
    if (idx >= total) return;
    int n = idx / (2 * K), k = idx % (2 * K);
    float v;
    if (k < K) v = src[k * 2 * H + n];
    else {
        int kk = k - K;
        if (n < H) v = -src[kk * 2 * H + H + n];
        else       v = src[kk * 2 * H + (n - H)];
    }
    dst[idx] = f2bf(v);
}

// pack to_grid (100,19) -> tgP[112][32] bf16; pack from_grid (19,100) -> fgP[32][128] bf16
__global__ void k_packgrid(const float* __restrict__ tg, const float* __restrict__ fg,
                           u16* __restrict__ tgP, u16* __restrict__ fgP) {
    int idx = blockIdx.x * 256 + threadIdx.x;
    if (idx < 112 * 32) {
        int p = idx >> 5, m = idx & 31;
        tgP[idx] = (p < 100 && m < 19) ? f2bf(tg[p * 19 + m]) : (u16)0;
    }
    int j = idx - 112 * 32;
    if (j >= 0 && j < 32 * 128) {
        int m = j >> 7, k = j & 127;
        fgP[j] = (m < 19 && k < 100) ? f2bf(fg[m * 100 + k]) : (u16)0;
    }
}

__global__ void k_init(u32* __restrict__ nmax, float* __restrict__ nsum, int n) {
    int idx = blockIdx.x * 256 + threadIdx.x;
    if (idx < n) { nmax[idx] = 0x007FFFFFu; /* enc(-inf) */ nsum[idx] = 0.f; }
}

// ---------------- CSR build over receivers (static per launch) ----------------
__global__ void k_deg(const int* __restrict__ rcv, u32* __restrict__ deg) {
    int e = blockIdx.x * 256 + threadIdx.x;
    if (e < E_EDGES) atomicAdd(&deg[rcv[e]], 1u);
}
__global__ __launch_bounds__(256) void k_pfx(const u32* __restrict__ deg,
                                             u32* __restrict__ rowstart, u32* __restrict__ cur) {
    __shared__ u32 ps[256];
    int t = threadIdx.x;
    u32 loc[16]; u32 s = 0;
#pragma unroll
    for (int i = 0; i < 16; i++) { loc[i] = s; s += deg[t * 16 + i]; }
    ps[t] = s;
    __syncthreads();
    for (int o = 1; o < 256; o <<= 1) {
        u32 v = (t >= o) ? ps[t - o] : 0u;
        __syncthreads();
        ps[t] += v;
        __syncthreads();
    }
    u32 base = (t == 0) ? 0u : ps[t - 1];
#pragma unroll
    for (int i = 0; i < 16; i++) { u32 v = base + loc[i]; rowstart[t * 16 + i] = v; cur[t * 16 + i] = v; }
}
__global__ void k_fill(const int* __restrict__ rcv, u32* __restrict__ cur, int* __restrict__ elist) {
    int e = blockIdx.x * 256 + threadIdx.x;
    if (e < E_EDGES) { u32 p = atomicAdd(&cur[rcv[e]], 1u); elist[p] = e; }
}

// ---------------- edge embeddings (f32 in -> bf16 A) ----------------
__global__ void k_ee(const float* __restrict__ dist, const int* __restrict__ species,
                     const int* __restrict__ snd, const int* __restrict__ rcv,
                     const float* __restrict__ semb, const float* __restrict__ remb,
                     u16* __restrict__ ee) {
    int idx = blockIdx.x * 256 + threadIdx.x;
    if (idx >= E_EDGES * 192) return;
    int e = idx / 192, c = idx % 192;
    float v;
    if (c < 64)       v = dist[e * 64 + c];
    else if (c < 128) v = semb[species[snd[e]] * 64 + (c - 64)];
    else              v = remb[species[rcv[e]] * 64 + (c - 128)];
    ee[idx] = f2bf(v);
}

// ---------------- GEMM (m97 structure): A (M,K) bf16 rm, BT (N,K) bf16 rm, C (M,N) bf16 ----------------
// global_load_lds staging, unpadded 64B rows. M%128==0, K%32==0; N guarded.
// Explicit s_waitcnt vmcnt(0) before barrier — async LDS-DMA must drain (round-6 race fix).
__global__ __launch_bounds__(256) void k_gemm(
    const u16* __restrict__ A, int lda,
    const u16* __restrict__ BT, int ldb,
    u16* __restrict__ C, int ldc,
    int N, int K,
    const float* __restrict__ bias) {
    __shared__ u16 As[128 * 32];
    __shared__ u16 Bs[128 * 32];
    int tid = threadIdx.x;
    int bm0 = blockIdx.x * 128;
    int bn0 = blockIdx.y * 128;
    int wave = tid >> 6, lane = tid & 63;
    int wm = (wave >> 1) * 64, wn = (wave & 1) * 64;
    int lrow = lane & 15, lk = (lane >> 4) * 8;

    // staging geometry: wave w covers rows w*16 + (lane>>2), 16B chunk (lane&3)
    int srow = (wave << 4) + (lane >> 2);        // 0..63
    int schunk = (lane & 3) << 3;                // u16 offset 0/8/16/24
    const u16* Arow0 = A + (size_t)(bm0 + srow) * lda + schunk;
    const u16* Arow1 = A + (size_t)(bm0 + srow + 64) * lda + schunk;
    int n0 = bn0 + srow;      if (n0 >= N) n0 = N - 1;
    int n1 = bn0 + srow + 64; if (n1 >= N) n1 = N - 1;
    const u16* Brow0 = BT + (size_t)n0 * ldb + schunk;
    const u16* Brow1 = BT + (size_t)n1 * ldb + schunk;
    u16* lA0 = &As[srow * 32 + schunk];
    u16* lA1 = &As[(srow + 64) * 32 + schunk];
    u16* lB0 = &Bs[srow * 32 + schunk];
    u16* lB1 = &Bs[(srow + 64) * 32 + schunk];

    floatx4 acc[4][4];
#pragma unroll
    for (int i = 0; i < 4; i++)
#pragma unroll
        for (int j = 0; j < 4; j++) acc[i][j] = floatx4{0.f, 0.f, 0.f, 0.f};

    for (int k0 = 0; k0 < K; k0 += 32) {
        gld16(Arow0 + k0, lA0);
        gld16(Arow1 + k0, lA1);
        gld16(Brow0 + k0, lB0);
        gld16(Brow1 + k0, lB1);
        asm volatile("s_waitcnt vmcnt(0)" ::: "memory");
        __syncthreads();
        short8 a[4], b[4];
#pragma unroll
        for (int i = 0; i < 4; i++) a[i] = *(const short8*)(&As[(wm + i * 16 + lrow) * 32 + lk]);
#pragma unroll
        for (int j = 0; j < 4; j++) b[j] = *(const short8*)(&Bs[(wn + j * 16 + lrow) * 32 + lk]);
#pragma unroll
        for (int i = 0; i < 4; i++)
#pragma unroll
            for (int j = 0; j < 4; j++)
                acc[i][j] = __builtin_amdgcn_mfma_f32_16x16x32_bf16(a[i], b[j], acc[i][j], 0, 0, 0);
        __syncthreads();
    }

    int q = lane >> 4;
#pragma unroll
    for (int i = 0; i < 4; i++) {
#pragma unroll
        for (int j = 0; j < 4; j++) {
            int col = bn0 + wn + j * 16 + lrow;
            if (col < N) {
                float bv = bias ? bias[col] : 0.f;
#pragma unroll
                for (int r = 0; r < 4; r++) {
                    int row = bm0 + wm + i * 16 + q * 4 + r;
                    C[(size_t)row * ldc + col] = f2bf(acc[i][j][r] + bv);
                }
            }
        }
    }
}

// ---------------- LayerNorm(64) + SiLU (bf16 io, f32 params) ----------------
__global__ __launch_bounds__(256) void k_ln_silu(const u16* __restrict__ in, u16* __restrict__ out,
                                                 const float* __restrict__ g, const float* __restrict__ b) {
    int tid = threadIdx.x;
    int e = blockIdx.x * 4 + (tid >> 6);
    int c = tid & 63;
    float x = bf2f(in[(size_t)e * 64 + c]);
    float s = x, s2 = x * x;
#pragma unroll
    for (int o = 32; o; o >>= 1) { s += __shfl_xor(s, o); s2 += __shfl_xor(s2, o); }
    float mu = s * (1.f / 64.f);
    float var = s2 * (1.f / 64.f) - mu * mu;
    float rs = rsqrtf(var + 1e-5f);
    float y = (x - mu) * rs * g[c] + b[c];
    out[(size_t)e * 64 + c] = f2bf(siluf_(y));
}

// ---------------- rotate: wigner @ concat(nf[snd],nf[rcv]); scale by x_edge; pack A1 (chunked) ----------------
__global__ __launch_bounds__(256) void k_rotate(const float* __restrict__ nf, const float* __restrict__ wig,
                                                const int* __restrict__ snd, const int* __restrict__ rcv,
                                                const u16* __restrict__ xe, u16* __restrict__ A1, int e0) {
    __shared__ float wl[2][475];
    int tid = threadIdx.x;
    for (int i = tid; i < 950; i += 256) {
        int ee = e0 + blockIdx.x * 2 + (i / 475);
        wl[i / 475][i % 475] = wig[(size_t)ee * 475 + (i % 475)];
    }
    __syncthreads();
    int le = tid >> 7, c = tid & 127;
    int el = blockIdx.x * 2 + le;       // chunk-local
    int e = e0 + el;                    // global
    int nd = (c < 64) ? snd[e] : rcv[e];
    int cc = c & 63;
    float msg[25];
#pragma unroll
    for (int k = 0; k < 25; k++) msg[k] = nf[(size_t)nd * 1600 + k * 64 + cc];
    const float* w = wl[le];
    size_t ebase = (size_t)el * 2432;
    size_t xbase = (size_t)el * 1536;
#pragma unroll
    for (int m = 0; m < 19; m++) {
        float r = 0.f;
#pragma unroll
        for (int k = 0; k < 25; k++) r += w[m * 25 + k] * msg[k];
        int a1c, xc;
        if (m < 5)       { a1c = m * 128;               xc = m * 128; }
        else if (m < 9)  { a1c = 640 + (m - 5) * 128;   xc = 640 + (m - 5) * 128; }
        else if (m < 13) { a1c = 1152 + (m - 9) * 128;  xc = 640 + (m - 9) * 128; }
        else if (m < 16) { a1c = 1664 + (m - 13) * 128; xc = 1152 + (m - 13) * 128; }
        else             { a1c = 2048 + (m - 16) * 128; xc = 1152 + (m - 16) * 128; }
        float sc = bf2f(xe[xbase + xc + c]);
        A1[ebase + a1c + c] = f2bf(r * sc);
    }
}

// ---------------- attention logits + segment max ----------------
__global__ __launch_bounds__(256) void k_logits(const u16* __restrict__ Y0, const int* __restrict__ rcv,
                                                const float* __restrict__ g, const float* __restrict__ b,
                                                const float* __restrict__ adot,
                                                float* __restrict__ logits, u32* __restrict__ nmax) {
    int e = blockIdx.x;
    int tid = threadIdx.x;
    int h = tid >> 5, c = tid & 31;
    float x = bf2f(Y0[(size_t)e * 640 + 320 + h * 32 + c]);
    float s = x, s2 = x * x;
#pragma unroll
    for (int o = 16; o; o >>= 1) { s += __shfl_xor(s, o); s2 += __shfl_xor(s2, o); }
    float mu = s * (1.f / 32.f);
    float var = s2 * (1.f / 32.f) - mu * mu;
    float rs = rsqrtf(var + 1e-5f);
    float a = (x - mu) * rs * g[c] + b[c];
    float f = 0.6f * a + 0.4f * a * (2.f * sigmoidf_(a) - 1.f);
    float l = f * adot[h * 32 + c];
#pragma unroll
    for (int o = 16; o; o >>= 1) l += __shfl_xor(l, o);
    if (c == 0) {
        logits[e * 8 + h] = l;
        atomicMax(&nmax[rcv[e] * 8 + h], encf(l));
    }
}

__global__ void k_expsum(const float* __restrict__ logits, const int* __restrict__ rcv,
                         const u32* __restrict__ nmax, float* __restrict__ ealpha, float* __restrict__ nsum) {
    int idx = blockIdx.x * 256 + threadIdx.x;
    if (idx >= E_EDGES * 8) return;
    int e = idx >> 3, h = idx & 7;
    int r = rcv[e];
    float amax = decf(nmax[r * 8 + h]);
    if (!(amax > -1e38f && amax < 1e38f)) amax = 0.f;
    float v = __expf(logits[idx] - amax);
    ealpha[idx] = v;
    atomicAdd(&nsum[r * 8 + h], v);
}

// ---------------- grid round-trip via MFMA ----------------
// LDS: Xs aliased into T1s (Xs fully consumed into registers before T1s written).
#define GR_XS_STR 40
#define GR_T1_STR 136
__global__ __launch_bounds__(256) void k_grid_mfma(
    const u16* __restrict__ Y0, const u16* __restrict__ Y1, const u16* __restrict__ Y2,
    const u16* __restrict__ tgP, const u16* __restrict__ fgP, u16* __restrict__ A2) {
    __shared__ u16 T1s[128 * GR_T1_STR];
    u16* Xs = T1s;                       // alias: see barrier discipline below
    int tid = threadIdx.x;
    int e0 = blockIdx.x * 2;
    // stage Xs[ec][m]: thread owns (le, c0-block, m-pair); packed u32 writes
    {
        int mp = tid & 15;                  // m-pair 0..15 -> m = 2mp, 2mp+1
        int c0 = ((tid >> 4) & 7) << 3;     // channel block 0..56
        int le = tid >> 7;                  // local edge 0/1
        int e = e0 + le;
        int m0 = 2 * mp, m1 = m0 + 1;
        uint4 va = {0, 0, 0, 0}, vb = {0, 0, 0, 0};
        if (m0 < 5)       va = *(const uint4*)(&Y0[(size_t)e * 640 + m0 * 64 + c0]);
        else if (m0 < 13) va = *(const uint4*)(&Y1[(size_t)e * 512 + (m0 - 5) * 64 + c0]);
        else if (m0 < 19) va = *(const uint4*)(&Y2[(size_t)e * 384 + (m0 - 13) * 64 + c0]);
        if (m1 < 5)       vb = *(const uint4*)(&Y0[(size_t)e * 640 + m1 * 64 + c0]);
        else if (m1 < 13) vb = *(const uint4*)(&Y1[(size_t)e * 512 + (m1 - 5) * 64 + c0]);
        else if (m1 < 19) vb = *(const uint4*)(&Y2[(size_t)e * 384 + (m1 - 13) * 64 + c0]);
        const u16* pa = (const u16*)&va;
        const u16* pb = (const u16*)&vb;
        int rbase = le * 64 + c0;
#pragma unroll
        for (int j = 0; j < 8; j++) {
            u32 w = (u32)pa[j] | ((u32)pb[j] << 16);
            *(u32*)(&Xs[(rbase + j) * GR_XS_STR + 2 * mp]) = w;
        }
    }
    __syncthreads();
    int wave = tid >> 6, lane = tid & 63;
    int wn = wave << 5;                     // this wave's 32 ec-columns
    int ln = lane & 15, q = lane >> 4;
    // GEMM1 (swapped): A = tgP (p x m), B^T = Xs (ec x m). Out rows = p, cols = ec.
    short8 bx0 = *(const short8*)(&Xs[(wn + ln) * GR_XS_STR + q * 8]);
    short8 bx1 = *(const short8*)(&Xs[(wn + 16 + ln) * GR_XS_STR + q * 8]);
    floatx4 acc1[2][7];
#pragma unroll
    for (int pt = 0; pt < 7; pt++) {
        short8 a = *(const short8*)(&tgP[(size_t)(pt * 16 + ln) * 32 + q * 8]);
        acc1[0][pt] = __builtin_amdgcn_mfma_f32_16x16x32_bf16(a, bx0, floatx4{0.f, 0.f, 0.f, 0.f}, 0, 0, 0);
        acc1[1][pt] = __builtin_amdgcn_mfma_f32_16x16x32_bf16(a, bx1, floatx4{0.f, 0.f, 0.f, 0.f}, 0, 0, 0);
    }
    __syncthreads();    // all Xs reads complete -> safe to overwrite (alias)
    // zero T1s pad cols 112..127 (cols 100..111 are exact zeros from the zeroed tgP rows)
    {
        int row = tid >> 1;
        uint4 z = {0, 0, 0, 0};
        *(uint4*)(&T1s[row * GR_T1_STR + 112 + (tid & 1) * 8]) = z;
    }
    // silu -> T1s[ec][p]: lane holds p = pt*16 + q*4 + r at ec = wn + i*16 + ln -> b64 writes
#pragma unroll
    for (int i = 0; i < 2; i++) {
        u16* dst = &T1s[(wn + i * 16 + ln) * GR_T1_STR + q * 4];
#pragma unroll
        for (int pt = 0; pt < 7; pt++) {
            uint2 pv;
            pv.x = pk_bf16(siluf_(acc1[i][pt][0]), siluf_(acc1[i][pt][1]));
            pv.y = pk_bf16(siluf_(acc1[i][pt][2]), siluf_(acc1[i][pt][3]));
            *(uint2*)(dst + pt * 16) = pv;
        }
    }
    __syncthreads();
    // GEMM2: K=128 (4 steps)
    floatx4 acc2[2][2];
    acc2[0][0] = floatx4{0.f, 0.f, 0.f, 0.f}; acc2[0][1] = floatx4{0.f, 0.f, 0.f, 0.f};
    acc2[1][0] = floatx4{0.f, 0.f, 0.f, 0.f}; acc2[1][1] = floatx4{0.f, 0.f, 0.f, 0.f};
#pragma unroll
    for (int ks = 0; ks < 4; ks++) {
        short8 c0 = *(const short8*)(&T1s[(wn + ln) * GR_T1_STR + ks * 32 + q * 8]);
        short8 c1 = *(const short8*)(&T1s[(wn + 16 + ln) * GR_T1_STR + ks * 32 + q * 8]);
#pragma unroll
        for (int ct = 0; ct < 2; ct++) {
            short8 b = *(const short8*)(&fgP[(size_t)(ct * 16 + ln) * 128 + ks * 32 + q * 8]);
            acc2[0][ct] = __builtin_amdgcn_mfma_f32_16x16x32_bf16(c0, b, acc2[0][ct], 0, 0, 0);
            acc2[1][ct] = __builtin_amdgcn_mfma_f32_16x16x32_bf16(c1, b, acc2[1][ct], 0, 0, 0);
        }
    }
    // direct store: lane holds col m'=ct*16+ln, rows q*4+r -> 4 consecutive c in A2
#pragma unroll
    for (int rt = 0; rt < 2; rt++) {
        int row = wn + rt * 16 + q * 4;
        int e = e0 + (row >> 6), c = row & 63;
#pragma unroll
        for (int ct = 0; ct < 2; ct++) {
            int mp = ct * 16 + ln;
            if (mp >= 1 && mp < 19) {
                uint2 pv;
                pv.x = pk_bf16(acc2[rt][ct][0], acc2[rt][ct][1]);
                pv.y = pk_bf16(acc2[rt][ct][2], acc2[rt][ct][3]);
                *(uint2*)(&A2[(size_t)e * 1216 + mp * 64 + c]) = pv;
            }
        }
    }
    // m=0 gate row
    if (tid < 128) {
        int e = e0 + (tid >> 6), c = tid & 63;
        float gate = bf2f(Y0[(size_t)e * 640 + 576 + c]);
        A2[(size_t)e * 1216 + c] = f2bf(siluf_(gate));
    }
}

// ---------------- gather: attention scale + wigner^T + segment-sum (no atomics) ----------------
// WAVE-PER-NODE, zero-sync, zero-LDS. Lane owns channel pair (2l, 2l+1) via packed u32
// bf16 loads (256B coalesced per load). Edge loop is wave-private: 950 FMA wave-insts
// per edge hide the next edge's load latency; 16 waves/CU give 16 independent streams.
// Wigner pointer kept scalar via readfirstlane. Two passes over the Z chunks.
__global__ __launch_bounds__(256) void k_gather(
    const u16* __restrict__ Z0, const u16* __restrict__ Z1, const u16* __restrict__ Z2,
    const float* __restrict__ wig, const float* __restrict__ ealpha, const float* __restrict__ nsum,
    const u32* __restrict__ rowstart, const u32* __restrict__ deg, const int* __restrict__ elist,
    float* __restrict__ node, int e0, int accum) {
    int n = blockIdx.x * 4 + (threadIdx.x >> 6);
    int lane = threadIdx.x & 63;
    int h = lane >> 3;                  // head of channels 2l,2l+1 (same head for both)
    float sden = __fdividef(1.f, nsum[n * 8 + h] + 1e-16f);
    float a0[25], a1[25];
#pragma unroll
    for (int k = 0; k < 25; k++) { a0[k] = 0.f; a1[k] = 0.f; }
    u32 lo = rowstart[n], cnt = deg[n];
    bool did = false;
    for (u32 i = 0; i < cnt; i++) {
        int e = __builtin_amdgcn_readfirstlane(elist[lo + i]);
        int el = e - e0;
        if ((u32)el >= (u32)EC) continue;       // wave-uniform
        did = true;
        float al = ealpha[e * 8 + h] * sden;
        // 19 packed z loads (2 bf16 channels per lane), all independent
        u32 zp[19];
        const u16* z0 = Z0 + (size_t)el * 640 + 2 * lane;
        const u16* z1 = Z1 + (size_t)el * 1024 + 2 * lane;
        const u16* z2 = Z2 + (size_t)el * 768 + 2 * lane;
#pragma unroll
        for (int m = 0; m < 5; m++) zp[m] = *(const u32*)(z0 + m * 128);
#pragma unroll
        for (int m = 0; m < 8; m++) zp[5 + m] = *(const u32*)(z1 + m * 128);
#pragma unroll
        for (int m = 0; m < 6; m++) zp[13 + m] = *(const u32*)(z2 + m * 128);
        const float* __restrict__ w = wig + (size_t)e * 475;
#pragma unroll
        for (int m = 0; m < 19; m++) {
            float s0 = bf2f((u16)(zp[m] & 0xffffu)) * al;
            float s1 = bf2f((u16)(zp[m] >> 16)) * al;
#pragma unroll
            for (int k = 0; k < 25; k++) {
                float wv = w[m * 25 + k];
                a0[k] = fmaf(wv, s0, a0[k]);
                a1[k] = fmaf(wv, s1, a1[k]);
            }
        }
    }
    float* nb = node + (size_t)n * 3200 + 2 * lane;
    if (accum) {
        if (!did) return;                       // wave-uniform
#pragma unroll
        for (int k = 0; k < 25; k++) {
            float2 v = *(float2*)(&nb[k * 128]);
            v.x += a0[k]; v.y += a1[k];
            *(float2*)(&nb[k * 128]) = v;
        }
    } else {
#pragma unroll
        for (int k = 0; k < 25; k++) {
            float2 v; v.x = a0[k]; v.y = a1[k];
            *(float2*)(&nb[k * 128]) = v;
        }
    }
}

// ---------------- final projection via MFMA ----------------
// grid (32 n-tiles, 25 k). Block: M=128 n-rows, N=64 d, K=128 c.
// A = node (f32, stride 3200) -> bf16 LDS; B = pwTb[l] (64x128 bf16).
#define PJ_STR 136
__global__ __launch_bounds__(256) void k_proj_mfma(
    const float* __restrict__ node, const u16* __restrict__ pwTb,
    const float* __restrict__ pb, float* __restrict__ out) {
    __shared__ u16 As[128 * PJ_STR];
    __shared__ u16 Bs[64 * PJ_STR];
    int tid = threadIdx.x;
    int n0 = blockIdx.x * 128;
    int k = blockIdx.y;
    int l = (int)sqrtf((float)k + 0.5f);
    // stage A: 128 rows x 128 c f32 -> bf16; thread i handles row=i>>5, c0=(i&31)*4
#pragma unroll
    for (int it = 0; it < 16; it++) {
        int i = tid + it * 256;
        int row = i >> 5;
        int c0 = (i & 31) << 2;
        float4 v = *(const float4*)(&node[(size_t)(n0 + row) * 3200 + k * 128 + c0]);
        uint2 pv;
        pv.x = pk_bf16(v.x, v.y);
        pv.y = pk_bf16(v.z, v.w);
        *(uint2*)(&As[row * PJ_STR + c0]) = pv;
    }
    // stage B: 64 rows (d) x 128 c bf16, 16B chunks
    const u16* pw = pwTb + (size_t)l * 8192;
#pragma unroll
    for (int jt = 0; jt < 4; jt++) {
        int j = tid + jt * 256;
        int d = j >> 4;
        int c0 = (j & 15) << 3;
        *(uint4*)(&Bs[d * PJ_STR + c0]) = *(const uint4*)(&pw[d * 128 + c0]);
    }
    __syncthreads();
    int wave = tid >> 6, lane = tid & 63;
    int wr = wave * 32;
    int ln = lane & 15, q = lane >> 4;
    floatx4 acc[2][4];
#pragma unroll
    for (int i = 0; i < 2; i++)
#pragma unroll
        for (int j = 0; j < 4; j++) acc[i][j] = floatx4{0.f, 0.f, 0.f, 0.f};
#pragma unroll
    for (int ks = 0; ks < 4; ks++) {
        short8 a0 = *(const short8*)(&As[(wr + ln) * PJ_STR + ks * 32 + q * 8]);
        short8 a1 = *(const short8*)(&As[(wr + 16 + ln) * PJ_STR + ks * 32 + q * 8]);
#pragma unroll
        for (int j = 0; j < 4; j++) {
            short8 b = *(const short8*)(&Bs[(j * 16 + ln) * PJ_STR + ks * 32 + q * 8]);
            acc[0][j] = __builtin_amdgcn_mfma_f32_16x16x32_bf16(a0, b, acc[0][j], 0, 0, 0);
            acc[1][j] = __builtin_amdgcn_mfma_f32_16x16x32_bf16(a1, b, acc[1][j], 0, 0, 0);
        }
    }
    // epilogue: row=wr+rt*16+q*4+r -> n; col d=j*16+ln; +pb at k==0
#pragma unroll
    for (int rt = 0; rt < 2; rt++)
#pragma unroll
        for (int j = 0; j < 4; j++) {
            int d = j * 16 + ln;
            float bv = (k == 0) ? pb[d] : 0.f;
#pragma unroll
            for (int r = 0; r < 4; r++) {
                int n = n0 + wr + rt * 16 + q * 4 + r;
                out[(size_t)n * 1600 + k * 64 + d] = acc[rt][j][r] + bv;
            }
        }
}

extern "C" void kernel_launch(void* const* d_in, const int* in_sizes, int n_in,
                              void* d_out, int out_size, void* d_ws, size_t ws_size,
                              hipStream_t stream) {
    const float* nf      = (const float*)d_in[0];
    const int* species   = (const int*)d_in[1];
    const float* dist    = (const float*)d_in[2];
    const int* snd       = (const int*)d_in[3];
    const int* rcv       = (const int*)d_in[4];
    const float* wig     = (const float*)d_in[5];
    const float* semb    = (const float*)d_in[6];
    const float* remb    = (const float*)d_in[7];
    const float* rad_w1  = (const float*)d_in[8];
    const float* rad_b1  = (const float*)d_in[9];
    const float* rad_g1  = (const float*)d_in[10];
    const float* rad_be1 = (const float*)d_in[11];
    const float* rad_w2  = (const float*)d_in[12];
    const float* rad_b2  = (const float*)d_in[13];
    const float* rad_g2  = (const float*)d_in[14];
    const float* rad_be2 = (const float*)d_in[15];
    const float* rad_w3  = (const float*)d_in[16];
    const float* rad_b3  = (const float*)d_in[17];
    const float* c1_w0   = (const float*)d_in[18];
    const float* c1_b0   = (const float*)d_in[19];
    const float* c1_wm1  = (const float*)d_in[20];
    const float* c1_wm2  = (const float*)d_in[21];
    const float* aln_g   = (const float*)d_in[22];
    const float* aln_b   = (const float*)d_in[23];
    const float* adot    = (const float*)d_in[24];
    const float* to_grid = (const float*)d_in[25];
    const float* from_grid=(const float*)d_in[26];
    const float* c2_w0   = (const float*)d_in[27];
    const float* c2_b0   = (const float*)d_in[28];
    const float* c2_wm1  = (const float*)d_in[29];
    const float* c2_wm2  = (const float*)d_in[30];
    const float* proj_w  = (const float*)d_in[31];
    const float* proj_b  = (const float*)d_in[32];

    char* ws = (char*)d_ws;
    size_t off = 0;
    auto take = [&](size_t bytes) -> char* {
        char* p = ws + off;
        off += (bytes + 255) & ~(size_t)255;
        return p;
    };
    // fixed section
    u16* w_rad1T  = (u16*)take(64 * 192 * 2);
    u16* w_rad2T  = (u16*)take(64 * 64 * 2);
    u16* w_rad3T  = (u16*)take(1536 * 64 * 2);
    u16* w_c1w0T  = (u16*)take(640 * 640 * 2);
    u16* w_c1m1T  = (u16*)take((size_t)512 * 1024 * 2);
    u16* w_c1m2T  = (u16*)take((size_t)384 * 768 * 2);
    u16* w_c2w0T  = (u16*)take((size_t)640 * 320 * 2);
    u16* w_c2m1T  = (u16*)take((size_t)1024 * 512 * 2);
    u16* w_c2m2T  = (u16*)take((size_t)768 * 384 * 2);
    u16* w_tgP    = (u16*)take(112 * 32 * 2);
    u16* w_fgP    = (u16*)take(32 * 128 * 2);
    u16* w_pwT    = (u16*)take(5 * 8192 * 2);
    float* logits = (float*)take((size_t)E_EDGES * 8 * 4);
    float* ealpha = (float*)take((size_t)E_EDGES * 8 * 4);
    u32* nmax     = (u32*)take((size_t)N_NODES_C * 8 * 4);
    float* nsum   = (float*)take((size_t)N_NODES_C * 8 * 4);
    float* node   = (float*)take((size_t)N_NODES_C * 3200 * 4);
    u16* a_h2     = (u16*)take((size_t)E_EDGES * 64 * 2);
    u32* c_deg    = (u32*)take((size_t)N_NODES_C * 4);
    u32* c_row    = (u32*)take((size_t)N_NODES_C * 4);
    u32* c_cur    = (u32*)take((size_t)N_NODES_C * 4);
    int* c_elist  = (int*)take((size_t)E_EDGES * 4);
    // arena — aliased by phase
    char* arena   = take(173015040);
    if (off > ws_size) {  // diagnostic: paint output so the failure mode is identifiable
        k_diag<<<(out_size + 255) / 256, 256, 0, stream>>>((float*)d_out, out_size);
        return;
    }

    u16* a_ee   = (u16*)(arena + 0);           // radial phase
    u16* a_ypre = (u16*)(arena + 9437184);
    u16* a_h1   = (u16*)(arena + 12582912);
    u16* a_xe   = (u16*)(arena + 0);           // per-chunk (EC,1536); radial staging dead
    u16* a_A1   = (u16*)(arena + 37748736);    // per-chunk (EC,2432)
    u16* a_Y0   = (u16*)(arena + 97517568);    // full (E,640)
    u16* a_Y1   = (u16*)(arena + 128974848);   // full (E,512)
    u16* a_Y2   = (u16*)(arena + 154140672);   // full (E,384) -> arena end
    u16* a_A2   = (u16*)(arena + 0);           // full (E,1216); xe/A1 dead
    u16* a_Z0   = (u16*)(arena + 59768832);    // per-chunk (EC,640)
    u16* a_Z1   = (u16*)(arena + 75497472);    // per-chunk (EC,1024)
    u16* a_Z2   = (u16*)(arena + 100663296);   // per-chunk (EC,768); overlaps dead Y0 region

    // ---- weight prep ----
    k_transpose<<<48, 256, 0, stream>>>(rad_w1, w_rad1T, 192, 64);
    k_transpose<<<16, 256, 0, stream>>>(rad_w2, w_rad2T, 64, 64);
    k_transpose<<<384, 256, 0, stream>>>(rad_w3, w_rad3T, 64, 1536);
    k_transpose<<<1600, 256, 0, stream>>>(c1_w0, w_c1w0T, 640, 640);
    k_transpose<<<800, 256, 0, stream>>>(c2_w0, w_c2w0T, 320, 640);
    k_combine<<<2048, 256, 0, stream>>>(c1_wm1, w_c1m1T, 512, 256);
    k_combine<<<1152, 256, 0, stream>>>(c1_wm2, w_c1m2T, 384, 192);
    k_combine<<<2048, 256, 0, stream>>>(c2_wm1, w_c2m1T, 256, 512);
    k_combine<<<1152, 256, 0, stream>>>(c2_wm2, w_c2m2T, 192, 384);
    k_packgrid<<<30, 256, 0, stream>>>(to_grid, from_grid, w_tgP, w_fgP);
    for (int l = 0; l < 5; l++)
        k_transpose<<<32, 256, 0, stream>>>(proj_w + (size_t)l * 8192, w_pwT + (size_t)l * 8192, 128, 64);
    k_init<<<128, 256, 0, stream>>>(nmax, nsum, N_NODES_C * 8);

    // ---- CSR build (receivers static per launch) ----
    hipMemsetAsync(c_deg, 0, (size_t)N_NODES_C * 4, stream);
    k_deg<<<96, 256, 0, stream>>>(rcv, c_deg);
    k_pfx<<<1, 256, 0, stream>>>(c_deg, c_row, c_cur);
    k_fill<<<96, 256, 0, stream>>>(rcv, c_cur, c_elist);

    // ---- radial MLP (full E) ----
    k_ee<<<(E_EDGES * 192 + 255) / 256, 256, 0, stream>>>(dist, species, snd, rcv, semb, remb, a_ee);
    k_gemm<<<dim3(192, 1), 256, 0, stream>>>(a_ee, 192, w_rad1T, 192, a_ypre, 64, 64, 192, rad_b1);
    k_ln_silu<<<6144, 256, 0, stream>>>(a_ypre, a_h1, rad_g1, rad_be1);
    k_gemm<<<dim3(192, 1), 256, 0, stream>>>(a_h1, 64, w_rad2T, 64, a_ypre, 64, 64, 64, rad_b2);
    k_ln_silu<<<6144, 256, 0, stream>>>(a_ypre, a_h2, rad_g2, rad_be2);

    // ---- chunked: x_edge gemm -> rotate -> conv1 ----
    for (int c = 0; c < 2; c++) {
        int e0 = c * EC;
        k_gemm<<<dim3(96, 12), 256, 0, stream>>>(a_h2 + (size_t)e0 * 64, 64, w_rad3T, 64,
                                                 a_xe, 1536, 1536, 64, rad_b3);
        k_rotate<<<EC / 2, 256, 0, stream>>>(nf, wig, snd, rcv, a_xe, a_A1, e0);
        k_gemm<<<dim3(96, 5), 256, 0, stream>>>(a_A1, 2432, w_c1w0T, 640,
                                                a_Y0 + (size_t)e0 * 640, 640, 640, 640, c1_b0);
        k_gemm<<<dim3(96, 4), 256, 0, stream>>>(a_A1 + 640, 2432, w_c1m1T, 1024,
                                                a_Y1 + (size_t)e0 * 512, 512, 512, 1024, nullptr);
        k_gemm<<<dim3(96, 3), 256, 0, stream>>>(a_A1 + 1664, 2432, w_c1m2T, 768,
                                                a_Y2 + (size_t)e0 * 384, 384, 384, 768, nullptr);
    }

    // ---- attention softmax pieces ----
    k_logits<<<E_EDGES, 256, 0, stream>>>(a_Y0, rcv, aln_g, aln_b, adot, logits, nmax);
    k_expsum<<<(E_EDGES * 8 + 255) / 256, 256, 0, stream>>>(logits, rcv, nmax, ealpha, nsum);

    // ---- grid nonlinearity -> packed A2 (full E, MFMA) ----
    k_grid_mfma<<<E_EDGES / 2, 256, 0, stream>>>(a_Y0, a_Y1, a_Y2, w_tgP, w_fgP, a_A2);

    // ---- chunked: conv2 -> gather (CSR, wave-per-node, no atomics/syncs) ----
    for (int c = 0; c < 2; c++) {
        int e0 = c * EC;
        k_gemm<<<dim3(96, 5), 256, 0, stream>>>(a_A2 + (size_t)e0 * 1216, 1216, w_c2w0T, 320,
                                                a_Z0, 640, 640, 320, c2_b0);
        k_gemm<<<dim3(96, 8), 256, 0, stream>>>(a_A2 + (size_t)e0 * 1216 + 320, 1216, w_c2m1T, 512,
                                                a_Z1, 1024, 1024, 512, nullptr);
        k_gemm<<<dim3(96, 6), 256, 0, stream>>>(a_A2 + (size_t)e0 * 1216 + 832, 1216, w_c2m2T, 384,
                                                a_Z2, 768, 768, 384, nullptr);
        k_gather<<<N_NODES_C / 4, 256, 0, stream>>>(a_Z0, a_Z1, a_Z2, wig, ealpha, nsum,
                                                    c_row, c_deg, c_elist, node, e0, c);
    }

    // ---- output projection (MFMA) ----
    k_proj_mfma<<<dim3(32, 25), 256, 0, stream>>>(node, w_pwT, proj_b, (float*)d_out);
}

// Round 6
// 1026.560 us; speedup vs baseline: 1.0683x; 1.0043x over previous
//
#include <hip/hip_runtime.h>

typedef unsigned short u16;
typedef unsigned int u32;
typedef __attribute__((ext_vector_type(8))) short short8;
typedef __attribute__((ext_vector_type(4))) float floatx4;

#define E_EDGES 24576
#define EC 12288            // edge chunk
#define N_NODES_C 4096

__device__ __forceinline__ float bf2f(u16 u) {
    union { u32 i; float f; } v; v.i = ((u32)u) << 16; return v.f;
}
__device__ __forceinline__ u16 f2bf(float f) {
    union { float f; u32 i; } v; v.f = f;
    u32 x = v.i;
    u32 r = (x + 0x7fffu + ((x >> 16) & 1u)) >> 16;
    return (u16)r;
}
// packed f32x2 -> bf16x2 in one VALU inst (RNE), no builtin on gfx950 -> inline asm
__device__ __forceinline__ u32 pk_bf16(float a, float b) {
    u32 r;
    asm("v_cvt_pk_bf16_f32 %0, %1, %2" : "=v"(r) : "v"(a), "v"(b));
    return r;
}
__device__ __forceinline__ u32 encf(float f) {
    union { float f; u32 i; } v; v.f = f;
    return (v.i & 0x80000000u) ? ~v.i : (v.i | 0x80000000u);
}
__device__ __forceinline__ float decf(u32 u) {
    union { u32 i; float f; } v;
    v.i = (u & 0x80000000u) ? (u ^ 0x80000000u) : ~u;
    return v.f;
}
// fast transcendentals: v_exp_f32 + v_rcp_f32
__device__ __forceinline__ float sigmoidf_(float x) { return __fdividef(1.f, 1.f + __expf(-x)); }
__device__ __forceinline__ float siluf_(float x) { return x * __fdividef(1.f, 1.f + __expf(-x)); }

// async global->LDS, 16B per lane; LDS dest must be wave-uniform base + lane*16
__device__ __forceinline__ void gld16(const u16* g, u16* l) {
    __builtin_amdgcn_global_load_lds((const __attribute__((address_space(1))) unsigned int*)g,
                                     (__attribute__((address_space(3))) unsigned int*)l, 16, 0, 0);
}

// diagnostic: ws too small -> paint output with 1000 (f32)
__global__ void k_diag(float* __restrict__ out, int n) {
    int i = blockIdx.x * 256 + threadIdx.x;
    if (i < n) out[i] = 1000.0f;
}

// ---------------- weight prep (f32 src -> bf16 transposed) ----------------
__global__ void k_transpose(const float* __restrict__ src, u16* __restrict__ dst, int K, int N) {
    int idx = blockIdx.x * 256 + threadIdx.x;
    if (idx >= K * N) return;
    int k = idx / N, n = idx % N;
    dst[n * K + k] = f2bf(src[idx]);
}
// combined complex weight, pre-transposed. src (K, 2H) f32: wa=cols[0:H), wb=cols[H:2H).
// dst (2H, 2K) bf16: dst[n][k] = k<K ? src[k][n] : (n<H ? -src[k-K][H+n] : src[k-K][n-H])
__global__ void k_combine(const float* __restrict__ src, u16* __restrict__ dst, int K, int H) {
    int total = 4 * K * H;
    int idx = blockIdx.x * 256 + threadIdx.x;
    if (idx >= total) return;
    int n = idx / (2 * K), k = idx % (2 * K);
    float v;
    if (k < K) v = src[k * 2 * H + n];
    else {
        int kk = k - K;
        if (n < H) v = -src[kk * 2 * H + H + n];
        else       v = src[kk * 2 * H + (n - H)];
    }
    dst[idx] = f2bf(v);
}

// pack to_grid (100,19) -> tgP[112][32] bf16; pack from_grid (19,100) -> fgP[32][128] bf16
__global__ void k_packgrid(const float* __restrict__ tg, const float* __restrict__ fg,
                           u16* __restrict__ tgP, u16* __restrict__ fgP) {
    int idx = blockIdx.x * 256 + threadIdx.x;
    if (idx < 112 * 32) {
        int p = idx >> 5, m = idx & 31;
        tgP[idx] = (p < 100 && m < 19) ? f2bf(tg[p * 19 + m]) : (u16)0;
    }
    int j = idx - 112 * 32;
    if (j >= 0 && j < 32 * 128) {
        int m = j >> 7, k = j & 127;
        fgP[j] = (m < 19 && k < 100) ? f2bf(fg[m * 100 + k]) : (u16)0;
    }
}

__global__ void k_init(u32* __restrict__ nmax, float* __restrict__ nsum, int n) {
    int idx = blockIdx.x * 256 + threadIdx.x;
    if (idx < n) { nmax[idx] = 0x007FFFFFu; /* enc(-inf) */ nsum[idx] = 0.f; }
}

// ---------------- CSR build over receivers (static per launch) ----------------
__global__ void k_deg(const int* __restrict__ rcv, u32* __restrict__ deg) {
    int e = blockIdx.x * 256 + threadIdx.x;
    if (e < E_EDGES) atomicAdd(&deg[rcv[e]], 1u);
}
__global__ __launch_bounds__(256) void k_pfx(const u32* __restrict__ deg,
                                             u32* __restrict__ rowstart, u32* __restrict__ cur) {
    __shared__ u32 ps[256];
    int t = threadIdx.x;
    u32 loc[16]; u32 s = 0;
#pragma unroll
    for (int i = 0; i < 16; i++) { loc[i] = s; s += deg[t * 16 + i]; }
    ps[t] = s;
    __syncthreads();
    for (int o = 1; o < 256; o <<= 1) {
        u32 v = (t >= o) ? ps[t - o] : 0u;
        __syncthreads();
        ps[t] += v;
        __syncthreads();
    }
    u32 base = (t == 0) ? 0u : ps[t - 1];
#pragma unroll
    for (int i = 0; i < 16; i++) { u32 v = base + loc[i]; rowstart[t * 16 + i] = v; cur[t * 16 + i] = v; }
}
__global__ void k_fill(const int* __restrict__ rcv, u32* __restrict__ cur, int* __restrict__ elist) {
    int e = blockIdx.x * 256 + threadIdx.x;
    if (e < E_EDGES) { u32 p = atomicAdd(&cur[rcv[e]], 1u); elist[p] = e; }
}

// ---------------- edge embeddings (f32 in -> bf16 A) ----------------
__global__ void k_ee(const float* __restrict__ dist, const int* __restrict__ species,
                     const int* __restrict__ snd, const int* __restrict__ rcv,
                     const float* __restrict__ semb, const float* __restrict__ remb,
                     u16* __restrict__ ee) {
    int idx = blockIdx.x * 256 + threadIdx.x;
    if (idx >= E_EDGES * 192) return;
    int e = idx / 192, c = idx % 192;
    float v;
    if (c < 64)       v = dist[e * 64 + c];
    else if (c < 128) v = semb[species[snd[e]] * 64 + (c - 64)];
    else              v = remb[species[rcv[e]] * 64 + (c - 128)];
    ee[idx] = f2bf(v);
}

// ---------------- GEMM (m97 structure): A (M,K) bf16 rm, BT (N,K) bf16 rm, C (M,N) bf16 ----------------
// global_load_lds staging, unpadded 64B rows. M%128==0, K%32==0; N%64==0 guarded.
// Explicit s_waitcnt vmcnt(0) before barrier — async LDS-DMA must drain (round-6 race fix).
// Operand-swapped MFMA (mfma(b,a)): lane holds 4 CONSECUTIVE COLS at one row ->
// epilogue = 2 cvt_pk + 1 uint2 store per quadrant (was 4x f2bf + 4 scalar u16 stores,
// stride-ldc). ~250 VALU insts/thread saved; dominates at our small-K shapes.
__global__ __launch_bounds__(256) void k_gemm(
    const u16* __restrict__ A, int lda,
    const u16* __restrict__ BT, int ldb,
    u16* __restrict__ C, int ldc,
    int N, int K,
    const float* __restrict__ bias) {
    __shared__ u16 As[128 * 32];
    __shared__ u16 Bs[128 * 32];
    int tid = threadIdx.x;
    int bm0 = blockIdx.x * 128;
    int bn0 = blockIdx.y * 128;
    int wave = tid >> 6, lane = tid & 63;
    int wm = (wave >> 1) * 64, wn = (wave & 1) * 64;
    int lrow = lane & 15, lk = (lane >> 4) * 8;

    // staging geometry: wave w covers rows w*16 + (lane>>2), 16B chunk (lane&3)
    int srow = (wave << 4) + (lane >> 2);        // 0..63
    int schunk = (lane & 3) << 3;                // u16 offset 0/8/16/24
    const u16* Arow0 = A + (size_t)(bm0 + srow) * lda + schunk;
    const u16* Arow1 = A + (size_t)(bm0 + srow + 64) * lda + schunk;
    int n0 = bn0 + srow;      if (n0 >= N) n0 = N - 1;
    int n1 = bn0 + srow + 64; if (n1 >= N) n1 = N - 1;
    const u16* Brow0 = BT + (size_t)n0 * ldb + schunk;
    const u16* Brow1 = BT + (size_t)n1 * ldb + schunk;
    u16* lA0 = &As[srow * 32 + schunk];
    u16* lA1 = &As[(srow + 64) * 32 + schunk];
    u16* lB0 = &Bs[srow * 32 + schunk];
    u16* lB1 = &Bs[(srow + 64) * 32 + schunk];

    floatx4 acc[4][4];
#pragma unroll
    for (int i = 0; i < 4; i++)
#pragma unroll
        for (int j = 0; j < 4; j++) acc[i][j] = floatx4{0.f, 0.f, 0.f, 0.f};

    for (int k0 = 0; k0 < K; k0 += 32) {
        gld16(Arow0 + k0, lA0);
        gld16(Arow1 + k0, lA1);
        gld16(Brow0 + k0, lB0);
        gld16(Brow1 + k0, lB1);
        asm volatile("s_waitcnt vmcnt(0)" ::: "memory");
        __syncthreads();
        short8 a[4], b[4];
#pragma unroll
        for (int i = 0; i < 4; i++) a[i] = *(const short8*)(&As[(wm + i * 16 + lrow) * 32 + lk]);
#pragma unroll
        for (int j = 0; j < 4; j++) b[j] = *(const short8*)(&Bs[(wn + j * 16 + lrow) * 32 + lk]);
#pragma unroll
        for (int i = 0; i < 4; i++)
#pragma unroll
            for (int j = 0; j < 4; j++)
                acc[i][j] = __builtin_amdgcn_mfma_f32_16x16x32_bf16(b[j], a[i], acc[i][j], 0, 0, 0);
        __syncthreads();
    }

    // epilogue: n-dim (lane&15) = output row from a[i]; m-dim ((lane>>4)*4+r) = output col from b[j]
    int q = lane >> 4;
#pragma unroll
    for (int i = 0; i < 4; i++) {
        int row = bm0 + wm + i * 16 + lrow;
#pragma unroll
        for (int j = 0; j < 4; j++) {
            int col = bn0 + wn + j * 16 + q * 4;
            if (col < N) {          // N%64==0, col%4==0 -> whole quad in-bounds
                float4 bv = bias ? *(const float4*)(&bias[col]) : float4{0.f, 0.f, 0.f, 0.f};
                uint2 pv;
                pv.x = pk_bf16(acc[i][j][0] + bv.x, acc[i][j][1] + bv.y);
                pv.y = pk_bf16(acc[i][j][2] + bv.z, acc[i][j][3] + bv.w);
                *(uint2*)(&C[(size_t)row * ldc + col]) = pv;
            }
        }
    }
}

// ---------------- LayerNorm(64) + SiLU (bf16 io, f32 params) ----------------
__global__ __launch_bounds__(256) void k_ln_silu(const u16* __restrict__ in, u16* __restrict__ out,
                                                 const float* __restrict__ g, const float* __restrict__ b) {
    int tid = threadIdx.x;
    int e = blockIdx.x * 4 + (tid >> 6);
    int c = tid & 63;
    float x = bf2f(in[(size_t)e * 64 + c]);
    float s = x, s2 = x * x;
#pragma unroll
    for (int o = 32; o; o >>= 1) { s += __shfl_xor(s, o); s2 += __shfl_xor(s2, o); }
    float mu = s * (1.f / 64.f);
    float var = s2 * (1.f / 64.f) - mu * mu;
    float rs = rsqrtf(var + 1e-5f);
    float y = (x - mu) * rs * g[c] + b[c];
    out[(size_t)e * 64 + c] = f2bf(siluf_(y));
}

// ---------------- rotate: wigner @ concat(nf[snd],nf[rcv]); scale by x_edge; pack A1 (chunked) ----------------
__global__ __launch_bounds__(256) void k_rotate(const float* __restrict__ nf, const float* __restrict__ wig,
                                                const int* __restrict__ snd, const int* __restrict__ rcv,
                                                const u16* __restrict__ xe, u16* __restrict__ A1, int e0) {
    __shared__ float wl[2][475];
    int tid = threadIdx.x;
    for (int i = tid; i < 950; i += 256) {
        int ee = e0 + blockIdx.x * 2 + (i / 475);
        wl[i / 475][i % 475] = wig[(size_t)ee * 475 + (i % 475)];
    }
    __syncthreads();
    int le = tid >> 7, c = tid & 127;
    int el = blockIdx.x * 2 + le;       // chunk-local
    int e = e0 + el;                    // global
    int nd = (c < 64) ? snd[e] : rcv[e];
    int cc = c & 63;
    float msg[25];
#pragma unroll
    for (int k = 0; k < 25; k++) msg[k] = nf[(size_t)nd * 1600 + k * 64 + cc];
    const float* w = wl[le];
    size_t ebase = (size_t)el * 2432;
    size_t xbase = (size_t)el * 1536;
#pragma unroll
    for (int m = 0; m < 19; m++) {
        float r = 0.f;
#pragma unroll
        for (int k = 0; k < 25; k++) r += w[m * 25 + k] * msg[k];
        int a1c, xc;
        if (m < 5)       { a1c = m * 128;               xc = m * 128; }
        else if (m < 9)  { a1c = 640 + (m - 5) * 128;   xc = 640 + (m - 5) * 128; }
        else if (m < 13) { a1c = 1152 + (m - 9) * 128;  xc = 640 + (m - 9) * 128; }
        else if (m < 16) { a1c = 1664 + (m - 13) * 128; xc = 1152 + (m - 13) * 128; }
        else             { a1c = 2048 + (m - 16) * 128; xc = 1152 + (m - 16) * 128; }
        float sc = bf2f(xe[xbase + xc + c]);
        A1[ebase + a1c + c] = f2bf(r * sc);
    }
}

// ---------------- attention logits + segment max ----------------
__global__ __launch_bounds__(256) void k_logits(const u16* __restrict__ Y0, const int* __restrict__ rcv,
                                                const float* __restrict__ g, const float* __restrict__ b,
                                                const float* __restrict__ adot,
                                                float* __restrict__ logits, u32* __restrict__ nmax) {
    int e = blockIdx.x;
    int tid = threadIdx.x;
    int h = tid >> 5, c = tid & 31;
    float x = bf2f(Y0[(size_t)e * 640 + 320 + h * 32 + c]);
    float s = x, s2 = x * x;
#pragma unroll
    for (int o = 16; o; o >>= 1) { s += __shfl_xor(s, o); s2 += __shfl_xor(s2, o); }
    float mu = s * (1.f / 32.f);
    float var = s2 * (1.f / 32.f) - mu * mu;
    float rs = rsqrtf(var + 1e-5f);
    float a = (x - mu) * rs * g[c] + b[c];
    float f = 0.6f * a + 0.4f * a * (2.f * sigmoidf_(a) - 1.f);
    float l = f * adot[h * 32 + c];
#pragma unroll
    for (int o = 16; o; o >>= 1) l += __shfl_xor(l, o);
    if (c == 0) {
        logits[e * 8 + h] = l;
        atomicMax(&nmax[rcv[e] * 8 + h], encf(l));
    }
}

__global__ void k_expsum(const float* __restrict__ logits, const int* __restrict__ rcv,
                         const u32* __restrict__ nmax, float* __restrict__ ealpha, float* __restrict__ nsum) {
    int idx = blockIdx.x * 256 + threadIdx.x;
    if (idx >= E_EDGES * 8) return;
    int e = idx >> 3, h = idx & 7;
    int r = rcv[e];
    float amax = decf(nmax[r * 8 + h]);
    if (!(amax > -1e38f && amax < 1e38f)) amax = 0.f;
    float v = __expf(logits[idx] - amax);
    ealpha[idx] = v;
    atomicAdd(&nsum[r * 8 + h], v);
}

// ---------------- grid round-trip via MFMA ----------------
// LDS: Xs aliased into T1s (Xs fully consumed into registers before T1s written).
#define GR_XS_STR 40
#define GR_T1_STR 136
__global__ __launch_bounds__(256) void k_grid_mfma(
    const u16* __restrict__ Y0, const u16* __restrict__ Y1, const u16* __restrict__ Y2,
    const u16* __restrict__ tgP, const u16* __restrict__ fgP, u16* __restrict__ A2) {
    __shared__ u16 T1s[128 * GR_T1_STR];
    u16* Xs = T1s;                       // alias: see barrier discipline below
    int tid = threadIdx.x;
    int e0 = blockIdx.x * 2;
    // stage Xs[ec][m]: thread owns (le, c0-block, m-pair); packed u32 writes
    {
        int mp = tid & 15;                  // m-pair 0..15 -> m = 2mp, 2mp+1
        int c0 = ((tid >> 4) & 7) << 3;     // channel block 0..56
        int le = tid >> 7;                  // local edge 0/1
        int e = e0 + le;
        int m0 = 2 * mp, m1 = m0 + 1;
        uint4 va = {0, 0, 0, 0}, vb = {0, 0, 0, 0};
        if (m0 < 5)       va = *(const uint4*)(&Y0[(size_t)e * 640 + m0 * 64 + c0]);
        else if (m0 < 13) va = *(const uint4*)(&Y1[(size_t)e * 512 + (m0 - 5) * 64 + c0]);
        else if (m0 < 19) va = *(const uint4*)(&Y2[(size_t)e * 384 + (m0 - 13) * 64 + c0]);
        if (m1 < 5)       vb = *(const uint4*)(&Y0[(size_t)e * 640 + m1 * 64 + c0]);
        else if (m1 < 13) vb = *(const uint4*)(&Y1[(size_t)e * 512 + (m1 - 5) * 64 + c0]);
        else if (m1 < 19) vb = *(const uint4*)(&Y2[(size_t)e * 384 + (m1 - 13) * 64 + c0]);
        const u16* pa = (const u16*)&va;
        const u16* pb = (const u16*)&vb;
        int rbase = le * 64 + c0;
#pragma unroll
        for (int j = 0; j < 8; j++) {
            u32 w = (u32)pa[j] | ((u32)pb[j] << 16);
            *(u32*)(&Xs[(rbase + j) * GR_XS_STR + 2 * mp]) = w;
        }
    }
    __syncthreads();
    int wave = tid >> 6, lane = tid & 63;
    int wn = wave << 5;                     // this wave's 32 ec-columns
    int ln = lane & 15, q = lane >> 4;
    // GEMM1 (swapped): A = tgP (p x m), B^T = Xs (ec x m). Out rows = p, cols = ec.
    short8 bx0 = *(const short8*)(&Xs[(wn + ln) * GR_XS_STR + q * 8]);
    short8 bx1 = *(const short8*)(&Xs[(wn + 16 + ln) * GR_XS_STR + q * 8]);
    floatx4 acc1[2][7];
#pragma unroll
    for (int pt = 0; pt < 7; pt++) {
        short8 a = *(const short8*)(&tgP[(size_t)(pt * 16 + ln) * 32 + q * 8]);
        acc1[0][pt] = __builtin_amdgcn_mfma_f32_16x16x32_bf16(a, bx0, floatx4{0.f, 0.f, 0.f, 0.f}, 0, 0, 0);
        acc1[1][pt] = __builtin_amdgcn_mfma_f32_16x16x32_bf16(a, bx1, floatx4{0.f, 0.f, 0.f, 0.f}, 0, 0, 0);
    }
    __syncthreads();    // all Xs reads complete -> safe to overwrite (alias)
    // zero T1s pad cols 112..127 (cols 100..111 are exact zeros from the zeroed tgP rows)
    {
        int row = tid >> 1;
        uint4 z = {0, 0, 0, 0};
        *(uint4*)(&T1s[row * GR_T1_STR + 112 + (tid & 1) * 8]) = z;
    }
    // silu -> T1s[ec][p]: lane holds p = pt*16 + q*4 + r at ec = wn + i*16 + ln -> b64 writes
#pragma unroll
    for (int i = 0; i < 2; i++) {
        u16* dst = &T1s[(wn + i * 16 + ln) * GR_T1_STR + q * 4];
#pragma unroll
        for (int pt = 0; pt < 7; pt++) {
            uint2 pv;
            pv.x = pk_bf16(siluf_(acc1[i][pt][0]), siluf_(acc1[i][pt][1]));
            pv.y = pk_bf16(siluf_(acc1[i][pt][2]), siluf_(acc1[i][pt][3]));
            *(uint2*)(dst + pt * 16) = pv;
        }
    }
    __syncthreads();
    // GEMM2: K=128 (4 steps)
    floatx4 acc2[2][2];
    acc2[0][0] = floatx4{0.f, 0.f, 0.f, 0.f}; acc2[0][1] = floatx4{0.f, 0.f, 0.f, 0.f};
    acc2[1][0] = floatx4{0.f, 0.f, 0.f, 0.f}; acc2[1][1] = floatx4{0.f, 0.f, 0.f, 0.f};
#pragma unroll
    for (int ks = 0; ks < 4; ks++) {
        short8 c0 = *(const short8*)(&T1s[(wn + ln) * GR_T1_STR + ks * 32 + q * 8]);
        short8 c1 = *(const short8*)(&T1s[(wn + 16 + ln) * GR_T1_STR + ks * 32 + q * 8]);
#pragma unroll
        for (int ct = 0; ct < 2; ct++) {
            short8 b = *(const short8*)(&fgP[(size_t)(ct * 16 + ln) * 128 + ks * 32 + q * 8]);
            acc2[0][ct] = __builtin_amdgcn_mfma_f32_16x16x32_bf16(c0, b, acc2[0][ct], 0, 0, 0);
            acc2[1][ct] = __builtin_amdgcn_mfma_f32_16x16x32_bf16(c1, b, acc2[1][ct], 0, 0, 0);
        }
    }
    // direct store: lane holds col m'=ct*16+ln, rows q*4+r -> 4 consecutive c in A2
#pragma unroll
    for (int rt = 0; rt < 2; rt++) {
        int row = wn + rt * 16 + q * 4;
        int e = e0 + (row >> 6), c = row & 63;
#pragma unroll
        for (int ct = 0; ct < 2; ct++) {
            int mp = ct * 16 + ln;
            if (mp >= 1 && mp < 19) {
                uint2 pv;
                pv.x = pk_bf16(acc2[rt][ct][0], acc2[rt][ct][1]);
                pv.y = pk_bf16(acc2[rt][ct][2], acc2[rt][ct][3]);
                *(uint2*)(&A2[(size_t)e * 1216 + mp * 64 + c]) = pv;
            }
        }
    }
    // m=0 gate row
    if (tid < 128) {
        int e = e0 + (tid >> 6), c = tid & 63;
        float gate = bf2f(Y0[(size_t)e * 640 + 576 + c]);
        A2[(size_t)e * 1216 + c] = f2bf(siluf_(gate));
    }
}

// ---------------- gather: attention scale + wigner^T + segment-sum (no atomics) ----------------
// WAVE-PER-NODE, zero-sync, zero-LDS. Lane owns channel pair (2l, 2l+1) via packed u32
// bf16 loads (256B coalesced per load). Edge loop is wave-private: 950 FMA wave-insts
// per edge hide the next edge's load latency; 16 waves/CU give 16 independent streams.
// Wigner pointer kept scalar via readfirstlane. Two passes over the Z chunks.
__global__ __launch_bounds__(256) void k_gather(
    const u16* __restrict__ Z0, const u16* __restrict__ Z1, const u16* __restrict__ Z2,
    const float* __restrict__ wig, const float* __restrict__ ealpha, const float* __restrict__ nsum,
    const u32* __restrict__ rowstart, const u32* __restrict__ deg, const int* __restrict__ elist,
    float* __restrict__ node, int e0, int accum) {
    int n = blockIdx.x * 4 + (threadIdx.x >> 6);
    int lane = threadIdx.x & 63;
    int h = lane >> 3;                  // head of channels 2l,2l+1 (same head for both)
    float sden = __fdividef(1.f, nsum[n * 8 + h] + 1e-16f);
    float a0[25], a1[25];
#pragma unroll
    for (int k = 0; k < 25; k++) { a0[k] = 0.f; a1[k] = 0.f; }
    u32 lo = rowstart[n], cnt = deg[n];
    bool did = false;
    for (u32 i = 0; i < cnt; i++) {
        int e = __builtin_amdgcn_readfirstlane(elist[lo + i]);
        int el = e - e0;
        if ((u32)el >= (u32)EC) continue;       // wave-uniform
        did = true;
        float al = ealpha[e * 8 + h] * sden;
        // 19 packed z loads (2 bf16 channels per lane), all independent
        u32 zp[19];
        const u16* z0 = Z0 + (size_t)el * 640 + 2 * lane;
        const u16* z1 = Z1 + (size_t)el * 1024 + 2 * lane;
        const u16* z2 = Z2 + (size_t)el * 768 + 2 * lane;
#pragma unroll
        for (int m = 0; m < 5; m++) zp[m] = *(const u32*)(z0 + m * 128);
#pragma unroll
        for (int m = 0; m < 8; m++) zp[5 + m] = *(const u32*)(z1 + m * 128);
#pragma unroll
        for (int m = 0; m < 6; m++) zp[13 + m] = *(const u32*)(z2 + m * 128);
        const float* __restrict__ w = wig + (size_t)e * 475;
#pragma unroll
        for (int m = 0; m < 19; m++) {
            float s0 = bf2f((u16)(zp[m] & 0xffffu)) * al;
            float s1 = bf2f((u16)(zp[m] >> 16)) * al;
#pragma unroll
            for (int k = 0; k < 25; k++) {
                float wv = w[m * 25 + k];
                a0[k] = fmaf(wv, s0, a0[k]);
                a1[k] = fmaf(wv, s1, a1[k]);
            }
        }
    }
    float* nb = node + (size_t)n * 3200 + 2 * lane;
    if (accum) {
        if (!did) return;                       // wave-uniform
#pragma unroll
        for (int k = 0; k < 25; k++) {
            float2 v = *(float2*)(&nb[k * 128]);
            v.x += a0[k]; v.y += a1[k];
            *(float2*)(&nb[k * 128]) = v;
        }
    } else {
#pragma unroll
        for (int k = 0; k < 25; k++) {
            float2 v; v.x = a0[k]; v.y = a1[k];
            *(float2*)(&nb[k * 128]) = v;
        }
    }
}

// ---------------- final projection via MFMA ----------------
// grid (32 n-tiles, 25 k). Block: M=128 n-rows, N=64 d, K=128 c.
// A = node (f32, stride 3200) -> bf16 LDS; B = pwTb[l] (64x128 bf16).
// Operand-swapped MFMA: lane holds 4 consecutive d at one n -> float4 stores.
#define PJ_STR 136
__global__ __launch_bounds__(256) void k_proj_mfma(
    const float* __restrict__ node, const u16* __restrict__ pwTb,
    const float* __restrict__ pb, float* __restrict__ out) {
    __shared__ u16 As[128 * PJ_STR];
    __shared__ u16 Bs[64 * PJ_STR];
    int tid = threadIdx.x;
    int n0 = blockIdx.x * 128;
    int k = blockIdx.y;
    int l = (int)sqrtf((float)k + 0.5f);
    // stage A: 128 rows x 128 c f32 -> bf16; thread i handles row=i>>5, c0=(i&31)*4
#pragma unroll
    for (int it = 0; it < 16; it++) {
        int i = tid + it * 256;
        int row = i >> 5;
        int c0 = (i & 31) << 2;
        float4 v = *(const float4*)(&node[(size_t)(n0 + row) * 3200 + k * 128 + c0]);
        uint2 pv;
        pv.x = pk_bf16(v.x, v.y);
        pv.y = pk_bf16(v.z, v.w);
        *(uint2*)(&As[row * PJ_STR + c0]) = pv;
    }
    // stage B: 64 rows (d) x 128 c bf16, 16B chunks
    const u16* pw = pwTb + (size_t)l * 8192;
#pragma unroll
    for (int jt = 0; jt < 4; jt++) {
        int j = tid + jt * 256;
        int d = j >> 4;
        int c0 = (j & 15) << 3;
        *(uint4*)(&Bs[d * PJ_STR + c0]) = *(const uint4*)(&pw[d * 128 + c0]);
    }
    __syncthreads();
    int wave = tid >> 6, lane = tid & 63;
    int wr = wave * 32;
    int ln = lane & 15, q = lane >> 4;
    floatx4 acc[2][4];
#pragma unroll
    for (int i = 0; i < 2; i++)
#pragma unroll
        for (int j = 0; j < 4; j++) acc[i][j] = floatx4{0.f, 0.f, 0.f, 0.f};
#pragma unroll
    for (int ks = 0; ks < 4; ks++) {
        short8 a0 = *(const short8*)(&As[(wr + ln) * PJ_STR + ks * 32 + q * 8]);
        short8 a1 = *(const short8*)(&As[(wr + 16 + ln) * PJ_STR + ks * 32 + q * 8]);
#pragma unroll
        for (int j = 0; j < 4; j++) {
            short8 b = *(const short8*)(&Bs[(j * 16 + ln) * PJ_STR + ks * 32 + q * 8]);
            acc[0][j] = __builtin_amdgcn_mfma_f32_16x16x32_bf16(b, a0, acc[0][j], 0, 0, 0);
            acc[1][j] = __builtin_amdgcn_mfma_f32_16x16x32_bf16(b, a1, acc[1][j], 0, 0, 0);
        }
    }
    // epilogue (swapped): n = n0+wr+rt*16+ln (row); d = j*16+q*4..+3 (4 consecutive cols)
#pragma unroll
    for (int rt = 0; rt < 2; rt++) {
        int n = n0 + wr + rt * 16 + ln;
#pragma unroll
        for (int j = 0; j < 4; j++) {
            int d = j * 16 + q * 4;
            float4 v;
            v.x = acc[rt][j][0]; v.y = acc[rt][j][1];
            v.z = acc[rt][j][2]; v.w = acc[rt][j][3];
            if (k == 0) {
                float4 bv = *(const float4*)(&pb[d]);
                v.x += bv.x; v.y += bv.y; v.z += bv.z; v.w += bv.w;
            }
            *(float4*)(&out[(size_t)n * 1600 + k * 64 + d]) = v;
        }
    }
}

extern "C" void kernel_launch(void* const* d_in, const int* in_sizes, int n_in,
                              void* d_out, int out_size, void* d_ws, size_t ws_size,
                              hipStream_t stream) {
    const float* nf      = (const float*)d_in[0];
    const int* species   = (const int*)d_in[1];
    const float* dist    = (const float*)d_in[2];
    const int* snd       = (const int*)d_in[3];
    const int* rcv       = (const int*)d_in[4];
    const float* wig     = (const float*)d_in[5];
    const float* semb    = (const float*)d_in[6];
    const float* remb    = (const float*)d_in[7];
    const float* rad_w1  = (const float*)d_in[8];
    const float* rad_b1  = (const float*)d_in[9];
    const float* rad_g1  = (const float*)d_in[10];
    const float* rad_be1 = (const float*)d_in[11];
    const float* rad_w2  = (const float*)d_in[12];
    const float* rad_b2  = (const float*)d_in[13];
    const float* rad_g2  = (const float*)d_in[14];
    const float* rad_be2 = (const float*)d_in[15];
    const float* rad_w3  = (const float*)d_in[16];
    const float* rad_b3  = (const float*)d_in[17];
    const float* c1_w0   = (const float*)d_in[18];
    const float* c1_b0   = (const float*)d_in[19];
    const float* c1_wm1  = (const float*)d_in[20];
    const float* c1_wm2  = (const float*)d_in[21];
    const float* aln_g   = (const float*)d_in[22];
    const float* aln_b   = (const float*)d_in[23];
    const float* adot    = (const float*)d_in[24];
    const float* to_grid = (const float*)d_in[25];
    const float* from_grid=(const float*)d_in[26];
    const float* c2_w0   = (const float*)d_in[27];
    const float* c2_b0   = (const float*)d_in[28];
    const float* c2_wm1  = (const float*)d_in[29];
    const float* c2_wm2  = (const float*)d_in[30];
    const float* proj_w  = (const float*)d_in[31];
    const float* proj_b  = (const float*)d_in[32];

    char* ws = (char*)d_ws;
    size_t off = 0;
    auto take = [&](size_t bytes) -> char* {
        char* p = ws + off;
        off += (bytes + 255) & ~(size_t)255;
        return p;
    };
    // fixed section
    u16* w_rad1T  = (u16*)take(64 * 192 * 2);
    u16* w_rad2T  = (u16*)take(64 * 64 * 2);
    u16* w_rad3T  = (u16*)take(1536 * 64 * 2);
    u16* w_c1w0T  = (u16*)take(640 * 640 * 2);
    u16* w_c1m1T  = (u16*)take((size_t)512 * 1024 * 2);
    u16* w_c1m2T  = (u16*)take((size_t)384 * 768 * 2);
    u16* w_c2w0T  = (u16*)take((size_t)640 * 320 * 2);
    u16* w_c2m1T  = (u16*)take((size_t)1024 * 512 * 2);
    u16* w_c2m2T  = (u16*)take((size_t)768 * 384 * 2);
    u16* w_tgP    = (u16*)take(112 * 32 * 2);
    u16* w_fgP    = (u16*)take(32 * 128 * 2);
    u16* w_pwT    = (u16*)take(5 * 8192 * 2);
    float* logits = (float*)take((size_t)E_EDGES * 8 * 4);
    float* ealpha = (float*)take((size_t)E_EDGES * 8 * 4);
    u32* nmax     = (u32*)take((size_t)N_NODES_C * 8 * 4);
    float* nsum   = (float*)take((size_t)N_NODES_C * 8 * 4);
    float* node   = (float*)take((size_t)N_NODES_C * 3200 * 4);
    u16* a_h2     = (u16*)take((size_t)E_EDGES * 64 * 2);
    u32* c_deg    = (u32*)take((size_t)N_NODES_C * 4);
    u32* c_row    = (u32*)take((size_t)N_NODES_C * 4);
    u32* c_cur    = (u32*)take((size_t)N_NODES_C * 4);
    int* c_elist  = (int*)take((size_t)E_EDGES * 4);
    // arena — aliased by phase
    char* arena   = take(173015040);
    if (off > ws_size) {  // diagnostic: paint output so the failure mode is identifiable
        k_diag<<<(out_size + 255) / 256, 256, 0, stream>>>((float*)d_out, out_size);
        return;
    }

    u16* a_ee   = (u16*)(arena + 0);           // radial phase
    u16* a_ypre = (u16*)(arena + 9437184);
    u16* a_h1   = (u16*)(arena + 12582912);
    u16* a_xe   = (u16*)(arena + 0);           // per-chunk (EC,1536); radial staging dead
    u16* a_A1   = (u16*)(arena + 37748736);    // per-chunk (EC,2432)
    u16* a_Y0   = (u16*)(arena + 97517568);    // full (E,640)
    u16* a_Y1   = (u16*)(arena + 128974848);   // full (E,512)
    u16* a_Y2   = (u16*)(arena + 154140672);   // full (E,384) -> arena end
    u16* a_A2   = (u16*)(arena + 0);           // full (E,1216); xe/A1 dead
    u16* a_Z0   = (u16*)(arena + 59768832);    // per-chunk (EC,640)
    u16* a_Z1   = (u16*)(arena + 75497472);    // per-chunk (EC,1024)
    u16* a_Z2   = (u16*)(arena + 100663296);   // per-chunk (EC,768); overlaps dead Y0 region

    // ---- weight prep ----
    k_transpose<<<48, 256, 0, stream>>>(rad_w1, w_rad1T, 192, 64);
    k_transpose<<<16, 256, 0, stream>>>(rad_w2, w_rad2T, 64, 64);
    k_transpose<<<384, 256, 0, stream>>>(rad_w3, w_rad3T, 64, 1536);
    k_transpose<<<1600, 256, 0, stream>>>(c1_w0, w_c1w0T, 640, 640);
    k_transpose<<<800, 256, 0, stream>>>(c2_w0, w_c2w0T, 320, 640);
    k_combine<<<2048, 256, 0, stream>>>(c1_wm1, w_c1m1T, 512, 256);
    k_combine<<<1152, 256, 0, stream>>>(c1_wm2, w_c1m2T, 384, 192);
    k_combine<<<2048, 256, 0, stream>>>(c2_wm1, w_c2m1T, 256, 512);
    k_combine<<<1152, 256, 0, stream>>>(c2_wm2, w_c2m2T, 192, 384);
    k_packgrid<<<30, 256, 0, stream>>>(to_grid, from_grid, w_tgP, w_fgP);
    for (int l = 0; l < 5; l++)
        k_transpose<<<32, 256, 0, stream>>>(proj_w + (size_t)l * 8192, w_pwT + (size_t)l * 8192, 128, 64);
    k_init<<<128, 256, 0, stream>>>(nmax, nsum, N_NODES_C * 8);

    // ---- CSR build (receivers static per launch) ----
    hipMemsetAsync(c_deg, 0, (size_t)N_NODES_C * 4, stream);
    k_deg<<<96, 256, 0, stream>>>(rcv, c_deg);
    k_pfx<<<1, 256, 0, stream>>>(c_deg, c_row, c_cur);
    k_fill<<<96, 256, 0, stream>>>(rcv, c_cur, c_elist);

    // ---- radial MLP (full E) ----
    k_ee<<<(E_EDGES * 192 + 255) / 256, 256, 0, stream>>>(dist, species, snd, rcv, semb, remb, a_ee);
    k_gemm<<<dim3(192, 1), 256, 0, stream>>>(a_ee, 192, w_rad1T, 192, a_ypre, 64, 64, 192, rad_b1);
    k_ln_silu<<<6144, 256, 0, stream>>>(a_ypre, a_h1, rad_g1, rad_be1);
    k_gemm<<<dim3(192, 1), 256, 0, stream>>>(a_h1, 64, w_rad2T, 64, a_ypre, 64, 64, 64, rad_b2);
    k_ln_silu<<<6144, 256, 0, stream>>>(a_ypre, a_h2, rad_g2, rad_be2);

    // ---- chunked: x_edge gemm -> rotate -> conv1 ----
    for (int c = 0; c < 2; c++) {
        int e0 = c * EC;
        k_gemm<<<dim3(96, 12), 256, 0, stream>>>(a_h2 + (size_t)e0 * 64, 64, w_rad3T, 64,
                                                 a_xe, 1536, 1536, 64, rad_b3);
        k_rotate<<<EC / 2, 256, 0, stream>>>(nf, wig, snd, rcv, a_xe, a_A1, e0);
        k_gemm<<<dim3(96, 5), 256, 0, stream>>>(a_A1, 2432, w_c1w0T, 640,
                                                a_Y0 + (size_t)e0 * 640, 640, 640, 640, c1_b0);
        k_gemm<<<dim3(96, 4), 256, 0, stream>>>(a_A1 + 640, 2432, w_c1m1T, 1024,
                                                a_Y1 + (size_t)e0 * 512, 512, 512, 1024, nullptr);
        k_gemm<<<dim3(96, 3), 256, 0, stream>>>(a_A1 + 1664, 2432, w_c1m2T, 768,
                                                a_Y2 + (size_t)e0 * 384, 384, 384, 768, nullptr);
    }

    // ---- attention softmax pieces ----
    k_logits<<<E_EDGES, 256, 0, stream>>>(a_Y0, rcv, aln_g, aln_b, adot, logits, nmax);
    k_expsum<<<(E_EDGES * 8 + 255) / 256, 256, 0, stream>>>(logits, rcv, nmax, ealpha, nsum);

    // ---- grid nonlinearity -> packed A2 (full E, MFMA) ----
    k_grid_mfma<<<E_EDGES / 2, 256, 0, stream>>>(a_Y0, a_Y1, a_Y2, w_tgP, w_fgP, a_A2);

    // ---- chunked: conv2 -> gather (CSR, wave-per-node, no atomics/syncs) ----
    for (int c = 0; c < 2; c++) {
        int e0 = c * EC;
        k_gemm<<<dim3(96, 5), 256, 0, stream>>>(a_A2 + (size_t)e0 * 1216, 1216, w_c2w0T, 320,
                                                a_Z0, 640, 640, 320, c2_b0);
        k_gemm<<<dim3(96, 8), 256, 0, stream>>>(a_A2 + (size_t)e0 * 1216 + 320, 1216, w_c2m1T, 512,
                                                a_Z1, 1024, 1024, 512, nullptr);
        k_gemm<<<dim3(96, 6), 256, 0, stream>>>(a_A2 + (size_t)e0 * 1216 + 832, 1216, w_c2m2T, 384,
                                                a_Z2, 768, 768, 384, nullptr);
        k_gather<<<N_NODES_C / 4, 256, 0, stream>>>(a_Z0, a_Z1, a_Z2, wig, ealpha, nsum,
                                                    c_row, c_deg, c_elist, node, e0, c);
    }

    // ---- output projection (MFMA) ----
    k_proj_mfma<<<dim3(32, 25), 256, 0, stream>>>(node, w_pwT, proj_b, (float*)d_out);
}

// Round 7
// 1016.155 us; speedup vs baseline: 1.0792x; 1.0102x over previous
//
#include <hip/hip_runtime.h>

typedef unsigned short u16;
typedef unsigned int u32;
typedef __attribute__((ext_vector_type(8))) short short8;
typedef __attribute__((ext_vector_type(4))) float floatx4;

#define E_EDGES 24576
#define EC 12288            // edge chunk
#define N_NODES_C 4096

__device__ __forceinline__ float bf2f(u16 u) {
    union { u32 i; float f; } v; v.i = ((u32)u) << 16; return v.f;
}
__device__ __forceinline__ u16 f2bf(float f) {
    union { float f; u32 i; } v; v.f = f;
    u32 x = v.i;
    u32 r = (x + 0x7fffu + ((x >> 16) & 1u)) >> 16;
    return (u16)r;
}
// packed f32x2 -> bf16x2 in one VALU inst (RNE), no builtin on gfx950 -> inline asm
__device__ __forceinline__ u32 pk_bf16(float a, float b) {
    u32 r;
    asm("v_cvt_pk_bf16_f32 %0, %1, %2" : "=v"(r) : "v"(a), "v"(b));
    return r;
}
__device__ __forceinline__ u32 encf(float f) {
    union { float f; u32 i; } v; v.f = f;
    return (v.i & 0x80000000u) ? ~v.i : (v.i | 0x80000000u);
}
__device__ __forceinline__ float decf(u32 u) {
    union { u32 i; float f; } v;
    v.i = (u & 0x80000000u) ? (u ^ 0x80000000u) : ~u;
    return v.f;
}
// fast transcendentals: v_exp_f32 + v_rcp_f32
__device__ __forceinline__ float sigmoidf_(float x) { return __fdividef(1.f, 1.f + __expf(-x)); }
__device__ __forceinline__ float siluf_(float x) { return x * __fdividef(1.f, 1.f + __expf(-x)); }

// async global->LDS, 16B per lane; LDS dest must be wave-uniform base + lane*16
__device__ __forceinline__ void gld16(const u16* g, u16* l) {
    __builtin_amdgcn_global_load_lds((const __attribute__((address_space(1))) unsigned int*)g,
                                     (__attribute__((address_space(3))) unsigned int*)l, 16, 0, 0);
}

// diagnostic: ws too small -> paint output with 1000 (f32)
__global__ void k_diag(float* __restrict__ out, int n) {
    int i = blockIdx.x * 256 + threadIdx.x;
    if (i < n) out[i] = 1000.0f;
}

// ---------------- weight prep (f32 src -> bf16 transposed) ----------------
__global__ void k_transpose(const float* __restrict__ src, u16* __restrict__ dst, int K, int N) {
    int idx = blockIdx.x * 256 + threadIdx.x;
    if (idx >= K * N) return;
    int k = idx / N, n = idx % N;
    dst[n * K + k] = f2bf(src[idx]);
}
// combined complex weight, pre-transposed. src (K, 2H) f32: wa=cols[0:H), wb=cols[H:2H).
// dst (2H, 2K) bf16: dst[n][k] = k<K ? src[k][n] : (n<H ? -src[k-K][H+n] : src[k-K][n-H])
__global__ void k_combine(const float* __restrict__ src, u16* __restrict__ dst, int K, int H) {
    int total = 4 * K * H;
    int idx = blockIdx.x * 256 + threadIdx.x;
    if (idx >= total) return;
    int n = idx / (2 * K), k = idx % (2 * K);
    float v;
    if (k < K) v = src[k * 2 * H + n];
    else {
        int kk = k - K;
        if (n < H) v = -src[kk * 2 * H + H + n];
        else       v = src[kk * 2 * H + (n - H)];
    }
    dst[idx] = f2bf(v);
}

// pack to_grid (100,19) -> tgP[112][32] bf16; pack from_grid (19,100) -> fgP[32][128] bf16
__global__ void k_packgrid(const float* __restrict__ tg, const float* __restrict__ fg,
                           u16* __restrict__ tgP, u16* __restrict__ fgP) {
    int idx = blockIdx.x * 256 + threadIdx.x;
    if (idx < 112 * 32) {
        int p = idx >> 5, m = idx & 31;
        tgP[idx] = (p < 100 && m < 19) ? f2bf(tg[p * 19 + m]) : (u16)0;
    }
    int j = idx - 112 * 32;
    if (j >= 0 && j < 32 * 128) {
        int m = j >> 7, k = j & 127;
        fgP[j] = (m < 19 && k < 100) ? f2bf(fg[m * 100 + k]) : (u16)0;
    }
}

__global__ void k_init(u32* __restrict__ nmax, float* __restrict__ nsum, int n) {
    int idx = blockIdx.x * 256 + threadIdx.x;
    if (idx < n) { nmax[idx] = 0x007FFFFFu; /* enc(-inf) */ nsum[idx] = 0.f; }
}

// ---------------- CSR build over receivers (static per launch) ----------------
__global__ void k_deg(const int* __restrict__ rcv, u32* __restrict__ deg) {
    int e = blockIdx.x * 256 + threadIdx.x;
    if (e < E_EDGES) atomicAdd(&deg[rcv[e]], 1u);
}
__global__ __launch_bounds__(256) void k_pfx(const u32* __restrict__ deg,
                                             u32* __restrict__ rowstart, u32* __restrict__ cur) {
    __shared__ u32 ps[256];
    int t = threadIdx.x;
    u32 loc[16]; u32 s = 0;
#pragma unroll
    for (int i = 0; i < 16; i++) { loc[i] = s; s += deg[t * 16 + i]; }
    ps[t] = s;
    __syncthreads();
    for (int o = 1; o < 256; o <<= 1) {
        u32 v = (t >= o) ? ps[t - o] : 0u;
        __syncthreads();
        ps[t] += v;
        __syncthreads();
    }
    u32 base = (t == 0) ? 0u : ps[t - 1];
#pragma unroll
    for (int i = 0; i < 16; i++) { u32 v = base + loc[i]; rowstart[t * 16 + i] = v; cur[t * 16 + i] = v; }
}
__global__ void k_fill(const int* __restrict__ rcv, u32* __restrict__ cur, int* __restrict__ elist) {
    int e = blockIdx.x * 256 + threadIdx.x;
    if (e < E_EDGES) { u32 p = atomicAdd(&cur[rcv[e]], 1u); elist[p] = e; }
}

// ---------------- edge embeddings (f32 in -> bf16 A) ----------------
__global__ void k_ee(const float* __restrict__ dist, const int* __restrict__ species,
                     const int* __restrict__ snd, const int* __restrict__ rcv,
                     const float* __restrict__ semb, const float* __restrict__ remb,
                     u16* __restrict__ ee) {
    int idx = blockIdx.x * 256 + threadIdx.x;
    if (idx >= E_EDGES * 192) return;
    int e = idx / 192, c = idx % 192;
    float v;
    if (c < 64)       v = dist[e * 64 + c];
    else if (c < 128) v = semb[species[snd[e]] * 64 + (c - 64)];
    else              v = remb[species[rcv[e]] * 64 + (c - 128)];
    ee[idx] = f2bf(v);
}

// ---------------- GEMM: A (M,K) bf16 rm, BT (N,K) bf16 rm, C (M,N) bf16 ----------------
// Double-buffered LDS staging with COUNTED vmcnt (T3 minimum-2-phase): tile t+1's
// global_load_lds issued BEFORE computing tile t; s_waitcnt vmcnt(4) waits only the
// 4 older loads, so HBM/L2 latency overlaps MFMA. Critical at our 1-3 blocks/CU grids
// where wave-level overlap can't hide the old vmcnt(0) full drain.
// Race discipline: end barrier of iter t ensures all waves done reading buf^1 before
// iter t+1's stage overwrites it; vmcnt(4)+front barrier ensures cur landed for all.
// Operand-swapped MFMA epilogue: lane holds 4 consecutive cols -> cvt_pk + uint2 store.
__global__ __launch_bounds__(256) void k_gemm(
    const u16* __restrict__ A, int lda,
    const u16* __restrict__ BT, int ldb,
    u16* __restrict__ C, int ldc,
    int N, int K,
    const float* __restrict__ bias) {
    __shared__ u16 As[2][128 * 32];
    __shared__ u16 Bs[2][128 * 32];
    int tid = threadIdx.x;
    int bm0 = blockIdx.x * 128;
    int bn0 = blockIdx.y * 128;
    int wave = tid >> 6, lane = tid & 63;
    int wm = (wave >> 1) * 64, wn = (wave & 1) * 64;
    int lrow = lane & 15, lk = (lane >> 4) * 8;

    // staging geometry: wave w covers rows w*16 + (lane>>2), 16B chunk (lane&3)
    int srow = (wave << 4) + (lane >> 2);        // 0..63
    int schunk = (lane & 3) << 3;                // u16 offset 0/8/16/24
    const u16* Arow0 = A + (size_t)(bm0 + srow) * lda + schunk;
    const u16* Arow1 = A + (size_t)(bm0 + srow + 64) * lda + schunk;
    int n0 = bn0 + srow;      if (n0 >= N) n0 = N - 1;
    int n1 = bn0 + srow + 64; if (n1 >= N) n1 = N - 1;
    const u16* Brow0 = BT + (size_t)n0 * ldb + schunk;
    const u16* Brow1 = BT + (size_t)n1 * ldb + schunk;

    auto stage = [&](int buf, int k0) {
        gld16(Arow0 + k0, &As[buf][srow * 32 + schunk]);
        gld16(Arow1 + k0, &As[buf][(srow + 64) * 32 + schunk]);
        gld16(Brow0 + k0, &Bs[buf][srow * 32 + schunk]);
        gld16(Brow1 + k0, &Bs[buf][(srow + 64) * 32 + schunk]);
    };

    floatx4 acc[4][4];
#pragma unroll
    for (int i = 0; i < 4; i++)
#pragma unroll
        for (int j = 0; j < 4; j++) acc[i][j] = floatx4{0.f, 0.f, 0.f, 0.f};

    int NT = K >> 5;
    stage(0, 0);
    for (int kt = 0; kt < NT; kt++) {
        int cur = kt & 1;
        if (kt + 1 < NT) {
            stage(cur ^ 1, (kt + 1) << 5);
            asm volatile("s_waitcnt vmcnt(4)" ::: "memory");   // wait only cur's 4 loads
        } else {
            asm volatile("s_waitcnt vmcnt(0)" ::: "memory");
        }
        __syncthreads();
        short8 a[4], b[4];
#pragma unroll
        for (int i = 0; i < 4; i++) a[i] = *(const short8*)(&As[cur][(wm + i * 16 + lrow) * 32 + lk]);
#pragma unroll
        for (int j = 0; j < 4; j++) b[j] = *(const short8*)(&Bs[cur][(wn + j * 16 + lrow) * 32 + lk]);
#pragma unroll
        for (int i = 0; i < 4; i++)
#pragma unroll
            for (int j = 0; j < 4; j++)
                acc[i][j] = __builtin_amdgcn_mfma_f32_16x16x32_bf16(b[j], a[i], acc[i][j], 0, 0, 0);
        __syncthreads();
    }

    // epilogue: n-dim (lane&15) = output row from a[i]; m-dim ((lane>>4)*4+r) = output col from b[j]
    int q = lane >> 4;
#pragma unroll
    for (int i = 0; i < 4; i++) {
        int row = bm0 + wm + i * 16 + lrow;
#pragma unroll
        for (int j = 0; j < 4; j++) {
            int col = bn0 + wn + j * 16 + q * 4;
            if (col < N) {          // N%64==0, col%4==0 -> whole quad in-bounds
                float4 bv = bias ? *(const float4*)(&bias[col]) : float4{0.f, 0.f, 0.f, 0.f};
                uint2 pv;
                pv.x = pk_bf16(acc[i][j][0] + bv.x, acc[i][j][1] + bv.y);
                pv.y = pk_bf16(acc[i][j][2] + bv.z, acc[i][j][3] + bv.w);
                *(uint2*)(&C[(size_t)row * ldc + col]) = pv;
            }
        }
    }
}

// ---------------- LayerNorm(64) + SiLU (bf16 io, f32 params) ----------------
__global__ __launch_bounds__(256) void k_ln_silu(const u16* __restrict__ in, u16* __restrict__ out,
                                                 const float* __restrict__ g, const float* __restrict__ b) {
    int tid = threadIdx.x;
    int e = blockIdx.x * 4 + (tid >> 6);
    int c = tid & 63;
    float x = bf2f(in[(size_t)e * 64 + c]);
    float s = x, s2 = x * x;
#pragma unroll
    for (int o = 32; o; o >>= 1) { s += __shfl_xor(s, o); s2 += __shfl_xor(s2, o); }
    float mu = s * (1.f / 64.f);
    float var = s2 * (1.f / 64.f) - mu * mu;
    float rs = rsqrtf(var + 1e-5f);
    float y = (x - mu) * rs * g[c] + b[c];
    out[(size_t)e * 64 + c] = f2bf(siluf_(y));
}

// ---------------- rotate: wigner @ concat(nf[snd],nf[rcv]); scale by x_edge; pack A1 (chunked) ----------------
__global__ __launch_bounds__(256) void k_rotate(const float* __restrict__ nf, const float* __restrict__ wig,
                                                const int* __restrict__ snd, const int* __restrict__ rcv,
                                                const u16* __restrict__ xe, u16* __restrict__ A1, int e0) {
    __shared__ float wl[2][475];
    int tid = threadIdx.x;
    for (int i = tid; i < 950; i += 256) {
        int ee = e0 + blockIdx.x * 2 + (i / 475);
        wl[i / 475][i % 475] = wig[(size_t)ee * 475 + (i % 475)];
    }
    __syncthreads();
    int le = tid >> 7, c = tid & 127;
    int el = blockIdx.x * 2 + le;       // chunk-local
    int e = e0 + el;                    // global
    int nd = (c < 64) ? snd[e] : rcv[e];
    int cc = c & 63;
    float msg[25];
#pragma unroll
    for (int k = 0; k < 25; k++) msg[k] = nf[(size_t)nd * 1600 + k * 64 + cc];
    const float* w = wl[le];
    size_t ebase = (size_t)el * 2432;
    size_t xbase = (size_t)el * 1536;
#pragma unroll
    for (int m = 0; m < 19; m++) {
        float r = 0.f;
#pragma unroll
        for (int k = 0; k < 25; k++) r += w[m * 25 + k] * msg[k];
        int a1c, xc;
        if (m < 5)       { a1c = m * 128;               xc = m * 128; }
        else if (m < 9)  { a1c = 640 + (m - 5) * 128;   xc = 640 + (m - 5) * 128; }
        else if (m < 13) { a1c = 1152 + (m - 9) * 128;  xc = 640 + (m - 9) * 128; }
        else if (m < 16) { a1c = 1664 + (m - 13) * 128; xc = 1152 + (m - 13) * 128; }
        else             { a1c = 2048 + (m - 16) * 128; xc = 1152 + (m - 16) * 128; }
        float sc = bf2f(xe[xbase + xc + c]);
        A1[ebase + a1c + c] = f2bf(r * sc);
    }
}

// ---------------- attention logits + segment max ----------------
__global__ __launch_bounds__(256) void k_logits(const u16* __restrict__ Y0, const int* __restrict__ rcv,
                                                const float* __restrict__ g, const float* __restrict__ b,
                                                const float* __restrict__ adot,
                                                float* __restrict__ logits, u32* __restrict__ nmax) {
    int e = blockIdx.x;
    int tid = threadIdx.x;
    int h = tid >> 5, c = tid & 31;
    float x = bf2f(Y0[(size_t)e * 640 + 320 + h * 32 + c]);
    float s = x, s2 = x * x;
#pragma unroll
    for (int o = 16; o; o >>= 1) { s += __shfl_xor(s, o); s2 += __shfl_xor(s2, o); }
    float mu = s * (1.f / 32.f);
    float var = s2 * (1.f / 32.f) - mu * mu;
    float rs = rsqrtf(var + 1e-5f);
    float a = (x - mu) * rs * g[c] + b[c];
    float f = 0.6f * a + 0.4f * a * (2.f * sigmoidf_(a) - 1.f);
    float l = f * adot[h * 32 + c];
#pragma unroll
    for (int o = 16; o; o >>= 1) l += __shfl_xor(l, o);
    if (c == 0) {
        logits[e * 8 + h] = l;
        atomicMax(&nmax[rcv[e] * 8 + h], encf(l));
    }
}

__global__ void k_expsum(const float* __restrict__ logits, const int* __restrict__ rcv,
                         const u32* __restrict__ nmax, float* __restrict__ ealpha, float* __restrict__ nsum) {
    int idx = blockIdx.x * 256 + threadIdx.x;
    if (idx >= E_EDGES * 8) return;
    int e = idx >> 3, h = idx & 7;
    int r = rcv[e];
    float amax = decf(nmax[r * 8 + h]);
    if (!(amax > -1e38f && amax < 1e38f)) amax = 0.f;
    float v = __expf(logits[idx] - amax);
    ealpha[idx] = v;
    atomicAdd(&nsum[r * 8 + h], v);
}

// ---------------- grid round-trip via MFMA ----------------
// LDS: Xs aliased into T1s (Xs fully consumed into registers before T1s written).
#define GR_XS_STR 40
#define GR_T1_STR 136
__global__ __launch_bounds__(256) void k_grid_mfma(
    const u16* __restrict__ Y0, const u16* __restrict__ Y1, const u16* __restrict__ Y2,
    const u16* __restrict__ tgP, const u16* __restrict__ fgP, u16* __restrict__ A2) {
    __shared__ u16 T1s[128 * GR_T1_STR];
    u16* Xs = T1s;                       // alias: see barrier discipline below
    int tid = threadIdx.x;
    int e0 = blockIdx.x * 2;
    // stage Xs[ec][m]: thread owns (le, c0-block, m-pair); packed u32 writes
    {
        int mp = tid & 15;                  // m-pair 0..15 -> m = 2mp, 2mp+1
        int c0 = ((tid >> 4) & 7) << 3;     // channel block 0..56
        int le = tid >> 7;                  // local edge 0/1
        int e = e0 + le;
        int m0 = 2 * mp, m1 = m0 + 1;
        uint4 va = {0, 0, 0, 0}, vb = {0, 0, 0, 0};
        if (m0 < 5)       va = *(const uint4*)(&Y0[(size_t)e * 640 + m0 * 64 + c0]);
        else if (m0 < 13) va = *(const uint4*)(&Y1[(size_t)e * 512 + (m0 - 5) * 64 + c0]);
        else if (m0 < 19) va = *(const uint4*)(&Y2[(size_t)e * 384 + (m0 - 13) * 64 + c0]);
        if (m1 < 5)       vb = *(const uint4*)(&Y0[(size_t)e * 640 + m1 * 64 + c0]);
        else if (m1 < 13) vb = *(const uint4*)(&Y1[(size_t)e * 512 + (m1 - 5) * 64 + c0]);
        else if (m1 < 19) vb = *(const uint4*)(&Y2[(size_t)e * 384 + (m1 - 13) * 64 + c0]);
        const u16* pa = (const u16*)&va;
        const u16* pb = (const u16*)&vb;
        int rbase = le * 64 + c0;
#pragma unroll
        for (int j = 0; j < 8; j++) {
            u32 w = (u32)pa[j] | ((u32)pb[j] << 16);
            *(u32*)(&Xs[(rbase + j) * GR_XS_STR + 2 * mp]) = w;
        }
    }
    __syncthreads();
    int wave = tid >> 6, lane = tid & 63;
    int wn = wave << 5;                     // this wave's 32 ec-columns
    int ln = lane & 15, q = lane >> 4;
    // GEMM1 (swapped): A = tgP (p x m), B^T = Xs (ec x m). Out rows = p, cols = ec.
    short8 bx0 = *(const short8*)(&Xs[(wn + ln) * GR_XS_STR + q * 8]);
    short8 bx1 = *(const short8*)(&Xs[(wn + 16 + ln) * GR_XS_STR + q * 8]);
    floatx4 acc1[2][7];
#pragma unroll
    for (int pt = 0; pt < 7; pt++) {
        short8 a = *(const short8*)(&tgP[(size_t)(pt * 16 + ln) * 32 + q * 8]);
        acc1[0][pt] = __builtin_amdgcn_mfma_f32_16x16x32_bf16(a, bx0, floatx4{0.f, 0.f, 0.f, 0.f}, 0, 0, 0);
        acc1[1][pt] = __builtin_amdgcn_mfma_f32_16x16x32_bf16(a, bx1, floatx4{0.f, 0.f, 0.f, 0.f}, 0, 0, 0);
    }
    __syncthreads();    // all Xs reads complete -> safe to overwrite (alias)
    // zero T1s pad cols 112..127 (cols 100..111 are exact zeros from the zeroed tgP rows)
    {
        int row = tid >> 1;
        uint4 z = {0, 0, 0, 0};
        *(uint4*)(&T1s[row * GR_T1_STR + 112 + (tid & 1) * 8]) = z;
    }
    // silu -> T1s[ec][p]: lane holds p = pt*16 + q*4 + r at ec = wn + i*16 + ln -> b64 writes
#pragma unroll
    for (int i = 0; i < 2; i++) {
        u16* dst = &T1s[(wn + i * 16 + ln) * GR_T1_STR + q * 4];
#pragma unroll
        for (int pt = 0; pt < 7; pt++) {
            uint2 pv;
            pv.x = pk_bf16(siluf_(acc1[i][pt][0]), siluf_(acc1[i][pt][1]));
            pv.y = pk_bf16(siluf_(acc1[i][pt][2]), siluf_(acc1[i][pt][3]));
            *(uint2*)(dst + pt * 16) = pv;
        }
    }
    __syncthreads();
    // GEMM2: K=128 (4 steps)
    floatx4 acc2[2][2];
    acc2[0][0] = floatx4{0.f, 0.f, 0.f, 0.f}; acc2[0][1] = floatx4{0.f, 0.f, 0.f, 0.f};
    acc2[1][0] = floatx4{0.f, 0.f, 0.f, 0.f}; acc2[1][1] = floatx4{0.f, 0.f, 0.f, 0.f};
#pragma unroll
    for (int ks = 0; ks < 4; ks++) {
        short8 c0 = *(const short8*)(&T1s[(wn + ln) * GR_T1_STR + ks * 32 + q * 8]);
        short8 c1 = *(const short8*)(&T1s[(wn + 16 + ln) * GR_T1_STR + ks * 32 + q * 8]);
#pragma unroll
        for (int ct = 0; ct < 2; ct++) {
            short8 b = *(const short8*)(&fgP[(size_t)(ct * 16 + ln) * 128 + ks * 32 + q * 8]);
            acc2[0][ct] = __builtin_amdgcn_mfma_f32_16x16x32_bf16(c0, b, acc2[0][ct], 0, 0, 0);
            acc2[1][ct] = __builtin_amdgcn_mfma_f32_16x16x32_bf16(c1, b, acc2[1][ct], 0, 0, 0);
        }
    }
    // direct store: lane holds col m'=ct*16+ln, rows q*4+r -> 4 consecutive c in A2
#pragma unroll
    for (int rt = 0; rt < 2; rt++) {
        int row = wn + rt * 16 + q * 4;
        int e = e0 + (row >> 6), c = row & 63;
#pragma unroll
        for (int ct = 0; ct < 2; ct++) {
            int mp = ct * 16 + ln;
            if (mp >= 1 && mp < 19) {
                uint2 pv;
                pv.x = pk_bf16(acc2[rt][ct][0], acc2[rt][ct][1]);
                pv.y = pk_bf16(acc2[rt][ct][2], acc2[rt][ct][3]);
                *(uint2*)(&A2[(size_t)e * 1216 + mp * 64 + c]) = pv;
            }
        }
    }
    // m=0 gate row
    if (tid < 128) {
        int e = e0 + (tid >> 6), c = tid & 63;
        float gate = bf2f(Y0[(size_t)e * 640 + 576 + c]);
        A2[(size_t)e * 1216 + c] = f2bf(siluf_(gate));
    }
}

// ---------------- gather: attention scale + wigner^T + segment-sum (no atomics) ----------------
// WAVE-PER-NODE, zero-sync, zero-LDS. Lane owns channel pair (2l, 2l+1) via packed u32
// bf16 loads (256B coalesced per load). Edge loop is wave-private: 950 FMA wave-insts
// per edge hide the next edge's load latency; 16 waves/CU give 16 independent streams.
// Wigner pointer kept scalar via readfirstlane. Two passes over the Z chunks.
__global__ __launch_bounds__(256) void k_gather(
    const u16* __restrict__ Z0, const u16* __restrict__ Z1, const u16* __restrict__ Z2,
    const float* __restrict__ wig, const float* __restrict__ ealpha, const float* __restrict__ nsum,
    const u32* __restrict__ rowstart, const u32* __restrict__ deg, const int* __restrict__ elist,
    float* __restrict__ node, int e0, int accum) {
    int n = blockIdx.x * 4 + (threadIdx.x >> 6);
    int lane = threadIdx.x & 63;
    int h = lane >> 3;                  // head of channels 2l,2l+1 (same head for both)
    float sden = __fdividef(1.f, nsum[n * 8 + h] + 1e-16f);
    float a0[25], a1[25];
#pragma unroll
    for (int k = 0; k < 25; k++) { a0[k] = 0.f; a1[k] = 0.f; }
    u32 lo = rowstart[n], cnt = deg[n];
    bool did = false;
    for (u32 i = 0; i < cnt; i++) {
        int e = __builtin_amdgcn_readfirstlane(elist[lo + i]);
        int el = e - e0;
        if ((u32)el >= (u32)EC) continue;       // wave-uniform
        did = true;
        float al = ealpha[e * 8 + h] * sden;
        // 19 packed z loads (2 bf16 channels per lane), all independent
        u32 zp[19];
        const u16* z0 = Z0 + (size_t)el * 640 + 2 * lane;
        const u16* z1 = Z1 + (size_t)el * 1024 + 2 * lane;
        const u16* z2 = Z2 + (size_t)el * 768 + 2 * lane;
#pragma unroll
        for (int m = 0; m < 5; m++) zp[m] = *(const u32*)(z0 + m * 128);
#pragma unroll
        for (int m = 0; m < 8; m++) zp[5 + m] = *(const u32*)(z1 + m * 128);
#pragma unroll
        for (int m = 0; m < 6; m++) zp[13 + m] = *(const u32*)(z2 + m * 128);
        const float* __restrict__ w = wig + (size_t)e * 475;
#pragma unroll
        for (int m = 0; m < 19; m++) {
            float s0 = bf2f((u16)(zp[m] & 0xffffu)) * al;
            float s1 = bf2f((u16)(zp[m] >> 16)) * al;
#pragma unroll
            for (int k = 0; k < 25; k++) {
                float wv = w[m * 25 + k];
                a0[k] = fmaf(wv, s0, a0[k]);
                a1[k] = fmaf(wv, s1, a1[k]);
            }
        }
    }
    float* nb = node + (size_t)n * 3200 + 2 * lane;
    if (accum) {
        if (!did) return;                       // wave-uniform
#pragma unroll
        for (int k = 0; k < 25; k++) {
            float2 v = *(float2*)(&nb[k * 128]);
            v.x += a0[k]; v.y += a1[k];
            *(float2*)(&nb[k * 128]) = v;
        }
    } else {
#pragma unroll
        for (int k = 0; k < 25; k++) {
            float2 v; v.x = a0[k]; v.y = a1[k];
            *(float2*)(&nb[k * 128]) = v;
        }
    }
}

// ---------------- final projection via MFMA ----------------
// grid (32 n-tiles, 25 k). Block: M=128 n-rows, N=64 d, K=128 c.
// A = node (f32, stride 3200) -> bf16 LDS; B = pwTb[l] (64x128 bf16).
// Operand-swapped MFMA: lane holds 4 consecutive d at one n -> float4 stores.
#define PJ_STR 136
__global__ __launch_bounds__(256) void k_proj_mfma(
    const float* __restrict__ node, const u16* __restrict__ pwTb,
    const float* __restrict__ pb, float* __restrict__ out) {
    __shared__ u16 As[128 * PJ_STR];
    __shared__ u16 Bs[64 * PJ_STR];
    int tid = threadIdx.x;
    int n0 = blockIdx.x * 128;
    int k = blockIdx.y;
    int l = (int)sqrtf((float)k + 0.5f);
    // stage A: 128 rows x 128 c f32 -> bf16; thread i handles row=i>>5, c0=(i&31)*4
#pragma unroll
    for (int it = 0; it < 16; it++) {
        int i = tid + it * 256;
        int row = i >> 5;
        int c0 = (i & 31) << 2;
        float4 v = *(const float4*)(&node[(size_t)(n0 + row) * 3200 + k * 128 + c0]);
        uint2 pv;
        pv.x = pk_bf16(v.x, v.y);
        pv.y = pk_bf16(v.z, v.w);
        *(uint2*)(&As[row * PJ_STR + c0]) = pv;
    }
    // stage B: 64 rows (d) x 128 c bf16, 16B chunks
    const u16* pw = pwTb + (size_t)l * 8192;
#pragma unroll
    for (int jt = 0; jt < 4; jt++) {
        int j = tid + jt * 256;
        int d = j >> 4;
        int c0 = (j & 15) << 3;
        *(uint4*)(&Bs[d * PJ_STR + c0]) = *(const uint4*)(&pw[d * 128 + c0]);
    }
    __syncthreads();
    int wave = tid >> 6, lane = tid & 63;
    int wr = wave * 32;
    int ln = lane & 15, q = lane >> 4;
    floatx4 acc[2][4];
#pragma unroll
    for (int i = 0; i < 2; i++)
#pragma unroll
        for (int j = 0; j < 4; j++) acc[i][j] = floatx4{0.f, 0.f, 0.f, 0.f};
#pragma unroll
    for (int ks = 0; ks < 4; ks++) {
        short8 a0 = *(const short8*)(&As[(wr + ln) * PJ_STR + ks * 32 + q * 8]);
        short8 a1 = *(const short8*)(&As[(wr + 16 + ln) * PJ_STR + ks * 32 + q * 8]);
#pragma unroll
        for (int j = 0; j < 4; j++) {
            short8 b = *(const short8*)(&Bs[(j * 16 + ln) * PJ_STR + ks * 32 + q * 8]);
            acc[0][j] = __builtin_amdgcn_mfma_f32_16x16x32_bf16(b, a0, acc[0][j], 0, 0, 0);
            acc[1][j] = __builtin_amdgcn_mfma_f32_16x16x32_bf16(b, a1, acc[1][j], 0, 0, 0);
        }
    }
    // epilogue (swapped): n = n0+wr+rt*16+ln (row); d = j*16+q*4..+3 (4 consecutive cols)
#pragma unroll
    for (int rt = 0; rt < 2; rt++) {
        int n = n0 + wr + rt * 16 + ln;
#pragma unroll
        for (int j = 0; j < 4; j++) {
            int d = j * 16 + q * 4;
            float4 v;
            v.x = acc[rt][j][0]; v.y = acc[rt][j][1];
            v.z = acc[rt][j][2]; v.w = acc[rt][j][3];
            if (k == 0) {
                float4 bv = *(const float4*)(&pb[d]);
                v.x += bv.x; v.y += bv.y; v.z += bv.z; v.w += bv.w;
            }
            *(float4*)(&out[(size_t)n * 1600 + k * 64 + d]) = v;
        }
    }
}

extern "C" void kernel_launch(void* const* d_in, const int* in_sizes, int n_in,
                              void* d_out, int out_size, void* d_ws, size_t ws_size,
                              hipStream_t stream) {
    const float* nf      = (const float*)d_in[0];
    const int* species   = (const int*)d_in[1];
    const float* dist    = (const float*)d_in[2];
    const int* snd       = (const int*)d_in[3];
    const int* rcv       = (const int*)d_in[4];
    const float* wig     = (const float*)d_in[5];
    const float* semb    = (const float*)d_in[6];
    const float* remb    = (const float*)d_in[7];
    const float* rad_w1  = (const float*)d_in[8];
    const float* rad_b1  = (const float*)d_in[9];
    const float* rad_g1  = (const float*)d_in[10];
    const float* rad_be1 = (const float*)d_in[11];
    const float* rad_w2  = (const float*)d_in[12];
    const float* rad_b2  = (const float*)d_in[13];
    const float* rad_g2  = (const float*)d_in[14];
    const float* rad_be2 = (const float*)d_in[15];
    const float* rad_w3  = (const float*)d_in[16];
    const float* rad_b3  = (const float*)d_in[17];
    const float* c1_w0   = (const float*)d_in[18];
    const float* c1_b0   = (const float*)d_in[19];
    const float* c1_wm1  = (const float*)d_in[20];
    const float* c1_wm2  = (const float*)d_in[21];
    const float* aln_g   = (const float*)d_in[22];
    const float* aln_b   = (const float*)d_in[23];
    const float* adot    = (const float*)d_in[24];
    const float* to_grid = (const float*)d_in[25];
    const float* from_grid=(const float*)d_in[26];
    const float* c2_w0   = (const float*)d_in[27];
    const float* c2_b0   = (const float*)d_in[28];
    const float* c2_wm1  = (const float*)d_in[29];
    const float* c2_wm2  = (const float*)d_in[30];
    const float* proj_w  = (const float*)d_in[31];
    const float* proj_b  = (const float*)d_in[32];

    char* ws = (char*)d_ws;
    size_t off = 0;
    auto take = [&](size_t bytes) -> char* {
        char* p = ws + off;
        off += (bytes + 255) & ~(size_t)255;
        return p;
    };
    // fixed section
    u16* w_rad1T  = (u16*)take(64 * 192 * 2);
    u16* w_rad2T  = (u16*)take(64 * 64 * 2);
    u16* w_rad3T  = (u16*)take(1536 * 64 * 2);
    u16* w_c1w0T  = (u16*)take(640 * 640 * 2);
    u16* w_c1m1T  = (u16*)take((size_t)512 * 1024 * 2);
    u16* w_c1m2T  = (u16*)take((size_t)384 * 768 * 2);
    u16* w_c2w0T  = (u16*)take((size_t)640 * 320 * 2);
    u16* w_c2m1T  = (u16*)take((size_t)1024 * 512 * 2);
    u16* w_c2m2T  = (u16*)take((size_t)768 * 384 * 2);
    u16* w_tgP    = (u16*)take(112 * 32 * 2);
    u16* w_fgP    = (u16*)take(32 * 128 * 2);
    u16* w_pwT    = (u16*)take(5 * 8192 * 2);
    float* logits = (float*)take((size_t)E_EDGES * 8 * 4);
    float* ealpha = (float*)take((size_t)E_EDGES * 8 * 4);
    u32* nmax     = (u32*)take((size_t)N_NODES_C * 8 * 4);
    float* nsum   = (float*)take((size_t)N_NODES_C * 8 * 4);
    float* node   = (float*)take((size_t)N_NODES_C * 3200 * 4);
    u16* a_h2     = (u16*)take((size_t)E_EDGES * 64 * 2);
    u32* c_deg    = (u32*)take((size_t)N_NODES_C * 4);
    u32* c_row    = (u32*)take((size_t)N_NODES_C * 4);
    u32* c_cur    = (u32*)take((size_t)N_NODES_C * 4);
    int* c_elist  = (int*)take((size_t)E_EDGES * 4);
    // arena — aliased by phase
    char* arena   = take(173015040);
    if (off > ws_size) {  // diagnostic: paint output so the failure mode is identifiable
        k_diag<<<(out_size + 255) / 256, 256, 0, stream>>>((float*)d_out, out_size);
        return;
    }

    u16* a_ee   = (u16*)(arena + 0);           // radial phase
    u16* a_ypre = (u16*)(arena + 9437184);
    u16* a_h1   = (u16*)(arena + 12582912);
    u16* a_xe   = (u16*)(arena + 0);           // per-chunk (EC,1536); radial staging dead
    u16* a_A1   = (u16*)(arena + 37748736);    // per-chunk (EC,2432)
    u16* a_Y0   = (u16*)(arena + 97517568);    // full (E,640)
    u16* a_Y1   = (u16*)(arena + 128974848);   // full (E,512)
    u16* a_Y2   = (u16*)(arena + 154140672);   // full (E,384) -> arena end
    u16* a_A2   = (u16*)(arena + 0);           // full (E,1216); xe/A1 dead
    u16* a_Z0   = (u16*)(arena + 59768832);    // per-chunk (EC,640)
    u16* a_Z1   = (u16*)(arena + 75497472);    // per-chunk (EC,1024)
    u16* a_Z2   = (u16*)(arena + 100663296);   // per-chunk (EC,768); overlaps dead Y0 region

    // ---- weight prep ----
    k_transpose<<<48, 256, 0, stream>>>(rad_w1, w_rad1T, 192, 64);
    k_transpose<<<16, 256, 0, stream>>>(rad_w2, w_rad2T, 64, 64);
    k_transpose<<<384, 256, 0, stream>>>(rad_w3, w_rad3T, 64, 1536);
    k_transpose<<<1600, 256, 0, stream>>>(c1_w0, w_c1w0T, 640, 640);
    k_transpose<<<800, 256, 0, stream>>>(c2_w0, w_c2w0T, 320, 640);
    k_combine<<<2048, 256, 0, stream>>>(c1_wm1, w_c1m1T, 512, 256);
    k_combine<<<1152, 256, 0, stream>>>(c1_wm2, w_c1m2T, 384, 192);
    k_combine<<<2048, 256, 0, stream>>>(c2_wm1, w_c2m1T, 256, 512);
    k_combine<<<1152, 256, 0, stream>>>(c2_wm2, w_c2m2T, 192, 384);
    k_packgrid<<<30, 256, 0, stream>>>(to_grid, from_grid, w_tgP, w_fgP);
    for (int l = 0; l < 5; l++)
        k_transpose<<<32, 256, 0, stream>>>(proj_w + (size_t)l * 8192, w_pwT + (size_t)l * 8192, 128, 64);
    k_init<<<128, 256, 0, stream>>>(nmax, nsum, N_NODES_C * 8);

    // ---- CSR build (receivers static per launch) ----
    hipMemsetAsync(c_deg, 0, (size_t)N_NODES_C * 4, stream);
    k_deg<<<96, 256, 0, stream>>>(rcv, c_deg);
    k_pfx<<<1, 256, 0, stream>>>(c_deg, c_row, c_cur);
    k_fill<<<96, 256, 0, stream>>>(rcv, c_cur, c_elist);

    // ---- radial MLP (full E) ----
    k_ee<<<(E_EDGES * 192 + 255) / 256, 256, 0, stream>>>(dist, species, snd, rcv, semb, remb, a_ee);
    k_gemm<<<dim3(192, 1), 256, 0, stream>>>(a_ee, 192, w_rad1T, 192, a_ypre, 64, 64, 192, rad_b1);
    k_ln_silu<<<6144, 256, 0, stream>>>(a_ypre, a_h1, rad_g1, rad_be1);
    k_gemm<<<dim3(192, 1), 256, 0, stream>>>(a_h1, 64, w_rad2T, 64, a_ypre, 64, 64, 64, rad_b2);
    k_ln_silu<<<6144, 256, 0, stream>>>(a_ypre, a_h2, rad_g2, rad_be2);

    // ---- chunked: x_edge gemm -> rotate -> conv1 ----
    for (int c = 0; c < 2; c++) {
        int e0 = c * EC;
        k_gemm<<<dim3(96, 12), 256, 0, stream>>>(a_h2 + (size_t)e0 * 64, 64, w_rad3T, 64,
                                                 a_xe, 1536, 1536, 64, rad_b3);
        k_rotate<<<EC / 2, 256, 0, stream>>>(nf, wig, snd, rcv, a_xe, a_A1, e0);
        k_gemm<<<dim3(96, 5), 256, 0, stream>>>(a_A1, 2432, w_c1w0T, 640,
                                                a_Y0 + (size_t)e0 * 640, 640, 640, 640, c1_b0);
        k_gemm<<<dim3(96, 4), 256, 0, stream>>>(a_A1 + 640, 2432, w_c1m1T, 1024,
                                                a_Y1 + (size_t)e0 * 512, 512, 512, 1024, nullptr);
        k_gemm<<<dim3(96, 3), 256, 0, stream>>>(a_A1 + 1664, 2432, w_c1m2T, 768,
                                                a_Y2 + (size_t)e0 * 384, 384, 384, 768, nullptr);
    }

    // ---- attention softmax pieces ----
    k_logits<<<E_EDGES, 256, 0, stream>>>(a_Y0, rcv, aln_g, aln_b, adot, logits, nmax);
    k_expsum<<<(E_EDGES * 8 + 255) / 256, 256, 0, stream>>>(logits, rcv, nmax, ealpha, nsum);

    // ---- grid nonlinearity -> packed A2 (full E, MFMA) ----
    k_grid_mfma<<<E_EDGES / 2, 256, 0, stream>>>(a_Y0, a_Y1, a_Y2, w_tgP, w_fgP, a_A2);

    // ---- chunked: conv2 -> gather (CSR, wave-per-node, no atomics/syncs) ----
    for (int c = 0; c < 2; c++) {
        int e0 = c * EC;
        k_gemm<<<dim3(96, 5), 256, 0, stream>>>(a_A2 + (size_t)e0 * 1216, 1216, w_c2w0T, 320,
                                                a_Z0, 640, 640, 320, c2_b0);
        k_gemm<<<dim3(96, 8), 256, 0, stream>>>(a_A2 + (size_t)e0 * 1216 + 320, 1216, w_c2m1T, 512,
                                                a_Z1, 1024, 1024, 512, nullptr);
        k_gemm<<<dim3(96, 6), 256, 0, stream>>>(a_A2 + (size_t)e0 * 1216 + 832, 1216, w_c2m2T, 384,
                                                a_Z2, 768, 768, 384, nullptr);
        k_gather<<<N_NODES_C / 4, 256, 0, stream>>>(a_Z0, a_Z1, a_Z2, wig, ealpha, nsum,
                                                    c_row, c_deg, c_elist, node, e0, c);
    }

    // ---- output projection (MFMA) ----
    k_proj_mfma<<<dim3(32, 25), 256, 0, stream>>>(node, w_pwT, proj_b, (float*)d_out);
}

// Round 8
// 911.803 us; speedup vs baseline: 1.2027x; 1.1144x over previous
//
#include <hip/hip_runtime.h>

typedef unsigned short u16;
typedef unsigned int u32;
typedef __attribute__((ext_vector_type(8))) short short8;
typedef __attribute__((ext_vector_type(4))) float floatx4;

#define E_EDGES 24576
#define EC 12288            // edge chunk
#define N_NODES_C 4096

__device__ __forceinline__ float bf2f(u16 u) {
    union { u32 i; float f; } v; v.i = ((u32)u) << 16; return v.f;
}
__device__ __forceinline__ u16 f2bf(float f) {
    union { float f; u32 i; } v; v.f = f;
    u32 x = v.i;
    u32 r = (x + 0x7fffu + ((x >> 16) & 1u)) >> 16;
    return (u16)r;
}
// packed f32x2 -> bf16x2 in one VALU inst (RNE), no builtin on gfx950 -> inline asm
__device__ __forceinline__ u32 pk_bf16(float a, float b) {
    u32 r;
    asm("v_cvt_pk_bf16_f32 %0, %1, %2" : "=v"(r) : "v"(a), "v"(b));
    return r;
}
__device__ __forceinline__ u32 encf(float f) {
    union { float f; u32 i; } v; v.f = f;
    return (v.i & 0x80000000u) ? ~v.i : (v.i | 0x80000000u);
}
__device__ __forceinline__ float decf(u32 u) {
    union { u32 i; float f; } v;
    v.i = (u & 0x80000000u) ? (u ^ 0x80000000u) : ~u;
    return v.f;
}
// fast transcendentals: v_exp_f32 + v_rcp_f32
__device__ __forceinline__ float sigmoidf_(float x) { return __fdividef(1.f, 1.f + __expf(-x)); }
__device__ __forceinline__ float siluf_(float x) { return x * __fdividef(1.f, 1.f + __expf(-x)); }

// async global->LDS, 16B per lane; LDS dest must be wave-uniform base + lane*16
__device__ __forceinline__ void gld16(const u16* g, u16* l) {
    __builtin_amdgcn_global_load_lds((const __attribute__((address_space(1))) unsigned int*)g,
                                     (__attribute__((address_space(3))) unsigned int*)l, 16, 0, 0);
}

// diagnostic: ws too small -> paint output with 1000 (f32)
__global__ void k_diag(float* __restrict__ out, int n) {
    int i = blockIdx.x * 256 + threadIdx.x;
    if (i < n) out[i] = 1000.0f;
}

// ================= fused prep: all weight prep + init + deg-zero + edge embeds =================
// 18 launches -> 1. All segments independent & memory-bound; block-range dispatch.
struct PrepArgs {
    const float *rad_w1, *rad_w2, *rad_w3, *c1_w0, *c2_w0;
    const float *c1_wm1, *c1_wm2, *c2_wm1, *c2_wm2;
    const float *to_grid, *from_grid, *proj_w;
    u16 *w_rad1T, *w_rad2T, *w_rad3T, *w_c1w0T, *w_c2w0T;
    u16 *w_c1m1T, *w_c1m2T, *w_c2m1T, *w_c2m2T;
    u16 *w_tgP, *w_fgP, *w_pwT;
    u32 *nmax; float *nsum; u32 *c_deg;
    const float *dist; const int *species, *snd, *rcv;
    const float *semb, *remb; u16 *ee;
};

__device__ __forceinline__ void prep_transpose(const float* __restrict__ src, u16* __restrict__ dst,
                                               int K, int N, int idx) {
    if (idx >= K * N) return;
    int k = idx / N, n = idx % N;
    dst[n * K + k] = f2bf(src[idx]);
}
__device__ __forceinline__ void prep_combine(const float* __restrict__ src, u16* __restrict__ dst,
                                             int K, int H, int idx) {
    if (idx >= 4 * K * H) return;
    int n = idx / (2 * K), k = idx % (2 * K);
    float v;
    if (k < K) v = src[k * 2 * H + n];
    else {
        int kk = k - K;
        if (n < H) v = -src[kk * 2 * H + H + n];
        else       v = src[kk * 2 * H + (n - H)];
    }
    dst[idx] = f2bf(v);
}

#define PB0 48      // rad1T (192x64)
#define PB1 16      // rad2T (64x64)
#define PB2 384     // rad3T (64x1536)
#define PB3 1600    // c1w0T (640x640)
#define PB4 800     // c2w0T (320x640)
#define PB5 2048    // c1m1 combine (512,256)
#define PB6 1152    // c1m2 (384,192)
#define PB7 2048    // c2m1 (256,512)
#define PB8 1152    // c2m2 (192,384)
#define PB9 30      // packgrid
#define PB10 160    // pwT (5 x 128x64)
#define PB11 128    // init nmax/nsum (32768)
#define PB12 16     // zero c_deg (4096)
#define PB13 18432  // edge embeds (E*192)
#define PREP_BLOCKS (PB0+PB1+PB2+PB3+PB4+PB5+PB6+PB7+PB8+PB9+PB10+PB11+PB12+PB13)

__global__ __launch_bounds__(256) void k_prep(PrepArgs a) {
    int bid = blockIdx.x;
    int tid = threadIdx.x;
    if (bid < PB0) { prep_transpose(a.rad_w1, a.w_rad1T, 192, 64, bid * 256 + tid); return; }
    bid -= PB0;
    if (bid < PB1) { prep_transpose(a.rad_w2, a.w_rad2T, 64, 64, bid * 256 + tid); return; }
    bid -= PB1;
    if (bid < PB2) { prep_transpose(a.rad_w3, a.w_rad3T, 64, 1536, bid * 256 + tid); return; }
    bid -= PB2;
    if (bid < PB3) { prep_transpose(a.c1_w0, a.w_c1w0T, 640, 640, bid * 256 + tid); return; }
    bid -= PB3;
    if (bid < PB4) { prep_transpose(a.c2_w0, a.w_c2w0T, 320, 640, bid * 256 + tid); return; }
    bid -= PB4;
    if (bid < PB5) { prep_combine(a.c1_wm1, a.w_c1m1T, 512, 256, bid * 256 + tid); return; }
    bid -= PB5;
    if (bid < PB6) { prep_combine(a.c1_wm2, a.w_c1m2T, 384, 192, bid * 256 + tid); return; }
    bid -= PB6;
    if (bid < PB7) { prep_combine(a.c2_wm1, a.w_c2m1T, 256, 512, bid * 256 + tid); return; }
    bid -= PB7;
    if (bid < PB8) { prep_combine(a.c2_wm2, a.w_c2m2T, 192, 384, bid * 256 + tid); return; }
    bid -= PB8;
    if (bid < PB9) {
        int idx = bid * 256 + tid;
        if (idx < 112 * 32) {
            int p = idx >> 5, m = idx & 31;
            a.w_tgP[idx] = (p < 100 && m < 19) ? f2bf(a.to_grid[p * 19 + m]) : (u16)0;
        }
        int j = idx - 112 * 32;
        if (j >= 0 && j < 32 * 128) {
            int m = j >> 7, k = j & 127;
            a.w_fgP[j] = (m < 19 && k < 100) ? f2bf(a.from_grid[m * 100 + k]) : (u16)0;
        }
        return;
    }
    bid -= PB9;
    if (bid < PB10) {
        int idx = bid * 256 + tid;          // < 40960
        int l = idx >> 13, rem = idx & 8191;
        prep_transpose(a.proj_w + (size_t)l * 8192, a.w_pwT + (size_t)l * 8192, 128, 64, rem);
        return;
    }
    bid -= PB10;
    if (bid < PB11) {
        int idx = bid * 256 + tid;
        if (idx < N_NODES_C * 8) { a.nmax[idx] = 0x007FFFFFu; a.nsum[idx] = 0.f; }
        return;
    }
    bid -= PB11;
    if (bid < PB12) {
        int idx = bid * 256 + tid;
        if (idx < N_NODES_C) a.c_deg[idx] = 0u;
        return;
    }
    bid -= PB12;
    {
        int idx = bid * 256 + tid;
        if (idx >= E_EDGES * 192) return;
        int e = idx / 192, c = idx % 192;
        float v;
        if (c < 64)       v = a.dist[e * 64 + c];
        else if (c < 128) v = a.semb[a.species[a.snd[e]] * 64 + (c - 64)];
        else              v = a.remb[a.species[a.rcv[e]] * 64 + (c - 128)];
        a.ee[idx] = f2bf(v);
    }
}

// ---------------- CSR build over receivers (static per launch) ----------------
__global__ void k_deg(const int* __restrict__ rcv, u32* __restrict__ deg) {
    int e = blockIdx.x * 256 + threadIdx.x;
    if (e < E_EDGES) atomicAdd(&deg[rcv[e]], 1u);
}
__global__ __launch_bounds__(256) void k_pfx(const u32* __restrict__ deg,
                                             u32* __restrict__ rowstart, u32* __restrict__ cur) {
    __shared__ u32 ps[256];
    int t = threadIdx.x;
    u32 loc[16]; u32 s = 0;
#pragma unroll
    for (int i = 0; i < 16; i++) { loc[i] = s; s += deg[t * 16 + i]; }
    ps[t] = s;
    __syncthreads();
    for (int o = 1; o < 256; o <<= 1) {
        u32 v = (t >= o) ? ps[t - o] : 0u;
        __syncthreads();
        ps[t] += v;
        __syncthreads();
    }
    u32 base = (t == 0) ? 0u : ps[t - 1];
#pragma unroll
    for (int i = 0; i < 16; i++) { u32 v = base + loc[i]; rowstart[t * 16 + i] = v; cur[t * 16 + i] = v; }
}
__global__ void k_fill(const int* __restrict__ rcv, u32* __restrict__ cur, int* __restrict__ elist) {
    int e = blockIdx.x * 256 + threadIdx.x;
    if (e < E_EDGES) { u32 p = atomicAdd(&cur[rcv[e]], 1u); elist[p] = e; }
}

// ---------------- GEMM: A (M,K) bf16 rm, BT (N,K) bf16 rm, C (M,N) bf16 ----------------
// Double-buffered LDS staging with counted vmcnt; operand-swapped MFMA epilogue
// (lane holds 4 consecutive cols -> cvt_pk + uint2 store).
__global__ __launch_bounds__(256) void k_gemm(
    const u16* __restrict__ A, int lda,
    const u16* __restrict__ BT, int ldb,
    u16* __restrict__ C, int ldc,
    int N, int K,
    const float* __restrict__ bias) {
    __shared__ u16 As[2][128 * 32];
    __shared__ u16 Bs[2][128 * 32];
    int tid = threadIdx.x;
    int bm0 = blockIdx.x * 128;
    int bn0 = blockIdx.y * 128;
    int wave = tid >> 6, lane = tid & 63;
    int wm = (wave >> 1) * 64, wn = (wave & 1) * 64;
    int lrow = lane & 15, lk = (lane >> 4) * 8;

    int srow = (wave << 4) + (lane >> 2);        // 0..63
    int schunk = (lane & 3) << 3;                // u16 offset 0/8/16/24
    const u16* Arow0 = A + (size_t)(bm0 + srow) * lda + schunk;
    const u16* Arow1 = A + (size_t)(bm0 + srow + 64) * lda + schunk;
    int n0 = bn0 + srow;      if (n0 >= N) n0 = N - 1;
    int n1 = bn0 + srow + 64; if (n1 >= N) n1 = N - 1;
    const u16* Brow0 = BT + (size_t)n0 * ldb + schunk;
    const u16* Brow1 = BT + (size_t)n1 * ldb + schunk;

    auto stage = [&](int buf, int k0) {
        gld16(Arow0 + k0, &As[buf][srow * 32 + schunk]);
        gld16(Arow1 + k0, &As[buf][(srow + 64) * 32 + schunk]);
        gld16(Brow0 + k0, &Bs[buf][srow * 32 + schunk]);
        gld16(Brow1 + k0, &Bs[buf][(srow + 64) * 32 + schunk]);
    };

    floatx4 acc[4][4];
#pragma unroll
    for (int i = 0; i < 4; i++)
#pragma unroll
        for (int j = 0; j < 4; j++) acc[i][j] = floatx4{0.f, 0.f, 0.f, 0.f};

    int NT = K >> 5;
    stage(0, 0);
    for (int kt = 0; kt < NT; kt++) {
        int cur = kt & 1;
        if (kt + 1 < NT) {
            stage(cur ^ 1, (kt + 1) << 5);
            asm volatile("s_waitcnt vmcnt(4)" ::: "memory");   // wait only cur's 4 loads
        } else {
            asm volatile("s_waitcnt vmcnt(0)" ::: "memory");
        }
        __syncthreads();
        short8 a[4], b[4];
#pragma unroll
        for (int i = 0; i < 4; i++) a[i] = *(const short8*)(&As[cur][(wm + i * 16 + lrow) * 32 + lk]);
#pragma unroll
        for (int j = 0; j < 4; j++) b[j] = *(const short8*)(&Bs[cur][(wn + j * 16 + lrow) * 32 + lk]);
#pragma unroll
        for (int i = 0; i < 4; i++)
#pragma unroll
            for (int j = 0; j < 4; j++)
                acc[i][j] = __builtin_amdgcn_mfma_f32_16x16x32_bf16(b[j], a[i], acc[i][j], 0, 0, 0);
        __syncthreads();
    }

    int q = lane >> 4;
#pragma unroll
    for (int i = 0; i < 4; i++) {
        int row = bm0 + wm + i * 16 + lrow;
#pragma unroll
        for (int j = 0; j < 4; j++) {
            int col = bn0 + wn + j * 16 + q * 4;
            if (col < N) {          // N%64==0, col%4==0 -> whole quad in-bounds
                float4 bv = bias ? *(const float4*)(&bias[col]) : float4{0.f, 0.f, 0.f, 0.f};
                uint2 pv;
                pv.x = pk_bf16(acc[i][j][0] + bv.x, acc[i][j][1] + bv.y);
                pv.y = pk_bf16(acc[i][j][2] + bv.z, acc[i][j][3] + bv.w);
                *(uint2*)(&C[(size_t)row * ldc + col]) = pv;
            }
        }
    }
}

// ---------------- batched 3-way GEMM (shared A base; per-task BT/C/N/K) ----------------
// Merges the 3 conv gemms of a phase into one dispatch: blockIdx.y range -> task.
// Saves launch gaps + lets tasks' blocks co-schedule (fill each other's tails).
struct GemmDesc {
    const u16* A; const u16* BT; u16* C;
    const float* bias;
    int lda, ldb, ldc, N, K;
};
struct Gemm3 {
    GemmDesc d[3];
    int cut0, cut1;
};
__global__ __launch_bounds__(256) void k_gemm3(Gemm3 g) {
    int y = blockIdx.y;
    GemmDesc d;
    int ytile;
    if (y < g.cut0)      { d = g.d[0]; ytile = y; }
    else if (y < g.cut1) { d = g.d[1]; ytile = y - g.cut0; }
    else                 { d = g.d[2]; ytile = y - g.cut1; }

    __shared__ u16 As[2][128 * 32];
    __shared__ u16 Bs[2][128 * 32];
    int tid = threadIdx.x;
    int bm0 = blockIdx.x * 128;
    int bn0 = ytile * 128;
    int wave = tid >> 6, lane = tid & 63;
    int wm = (wave >> 1) * 64, wn = (wave & 1) * 64;
    int lrow = lane & 15, lk = (lane >> 4) * 8;

    int srow = (wave << 4) + (lane >> 2);
    int schunk = (lane & 3) << 3;
    const u16* Arow0 = d.A + (size_t)(bm0 + srow) * d.lda + schunk;
    const u16* Arow1 = d.A + (size_t)(bm0 + srow + 64) * d.lda + schunk;
    int n0 = bn0 + srow;      if (n0 >= d.N) n0 = d.N - 1;
    int n1 = bn0 + srow + 64; if (n1 >= d.N) n1 = d.N - 1;
    const u16* Brow0 = d.BT + (size_t)n0 * d.ldb + schunk;
    const u16* Brow1 = d.BT + (size_t)n1 * d.ldb + schunk;

    auto stage = [&](int buf, int k0) {
        gld16(Arow0 + k0, &As[buf][srow * 32 + schunk]);
        gld16(Arow1 + k0, &As[buf][(srow + 64) * 32 + schunk]);
        gld16(Brow0 + k0, &Bs[buf][srow * 32 + schunk]);
        gld16(Brow1 + k0, &Bs[buf][(srow + 64) * 32 + schunk]);
    };

    floatx4 acc[4][4];
#pragma unroll
    for (int i = 0; i < 4; i++)
#pragma unroll
        for (int j = 0; j < 4; j++) acc[i][j] = floatx4{0.f, 0.f, 0.f, 0.f};

    int NT = d.K >> 5;
    stage(0, 0);
    for (int kt = 0; kt < NT; kt++) {
        int cur = kt & 1;
        if (kt + 1 < NT) {
            stage(cur ^ 1, (kt + 1) << 5);
            asm volatile("s_waitcnt vmcnt(4)" ::: "memory");
        } else {
            asm volatile("s_waitcnt vmcnt(0)" ::: "memory");
        }
        __syncthreads();
        short8 a[4], b[4];
#pragma unroll
        for (int i = 0; i < 4; i++) a[i] = *(const short8*)(&As[cur][(wm + i * 16 + lrow) * 32 + lk]);
#pragma unroll
        for (int j = 0; j < 4; j++) b[j] = *(const short8*)(&Bs[cur][(wn + j * 16 + lrow) * 32 + lk]);
#pragma unroll
        for (int i = 0; i < 4; i++)
#pragma unroll
            for (int j = 0; j < 4; j++)
                acc[i][j] = __builtin_amdgcn_mfma_f32_16x16x32_bf16(b[j], a[i], acc[i][j], 0, 0, 0);
        __syncthreads();
    }

    int q = lane >> 4;
#pragma unroll
    for (int i = 0; i < 4; i++) {
        int row = bm0 + wm + i * 16 + lrow;
#pragma unroll
        for (int j = 0; j < 4; j++) {
            int col = bn0 + wn + j * 16 + q * 4;
            if (col < d.N) {
                float4 bv = d.bias ? *(const float4*)(&d.bias[col]) : float4{0.f, 0.f, 0.f, 0.f};
                uint2 pv;
                pv.x = pk_bf16(acc[i][j][0] + bv.x, acc[i][j][1] + bv.y);
                pv.y = pk_bf16(acc[i][j][2] + bv.z, acc[i][j][3] + bv.w);
                *(uint2*)(&d.C[(size_t)row * d.ldc + col]) = pv;
            }
        }
    }
}

// ---------------- LayerNorm(64) + SiLU (bf16 io, f32 params) ----------------
__global__ __launch_bounds__(256) void k_ln_silu(const u16* __restrict__ in, u16* __restrict__ out,
                                                 const float* __restrict__ g, const float* __restrict__ b) {
    int tid = threadIdx.x;
    int e = blockIdx.x * 4 + (tid >> 6);
    int c = tid & 63;
    float x = bf2f(in[(size_t)e * 64 + c]);
    float s = x, s2 = x * x;
#pragma unroll
    for (int o = 32; o; o >>= 1) { s += __shfl_xor(s, o); s2 += __shfl_xor(s2, o); }
    float mu = s * (1.f / 64.f);
    float var = s2 * (1.f / 64.f) - mu * mu;
    float rs = rsqrtf(var + 1e-5f);
    float y = (x - mu) * rs * g[c] + b[c];
    out[(size_t)e * 64 + c] = f2bf(siluf_(y));
}

// ---------------- rotate: wigner @ concat(nf[snd],nf[rcv]); scale by x_edge; pack A1 (chunked) ----------------
__global__ __launch_bounds__(256) void k_rotate(const float* __restrict__ nf, const float* __restrict__ wig,
                                                const int* __restrict__ snd, const int* __restrict__ rcv,
                                                const u16* __restrict__ xe, u16* __restrict__ A1, int e0) {
    __shared__ float wl[2][475];
    int tid = threadIdx.x;
    for (int i = tid; i < 950; i += 256) {
        int ee = e0 + blockIdx.x * 2 + (i / 475);
        wl[i / 475][i % 475] = wig[(size_t)ee * 475 + (i % 475)];
    }
    __syncthreads();
    int le = tid >> 7, c = tid & 127;
    int el = blockIdx.x * 2 + le;       // chunk-local
    int e = e0 + el;                    // global
    int nd = (c < 64) ? snd[e] : rcv[e];
    int cc = c & 63;
    float msg[25];
#pragma unroll
    for (int k = 0; k < 25; k++) msg[k] = nf[(size_t)nd * 1600 + k * 64 + cc];
    const float* w = wl[le];
    size_t ebase = (size_t)el * 2432;
    size_t xbase = (size_t)el * 1536;
#pragma unroll
    for (int m = 0; m < 19; m++) {
        float r = 0.f;
#pragma unroll
        for (int k = 0; k < 25; k++) r += w[m * 25 + k] * msg[k];
        int a1c, xc;
        if (m < 5)       { a1c = m * 128;               xc = m * 128; }
        else if (m < 9)  { a1c = 640 + (m - 5) * 128;   xc = 640 + (m - 5) * 128; }
        else if (m < 13) { a1c = 1152 + (m - 9) * 128;  xc = 640 + (m - 9) * 128; }
        else if (m < 16) { a1c = 1664 + (m - 13) * 128; xc = 1152 + (m - 13) * 128; }
        else             { a1c = 2048 + (m - 16) * 128; xc = 1152 + (m - 16) * 128; }
        float sc = bf2f(xe[xbase + xc + c]);
        A1[ebase + a1c + c] = f2bf(r * sc);
    }
}

// ---------------- attention logits + segment max ----------------
__global__ __launch_bounds__(256) void k_logits(const u16* __restrict__ Y0, const int* __restrict__ rcv,
                                                const float* __restrict__ g, const float* __restrict__ b,
                                                const float* __restrict__ adot,
                                                float* __restrict__ logits, u32* __restrict__ nmax) {
    int e = blockIdx.x;
    int tid = threadIdx.x;
    int h = tid >> 5, c = tid & 31;
    float x = bf2f(Y0[(size_t)e * 640 + 320 + h * 32 + c]);
    float s = x, s2 = x * x;
#pragma unroll
    for (int o = 16; o; o >>= 1) { s += __shfl_xor(s, o); s2 += __shfl_xor(s2, o); }
    float mu = s * (1.f / 32.f);
    float var = s2 * (1.f / 32.f) - mu * mu;
    float rs = rsqrtf(var + 1e-5f);
    float a = (x - mu) * rs * g[c] + b[c];
    float f = 0.6f * a + 0.4f * a * (2.f * sigmoidf_(a) - 1.f);
    float l = f * adot[h * 32 + c];
#pragma unroll
    for (int o = 16; o; o >>= 1) l += __shfl_xor(l, o);
    if (c == 0) {
        logits[e * 8 + h] = l;
        atomicMax(&nmax[rcv[e] * 8 + h], encf(l));
    }
}

__global__ void k_expsum(const float* __restrict__ logits, const int* __restrict__ rcv,
                         const u32* __restrict__ nmax, float* __restrict__ ealpha, float* __restrict__ nsum) {
    int idx = blockIdx.x * 256 + threadIdx.x;
    if (idx >= E_EDGES * 8) return;
    int e = idx >> 3, h = idx & 7;
    int r = rcv[e];
    float amax = decf(nmax[r * 8 + h]);
    if (!(amax > -1e38f && amax < 1e38f)) amax = 0.f;
    float v = __expf(logits[idx] - amax);
    ealpha[idx] = v;
    atomicAdd(&nsum[r * 8 + h], v);
}

// ---------------- grid round-trip via MFMA ----------------
// LDS: Xs aliased into T1s (Xs fully consumed into registers before T1s written).
#define GR_XS_STR 40
#define GR_T1_STR 136
__global__ __launch_bounds__(256) void k_grid_mfma(
    const u16* __restrict__ Y0, const u16* __restrict__ Y1, const u16* __restrict__ Y2,
    const u16* __restrict__ tgP, const u16* __restrict__ fgP, u16* __restrict__ A2) {
    __shared__ u16 T1s[128 * GR_T1_STR];
    u16* Xs = T1s;                       // alias: see barrier discipline below
    int tid = threadIdx.x;
    int e0 = blockIdx.x * 2;
    // stage Xs[ec][m]: thread owns (le, c0-block, m-pair); packed u32 writes
    {
        int mp = tid & 15;                  // m-pair 0..15 -> m = 2mp, 2mp+1
        int c0 = ((tid >> 4) & 7) << 3;     // channel block 0..56
        int le = tid >> 7;                  // local edge 0/1
        int e = e0 + le;
        int m0 = 2 * mp, m1 = m0 + 1;
        uint4 va = {0, 0, 0, 0}, vb = {0, 0, 0, 0};
        if (m0 < 5)       va = *(const uint4*)(&Y0[(size_t)e * 640 + m0 * 64 + c0]);
        else if (m0 < 13) va = *(const uint4*)(&Y1[(size_t)e * 512 + (m0 - 5) * 64 + c0]);
        else if (m0 < 19) va = *(const uint4*)(&Y2[(size_t)e * 384 + (m0 - 13) * 64 + c0]);
        if (m1 < 5)       vb = *(const uint4*)(&Y0[(size_t)e * 640 + m1 * 64 + c0]);
        else if (m1 < 13) vb = *(const uint4*)(&Y1[(size_t)e * 512 + (m1 - 5) * 64 + c0]);
        else if (m1 < 19) vb = *(const uint4*)(&Y2[(size_t)e * 384 + (m1 - 13) * 64 + c0]);
        const u16* pa = (const u16*)&va;
        const u16* pb = (const u16*)&vb;
        int rbase = le * 64 + c0;
#pragma unroll
        for (int j = 0; j < 8; j++) {
            u32 w = (u32)pa[j] | ((u32)pb[j] << 16);
            *(u32*)(&Xs[(rbase + j) * GR_XS_STR + 2 * mp]) = w;
        }
    }
    __syncthreads();
    int wave = tid >> 6, lane = tid & 63;
    int wn = wave << 5;                     // this wave's 32 ec-columns
    int ln = lane & 15, q = lane >> 4;
    // GEMM1 (swapped): A = tgP (p x m), B^T = Xs (ec x m). Out rows = p, cols = ec.
    short8 bx0 = *(const short8*)(&Xs[(wn + ln) * GR_XS_STR + q * 8]);
    short8 bx1 = *(const short8*)(&Xs[(wn + 16 + ln) * GR_XS_STR + q * 8]);
    floatx4 acc1[2][7];
#pragma unroll
    for (int pt = 0; pt < 7; pt++) {
        short8 a = *(const short8*)(&tgP[(size_t)(pt * 16 + ln) * 32 + q * 8]);
        acc1[0][pt] = __builtin_amdgcn_mfma_f32_16x16x32_bf16(a, bx0, floatx4{0.f, 0.f, 0.f, 0.f}, 0, 0, 0);
        acc1[1][pt] = __builtin_amdgcn_mfma_f32_16x16x32_bf16(a, bx1, floatx4{0.f, 0.f, 0.f, 0.f}, 0, 0, 0);
    }
    __syncthreads();    // all Xs reads complete -> safe to overwrite (alias)
    // zero T1s pad cols 112..127 (cols 100..111 are exact zeros from the zeroed tgP rows)
    {
        int row = tid >> 1;
        uint4 z = {0, 0, 0, 0};
        *(uint4*)(&T1s[row * GR_T1_STR + 112 + (tid & 1) * 8]) = z;
    }
    // silu -> T1s[ec][p]: lane holds p = pt*16 + q*4 + r at ec = wn + i*16 + ln -> b64 writes
#pragma unroll
    for (int i = 0; i < 2; i++) {
        u16* dst = &T1s[(wn + i * 16 + ln) * GR_T1_STR + q * 4];
#pragma unroll
        for (int pt = 0; pt < 7; pt++) {
            uint2 pv;
            pv.x = pk_bf16(siluf_(acc1[i][pt][0]), siluf_(acc1[i][pt][1]));
            pv.y = pk_bf16(siluf_(acc1[i][pt][2]), siluf_(acc1[i][pt][3]));
            *(uint2*)(dst + pt * 16) = pv;
        }
    }
    __syncthreads();
    // GEMM2: K=128 (4 steps)
    floatx4 acc2[2][2];
    acc2[0][0] = floatx4{0.f, 0.f, 0.f, 0.f}; acc2[0][1] = floatx4{0.f, 0.f, 0.f, 0.f};
    acc2[1][0] = floatx4{0.f, 0.f, 0.f, 0.f}; acc2[1][1] = floatx4{0.f, 0.f, 0.f, 0.f};
#pragma unroll
    for (int ks = 0; ks < 4; ks++) {
        short8 c0 = *(const short8*)(&T1s[(wn + ln) * GR_T1_STR + ks * 32 + q * 8]);
        short8 c1 = *(const short8*)(&T1s[(wn + 16 + ln) * GR_T1_STR + ks * 32 + q * 8]);
#pragma unroll
        for (int ct = 0; ct < 2; ct++) {
            short8 b = *(const short8*)(&fgP[(size_t)(ct * 16 + ln) * 128 + ks * 32 + q * 8]);
            acc2[0][ct] = __builtin_amdgcn_mfma_f32_16x16x32_bf16(c0, b, acc2[0][ct], 0, 0, 0);
            acc2[1][ct] = __builtin_amdgcn_mfma_f32_16x16x32_bf16(c1, b, acc2[1][ct], 0, 0, 0);
        }
    }
    // direct store: lane holds col m'=ct*16+ln, rows q*4+r -> 4 consecutive c in A2
#pragma unroll
    for (int rt = 0; rt < 2; rt++) {
        int row = wn + rt * 16 + q * 4;
        int e = e0 + (row >> 6), c = row & 63;
#pragma unroll
        for (int ct = 0; ct < 2; ct++) {
            int mp = ct * 16 + ln;
            if (mp >= 1 && mp < 19) {
                uint2 pv;
                pv.x = pk_bf16(acc2[rt][ct][0], acc2[rt][ct][1]);
                pv.y = pk_bf16(acc2[rt][ct][2], acc2[rt][ct][3]);
                *(uint2*)(&A2[(size_t)e * 1216 + mp * 64 + c]) = pv;
            }
        }
    }
    // m=0 gate row
    if (tid < 128) {
        int e = e0 + (tid >> 6), c = tid & 63;
        float gate = bf2f(Y0[(size_t)e * 640 + 576 + c]);
        A2[(size_t)e * 1216 + c] = f2bf(siluf_(gate));
    }
}

// ---------------- gather: attention scale + wigner^T + segment-sum (no atomics) ----------------
// WAVE-PER-NODE, zero-sync, zero-LDS. Lane owns channel pair (2l, 2l+1) via packed u32
// bf16 loads. Wigner pointer kept scalar via readfirstlane. Two passes over Z chunks.
__global__ __launch_bounds__(256) void k_gather(
    const u16* __restrict__ Z0, const u16* __restrict__ Z1, const u16* __restrict__ Z2,
    const float* __restrict__ wig, const float* __restrict__ ealpha, const float* __restrict__ nsum,
    const u32* __restrict__ rowstart, const u32* __restrict__ deg, const int* __restrict__ elist,
    float* __restrict__ node, int e0, int accum) {
    int n = blockIdx.x * 4 + (threadIdx.x >> 6);
    int lane = threadIdx.x & 63;
    int h = lane >> 3;                  // head of channels 2l,2l+1 (same head for both)
    float sden = __fdividef(1.f, nsum[n * 8 + h] + 1e-16f);
    float a0[25], a1[25];
#pragma unroll
    for (int k = 0; k < 25; k++) { a0[k] = 0.f; a1[k] = 0.f; }
    u32 lo = rowstart[n], cnt = deg[n];
    bool did = false;
    for (u32 i = 0; i < cnt; i++) {
        int e = __builtin_amdgcn_readfirstlane(elist[lo + i]);
        int el = e - e0;
        if ((u32)el >= (u32)EC) continue;       // wave-uniform
        did = true;
        float al = ealpha[e * 8 + h] * sden;
        u32 zp[19];
        const u16* z0 = Z0 + (size_t)el * 640 + 2 * lane;
        const u16* z1 = Z1 + (size_t)el * 1024 + 2 * lane;
        const u16* z2 = Z2 + (size_t)el * 768 + 2 * lane;
#pragma unroll
        for (int m = 0; m < 5; m++) zp[m] = *(const u32*)(z0 + m * 128);
#pragma unroll
        for (int m = 0; m < 8; m++) zp[5 + m] = *(const u32*)(z1 + m * 128);
#pragma unroll
        for (int m = 0; m < 6; m++) zp[13 + m] = *(const u32*)(z2 + m * 128);
        const float* __restrict__ w = wig + (size_t)e * 475;
#pragma unroll
        for (int m = 0; m < 19; m++) {
            float s0 = bf2f((u16)(zp[m] & 0xffffu)) * al;
            float s1 = bf2f((u16)(zp[m] >> 16)) * al;
#pragma unroll
            for (int k = 0; k < 25; k++) {
                float wv = w[m * 25 + k];
                a0[k] = fmaf(wv, s0, a0[k]);
                a1[k] = fmaf(wv, s1, a1[k]);
            }
        }
    }
    float* nb = node + (size_t)n * 3200 + 2 * lane;
    if (accum) {
        if (!did) return;                       // wave-uniform
#pragma unroll
        for (int k = 0; k < 25; k++) {
            float2 v = *(float2*)(&nb[k * 128]);
            v.x += a0[k]; v.y += a1[k];
            *(float2*)(&nb[k * 128]) = v;
        }
    } else {
#pragma unroll
        for (int k = 0; k < 25; k++) {
            float2 v; v.x = a0[k]; v.y = a1[k];
            *(float2*)(&nb[k * 128]) = v;
        }
    }
}

// ---------------- final projection via MFMA ----------------
// Operand-swapped MFMA: lane holds 4 consecutive d at one n -> float4 stores.
#define PJ_STR 136
__global__ __launch_bounds__(256) void k_proj_mfma(
    const float* __restrict__ node, const u16* __restrict__ pwTb,
    const float* __restrict__ pb, float* __restrict__ out) {
    __shared__ u16 As[128 * PJ_STR];
    __shared__ u16 Bs[64 * PJ_STR];
    int tid = threadIdx.x;
    int n0 = blockIdx.x * 128;
    int k = blockIdx.y;
    int l = (int)sqrtf((float)k + 0.5f);
#pragma unroll
    for (int it = 0; it < 16; it++) {
        int i = tid + it * 256;
        int row = i >> 5;
        int c0 = (i & 31) << 2;
        float4 v = *(const float4*)(&node[(size_t)(n0 + row) * 3200 + k * 128 + c0]);
        uint2 pv;
        pv.x = pk_bf16(v.x, v.y);
        pv.y = pk_bf16(v.z, v.w);
        *(uint2*)(&As[row * PJ_STR + c0]) = pv;
    }
    const u16* pw = pwTb + (size_t)l * 8192;
#pragma unroll
    for (int jt = 0; jt < 4; jt++) {
        int j = tid + jt * 256;
        int d = j >> 4;
        int c0 = (j & 15) << 3;
        *(uint4*)(&Bs[d * PJ_STR + c0]) = *(const uint4*)(&pw[d * 128 + c0]);
    }
    __syncthreads();
    int wave = tid >> 6, lane = tid & 63;
    int wr = wave * 32;
    int ln = lane & 15, q = lane >> 4;
    floatx4 acc[2][4];
#pragma unroll
    for (int i = 0; i < 2; i++)
#pragma unroll
        for (int j = 0; j < 4; j++) acc[i][j] = floatx4{0.f, 0.f, 0.f, 0.f};
#pragma unroll
    for (int ks = 0; ks < 4; ks++) {
        short8 a0 = *(const short8*)(&As[(wr + ln) * PJ_STR + ks * 32 + q * 8]);
        short8 a1 = *(const short8*)(&As[(wr + 16 + ln) * PJ_STR + ks * 32 + q * 8]);
#pragma unroll
        for (int j = 0; j < 4; j++) {
            short8 b = *(const short8*)(&Bs[(j * 16 + ln) * PJ_STR + ks * 32 + q * 8]);
            acc[0][j] = __builtin_amdgcn_mfma_f32_16x16x32_bf16(b, a0, acc[0][j], 0, 0, 0);
            acc[1][j] = __builtin_amdgcn_mfma_f32_16x16x32_bf16(b, a1, acc[1][j], 0, 0, 0);
        }
    }
#pragma unroll
    for (int rt = 0; rt < 2; rt++) {
        int n = n0 + wr + rt * 16 + ln;
#pragma unroll
        for (int j = 0; j < 4; j++) {
            int d = j * 16 + q * 4;
            float4 v;
            v.x = acc[rt][j][0]; v.y = acc[rt][j][1];
            v.z = acc[rt][j][2]; v.w = acc[rt][j][3];
            if (k == 0) {
                float4 bv = *(const float4*)(&pb[d]);
                v.x += bv.x; v.y += bv.y; v.z += bv.z; v.w += bv.w;
            }
            *(float4*)(&out[(size_t)n * 1600 + k * 64 + d]) = v;
        }
    }
}

extern "C" void kernel_launch(void* const* d_in, const int* in_sizes, int n_in,
                              void* d_out, int out_size, void* d_ws, size_t ws_size,
                              hipStream_t stream) {
    const float* nf      = (const float*)d_in[0];
    const int* species   = (const int*)d_in[1];
    const float* dist    = (const float*)d_in[2];
    const int* snd       = (const int*)d_in[3];
    const int* rcv       = (const int*)d_in[4];
    const float* wig     = (const float*)d_in[5];
    const float* semb    = (const float*)d_in[6];
    const float* remb    = (const float*)d_in[7];
    const float* rad_w1  = (const float*)d_in[8];
    const float* rad_b1  = (const float*)d_in[9];
    const float* rad_g1  = (const float*)d_in[10];
    const float* rad_be1 = (const float*)d_in[11];
    const float* rad_w2  = (const float*)d_in[12];
    const float* rad_b2  = (const float*)d_in[13];
    const float* rad_g2  = (const float*)d_in[14];
    const float* rad_be2 = (const float*)d_in[15];
    const float* rad_w3  = (const float*)d_in[16];
    const float* rad_b3  = (const float*)d_in[17];
    const float* c1_w0   = (const float*)d_in[18];
    const float* c1_b0   = (const float*)d_in[19];
    const float* c1_wm1  = (const float*)d_in[20];
    const float* c1_wm2  = (const float*)d_in[21];
    const float* aln_g   = (const float*)d_in[22];
    const float* aln_b   = (const float*)d_in[23];
    const float* adot    = (const float*)d_in[24];
    const float* to_grid = (const float*)d_in[25];
    const float* from_grid=(const float*)d_in[26];
    const float* c2_w0   = (const float*)d_in[27];
    const float* c2_b0   = (const float*)d_in[28];
    const float* c2_wm1  = (const float*)d_in[29];
    const float* c2_wm2  = (const float*)d_in[30];
    const float* proj_w  = (const float*)d_in[31];
    const float* proj_b  = (const float*)d_in[32];

    char* ws = (char*)d_ws;
    size_t off = 0;
    auto take = [&](size_t bytes) -> char* {
        char* p = ws + off;
        off += (bytes + 255) & ~(size_t)255;
        return p;
    };
    // fixed section
    u16* w_rad1T  = (u16*)take(64 * 192 * 2);
    u16* w_rad2T  = (u16*)take(64 * 64 * 2);
    u16* w_rad3T  = (u16*)take(1536 * 64 * 2);
    u16* w_c1w0T  = (u16*)take(640 * 640 * 2);
    u16* w_c1m1T  = (u16*)take((size_t)512 * 1024 * 2);
    u16* w_c1m2T  = (u16*)take((size_t)384 * 768 * 2);
    u16* w_c2w0T  = (u16*)take((size_t)640 * 320 * 2);
    u16* w_c2m1T  = (u16*)take((size_t)1024 * 512 * 2);
    u16* w_c2m2T  = (u16*)take((size_t)768 * 384 * 2);
    u16* w_tgP    = (u16*)take(112 * 32 * 2);
    u16* w_fgP    = (u16*)take(32 * 128 * 2);
    u16* w_pwT    = (u16*)take(5 * 8192 * 2);
    float* logits = (float*)take((size_t)E_EDGES * 8 * 4);
    float* ealpha = (float*)take((size_t)E_EDGES * 8 * 4);
    u32* nmax     = (u32*)take((size_t)N_NODES_C * 8 * 4);
    float* nsum   = (float*)take((size_t)N_NODES_C * 8 * 4);
    float* node   = (float*)take((size_t)N_NODES_C * 3200 * 4);
    u16* a_h2     = (u16*)take((size_t)E_EDGES * 64 * 2);
    u32* c_deg    = (u32*)take((size_t)N_NODES_C * 4);
    u32* c_row    = (u32*)take((size_t)N_NODES_C * 4);
    u32* c_cur    = (u32*)take((size_t)N_NODES_C * 4);
    int* c_elist  = (int*)take((size_t)E_EDGES * 4);
    // arena — aliased by phase
    char* arena   = take(173015040);
    if (off > ws_size) {  // diagnostic: paint output so the failure mode is identifiable
        k_diag<<<(out_size + 255) / 256, 256, 0, stream>>>((float*)d_out, out_size);
        return;
    }

    u16* a_ee   = (u16*)(arena + 0);           // radial phase
    u16* a_ypre = (u16*)(arena + 9437184);
    u16* a_h1   = (u16*)(arena + 12582912);
    u16* a_xe   = (u16*)(arena + 0);           // per-chunk (EC,1536); radial staging dead
    u16* a_A1   = (u16*)(arena + 37748736);    // per-chunk (EC,2432)
    u16* a_Y0   = (u16*)(arena + 97517568);    // full (E,640)
    u16* a_Y1   = (u16*)(arena + 128974848);   // full (E,512)
    u16* a_Y2   = (u16*)(arena + 154140672);   // full (E,384) -> arena end
    u16* a_A2   = (u16*)(arena + 0);           // full (E,1216); xe/A1 dead
    u16* a_Z0   = (u16*)(arena + 59768832);    // per-chunk (EC,640)
    u16* a_Z1   = (u16*)(arena + 75497472);    // per-chunk (EC,1024)
    u16* a_Z2   = (u16*)(arena + 100663296);   // per-chunk (EC,768); overlaps dead Y0 region

    // ---- fused prep (weights + init + deg-zero + edge embeds): 18 launches -> 1 ----
    PrepArgs pa;
    pa.rad_w1 = rad_w1; pa.rad_w2 = rad_w2; pa.rad_w3 = rad_w3;
    pa.c1_w0 = c1_w0; pa.c2_w0 = c2_w0;
    pa.c1_wm1 = c1_wm1; pa.c1_wm2 = c1_wm2; pa.c2_wm1 = c2_wm1; pa.c2_wm2 = c2_wm2;
    pa.to_grid = to_grid; pa.from_grid = from_grid; pa.proj_w = proj_w;
    pa.w_rad1T = w_rad1T; pa.w_rad2T = w_rad2T; pa.w_rad3T = w_rad3T;
    pa.w_c1w0T = w_c1w0T; pa.w_c2w0T = w_c2w0T;
    pa.w_c1m1T = w_c1m1T; pa.w_c1m2T = w_c1m2T; pa.w_c2m1T = w_c2m1T; pa.w_c2m2T = w_c2m2T;
    pa.w_tgP = w_tgP; pa.w_fgP = w_fgP; pa.w_pwT = w_pwT;
    pa.nmax = nmax; pa.nsum = nsum; pa.c_deg = c_deg;
    pa.dist = dist; pa.species = species; pa.snd = snd; pa.rcv = rcv;
    pa.semb = semb; pa.remb = remb; pa.ee = a_ee;
    k_prep<<<PREP_BLOCKS, 256, 0, stream>>>(pa);

    // ---- CSR build (receivers static per launch; c_deg zeroed in prep) ----
    k_deg<<<96, 256, 0, stream>>>(rcv, c_deg);
    k_pfx<<<1, 256, 0, stream>>>(c_deg, c_row, c_cur);
    k_fill<<<96, 256, 0, stream>>>(rcv, c_cur, c_elist);

    // ---- radial MLP (full E) ----
    k_gemm<<<dim3(192, 1), 256, 0, stream>>>(a_ee, 192, w_rad1T, 192, a_ypre, 64, 64, 192, rad_b1);
    k_ln_silu<<<6144, 256, 0, stream>>>(a_ypre, a_h1, rad_g1, rad_be1);
    k_gemm<<<dim3(192, 1), 256, 0, stream>>>(a_h1, 64, w_rad2T, 64, a_ypre, 64, 64, 64, rad_b2);
    k_ln_silu<<<6144, 256, 0, stream>>>(a_ypre, a_h2, rad_g2, rad_be2);

    // ---- chunked: x_edge gemm -> rotate -> conv1 (3 gemms fused into 1 launch) ----
    for (int c = 0; c < 2; c++) {
        int e0 = c * EC;
        k_gemm<<<dim3(96, 12), 256, 0, stream>>>(a_h2 + (size_t)e0 * 64, 64, w_rad3T, 64,
                                                 a_xe, 1536, 1536, 64, rad_b3);
        k_rotate<<<EC / 2, 256, 0, stream>>>(nf, wig, snd, rcv, a_xe, a_A1, e0);
        Gemm3 g1;
        g1.d[0] = { a_A1,        w_c1w0T, a_Y0 + (size_t)e0 * 640, c1_b0,   2432, 640,  640, 640, 640 };
        g1.d[1] = { a_A1 + 640,  w_c1m1T, a_Y1 + (size_t)e0 * 512, nullptr, 2432, 1024, 512, 512, 1024 };
        g1.d[2] = { a_A1 + 1664, w_c1m2T, a_Y2 + (size_t)e0 * 384, nullptr, 2432, 768,  384, 384, 768 };
        g1.cut0 = 5; g1.cut1 = 9;   // 5 + 4 + 3 = 12 y-tiles
        k_gemm3<<<dim3(96, 12), 256, 0, stream>>>(g1);
    }

    // ---- attention softmax pieces ----
    k_logits<<<E_EDGES, 256, 0, stream>>>(a_Y0, rcv, aln_g, aln_b, adot, logits, nmax);
    k_expsum<<<(E_EDGES * 8 + 255) / 256, 256, 0, stream>>>(logits, rcv, nmax, ealpha, nsum);

    // ---- grid nonlinearity -> packed A2 (full E, MFMA) ----
    k_grid_mfma<<<E_EDGES / 2, 256, 0, stream>>>(a_Y0, a_Y1, a_Y2, w_tgP, w_fgP, a_A2);

    // ---- chunked: conv2 (3 gemms fused) -> gather ----
    for (int c = 0; c < 2; c++) {
        int e0 = c * EC;
        Gemm3 g2;
        g2.d[0] = { a_A2 + (size_t)e0 * 1216,       w_c2w0T, a_Z0, c2_b0,   1216, 320, 640,  640,  320 };
        g2.d[1] = { a_A2 + (size_t)e0 * 1216 + 320, w_c2m1T, a_Z1, nullptr, 1216, 512, 1024, 1024, 512 };
        g2.d[2] = { a_A2 + (size_t)e0 * 1216 + 832, w_c2m2T, a_Z2, nullptr, 1216, 384, 768,  768,  384 };
        g2.cut0 = 5; g2.cut1 = 13;  // 5 + 8 + 6 = 19 y-tiles
        k_gemm3<<<dim3(96, 19), 256, 0, stream>>>(g2);
        k_gather<<<N_NODES_C / 4, 256, 0, stream>>>(a_Z0, a_Z1, a_Z2, wig, ealpha, nsum,
                                                    c_row, c_deg, c_elist, node, e0, c);
    }

    // ---- output projection (MFMA) ----
    k_proj_mfma<<<dim3(32, 25), 256, 0, stream>>>(node, w_pwT, proj_b, (float*)d_out);
}

// Round 9
// 900.098 us; speedup vs baseline: 1.2184x; 1.0130x over previous
//
#include <hip/hip_runtime.h>

typedef unsigned short u16;
typedef unsigned int u32;
typedef __attribute__((ext_vector_type(8))) short short8;
typedef __attribute__((ext_vector_type(4))) float floatx4;

#define E_EDGES 24576
#define EC 12288            // edge chunk
#define N_NODES_C 4096

__device__ __forceinline__ float bf2f(u16 u) {
    union { u32 i; float f; } v; v.i = ((u32)u) << 16; return v.f;
}
__device__ __forceinline__ u16 f2bf(float f) {
    union { float f; u32 i; } v; v.f = f;
    u32 x = v.i;
    u32 r = (x + 0x7fffu + ((x >> 16) & 1u)) >> 16;
    return (u16)r;
}
// packed f32x2 -> bf16x2 in one VALU inst (RNE), no builtin on gfx950 -> inline asm
__device__ __forceinline__ u32 pk_bf16(float a, float b) {
    u32 r;
    asm("v_cvt_pk_bf16_f32 %0, %1, %2" : "=v"(r) : "v"(a), "v"(b));
    return r;
}
__device__ __forceinline__ u32 encf(float f) {
    union { float f; u32 i; } v; v.f = f;
    return (v.i & 0x80000000u) ? ~v.i : (v.i | 0x80000000u);
}
__device__ __forceinline__ float decf(u32 u) {
    union { u32 i; float f; } v;
    v.i = (u & 0x80000000u) ? (u ^ 0x80000000u) : ~u;
    return v.f;
}
// fast transcendentals: v_exp_f32 + v_rcp_f32
__device__ __forceinline__ float sigmoidf_(float x) { return __fdividef(1.f, 1.f + __expf(-x)); }
__device__ __forceinline__ float siluf_(float x) { return x * __fdividef(1.f, 1.f + __expf(-x)); }

// async global->LDS, 16B per lane; LDS dest must be wave-uniform base + lane*16
__device__ __forceinline__ void gld16(const u16* g, u16* l) {
    __builtin_amdgcn_global_load_lds((const __attribute__((address_space(1))) unsigned int*)g,
                                     (__attribute__((address_space(3))) unsigned int*)l, 16, 0, 0);
}

// diagnostic: ws too small -> paint output with 1000 (f32)
__global__ void k_diag(float* __restrict__ out, int n) {
    int i = blockIdx.x * 256 + threadIdx.x;
    if (i < n) out[i] = 1000.0f;
}

// ================= fused prep: all weight prep + init + deg-zero + edge embeds =================
struct PrepArgs {
    const float *rad_w1, *rad_w2, *rad_w3, *c1_w0, *c2_w0;
    const float *c1_wm1, *c1_wm2, *c2_wm1, *c2_wm2;
    const float *to_grid, *from_grid, *proj_w;
    u16 *w_rad1T, *w_rad2T, *w_rad3T, *w_c1w0T, *w_c2w0T;
    u16 *w_c1m1T, *w_c1m2T, *w_c2m1T, *w_c2m2T;
    u16 *w_tgP, *w_fgP, *w_pwT;
    u32 *nmax; float *nsum; u32 *c_deg;
    const float *dist; const int *species, *snd, *rcv;
    const float *semb, *remb; u16 *ee;
};

__device__ __forceinline__ void prep_transpose(const float* __restrict__ src, u16* __restrict__ dst,
                                               int K, int N, int idx) {
    if (idx >= K * N) return;
    int k = idx / N, n = idx % N;
    dst[n * K + k] = f2bf(src[idx]);
}
__device__ __forceinline__ void prep_combine(const float* __restrict__ src, u16* __restrict__ dst,
                                             int K, int H, int idx) {
    if (idx >= 4 * K * H) return;
    int n = idx / (2 * K), k = idx % (2 * K);
    float v;
    if (k < K) v = src[k * 2 * H + n];
    else {
        int kk = k - K;
        if (n < H) v = -src[kk * 2 * H + H + n];
        else       v = src[kk * 2 * H + (n - H)];
    }
    dst[idx] = f2bf(v);
}

#define PB0 48
#define PB1 16
#define PB2 384
#define PB3 1600
#define PB4 800
#define PB5 2048
#define PB6 1152
#define PB7 2048
#define PB8 1152
#define PB9 30
#define PB10 160
#define PB11 128
#define PB12 16
#define PB13 18432
#define PREP_BLOCKS (PB0+PB1+PB2+PB3+PB4+PB5+PB6+PB7+PB8+PB9+PB10+PB11+PB12+PB13)

__global__ __launch_bounds__(256) void k_prep(PrepArgs a) {
    int bid = blockIdx.x;
    int tid = threadIdx.x;
    if (bid < PB0) { prep_transpose(a.rad_w1, a.w_rad1T, 192, 64, bid * 256 + tid); return; }
    bid -= PB0;
    if (bid < PB1) { prep_transpose(a.rad_w2, a.w_rad2T, 64, 64, bid * 256 + tid); return; }
    bid -= PB1;
    if (bid < PB2) { prep_transpose(a.rad_w3, a.w_rad3T, 64, 1536, bid * 256 + tid); return; }
    bid -= PB2;
    if (bid < PB3) { prep_transpose(a.c1_w0, a.w_c1w0T, 640, 640, bid * 256 + tid); return; }
    bid -= PB3;
    if (bid < PB4) { prep_transpose(a.c2_w0, a.w_c2w0T, 320, 640, bid * 256 + tid); return; }
    bid -= PB4;
    if (bid < PB5) { prep_combine(a.c1_wm1, a.w_c1m1T, 512, 256, bid * 256 + tid); return; }
    bid -= PB5;
    if (bid < PB6) { prep_combine(a.c1_wm2, a.w_c1m2T, 384, 192, bid * 256 + tid); return; }
    bid -= PB6;
    if (bid < PB7) { prep_combine(a.c2_wm1, a.w_c2m1T, 256, 512, bid * 256 + tid); return; }
    bid -= PB7;
    if (bid < PB8) { prep_combine(a.c2_wm2, a.w_c2m2T, 192, 384, bid * 256 + tid); return; }
    bid -= PB8;
    if (bid < PB9) {
        int idx = bid * 256 + tid;
        if (idx < 112 * 32) {
            int p = idx >> 5, m = idx & 31;
            a.w_tgP[idx] = (p < 100 && m < 19) ? f2bf(a.to_grid[p * 19 + m]) : (u16)0;
        }
        int j = idx - 112 * 32;
        if (j >= 0 && j < 32 * 128) {
            int m = j >> 7, k = j & 127;
            a.w_fgP[j] = (m < 19 && k < 100) ? f2bf(a.from_grid[m * 100 + k]) : (u16)0;
        }
        return;
    }
    bid -= PB9;
    if (bid < PB10) {
        int idx = bid * 256 + tid;
        int l = idx >> 13, rem = idx & 8191;
        prep_transpose(a.proj_w + (size_t)l * 8192, a.w_pwT + (size_t)l * 8192, 128, 64, rem);
        return;
    }
    bid -= PB10;
    if (bid < PB11) {
        int idx = bid * 256 + tid;
        if (idx < N_NODES_C * 8) { a.nmax[idx] = 0x007FFFFFu; a.nsum[idx] = 0.f; }
        return;
    }
    bid -= PB11;
    if (bid < PB12) {
        int idx = bid * 256 + tid;
        if (idx < N_NODES_C) a.c_deg[idx] = 0u;
        return;
    }
    bid -= PB12;
    {
        int idx = bid * 256 + tid;
        if (idx >= E_EDGES * 192) return;
        int e = idx / 192, c = idx % 192;
        float v;
        if (c < 64)       v = a.dist[e * 64 + c];
        else if (c < 128) v = a.semb[a.species[a.snd[e]] * 64 + (c - 64)];
        else              v = a.remb[a.species[a.rcv[e]] * 64 + (c - 128)];
        a.ee[idx] = f2bf(v);
    }
}

// ---------------- CSR build over receivers (static per launch) ----------------
__global__ void k_deg(const int* __restrict__ rcv, u32* __restrict__ deg) {
    int e = blockIdx.x * 256 + threadIdx.x;
    if (e < E_EDGES) atomicAdd(&deg[rcv[e]], 1u);
}
__global__ __launch_bounds__(256) void k_pfx(const u32* __restrict__ deg,
                                             u32* __restrict__ rowstart, u32* __restrict__ cur) {
    __shared__ u32 ps[256];
    int t = threadIdx.x;
    u32 loc[16]; u32 s = 0;
#pragma unroll
    for (int i = 0; i < 16; i++) { loc[i] = s; s += deg[t * 16 + i]; }
    ps[t] = s;
    __syncthreads();
    for (int o = 1; o < 256; o <<= 1) {
        u32 v = (t >= o) ? ps[t - o] : 0u;
        __syncthreads();
        ps[t] += v;
        __syncthreads();
    }
    u32 base = (t == 0) ? 0u : ps[t - 1];
#pragma unroll
    for (int i = 0; i < 16; i++) { u32 v = base + loc[i]; rowstart[t * 16 + i] = v; cur[t * 16 + i] = v; }
}
__global__ void k_fill(const int* __restrict__ rcv, u32* __restrict__ cur, int* __restrict__ elist) {
    int e = blockIdx.x * 256 + threadIdx.x;
    if (e < E_EDGES) { u32 p = atomicAdd(&cur[rcv[e]], 1u); elist[p] = e; }
}

// ---------------- fused radial MLP: silu(LN(ee@W1+b1)) -> silu(LN(.@W2+b2)) -> h2 ----------------
// One kernel replaces gemm+ln_silu+gemm+ln_silu (4 dispatches). 128 edges/block, 4 waves.
// MFMA swapped-operand layout (lane = edge-row ln, cols j*16+q*4+r); row-LN via lane-local
// 16-col partial + shfl_xor(16/32) butterfly over the q groups. Y1 through LDS (stride 72
// u16 = 144B, 16B-aligned, ~4-way banked).
__global__ __launch_bounds__(256) void k_radmlp(
    const u16* __restrict__ ee, const u16* __restrict__ w1T, const u16* __restrict__ w2T,
    const float* __restrict__ b1, const float* __restrict__ g1, const float* __restrict__ be1,
    const float* __restrict__ b2, const float* __restrict__ g2, const float* __restrict__ be2,
    u16* __restrict__ h2) {
    __shared__ u16 Y1s[128 * 72];
    int tid = threadIdx.x;
    int wave = tid >> 6, lane = tid & 63;
    int ln = lane & 15, q = lane >> 4;
    int wm = wave * 32;
    int e0 = blockIdx.x * 128;

    floatx4 acc[2][4];
#pragma unroll
    for (int i = 0; i < 2; i++)
#pragma unroll
        for (int j = 0; j < 4; j++) acc[i][j] = floatx4{0.f, 0.f, 0.f, 0.f};
    // GEMM1: K=192
#pragma unroll
    for (int ks = 0; ks < 6; ks++) {
        short8 a0 = *(const short8*)(&ee[(size_t)(e0 + wm + ln) * 192 + ks * 32 + q * 8]);
        short8 a1 = *(const short8*)(&ee[(size_t)(e0 + wm + 16 + ln) * 192 + ks * 32 + q * 8]);
#pragma unroll
        for (int j = 0; j < 4; j++) {
            short8 b = *(const short8*)(&w1T[(size_t)(j * 16 + ln) * 192 + ks * 32 + q * 8]);
            acc[0][j] = __builtin_amdgcn_mfma_f32_16x16x32_bf16(b, a0, acc[0][j], 0, 0, 0);
            acc[1][j] = __builtin_amdgcn_mfma_f32_16x16x32_bf16(b, a1, acc[1][j], 0, 0, 0);
        }
    }
    // LN1 + silu -> Y1s
#pragma unroll
    for (int i = 0; i < 2; i++) {
        float s = 0.f, s2 = 0.f;
#pragma unroll
        for (int j = 0; j < 4; j++) {
            int cb = j * 16 + q * 4;
            float4 bv = *(const float4*)(&b1[cb]);
            float vb[4] = {bv.x, bv.y, bv.z, bv.w};
#pragma unroll
            for (int r = 0; r < 4; r++) {
                float v = acc[i][j][r] + vb[r];
                acc[i][j][r] = v;
                s += v; s2 += v * v;
            }
        }
        s += __shfl_xor(s, 16); s += __shfl_xor(s, 32);
        s2 += __shfl_xor(s2, 16); s2 += __shfl_xor(s2, 32);
        float mu = s * (1.f / 64.f);
        float var = s2 * (1.f / 64.f) - mu * mu;
        float rs = rsqrtf(var + 1e-5f);
        int row = wm + i * 16 + ln;
#pragma unroll
        for (int j = 0; j < 4; j++) {
            int cb = j * 16 + q * 4;
            float4 gv = *(const float4*)(&g1[cb]);
            float4 ev = *(const float4*)(&be1[cb]);
            float y0 = (acc[i][j][0] - mu) * rs * gv.x + ev.x;
            float y1 = (acc[i][j][1] - mu) * rs * gv.y + ev.y;
            float y2 = (acc[i][j][2] - mu) * rs * gv.z + ev.z;
            float y3 = (acc[i][j][3] - mu) * rs * gv.w + ev.w;
            uint2 pv;
            pv.x = pk_bf16(siluf_(y0), siluf_(y1));
            pv.y = pk_bf16(siluf_(y2), siluf_(y3));
            *(uint2*)(&Y1s[row * 72 + cb]) = pv;
        }
    }
    __syncthreads();
    // GEMM2: K=64
#pragma unroll
    for (int i = 0; i < 2; i++)
#pragma unroll
        for (int j = 0; j < 4; j++) acc[i][j] = floatx4{0.f, 0.f, 0.f, 0.f};
#pragma unroll
    for (int ks = 0; ks < 2; ks++) {
        short8 a0 = *(const short8*)(&Y1s[(wm + ln) * 72 + ks * 32 + q * 8]);
        short8 a1 = *(const short8*)(&Y1s[(wm + 16 + ln) * 72 + ks * 32 + q * 8]);
#pragma unroll
        for (int j = 0; j < 4; j++) {
            short8 b = *(const short8*)(&w2T[(size_t)(j * 16 + ln) * 64 + ks * 32 + q * 8]);
            acc[0][j] = __builtin_amdgcn_mfma_f32_16x16x32_bf16(b, a0, acc[0][j], 0, 0, 0);
            acc[1][j] = __builtin_amdgcn_mfma_f32_16x16x32_bf16(b, a1, acc[1][j], 0, 0, 0);
        }
    }
    // LN2 + silu -> h2 (global, uint2 stores)
#pragma unroll
    for (int i = 0; i < 2; i++) {
        float s = 0.f, s2 = 0.f;
#pragma unroll
        for (int j = 0; j < 4; j++) {
            int cb = j * 16 + q * 4;
            float4 bv = *(const float4*)(&b2[cb]);
            float vb[4] = {bv.x, bv.y, bv.z, bv.w};
#pragma unroll
            for (int r = 0; r < 4; r++) {
                float v = acc[i][j][r] + vb[r];
                acc[i][j][r] = v;
                s += v; s2 += v * v;
            }
        }
        s += __shfl_xor(s, 16); s += __shfl_xor(s, 32);
        s2 += __shfl_xor(s2, 16); s2 += __shfl_xor(s2, 32);
        float mu = s * (1.f / 64.f);
        float var = s2 * (1.f / 64.f) - mu * mu;
        float rs = rsqrtf(var + 1e-5f);
        int row = e0 + wm + i * 16 + ln;
#pragma unroll
        for (int j = 0; j < 4; j++) {
            int cb = j * 16 + q * 4;
            float4 gv = *(const float4*)(&g2[cb]);
            float4 ev = *(const float4*)(&be2[cb]);
            float y0 = (acc[i][j][0] - mu) * rs * gv.x + ev.x;
            float y1 = (acc[i][j][1] - mu) * rs * gv.y + ev.y;
            float y2 = (acc[i][j][2] - mu) * rs * gv.z + ev.z;
            float y3 = (acc[i][j][3] - mu) * rs * gv.w + ev.w;
            uint2 pv;
            pv.x = pk_bf16(siluf_(y0), siluf_(y1));
            pv.y = pk_bf16(siluf_(y2), siluf_(y3));
            *(uint2*)(&h2[(size_t)row * 64 + cb]) = pv;
        }
    }
}

// ---------------- GEMM: A (M,K) bf16 rm, BT (N,K) bf16 rm, C (M,N) bf16 ----------------
// Double-buffered LDS staging with counted vmcnt; operand-swapped MFMA epilogue.
__global__ __launch_bounds__(256) void k_gemm(
    const u16* __restrict__ A, int lda,
    const u16* __restrict__ BT, int ldb,
    u16* __restrict__ C, int ldc,
    int N, int K,
    const float* __restrict__ bias) {
    __shared__ u16 As[2][128 * 32];
    __shared__ u16 Bs[2][128 * 32];
    int tid = threadIdx.x;
    int bm0 = blockIdx.x * 128;
    int bn0 = blockIdx.y * 128;
    int wave = tid >> 6, lane = tid & 63;
    int wm = (wave >> 1) * 64, wn = (wave & 1) * 64;
    int lrow = lane & 15, lk = (lane >> 4) * 8;

    int srow = (wave << 4) + (lane >> 2);
    int schunk = (lane & 3) << 3;
    const u16* Arow0 = A + (size_t)(bm0 + srow) * lda + schunk;
    const u16* Arow1 = A + (size_t)(bm0 + srow + 64) * lda + schunk;
    int n0 = bn0 + srow;      if (n0 >= N) n0 = N - 1;
    int n1 = bn0 + srow + 64; if (n1 >= N) n1 = N - 1;
    const u16* Brow0 = BT + (size_t)n0 * ldb + schunk;
    const u16* Brow1 = BT + (size_t)n1 * ldb + schunk;

    auto stage = [&](int buf, int k0) {
        gld16(Arow0 + k0, &As[buf][srow * 32 + schunk]);
        gld16(Arow1 + k0, &As[buf][(srow + 64) * 32 + schunk]);
        gld16(Brow0 + k0, &Bs[buf][srow * 32 + schunk]);
        gld16(Brow1 + k0, &Bs[buf][(srow + 64) * 32 + schunk]);
    };

    floatx4 acc[4][4];
#pragma unroll
    for (int i = 0; i < 4; i++)
#pragma unroll
        for (int j = 0; j < 4; j++) acc[i][j] = floatx4{0.f, 0.f, 0.f, 0.f};

    int NT = K >> 5;
    stage(0, 0);
    for (int kt = 0; kt < NT; kt++) {
        int cur = kt & 1;
        if (kt + 1 < NT) {
            stage(cur ^ 1, (kt + 1) << 5);
            asm volatile("s_waitcnt vmcnt(4)" ::: "memory");
        } else {
            asm volatile("s_waitcnt vmcnt(0)" ::: "memory");
        }
        __syncthreads();
        short8 a[4], b[4];
#pragma unroll
        for (int i = 0; i < 4; i++) a[i] = *(const short8*)(&As[cur][(wm + i * 16 + lrow) * 32 + lk]);
#pragma unroll
        for (int j = 0; j < 4; j++) b[j] = *(const short8*)(&Bs[cur][(wn + j * 16 + lrow) * 32 + lk]);
#pragma unroll
        for (int i = 0; i < 4; i++)
#pragma unroll
            for (int j = 0; j < 4; j++)
                acc[i][j] = __builtin_amdgcn_mfma_f32_16x16x32_bf16(b[j], a[i], acc[i][j], 0, 0, 0);
        __syncthreads();
    }

    int q = lane >> 4;
#pragma unroll
    for (int i = 0; i < 4; i++) {
        int row = bm0 + wm + i * 16 + lrow;
#pragma unroll
        for (int j = 0; j < 4; j++) {
            int col = bn0 + wn + j * 16 + q * 4;
            if (col < N) {
                float4 bv = bias ? *(const float4*)(&bias[col]) : float4{0.f, 0.f, 0.f, 0.f};
                uint2 pv;
                pv.x = pk_bf16(acc[i][j][0] + bv.x, acc[i][j][1] + bv.y);
                pv.y = pk_bf16(acc[i][j][2] + bv.z, acc[i][j][3] + bv.w);
                *(uint2*)(&C[(size_t)row * ldc + col]) = pv;
            }
        }
    }
}

// ---------------- batched 3-way GEMM + optional fused expsum plane ----------------
struct GemmDesc {
    const u16* A; const u16* BT; u16* C;
    const float* bias;
    int lda, ldb, ldc, N, K;
};
struct Gemm3 {
    GemmDesc d[3];
    int cut0, cut1, nY;     // blocks with blockIdx.y >= nY run the expsum plane
    const float* logits; const int* rcv; const u32* nmax;
    float* ealpha; float* nsum;
};
__global__ __launch_bounds__(256) void k_gemm3(Gemm3 g) {
    int y = blockIdx.y;
    if (y >= g.nY) {
        // fused expsum: 96 x-blocks * 256 threads * 8 iters = E*8 exactly
        int base = blockIdx.x * 256 + threadIdx.x;
#pragma unroll
        for (int it = 0; it < 8; it++) {
            int idx = it * 24576 + base;
            int e = idx >> 3, h = idx & 7;
            int r = g.rcv[e];
            float amax = decf(g.nmax[r * 8 + h]);
            if (!(amax > -1e38f && amax < 1e38f)) amax = 0.f;
            float v = __expf(g.logits[idx] - amax);
            g.ealpha[idx] = v;
            atomicAdd(&g.nsum[r * 8 + h], v);
        }
        return;
    }
    GemmDesc d;
    int ytile;
    if (y < g.cut0)      { d = g.d[0]; ytile = y; }
    else if (y < g.cut1) { d = g.d[1]; ytile = y - g.cut0; }
    else                 { d = g.d[2]; ytile = y - g.cut1; }

    __shared__ u16 As[2][128 * 32];
    __shared__ u16 Bs[2][128 * 32];
    int tid = threadIdx.x;
    int bm0 = blockIdx.x * 128;
    int bn0 = ytile * 128;
    int wave = tid >> 6, lane = tid & 63;
    int wm = (wave >> 1) * 64, wn = (wave & 1) * 64;
    int lrow = lane & 15, lk = (lane >> 4) * 8;

    int srow = (wave << 4) + (lane >> 2);
    int schunk = (lane & 3) << 3;
    const u16* Arow0 = d.A + (size_t)(bm0 + srow) * d.lda + schunk;
    const u16* Arow1 = d.A + (size_t)(bm0 + srow + 64) * d.lda + schunk;
    int n0 = bn0 + srow;      if (n0 >= d.N) n0 = d.N - 1;
    int n1 = bn0 + srow + 64; if (n1 >= d.N) n1 = d.N - 1;
    const u16* Brow0 = d.BT + (size_t)n0 * d.ldb + schunk;
    const u16* Brow1 = d.BT + (size_t)n1 * d.ldb + schunk;

    auto stage = [&](int buf, int k0) {
        gld16(Arow0 + k0, &As[buf][srow * 32 + schunk]);
        gld16(Arow1 + k0, &As[buf][(srow + 64) * 32 + schunk]);
        gld16(Brow0 + k0, &Bs[buf][srow * 32 + schunk]);
        gld16(Brow1 + k0, &Bs[buf][(srow + 64) * 32 + schunk]);
    };

    floatx4 acc[4][4];
#pragma unroll
    for (int i = 0; i < 4; i++)
#pragma unroll
        for (int j = 0; j < 4; j++) acc[i][j] = floatx4{0.f, 0.f, 0.f, 0.f};

    int NT = d.K >> 5;
    stage(0, 0);
    for (int kt = 0; kt < NT; kt++) {
        int cur = kt & 1;
        if (kt + 1 < NT) {
            stage(cur ^ 1, (kt + 1) << 5);
            asm volatile("s_waitcnt vmcnt(4)" ::: "memory");
        } else {
            asm volatile("s_waitcnt vmcnt(0)" ::: "memory");
        }
        __syncthreads();
        short8 a[4], b[4];
#pragma unroll
        for (int i = 0; i < 4; i++) a[i] = *(const short8*)(&As[cur][(wm + i * 16 + lrow) * 32 + lk]);
#pragma unroll
        for (int j = 0; j < 4; j++) b[j] = *(const short8*)(&Bs[cur][(wn + j * 16 + lrow) * 32 + lk]);
#pragma unroll
        for (int i = 0; i < 4; i++)
#pragma unroll
            for (int j = 0; j < 4; j++)
                acc[i][j] = __builtin_amdgcn_mfma_f32_16x16x32_bf16(b[j], a[i], acc[i][j], 0, 0, 0);
        __syncthreads();
    }

    int q = lane >> 4;
#pragma unroll
    for (int i = 0; i < 4; i++) {
        int row = bm0 + wm + i * 16 + lrow;
#pragma unroll
        for (int j = 0; j < 4; j++) {
            int col = bn0 + wn + j * 16 + q * 4;
            if (col < d.N) {
                float4 bv = d.bias ? *(const float4*)(&d.bias[col]) : float4{0.f, 0.f, 0.f, 0.f};
                uint2 pv;
                pv.x = pk_bf16(acc[i][j][0] + bv.x, acc[i][j][1] + bv.y);
                pv.y = pk_bf16(acc[i][j][2] + bv.z, acc[i][j][3] + bv.w);
                *(uint2*)(&d.C[(size_t)row * d.ldc + col]) = pv;
            }
        }
    }
}

// ---------------- rotate: wigner @ concat(nf[snd],nf[rcv]); scale by x_edge; pack A1 (chunked) ----------------
__global__ __launch_bounds__(256) void k_rotate(const float* __restrict__ nf, const float* __restrict__ wig,
                                                const int* __restrict__ snd, const int* __restrict__ rcv,
                                                const u16* __restrict__ xe, u16* __restrict__ A1, int e0) {
    __shared__ float wl[2][475];
    int tid = threadIdx.x;
    for (int i = tid; i < 950; i += 256) {
        int ee = e0 + blockIdx.x * 2 + (i / 475);
        wl[i / 475][i % 475] = wig[(size_t)ee * 475 + (i % 475)];
    }
    __syncthreads();
    int le = tid >> 7, c = tid & 127;
    int el = blockIdx.x * 2 + le;       // chunk-local
    int e = e0 + el;                    // global
    int nd = (c < 64) ? snd[e] : rcv[e];
    int cc = c & 63;
    float msg[25];
#pragma unroll
    for (int k = 0; k < 25; k++) msg[k] = nf[(size_t)nd * 1600 + k * 64 + cc];
    const float* w = wl[le];
    size_t ebase = (size_t)el * 2432;
    size_t xbase = (size_t)el * 1536;
#pragma unroll
    for (int m = 0; m < 19; m++) {
        float r = 0.f;
#pragma unroll
        for (int k = 0; k < 25; k++) r += w[m * 25 + k] * msg[k];
        int a1c, xc;
        if (m < 5)       { a1c = m * 128;               xc = m * 128; }
        else if (m < 9)  { a1c = 640 + (m - 5) * 128;   xc = 640 + (m - 5) * 128; }
        else if (m < 13) { a1c = 1152 + (m - 9) * 128;  xc = 640 + (m - 9) * 128; }
        else if (m < 16) { a1c = 1664 + (m - 13) * 128; xc = 1152 + (m - 13) * 128; }
        else             { a1c = 2048 + (m - 16) * 128; xc = 1152 + (m - 16) * 128; }
        float sc = bf2f(xe[xbase + xc + c]);
        A1[ebase + a1c + c] = f2bf(r * sc);
    }
}

// ---------------- grid round-trip via MFMA + fused logits plane ----------------
// blocks [0, E/2): grid work; blocks [E/2, E/2+E): attention logits (independent, both read Y0).
#define GR_XS_STR 40
#define GR_T1_STR 136
__global__ __launch_bounds__(256) void k_grid_logits(
    const u16* __restrict__ Y0, const u16* __restrict__ Y1, const u16* __restrict__ Y2,
    const u16* __restrict__ tgP, const u16* __restrict__ fgP, u16* __restrict__ A2,
    const int* __restrict__ rcv, const float* __restrict__ lg, const float* __restrict__ lb,
    const float* __restrict__ adot, float* __restrict__ logits, u32* __restrict__ nmax) {
    __shared__ u16 T1s[128 * GR_T1_STR];
    int tid = threadIdx.x;
    if (blockIdx.x >= E_EDGES / 2) {
        // ---- logits plane: one edge per block ----
        int e = blockIdx.x - E_EDGES / 2;
        int h = tid >> 5, c = tid & 31;
        float x = bf2f(Y0[(size_t)e * 640 + 320 + h * 32 + c]);
        float s = x, s2 = x * x;
#pragma unroll
        for (int o = 16; o; o >>= 1) { s += __shfl_xor(s, o); s2 += __shfl_xor(s2, o); }
        float mu = s * (1.f / 32.f);
        float var = s2 * (1.f / 32.f) - mu * mu;
        float rs = rsqrtf(var + 1e-5f);
        float a = (x - mu) * rs * lg[c] + lb[c];
        float f = 0.6f * a + 0.4f * a * (2.f * sigmoidf_(a) - 1.f);
        float l = f * adot[h * 32 + c];
#pragma unroll
        for (int o = 16; o; o >>= 1) l += __shfl_xor(l, o);
        if (c == 0) {
            logits[e * 8 + h] = l;
            atomicMax(&nmax[rcv[e] * 8 + h], encf(l));
        }
        return;
    }
    u16* Xs = T1s;                       // alias: Xs consumed before T1s written
    int e0 = blockIdx.x * 2;
    {
        int mp = tid & 15;
        int c0 = ((tid >> 4) & 7) << 3;
        int le = tid >> 7;
        int e = e0 + le;
        int m0 = 2 * mp, m1 = m0 + 1;
        uint4 va = {0, 0, 0, 0}, vb = {0, 0, 0, 0};
        if (m0 < 5)       va = *(const uint4*)(&Y0[(size_t)e * 640 + m0 * 64 + c0]);
        else if (m0 < 13) va = *(const uint4*)(&Y1[(size_t)e * 512 + (m0 - 5) * 64 + c0]);
        else if (m0 < 19) va = *(const uint4*)(&Y2[(size_t)e * 384 + (m0 - 13) * 64 + c0]);
        if (m1 < 5)       vb = *(const uint4*)(&Y0[(size_t)e * 640 + m1 * 64 + c0]);
        else if (m1 < 13) vb = *(const uint4*)(&Y1[(size_t)e * 512 + (m1 - 5) * 64 + c0]);
        else if (m1 < 19) vb = *(const uint4*)(&Y2[(size_t)e * 384 + (m1 - 13) * 64 + c0]);
        const u16* pa = (const u16*)&va;
        const u16* pb = (const u16*)&vb;
        int rbase = le * 64 + c0;
#pragma unroll
        for (int j = 0; j < 8; j++) {
            u32 w = (u32)pa[j] | ((u32)pb[j] << 16);
            *(u32*)(&Xs[(rbase + j) * GR_XS_STR + 2 * mp]) = w;
        }
    }
    __syncthreads();
    int wave = tid >> 6, lane = tid & 63;
    int wn = wave << 5;
    int ln = lane & 15, q = lane >> 4;
    short8 bx0 = *(const short8*)(&Xs[(wn + ln) * GR_XS_STR + q * 8]);
    short8 bx1 = *(const short8*)(&Xs[(wn + 16 + ln) * GR_XS_STR + q * 8]);
    floatx4 acc1[2][7];
#pragma unroll
    for (int pt = 0; pt < 7; pt++) {
        short8 a = *(const short8*)(&tgP[(size_t)(pt * 16 + ln) * 32 + q * 8]);
        acc1[0][pt] = __builtin_amdgcn_mfma_f32_16x16x32_bf16(a, bx0, floatx4{0.f, 0.f, 0.f, 0.f}, 0, 0, 0);
        acc1[1][pt] = __builtin_amdgcn_mfma_f32_16x16x32_bf16(a, bx1, floatx4{0.f, 0.f, 0.f, 0.f}, 0, 0, 0);
    }
    __syncthreads();
    {
        int row = tid >> 1;
        uint4 z = {0, 0, 0, 0};
        *(uint4*)(&T1s[row * GR_T1_STR + 112 + (tid & 1) * 8]) = z;
    }
#pragma unroll
    for (int i = 0; i < 2; i++) {
        u16* dst = &T1s[(wn + i * 16 + ln) * GR_T1_STR + q * 4];
#pragma unroll
        for (int pt = 0; pt < 7; pt++) {
            uint2 pv;
            pv.x = pk_bf16(siluf_(acc1[i][pt][0]), siluf_(acc1[i][pt][1]));
            pv.y = pk_bf16(siluf_(acc1[i][pt][2]), siluf_(acc1[i][pt][3]));
            *(uint2*)(dst + pt * 16) = pv;
        }
    }
    __syncthreads();
    floatx4 acc2[2][2];
    acc2[0][0] = floatx4{0.f, 0.f, 0.f, 0.f}; acc2[0][1] = floatx4{0.f, 0.f, 0.f, 0.f};
    acc2[1][0] = floatx4{0.f, 0.f, 0.f, 0.f}; acc2[1][1] = floatx4{0.f, 0.f, 0.f, 0.f};
#pragma unroll
    for (int ks = 0; ks < 4; ks++) {
        short8 c0 = *(const short8*)(&T1s[(wn + ln) * GR_T1_STR + ks * 32 + q * 8]);
        short8 c1 = *(const short8*)(&T1s[(wn + 16 + ln) * GR_T1_STR + ks * 32 + q * 8]);
#pragma unroll
        for (int ct = 0; ct < 2; ct++) {
            short8 b = *(const short8*)(&fgP[(size_t)(ct * 16 + ln) * 128 + ks * 32 + q * 8]);
            acc2[0][ct] = __builtin_amdgcn_mfma_f32_16x16x32_bf16(c0, b, acc2[0][ct], 0, 0, 0);
            acc2[1][ct] = __builtin_amdgcn_mfma_f32_16x16x32_bf16(c1, b, acc2[1][ct], 0, 0, 0);
        }
    }
#pragma unroll
    for (int rt = 0; rt < 2; rt++) {
        int row = wn + rt * 16 + q * 4;
        int e = e0 + (row >> 6), c = row & 63;
#pragma unroll
        for (int ct = 0; ct < 2; ct++) {
            int mp = ct * 16 + ln;
            if (mp >= 1 && mp < 19) {
                uint2 pv;
                pv.x = pk_bf16(acc2[rt][ct][0], acc2[rt][ct][1]);
                pv.y = pk_bf16(acc2[rt][ct][2], acc2[rt][ct][3]);
                *(uint2*)(&A2[(size_t)e * 1216 + mp * 64 + c]) = pv;
            }
        }
    }
    if (tid < 128) {
        int e = e0 + (tid >> 6), c = tid & 63;
        float gate = bf2f(Y0[(size_t)e * 640 + 576 + c]);
        A2[(size_t)e * 1216 + c] = f2bf(siluf_(gate));
    }
}

// ---------------- gather: attention scale + wigner^T + segment-sum (no atomics) ----------------
// WAVE-PER-NODE, zero-sync, zero-LDS. Two passes over Z chunks.
__global__ __launch_bounds__(256) void k_gather(
    const u16* __restrict__ Z0, const u16* __restrict__ Z1, const u16* __restrict__ Z2,
    const float* __restrict__ wig, const float* __restrict__ ealpha, const float* __restrict__ nsum,
    const u32* __restrict__ rowstart, const u32* __restrict__ deg, const int* __restrict__ elist,
    float* __restrict__ node, int e0, int accum) {
    int n = blockIdx.x * 4 + (threadIdx.x >> 6);
    int lane = threadIdx.x & 63;
    int h = lane >> 3;
    float sden = __fdividef(1.f, nsum[n * 8 + h] + 1e-16f);
    float a0[25], a1[25];
#pragma unroll
    for (int k = 0; k < 25; k++) { a0[k] = 0.f; a1[k] = 0.f; }
    u32 lo = rowstart[n], cnt = deg[n];
    bool did = false;
    for (u32 i = 0; i < cnt; i++) {
        int e = __builtin_amdgcn_readfirstlane(elist[lo + i]);
        int el = e - e0;
        if ((u32)el >= (u32)EC) continue;       // wave-uniform
        did = true;
        float al = ealpha[e * 8 + h] * sden;
        u32 zp[19];
        const u16* z0 = Z0 + (size_t)el * 640 + 2 * lane;
        const u16* z1 = Z1 + (size_t)el * 1024 + 2 * lane;
        const u16* z2 = Z2 + (size_t)el * 768 + 2 * lane;
#pragma unroll
        for (int m = 0; m < 5; m++) zp[m] = *(const u32*)(z0 + m * 128);
#pragma unroll
        for (int m = 0; m < 8; m++) zp[5 + m] = *(const u32*)(z1 + m * 128);
#pragma unroll
        for (int m = 0; m < 6; m++) zp[13 + m] = *(const u32*)(z2 + m * 128);
        const float* __restrict__ w = wig + (size_t)e * 475;
#pragma unroll
        for (int m = 0; m < 19; m++) {
            float s0 = bf2f((u16)(zp[m] & 0xffffu)) * al;
            float s1 = bf2f((u16)(zp[m] >> 16)) * al;
#pragma unroll
            for (int k = 0; k < 25; k++) {
                float wv = w[m * 25 + k];
                a0[k] = fmaf(wv, s0, a0[k]);
                a1[k] = fmaf(wv, s1, a1[k]);
            }
        }
    }
    float* nb = node + (size_t)n * 3200 + 2 * lane;
    if (accum) {
        if (!did) return;
#pragma unroll
        for (int k = 0; k < 25; k++) {
            float2 v = *(float2*)(&nb[k * 128]);
            v.x += a0[k]; v.y += a1[k];
            *(float2*)(&nb[k * 128]) = v;
        }
    } else {
#pragma unroll
        for (int k = 0; k < 25; k++) {
            float2 v; v.x = a0[k]; v.y = a1[k];
            *(float2*)(&nb[k * 128]) = v;
        }
    }
}

// ---------------- final projection via MFMA ----------------
#define PJ_STR 136
__global__ __launch_bounds__(256) void k_proj_mfma(
    const float* __restrict__ node, const u16* __restrict__ pwTb,
    const float* __restrict__ pb, float* __restrict__ out) {
    __shared__ u16 As[128 * PJ_STR];
    __shared__ u16 Bs[64 * PJ_STR];
    int tid = threadIdx.x;
    int n0 = blockIdx.x * 128;
    int k = blockIdx.y;
    int l = (int)sqrtf((float)k + 0.5f);
#pragma unroll
    for (int it = 0; it < 16; it++) {
        int i = tid + it * 256;
        int row = i >> 5;
        int c0 = (i & 31) << 2;
        float4 v = *(const float4*)(&node[(size_t)(n0 + row) * 3200 + k * 128 + c0]);
        uint2 pv;
        pv.x = pk_bf16(v.x, v.y);
        pv.y = pk_bf16(v.z, v.w);
        *(uint2*)(&As[row * PJ_STR + c0]) = pv;
    }
    const u16* pw = pwTb + (size_t)l * 8192;
#pragma unroll
    for (int jt = 0; jt < 4; jt++) {
        int j = tid + jt * 256;
        int d = j >> 4;
        int c0 = (j & 15) << 3;
        *(uint4*)(&Bs[d * PJ_STR + c0]) = *(const uint4*)(&pw[d * 128 + c0]);
    }
    __syncthreads();
    int wave = tid >> 6, lane = tid & 63;
    int wr = wave * 32;
    int ln = lane & 15, q = lane >> 4;
    floatx4 acc[2][4];
#pragma unroll
    for (int i = 0; i < 2; i++)
#pragma unroll
        for (int j = 0; j < 4; j++) acc[i][j] = floatx4{0.f, 0.f, 0.f, 0.f};
#pragma unroll
    for (int ks = 0; ks < 4; ks++) {
        short8 a0 = *(const short8*)(&As[(wr + ln) * PJ_STR + ks * 32 + q * 8]);
        short8 a1 = *(const short8*)(&As[(wr + 16 + ln) * PJ_STR + ks * 32 + q * 8]);
#pragma unroll
        for (int j = 0; j < 4; j++) {
            short8 b = *(const short8*)(&Bs[(j * 16 + ln) * PJ_STR + ks * 32 + q * 8]);
            acc[0][j] = __builtin_amdgcn_mfma_f32_16x16x32_bf16(b, a0, acc[0][j], 0, 0, 0);
            acc[1][j] = __builtin_amdgcn_mfma_f32_16x16x32_bf16(b, a1, acc[1][j], 0, 0, 0);
        }
    }
#pragma unroll
    for (int rt = 0; rt < 2; rt++) {
        int n = n0 + wr + rt * 16 + ln;
#pragma unroll
        for (int j = 0; j < 4; j++) {
            int d = j * 16 + q * 4;
            float4 v;
            v.x = acc[rt][j][0]; v.y = acc[rt][j][1];
            v.z = acc[rt][j][2]; v.w = acc[rt][j][3];
            if (k == 0) {
                float4 bv = *(const float4*)(&pb[d]);
                v.x += bv.x; v.y += bv.y; v.z += bv.z; v.w += bv.w;
            }
            *(float4*)(&out[(size_t)n * 1600 + k * 64 + d]) = v;
        }
    }
}

extern "C" void kernel_launch(void* const* d_in, const int* in_sizes, int n_in,
                              void* d_out, int out_size, void* d_ws, size_t ws_size,
                              hipStream_t stream) {
    const float* nf      = (const float*)d_in[0];
    const int* species   = (const int*)d_in[1];
    const float* dist    = (const float*)d_in[2];
    const int* snd       = (const int*)d_in[3];
    const int* rcv       = (const int*)d_in[4];
    const float* wig     = (const float*)d_in[5];
    const float* semb    = (const float*)d_in[6];
    const float* remb    = (const float*)d_in[7];
    const float* rad_w1  = (const float*)d_in[8];
    const float* rad_b1  = (const float*)d_in[9];
    const float* rad_g1  = (const float*)d_in[10];
    const float* rad_be1 = (const float*)d_in[11];
    const float* rad_w2  = (const float*)d_in[12];
    const float* rad_b2  = (const float*)d_in[13];
    const float* rad_g2  = (const float*)d_in[14];
    const float* rad_be2 = (const float*)d_in[15];
    const float* rad_w3  = (const float*)d_in[16];
    const float* rad_b3  = (const float*)d_in[17];
    const float* c1_w0   = (const float*)d_in[18];
    const float* c1_b0   = (const float*)d_in[19];
    const float* c1_wm1  = (const float*)d_in[20];
    const float* c1_wm2  = (const float*)d_in[21];
    const float* aln_g   = (const float*)d_in[22];
    const float* aln_b   = (const float*)d_in[23];
    const float* adot    = (const float*)d_in[24];
    const float* to_grid = (const float*)d_in[25];
    const float* from_grid=(const float*)d_in[26];
    const float* c2_w0   = (const float*)d_in[27];
    const float* c2_b0   = (const float*)d_in[28];
    const float* c2_wm1  = (const float*)d_in[29];
    const float* c2_wm2  = (const float*)d_in[30];
    const float* proj_w  = (const float*)d_in[31];
    const float* proj_b  = (const float*)d_in[32];

    char* ws = (char*)d_ws;
    size_t off = 0;
    auto take = [&](size_t bytes) -> char* {
        char* p = ws + off;
        off += (bytes + 255) & ~(size_t)255;
        return p;
    };
    // fixed section
    u16* w_rad1T  = (u16*)take(64 * 192 * 2);
    u16* w_rad2T  = (u16*)take(64 * 64 * 2);
    u16* w_rad3T  = (u16*)take(1536 * 64 * 2);
    u16* w_c1w0T  = (u16*)take(640 * 640 * 2);
    u16* w_c1m1T  = (u16*)take((size_t)512 * 1024 * 2);
    u16* w_c1m2T  = (u16*)take((size_t)384 * 768 * 2);
    u16* w_c2w0T  = (u16*)take((size_t)640 * 320 * 2);
    u16* w_c2m1T  = (u16*)take((size_t)1024 * 512 * 2);
    u16* w_c2m2T  = (u16*)take((size_t)768 * 384 * 2);
    u16* w_tgP    = (u16*)take(112 * 32 * 2);
    u16* w_fgP    = (u16*)take(32 * 128 * 2);
    u16* w_pwT    = (u16*)take(5 * 8192 * 2);
    float* logits = (float*)take((size_t)E_EDGES * 8 * 4);
    float* ealpha = (float*)take((size_t)E_EDGES * 8 * 4);
    u32* nmax     = (u32*)take((size_t)N_NODES_C * 8 * 4);
    float* nsum   = (float*)take((size_t)N_NODES_C * 8 * 4);
    float* node   = (float*)take((size_t)N_NODES_C * 3200 * 4);
    u16* a_h2     = (u16*)take((size_t)E_EDGES * 64 * 2);
    u32* c_deg    = (u32*)take((size_t)N_NODES_C * 4);
    u32* c_row    = (u32*)take((size_t)N_NODES_C * 4);
    u32* c_cur    = (u32*)take((size_t)N_NODES_C * 4);
    int* c_elist  = (int*)take((size_t)E_EDGES * 4);
    // arena — aliased by phase
    char* arena   = take(173015040);
    if (off > ws_size) {  // diagnostic: paint output so the failure mode is identifiable
        k_diag<<<(out_size + 255) / 256, 256, 0, stream>>>((float*)d_out, out_size);
        return;
    }

    u16* a_ee   = (u16*)(arena + 0);           // radial phase
    u16* a_xe   = (u16*)(arena + 0);           // per-chunk (EC,1536); ee dead after radmlp... (ee read once)
    u16* a_A1   = (u16*)(arena + 37748736);    // per-chunk (EC,2432)
    u16* a_Y0   = (u16*)(arena + 97517568);    // full (E,640)
    u16* a_Y1   = (u16*)(arena + 128974848);   // full (E,512)
    u16* a_Y2   = (u16*)(arena + 154140672);   // full (E,384) -> arena end
    u16* a_A2   = (u16*)(arena + 0);           // full (E,1216); xe/A1 dead
    u16* a_Z0   = (u16*)(arena + 59768832);    // per-chunk (EC,640)
    u16* a_Z1   = (u16*)(arena + 75497472);    // per-chunk (EC,1024)
    u16* a_Z2   = (u16*)(arena + 100663296);   // per-chunk (EC,768); overlaps dead Y0 region

    // NOTE: a_ee (9.4MB at arena+0) is consumed by k_radmlp BEFORE the first chunk's
    // x_edge gemm writes a_xe (also arena+0) — sequential launches, no overlap hazard.

    // ---- fused prep (weights + init + deg-zero + edge embeds): 1 launch ----
    PrepArgs pa;
    pa.rad_w1 = rad_w1; pa.rad_w2 = rad_w2; pa.rad_w3 = rad_w3;
    pa.c1_w0 = c1_w0; pa.c2_w0 = c2_w0;
    pa.c1_wm1 = c1_wm1; pa.c1_wm2 = c1_wm2; pa.c2_wm1 = c2_wm1; pa.c2_wm2 = c2_wm2;
    pa.to_grid = to_grid; pa.from_grid = from_grid; pa.proj_w = proj_w;
    pa.w_rad1T = w_rad1T; pa.w_rad2T = w_rad2T; pa.w_rad3T = w_rad3T;
    pa.w_c1w0T = w_c1w0T; pa.w_c2w0T = w_c2w0T;
    pa.w_c1m1T = w_c1m1T; pa.w_c1m2T = w_c1m2T; pa.w_c2m1T = w_c2m1T; pa.w_c2m2T = w_c2m2T;
    pa.w_tgP = w_tgP; pa.w_fgP = w_fgP; pa.w_pwT = w_pwT;
    pa.nmax = nmax; pa.nsum = nsum; pa.c_deg = c_deg;
    pa.dist = dist; pa.species = species; pa.snd = snd; pa.rcv = rcv;
    pa.semb = semb; pa.remb = remb; pa.ee = a_ee;
    k_prep<<<PREP_BLOCKS, 256, 0, stream>>>(pa);

    // ---- CSR build ----
    k_deg<<<96, 256, 0, stream>>>(rcv, c_deg);
    k_pfx<<<1, 256, 0, stream>>>(c_deg, c_row, c_cur);
    k_fill<<<96, 256, 0, stream>>>(rcv, c_cur, c_elist);

    // ---- fused radial MLP (gemm+LN+silu+gemm+LN+silu): 4 launches -> 1 ----
    k_radmlp<<<192, 256, 0, stream>>>(a_ee, w_rad1T, w_rad2T,
                                      rad_b1, rad_g1, rad_be1,
                                      rad_b2, rad_g2, rad_be2, a_h2);

    // ---- chunked: x_edge gemm -> rotate -> conv1 (3 gemms fused) ----
    for (int c = 0; c < 2; c++) {
        int e0 = c * EC;
        k_gemm<<<dim3(96, 12), 256, 0, stream>>>(a_h2 + (size_t)e0 * 64, 64, w_rad3T, 64,
                                                 a_xe, 1536, 1536, 64, rad_b3);
        k_rotate<<<EC / 2, 256, 0, stream>>>(nf, wig, snd, rcv, a_xe, a_A1, e0);
        Gemm3 g1;
        g1.d[0] = { a_A1,        w_c1w0T, a_Y0 + (size_t)e0 * 640, c1_b0,   2432, 640,  640, 640, 640 };
        g1.d[1] = { a_A1 + 640,  w_c1m1T, a_Y1 + (size_t)e0 * 512, nullptr, 2432, 1024, 512, 512, 1024 };
        g1.d[2] = { a_A1 + 1664, w_c1m2T, a_Y2 + (size_t)e0 * 384, nullptr, 2432, 768,  384, 384, 768 };
        g1.cut0 = 5; g1.cut1 = 9; g1.nY = 12;
        g1.logits = nullptr; g1.rcv = nullptr; g1.nmax = nullptr; g1.ealpha = nullptr; g1.nsum = nullptr;
        k_gemm3<<<dim3(96, 12), 256, 0, stream>>>(g1);
    }

    // ---- grid nonlinearity + attention logits (fused; independent, both read Y0) ----
    k_grid_logits<<<E_EDGES / 2 + E_EDGES, 256, 0, stream>>>(
        a_Y0, a_Y1, a_Y2, w_tgP, w_fgP, a_A2,
        rcv, aln_g, aln_b, adot, logits, nmax);

    // ---- chunked: conv2 (3 gemms fused; chunk0 carries the expsum plane) -> gather ----
    for (int c = 0; c < 2; c++) {
        int e0 = c * EC;
        Gemm3 g2;
        g2.d[0] = { a_A2 + (size_t)e0 * 1216,       w_c2w0T, a_Z0, c2_b0,   1216, 320, 640,  640,  320 };
        g2.d[1] = { a_A2 + (size_t)e0 * 1216 + 320, w_c2m1T, a_Z1, nullptr, 1216, 512, 1024, 1024, 512 };
        g2.d[2] = { a_A2 + (size_t)e0 * 1216 + 832, w_c2m2T, a_Z2, nullptr, 1216, 384, 768,  768,  384 };
        g2.cut0 = 5; g2.cut1 = 13; g2.nY = 19;
        g2.logits = logits; g2.rcv = rcv; g2.nmax = nmax; g2.ealpha = ealpha; g2.nsum = nsum;
        int gy = (c == 0) ? 20 : 19;        // chunk0 carries the expsum plane (deps: logits done)
        k_gemm3<<<dim3(96, gy), 256, 0, stream>>>(g2);
        k_gather<<<N_NODES_C / 4, 256, 0, stream>>>(a_Z0, a_Z1, a_Z2, wig, ealpha, nsum,
                                                    c_row, c_deg, c_elist, node, e0, c);
    }

    // ---- output projection (MFMA) ----
    k_proj_mfma<<<dim3(32, 25), 256, 0, stream>>>(node, w_pwT, proj_b, (float*)d_out);
}

// Round 10
// 897.861 us; speedup vs baseline: 1.2214x; 1.0025x over previous
//
#include <hip/hip_runtime.h>

typedef unsigned short u16;
typedef unsigned int u32;
typedef __attribute__((ext_vector_type(8))) short short8;
typedef __attribute__((ext_vector_type(4))) float floatx4;

#define E_EDGES 24576
#define EC 12288            // edge chunk
#define N_NODES_C 4096

__device__ __forceinline__ float bf2f(u16 u) {
    union { u32 i; float f; } v; v.i = ((u32)u) << 16; return v.f;
}
__device__ __forceinline__ u16 f2bf(float f) {
    union { float f; u32 i; } v; v.f = f;
    u32 x = v.i;
    u32 r = (x + 0x7fffu + ((x >> 16) & 1u)) >> 16;
    return (u16)r;
}
// packed f32x2 -> bf16x2 in one VALU inst (RNE), no builtin on gfx950 -> inline asm
__device__ __forceinline__ u32 pk_bf16(float a, float b) {
    u32 r;
    asm("v_cvt_pk_bf16_f32 %0, %1, %2" : "=v"(r) : "v"(a), "v"(b));
    return r;
}
__device__ __forceinline__ u32 encf(float f) {
    union { float f; u32 i; } v; v.f = f;
    return (v.i & 0x80000000u) ? ~v.i : (v.i | 0x80000000u);
}
__device__ __forceinline__ float decf(u32 u) {
    union { u32 i; float f; } v;
    v.i = (u & 0x80000000u) ? (u ^ 0x80000000u) : ~u;
    return v.f;
}
// fast transcendentals: v_exp_f32 + v_rcp_f32
__device__ __forceinline__ float sigmoidf_(float x) { return __fdividef(1.f, 1.f + __expf(-x)); }
__device__ __forceinline__ float siluf_(float x) { return x * __fdividef(1.f, 1.f + __expf(-x)); }

// async global->LDS, 16B per lane; LDS dest must be wave-uniform base + lane*16
__device__ __forceinline__ void gld16(const u16* g, u16* l) {
    __builtin_amdgcn_global_load_lds((const __attribute__((address_space(1))) unsigned int*)g,
                                     (__attribute__((address_space(3))) unsigned int*)l, 16, 0, 0);
}

// diagnostic: ws too small -> paint output with 1000 (f32)
__global__ void k_diag(float* __restrict__ out, int n) {
    int i = blockIdx.x * 256 + threadIdx.x;
    if (i < n) out[i] = 1000.0f;
}

// ================= fused prep: all weight prep + init + deg-zero + edge embeds =================
struct PrepArgs {
    const float *rad_w1, *rad_w2, *rad_w3, *c1_w0, *c2_w0;
    const float *c1_wm1, *c1_wm2, *c2_wm1, *c2_wm2;
    const float *to_grid, *from_grid, *proj_w;
    u16 *w_rad1T, *w_rad2T, *w_rad3T, *w_c1w0T, *w_c2w0T;
    u16 *w_c1m1T, *w_c1m2T, *w_c2m1T, *w_c2m2T;
    u16 *w_tgP, *w_fgP, *w_pwT;
    u32 *nmax; float *nsum; u32 *c_deg;
    const float *dist; const int *species, *snd, *rcv;
    const float *semb, *remb; u16 *ee;
};

__device__ __forceinline__ void prep_transpose(const float* __restrict__ src, u16* __restrict__ dst,
                                               int K, int N, int idx) {
    if (idx >= K * N) return;
    int k = idx / N, n = idx % N;
    dst[n * K + k] = f2bf(src[idx]);
}
__device__ __forceinline__ void prep_combine(const float* __restrict__ src, u16* __restrict__ dst,
                                             int K, int H, int idx) {
    if (idx >= 4 * K * H) return;
    int n = idx / (2 * K), k = idx % (2 * K);
    float v;
    if (k < K) v = src[k * 2 * H + n];
    else {
        int kk = k - K;
        if (n < H) v = -src[kk * 2 * H + H + n];
        else       v = src[kk * 2 * H + (n - H)];
    }
    dst[idx] = f2bf(v);
}

#define PB0 48
#define PB1 16
#define PB2 384
#define PB3 1600
#define PB4 800
#define PB5 2048
#define PB6 1152
#define PB7 2048
#define PB8 1152
#define PB9 30
#define PB10 160
#define PB11 128
#define PB12 16
#define PB13 18432
#define PREP_BLOCKS (PB0+PB1+PB2+PB3+PB4+PB5+PB6+PB7+PB8+PB9+PB10+PB11+PB12+PB13)

__global__ __launch_bounds__(256) void k_prep(PrepArgs a) {
    int bid = blockIdx.x;
    int tid = threadIdx.x;
    if (bid < PB0) { prep_transpose(a.rad_w1, a.w_rad1T, 192, 64, bid * 256 + tid); return; }
    bid -= PB0;
    if (bid < PB1) { prep_transpose(a.rad_w2, a.w_rad2T, 64, 64, bid * 256 + tid); return; }
    bid -= PB1;
    if (bid < PB2) { prep_transpose(a.rad_w3, a.w_rad3T, 64, 1536, bid * 256 + tid); return; }
    bid -= PB2;
    if (bid < PB3) { prep_transpose(a.c1_w0, a.w_c1w0T, 640, 640, bid * 256 + tid); return; }
    bid -= PB3;
    if (bid < PB4) { prep_transpose(a.c2_w0, a.w_c2w0T, 320, 640, bid * 256 + tid); return; }
    bid -= PB4;
    if (bid < PB5) { prep_combine(a.c1_wm1, a.w_c1m1T, 512, 256, bid * 256 + tid); return; }
    bid -= PB5;
    if (bid < PB6) { prep_combine(a.c1_wm2, a.w_c1m2T, 384, 192, bid * 256 + tid); return; }
    bid -= PB6;
    if (bid < PB7) { prep_combine(a.c2_wm1, a.w_c2m1T, 256, 512, bid * 256 + tid); return; }
    bid -= PB7;
    if (bid < PB8) { prep_combine(a.c2_wm2, a.w_c2m2T, 192, 384, bid * 256 + tid); return; }
    bid -= PB8;
    if (bid < PB9) {
        int idx = bid * 256 + tid;
        if (idx < 112 * 32) {
            int p = idx >> 5, m = idx & 31;
            a.w_tgP[idx] = (p < 100 && m < 19) ? f2bf(a.to_grid[p * 19 + m]) : (u16)0;
        }
        int j = idx - 112 * 32;
        if (j >= 0 && j < 32 * 128) {
            int m = j >> 7, k = j & 127;
            a.w_fgP[j] = (m < 19 && k < 100) ? f2bf(a.from_grid[m * 100 + k]) : (u16)0;
        }
        return;
    }
    bid -= PB9;
    if (bid < PB10) {
        int idx = bid * 256 + tid;
        int l = idx >> 13, rem = idx & 8191;
        prep_transpose(a.proj_w + (size_t)l * 8192, a.w_pwT + (size_t)l * 8192, 128, 64, rem);
        return;
    }
    bid -= PB10;
    if (bid < PB11) {
        int idx = bid * 256 + tid;
        if (idx < N_NODES_C * 8) { a.nmax[idx] = 0x007FFFFFu; a.nsum[idx] = 0.f; }
        return;
    }
    bid -= PB11;
    if (bid < PB12) {
        int idx = bid * 256 + tid;
        if (idx < N_NODES_C) a.c_deg[idx] = 0u;
        return;
    }
    bid -= PB12;
    {
        int idx = bid * 256 + tid;
        if (idx >= E_EDGES * 192) return;
        int e = idx / 192, c = idx % 192;
        float v;
        if (c < 64)       v = a.dist[e * 64 + c];
        else if (c < 128) v = a.semb[a.species[a.snd[e]] * 64 + (c - 64)];
        else              v = a.remb[a.species[a.rcv[e]] * 64 + (c - 128)];
        a.ee[idx] = f2bf(v);
    }
}

// ---------------- CSR build over receivers (static per launch) ----------------
__global__ void k_deg(const int* __restrict__ rcv, u32* __restrict__ deg) {
    int e = blockIdx.x * 256 + threadIdx.x;
    if (e < E_EDGES) atomicAdd(&deg[rcv[e]], 1u);
}
__global__ __launch_bounds__(256) void k_pfx(const u32* __restrict__ deg,
                                             u32* __restrict__ rowstart, u32* __restrict__ cur) {
    __shared__ u32 ps[256];
    int t = threadIdx.x;
    u32 loc[16]; u32 s = 0;
#pragma unroll
    for (int i = 0; i < 16; i++) { loc[i] = s; s += deg[t * 16 + i]; }
    ps[t] = s;
    __syncthreads();
    for (int o = 1; o < 256; o <<= 1) {
        u32 v = (t >= o) ? ps[t - o] : 0u;
        __syncthreads();
        ps[t] += v;
        __syncthreads();
    }
    u32 base = (t == 0) ? 0u : ps[t - 1];
#pragma unroll
    for (int i = 0; i < 16; i++) { u32 v = base + loc[i]; rowstart[t * 16 + i] = v; cur[t * 16 + i] = v; }
}
__global__ void k_fill(const int* __restrict__ rcv, u32* __restrict__ cur, int* __restrict__ elist) {
    int e = blockIdx.x * 256 + threadIdx.x;
    if (e < E_EDGES) { u32 p = atomicAdd(&cur[rcv[e]], 1u); elist[p] = e; }
}

// ---------------- fused radial MLP: silu(LN(ee@W1+b1)) -> silu(LN(.@W2+b2)) -> h2 ----------------
__global__ __launch_bounds__(256) void k_radmlp(
    const u16* __restrict__ ee, const u16* __restrict__ w1T, const u16* __restrict__ w2T,
    const float* __restrict__ b1, const float* __restrict__ g1, const float* __restrict__ be1,
    const float* __restrict__ b2, const float* __restrict__ g2, const float* __restrict__ be2,
    u16* __restrict__ h2) {
    __shared__ u16 Y1s[128 * 72];
    int tid = threadIdx.x;
    int wave = tid >> 6, lane = tid & 63;
    int ln = lane & 15, q = lane >> 4;
    int wm = wave * 32;
    int e0 = blockIdx.x * 128;

    floatx4 acc[2][4];
#pragma unroll
    for (int i = 0; i < 2; i++)
#pragma unroll
        for (int j = 0; j < 4; j++) acc[i][j] = floatx4{0.f, 0.f, 0.f, 0.f};
    // GEMM1: K=192
#pragma unroll
    for (int ks = 0; ks < 6; ks++) {
        short8 a0 = *(const short8*)(&ee[(size_t)(e0 + wm + ln) * 192 + ks * 32 + q * 8]);
        short8 a1 = *(const short8*)(&ee[(size_t)(e0 + wm + 16 + ln) * 192 + ks * 32 + q * 8]);
#pragma unroll
        for (int j = 0; j < 4; j++) {
            short8 b = *(const short8*)(&w1T[(size_t)(j * 16 + ln) * 192 + ks * 32 + q * 8]);
            acc[0][j] = __builtin_amdgcn_mfma_f32_16x16x32_bf16(b, a0, acc[0][j], 0, 0, 0);
            acc[1][j] = __builtin_amdgcn_mfma_f32_16x16x32_bf16(b, a1, acc[1][j], 0, 0, 0);
        }
    }
    // LN1 + silu -> Y1s
#pragma unroll
    for (int i = 0; i < 2; i++) {
        float s = 0.f, s2 = 0.f;
#pragma unroll
        for (int j = 0; j < 4; j++) {
            int cb = j * 16 + q * 4;
            float4 bv = *(const float4*)(&b1[cb]);
            float vb[4] = {bv.x, bv.y, bv.z, bv.w};
#pragma unroll
            for (int r = 0; r < 4; r++) {
                float v = acc[i][j][r] + vb[r];
                acc[i][j][r] = v;
                s += v; s2 += v * v;
            }
        }
        s += __shfl_xor(s, 16); s += __shfl_xor(s, 32);
        s2 += __shfl_xor(s2, 16); s2 += __shfl_xor(s2, 32);
        float mu = s * (1.f / 64.f);
        float var = s2 * (1.f / 64.f) - mu * mu;
        float rs = rsqrtf(var + 1e-5f);
        int row = wm + i * 16 + ln;
#pragma unroll
        for (int j = 0; j < 4; j++) {
            int cb = j * 16 + q * 4;
            float4 gv = *(const float4*)(&g1[cb]);
            float4 ev = *(const float4*)(&be1[cb]);
            float y0 = (acc[i][j][0] - mu) * rs * gv.x + ev.x;
            float y1 = (acc[i][j][1] - mu) * rs * gv.y + ev.y;
            float y2 = (acc[i][j][2] - mu) * rs * gv.z + ev.z;
            float y3 = (acc[i][j][3] - mu) * rs * gv.w + ev.w;
            uint2 pv;
            pv.x = pk_bf16(siluf_(y0), siluf_(y1));
            pv.y = pk_bf16(siluf_(y2), siluf_(y3));
            *(uint2*)(&Y1s[row * 72 + cb]) = pv;
        }
    }
    __syncthreads();
    // GEMM2: K=64
#pragma unroll
    for (int i = 0; i < 2; i++)
#pragma unroll
        for (int j = 0; j < 4; j++) acc[i][j] = floatx4{0.f, 0.f, 0.f, 0.f};
#pragma unroll
    for (int ks = 0; ks < 2; ks++) {
        short8 a0 = *(const short8*)(&Y1s[(wm + ln) * 72 + ks * 32 + q * 8]);
        short8 a1 = *(const short8*)(&Y1s[(wm + 16 + ln) * 72 + ks * 32 + q * 8]);
#pragma unroll
        for (int j = 0; j < 4; j++) {
            short8 b = *(const short8*)(&w2T[(size_t)(j * 16 + ln) * 64 + ks * 32 + q * 8]);
            acc[0][j] = __builtin_amdgcn_mfma_f32_16x16x32_bf16(b, a0, acc[0][j], 0, 0, 0);
            acc[1][j] = __builtin_amdgcn_mfma_f32_16x16x32_bf16(b, a1, acc[1][j], 0, 0, 0);
        }
    }
    // LN2 + silu -> h2 (global, uint2 stores)
#pragma unroll
    for (int i = 0; i < 2; i++) {
        float s = 0.f, s2 = 0.f;
#pragma unroll
        for (int j = 0; j < 4; j++) {
            int cb = j * 16 + q * 4;
            float4 bv = *(const float4*)(&b2[cb]);
            float vb[4] = {bv.x, bv.y, bv.z, bv.w};
#pragma unroll
            for (int r = 0; r < 4; r++) {
                float v = acc[i][j][r] + vb[r];
                acc[i][j][r] = v;
                s += v; s2 += v * v;
            }
        }
        s += __shfl_xor(s, 16); s += __shfl_xor(s, 32);
        s2 += __shfl_xor(s2, 16); s2 += __shfl_xor(s2, 32);
        float mu = s * (1.f / 64.f);
        float var = s2 * (1.f / 64.f) - mu * mu;
        float rs = rsqrtf(var + 1e-5f);
        int row = e0 + wm + i * 16 + ln;
#pragma unroll
        for (int j = 0; j < 4; j++) {
            int cb = j * 16 + q * 4;
            float4 gv = *(const float4*)(&g2[cb]);
            float4 ev = *(const float4*)(&be2[cb]);
            float y0 = (acc[i][j][0] - mu) * rs * gv.x + ev.x;
            float y1 = (acc[i][j][1] - mu) * rs * gv.y + ev.y;
            float y2 = (acc[i][j][2] - mu) * rs * gv.z + ev.z;
            float y3 = (acc[i][j][3] - mu) * rs * gv.w + ev.w;
            uint2 pv;
            pv.x = pk_bf16(siluf_(y0), siluf_(y1));
            pv.y = pk_bf16(siluf_(y2), siluf_(y3));
            *(uint2*)(&h2[(size_t)row * 64 + cb]) = pv;
        }
    }
}

// ---------------- GEMM: A (M,K) bf16 rm, BT (N,K) bf16 rm, C (M,N) bf16 ----------------
__global__ __launch_bounds__(256) void k_gemm(
    const u16* __restrict__ A, int lda,
    const u16* __restrict__ BT, int ldb,
    u16* __restrict__ C, int ldc,
    int N, int K,
    const float* __restrict__ bias) {
    __shared__ u16 As[2][128 * 32];
    __shared__ u16 Bs[2][128 * 32];
    int tid = threadIdx.x;
    int bm0 = blockIdx.x * 128;
    int bn0 = blockIdx.y * 128;
    int wave = tid >> 6, lane = tid & 63;
    int wm = (wave >> 1) * 64, wn = (wave & 1) * 64;
    int lrow = lane & 15, lk = (lane >> 4) * 8;

    int srow = (wave << 4) + (lane >> 2);
    int schunk = (lane & 3) << 3;
    const u16* Arow0 = A + (size_t)(bm0 + srow) * lda + schunk;
    const u16* Arow1 = A + (size_t)(bm0 + srow + 64) * lda + schunk;
    int n0 = bn0 + srow;      if (n0 >= N) n0 = N - 1;
    int n1 = bn0 + srow + 64; if (n1 >= N) n1 = N - 1;
    const u16* Brow0 = BT + (size_t)n0 * ldb + schunk;
    const u16* Brow1 = BT + (size_t)n1 * ldb + schunk;

    auto stage = [&](int buf, int k0) {
        gld16(Arow0 + k0, &As[buf][srow * 32 + schunk]);
        gld16(Arow1 + k0, &As[buf][(srow + 64) * 32 + schunk]);
        gld16(Brow0 + k0, &Bs[buf][srow * 32 + schunk]);
        gld16(Brow1 + k0, &Bs[buf][(srow + 64) * 32 + schunk]);
    };

    floatx4 acc[4][4];
#pragma unroll
    for (int i = 0; i < 4; i++)
#pragma unroll
        for (int j = 0; j < 4; j++) acc[i][j] = floatx4{0.f, 0.f, 0.f, 0.f};

    int NT = K >> 5;
    stage(0, 0);
    for (int kt = 0; kt < NT; kt++) {
        int cur = kt & 1;
        if (kt + 1 < NT) {
            stage(cur ^ 1, (kt + 1) << 5);
            asm volatile("s_waitcnt vmcnt(4)" ::: "memory");
        } else {
            asm volatile("s_waitcnt vmcnt(0)" ::: "memory");
        }
        __syncthreads();
        short8 a[4], b[4];
#pragma unroll
        for (int i = 0; i < 4; i++) a[i] = *(const short8*)(&As[cur][(wm + i * 16 + lrow) * 32 + lk]);
#pragma unroll
        for (int j = 0; j < 4; j++) b[j] = *(const short8*)(&Bs[cur][(wn + j * 16 + lrow) * 32 + lk]);
#pragma unroll
        for (int i = 0; i < 4; i++)
#pragma unroll
            for (int j = 0; j < 4; j++)
                acc[i][j] = __builtin_amdgcn_mfma_f32_16x16x32_bf16(b[j], a[i], acc[i][j], 0, 0, 0);
        __syncthreads();
    }

    int q = lane >> 4;
#pragma unroll
    for (int i = 0; i < 4; i++) {
        int row = bm0 + wm + i * 16 + lrow;
#pragma unroll
        for (int j = 0; j < 4; j++) {
            int col = bn0 + wn + j * 16 + q * 4;
            if (col < N) {
                float4 bv = bias ? *(const float4*)(&bias[col]) : float4{0.f, 0.f, 0.f, 0.f};
                uint2 pv;
                pv.x = pk_bf16(acc[i][j][0] + bv.x, acc[i][j][1] + bv.y);
                pv.y = pk_bf16(acc[i][j][2] + bv.z, acc[i][j][3] + bv.w);
                *(uint2*)(&C[(size_t)row * ldc + col]) = pv;
            }
        }
    }
}

// ---------------- batched 3-way GEMM + optional fused expsum plane ----------------
struct GemmDesc {
    const u16* A; const u16* BT; u16* C;
    const float* bias;
    int lda, ldb, ldc, N, K;
};
struct Gemm3 {
    GemmDesc d[3];
    int cut0, cut1, nY;     // blocks with blockIdx.y >= nY run the expsum plane
    const float* logits; const int* rcv; const u32* nmax;
    float* ealpha; float* nsum;
};
__global__ __launch_bounds__(256) void k_gemm3(Gemm3 g) {
    int y = blockIdx.y;
    if (y >= g.nY) {
        // fused expsum: 96 x-blocks * 256 threads * 8 iters = E*8 exactly
        int base = blockIdx.x * 256 + threadIdx.x;
#pragma unroll
        for (int it = 0; it < 8; it++) {
            int idx = it * 24576 + base;
            int e = idx >> 3, h = idx & 7;
            int r = g.rcv[e];
            float amax = decf(g.nmax[r * 8 + h]);
            if (!(amax > -1e38f && amax < 1e38f)) amax = 0.f;
            float v = __expf(g.logits[idx] - amax);
            g.ealpha[idx] = v;
            atomicAdd(&g.nsum[r * 8 + h], v);
        }
        return;
    }
    GemmDesc d;
    int ytile;
    if (y < g.cut0)      { d = g.d[0]; ytile = y; }
    else if (y < g.cut1) { d = g.d[1]; ytile = y - g.cut0; }
    else                 { d = g.d[2]; ytile = y - g.cut1; }

    __shared__ u16 As[2][128 * 32];
    __shared__ u16 Bs[2][128 * 32];
    int tid = threadIdx.x;
    int bm0 = blockIdx.x * 128;
    int bn0 = ytile * 128;
    int wave = tid >> 6, lane = tid & 63;
    int wm = (wave >> 1) * 64, wn = (wave & 1) * 64;
    int lrow = lane & 15, lk = (lane >> 4) * 8;

    int srow = (wave << 4) + (lane >> 2);
    int schunk = (lane & 3) << 3;
    const u16* Arow0 = d.A + (size_t)(bm0 + srow) * d.lda + schunk;
    const u16* Arow1 = d.A + (size_t)(bm0 + srow + 64) * d.lda + schunk;
    int n0 = bn0 + srow;      if (n0 >= d.N) n0 = d.N - 1;
    int n1 = bn0 + srow + 64; if (n1 >= d.N) n1 = d.N - 1;
    const u16* Brow0 = d.BT + (size_t)n0 * d.ldb + schunk;
    const u16* Brow1 = d.BT + (size_t)n1 * d.ldb + schunk;

    auto stage = [&](int buf, int k0) {
        gld16(Arow0 + k0, &As[buf][srow * 32 + schunk]);
        gld16(Arow1 + k0, &As[buf][(srow + 64) * 32 + schunk]);
        gld16(Brow0 + k0, &Bs[buf][srow * 32 + schunk]);
        gld16(Brow1 + k0, &Bs[buf][(srow + 64) * 32 + schunk]);
    };

    floatx4 acc[4][4];
#pragma unroll
    for (int i = 0; i < 4; i++)
#pragma unroll
        for (int j = 0; j < 4; j++) acc[i][j] = floatx4{0.f, 0.f, 0.f, 0.f};

    int NT = d.K >> 5;
    stage(0, 0);
    for (int kt = 0; kt < NT; kt++) {
        int cur = kt & 1;
        if (kt + 1 < NT) {
            stage(cur ^ 1, (kt + 1) << 5);
            asm volatile("s_waitcnt vmcnt(4)" ::: "memory");
        } else {
            asm volatile("s_waitcnt vmcnt(0)" ::: "memory");
        }
        __syncthreads();
        short8 a[4], b[4];
#pragma unroll
        for (int i = 0; i < 4; i++) a[i] = *(const short8*)(&As[cur][(wm + i * 16 + lrow) * 32 + lk]);
#pragma unroll
        for (int j = 0; j < 4; j++) b[j] = *(const short8*)(&Bs[cur][(wn + j * 16 + lrow) * 32 + lk]);
#pragma unroll
        for (int i = 0; i < 4; i++)
#pragma unroll
            for (int j = 0; j < 4; j++)
                acc[i][j] = __builtin_amdgcn_mfma_f32_16x16x32_bf16(b[j], a[i], acc[i][j], 0, 0, 0);
        __syncthreads();
    }

    int q = lane >> 4;
#pragma unroll
    for (int i = 0; i < 4; i++) {
        int row = bm0 + wm + i * 16 + lrow;
#pragma unroll
        for (int j = 0; j < 4; j++) {
            int col = bn0 + wn + j * 16 + q * 4;
            if (col < d.N) {
                float4 bv = d.bias ? *(const float4*)(&d.bias[col]) : float4{0.f, 0.f, 0.f, 0.f};
                uint2 pv;
                pv.x = pk_bf16(acc[i][j][0] + bv.x, acc[i][j][1] + bv.y);
                pv.y = pk_bf16(acc[i][j][2] + bv.z, acc[i][j][3] + bv.w);
                *(uint2*)(&d.C[(size_t)row * d.ldc + col]) = pv;
            }
        }
    }
}

// ---------------- rotate: wigner @ concat(nf[snd],nf[rcv]); scale by x_edge; pack A1 (chunked) ----------------
__global__ __launch_bounds__(256) void k_rotate(const float* __restrict__ nf, const float* __restrict__ wig,
                                                const int* __restrict__ snd, const int* __restrict__ rcv,
                                                const u16* __restrict__ xe, u16* __restrict__ A1, int e0) {
    __shared__ float wl[2][475];
    int tid = threadIdx.x;
    for (int i = tid; i < 950; i += 256) {
        int ee = e0 + blockIdx.x * 2 + (i / 475);
        wl[i / 475][i % 475] = wig[(size_t)ee * 475 + (i % 475)];
    }
    __syncthreads();
    int le = tid >> 7, c = tid & 127;
    int el = blockIdx.x * 2 + le;       // chunk-local
    int e = e0 + el;                    // global
    int nd = (c < 64) ? snd[e] : rcv[e];
    int cc = c & 63;
    float msg[25];
#pragma unroll
    for (int k = 0; k < 25; k++) msg[k] = nf[(size_t)nd * 1600 + k * 64 + cc];
    const float* w = wl[le];
    size_t ebase = (size_t)el * 2432;
    size_t xbase = (size_t)el * 1536;
#pragma unroll
    for (int m = 0; m < 19; m++) {
        float r = 0.f;
#pragma unroll
        for (int k = 0; k < 25; k++) r += w[m * 25 + k] * msg[k];
        int a1c, xc;
        if (m < 5)       { a1c = m * 128;               xc = m * 128; }
        else if (m < 9)  { a1c = 640 + (m - 5) * 128;   xc = 640 + (m - 5) * 128; }
        else if (m < 13) { a1c = 1152 + (m - 9) * 128;  xc = 640 + (m - 9) * 128; }
        else if (m < 16) { a1c = 1664 + (m - 13) * 128; xc = 1152 + (m - 13) * 128; }
        else             { a1c = 2048 + (m - 16) * 128; xc = 1152 + (m - 16) * 128; }
        float sc = bf2f(xe[xbase + xc + c]);
        A1[ebase + a1c + c] = f2bf(r * sc);
    }
}

// ---------------- grid round-trip via MFMA + fused logits plane ----------------
// blocks [0, E/2): grid work; blocks [E/2, E/2+E/8): logits, 8 EDGES PER BLOCK.
// (R9 lesson: 1-edge logits blocks at 34KB-LDS occupancy cost ~30us in block-scheduling
//  waves; 8x amortization cuts the block count to 3072.)
#define GR_XS_STR 40
#define GR_T1_STR 136
__global__ __launch_bounds__(256) void k_grid_logits(
    const u16* __restrict__ Y0, const u16* __restrict__ Y1, const u16* __restrict__ Y2,
    const u16* __restrict__ tgP, const u16* __restrict__ fgP, u16* __restrict__ A2,
    const int* __restrict__ rcv, const float* __restrict__ lg, const float* __restrict__ lb,
    const float* __restrict__ adot, float* __restrict__ logits, u32* __restrict__ nmax) {
    __shared__ u16 T1s[128 * GR_T1_STR];
    int tid = threadIdx.x;
    if (blockIdx.x >= E_EDGES / 2) {
        // ---- logits plane: 8 edges per block (independent iterations pipeline) ----
        int ebase = (blockIdx.x - E_EDGES / 2) * 8;
        int h = tid >> 5, c = tid & 31;
        float gv = lg[c], bv = lb[c], av = adot[h * 32 + c];
#pragma unroll
        for (int it = 0; it < 8; it++) {
            int e = ebase + it;
            float x = bf2f(Y0[(size_t)e * 640 + 320 + h * 32 + c]);
            float s = x, s2 = x * x;
#pragma unroll
            for (int o = 16; o; o >>= 1) { s += __shfl_xor(s, o); s2 += __shfl_xor(s2, o); }
            float mu = s * (1.f / 32.f);
            float var = s2 * (1.f / 32.f) - mu * mu;
            float rs = rsqrtf(var + 1e-5f);
            float a = (x - mu) * rs * gv + bv;
            float f = 0.6f * a + 0.4f * a * (2.f * sigmoidf_(a) - 1.f);
            float l = f * av;
#pragma unroll
            for (int o = 16; o; o >>= 1) l += __shfl_xor(l, o);
            if (c == 0) {
                logits[e * 8 + h] = l;
                atomicMax(&nmax[rcv[e] * 8 + h], encf(l));
            }
        }
        return;
    }
    u16* Xs = T1s;                       // alias: Xs consumed before T1s written
    int e0 = blockIdx.x * 2;
    {
        int mp = tid & 15;
        int c0 = ((tid >> 4) & 7) << 3;
        int le = tid >> 7;
        int e = e0 + le;
        int m0 = 2 * mp, m1 = m0 + 1;
        uint4 va = {0, 0, 0, 0}, vb = {0, 0, 0, 0};
        if (m0 < 5)       va = *(const uint4*)(&Y0[(size_t)e * 640 + m0 * 64 + c0]);
        else if (m0 < 13) va = *(const uint4*)(&Y1[(size_t)e * 512 + (m0 - 5) * 64 + c0]);
        else if (m0 < 19) va = *(const uint4*)(&Y2[(size_t)e * 384 + (m0 - 13) * 64 + c0]);
        if (m1 < 5)       vb = *(const uint4*)(&Y0[(size_t)e * 640 + m1 * 64 + c0]);
        else if (m1 < 13) vb = *(const uint4*)(&Y1[(size_t)e * 512 + (m1 - 5) * 64 + c0]);
        else if (m1 < 19) vb = *(const uint4*)(&Y2[(size_t)e * 384 + (m1 - 13) * 64 + c0]);
        const u16* pa = (const u16*)&va;
        const u16* pb = (const u16*)&vb;
        int rbase = le * 64 + c0;
#pragma unroll
        for (int j = 0; j < 8; j++) {
            u32 w = (u32)pa[j] | ((u32)pb[j] << 16);
            *(u32*)(&Xs[(rbase + j) * GR_XS_STR + 2 * mp]) = w;
        }
    }
    __syncthreads();
    int wave = tid >> 6, lane = tid & 63;
    int wn = wave << 5;
    int ln = lane & 15, q = lane >> 4;
    short8 bx0 = *(const short8*)(&Xs[(wn + ln) * GR_XS_STR + q * 8]);
    short8 bx1 = *(const short8*)(&Xs[(wn + 16 + ln) * GR_XS_STR + q * 8]);
    floatx4 acc1[2][7];
#pragma unroll
    for (int pt = 0; pt < 7; pt++) {
        short8 a = *(const short8*)(&tgP[(size_t)(pt * 16 + ln) * 32 + q * 8]);
        acc1[0][pt] = __builtin_amdgcn_mfma_f32_16x16x32_bf16(a, bx0, floatx4{0.f, 0.f, 0.f, 0.f}, 0, 0, 0);
        acc1[1][pt] = __builtin_amdgcn_mfma_f32_16x16x32_bf16(a, bx1, floatx4{0.f, 0.f, 0.f, 0.f}, 0, 0, 0);
    }
    __syncthreads();
    {
        int row = tid >> 1;
        uint4 z = {0, 0, 0, 0};
        *(uint4*)(&T1s[row * GR_T1_STR + 112 + (tid & 1) * 8]) = z;
    }
#pragma unroll
    for (int i = 0; i < 2; i++) {
        u16* dst = &T1s[(wn + i * 16 + ln) * GR_T1_STR + q * 4];
#pragma unroll
        for (int pt = 0; pt < 7; pt++) {
            uint2 pv;
            pv.x = pk_bf16(siluf_(acc1[i][pt][0]), siluf_(acc1[i][pt][1]));
            pv.y = pk_bf16(siluf_(acc1[i][pt][2]), siluf_(acc1[i][pt][3]));
            *(uint2*)(dst + pt * 16) = pv;
        }
    }
    __syncthreads();
    floatx4 acc2[2][2];
    acc2[0][0] = floatx4{0.f, 0.f, 0.f, 0.f}; acc2[0][1] = floatx4{0.f, 0.f, 0.f, 0.f};
    acc2[1][0] = floatx4{0.f, 0.f, 0.f, 0.f}; acc2[1][1] = floatx4{0.f, 0.f, 0.f, 0.f};
#pragma unroll
    for (int ks = 0; ks < 4; ks++) {
        short8 c0 = *(const short8*)(&T1s[(wn + ln) * GR_T1_STR + ks * 32 + q * 8]);
        short8 c1 = *(const short8*)(&T1s[(wn + 16 + ln) * GR_T1_STR + ks * 32 + q * 8]);
#pragma unroll
        for (int ct = 0; ct < 2; ct++) {
            short8 b = *(const short8*)(&fgP[(size_t)(ct * 16 + ln) * 128 + ks * 32 + q * 8]);
            acc2[0][ct] = __builtin_amdgcn_mfma_f32_16x16x32_bf16(c0, b, acc2[0][ct], 0, 0, 0);
            acc2[1][ct] = __builtin_amdgcn_mfma_f32_16x16x32_bf16(c1, b, acc2[1][ct], 0, 0, 0);
        }
    }
#pragma unroll
    for (int rt = 0; rt < 2; rt++) {
        int row = wn + rt * 16 + q * 4;
        int e = e0 + (row >> 6), c = row & 63;
#pragma unroll
        for (int ct = 0; ct < 2; ct++) {
            int mp = ct * 16 + ln;
            if (mp >= 1 && mp < 19) {
                uint2 pv;
                pv.x = pk_bf16(acc2[rt][ct][0], acc2[rt][ct][1]);
                pv.y = pk_bf16(acc2[rt][ct][2], acc2[rt][ct][3]);
                *(uint2*)(&A2[(size_t)e * 1216 + mp * 64 + c]) = pv;
            }
        }
    }
    if (tid < 128) {
        int e = e0 + (tid >> 6), c = tid & 63;
        float gate = bf2f(Y0[(size_t)e * 640 + 576 + c]);
        A2[(size_t)e * 1216 + c] = f2bf(siluf_(gate));
    }
}

// ---------------- gather: attention scale + wigner^T + segment-sum (no atomics) ----------------
__global__ __launch_bounds__(256) void k_gather(
    const u16* __restrict__ Z0, const u16* __restrict__ Z1, const u16* __restrict__ Z2,
    const float* __restrict__ wig, const float* __restrict__ ealpha, const float* __restrict__ nsum,
    const u32* __restrict__ rowstart, const u32* __restrict__ deg, const int* __restrict__ elist,
    float* __restrict__ node, int e0, int accum) {
    int n = blockIdx.x * 4 + (threadIdx.x >> 6);
    int lane = threadIdx.x & 63;
    int h = lane >> 3;
    float sden = __fdividef(1.f, nsum[n * 8 + h] + 1e-16f);
    float a0[25], a1[25];
#pragma unroll
    for (int k = 0; k < 25; k++) { a0[k] = 0.f; a1[k] = 0.f; }
    u32 lo = rowstart[n], cnt = deg[n];
    bool did = false;
    for (u32 i = 0; i < cnt; i++) {
        int e = __builtin_amdgcn_readfirstlane(elist[lo + i]);
        int el = e - e0;
        if ((u32)el >= (u32)EC) continue;       // wave-uniform
        did = true;
        float al = ealpha[e * 8 + h] * sden;
        u32 zp[19];
        const u16* z0 = Z0 + (size_t)el * 640 + 2 * lane;
        const u16* z1 = Z1 + (size_t)el * 1024 + 2 * lane;
        const u16* z2 = Z2 + (size_t)el * 768 + 2 * lane;
#pragma unroll
        for (int m = 0; m < 5; m++) zp[m] = *(const u32*)(z0 + m * 128);
#pragma unroll
        for (int m = 0; m < 8; m++) zp[5 + m] = *(const u32*)(z1 + m * 128);
#pragma unroll
        for (int m = 0; m < 6; m++) zp[13 + m] = *(const u32*)(z2 + m * 128);
        const float* __restrict__ w = wig + (size_t)e * 475;
#pragma unroll
        for (int m = 0; m < 19; m++) {
            float s0 = bf2f((u16)(zp[m] & 0xffffu)) * al;
            float s1 = bf2f((u16)(zp[m] >> 16)) * al;
#pragma unroll
            for (int k = 0; k < 25; k++) {
                float wv = w[m * 25 + k];
                a0[k] = fmaf(wv, s0, a0[k]);
                a1[k] = fmaf(wv, s1, a1[k]);
            }
        }
    }
    float* nb = node + (size_t)n * 3200 + 2 * lane;
    if (accum) {
        if (!did) return;
#pragma unroll
        for (int k = 0; k < 25; k++) {
            float2 v = *(float2*)(&nb[k * 128]);
            v.x += a0[k]; v.y += a1[k];
            *(float2*)(&nb[k * 128]) = v;
        }
    } else {
#pragma unroll
        for (int k = 0; k < 25; k++) {
            float2 v; v.x = a0[k]; v.y = a1[k];
            *(float2*)(&nb[k * 128]) = v;
        }
    }
}

// ---------------- final projection via MFMA ----------------
#define PJ_STR 136
__global__ __launch_bounds__(256) void k_proj_mfma(
    const float* __restrict__ node, const u16* __restrict__ pwTb,
    const float* __restrict__ pb, float* __restrict__ out) {
    __shared__ u16 As[128 * PJ_STR];
    __shared__ u16 Bs[64 * PJ_STR];
    int tid = threadIdx.x;
    int n0 = blockIdx.x * 128;
    int k = blockIdx.y;
    int l = (int)sqrtf((float)k + 0.5f);
#pragma unroll
    for (int it = 0; it < 16; it++) {
        int i = tid + it * 256;
        int row = i >> 5;
        int c0 = (i & 31) << 2;
        float4 v = *(const float4*)(&node[(size_t)(n0 + row) * 3200 + k * 128 + c0]);
        uint2 pv;
        pv.x = pk_bf16(v.x, v.y);
        pv.y = pk_bf16(v.z, v.w);
        *(uint2*)(&As[row * PJ_STR + c0]) = pv;
    }
    const u16* pw = pwTb + (size_t)l * 8192;
#pragma unroll
    for (int jt = 0; jt < 4; jt++) {
        int j = tid + jt * 256;
        int d = j >> 4;
        int c0 = (j & 15) << 3;
        *(uint4*)(&Bs[d * PJ_STR + c0]) = *(const uint4*)(&pw[d * 128 + c0]);
    }
    __syncthreads();
    int wave = tid >> 6, lane = tid & 63;
    int wr = wave * 32;
    int ln = lane & 15, q = lane >> 4;
    floatx4 acc[2][4];
#pragma unroll
    for (int i = 0; i < 2; i++)
#pragma unroll
        for (int j = 0; j < 4; j++) acc[i][j] = floatx4{0.f, 0.f, 0.f, 0.f};
#pragma unroll
    for (int ks = 0; ks < 4; ks++) {
        short8 a0 = *(const short8*)(&As[(wr + ln) * PJ_STR + ks * 32 + q * 8]);
        short8 a1 = *(const short8*)(&As[(wr + 16 + ln) * PJ_STR + ks * 32 + q * 8]);
#pragma unroll
        for (int j = 0; j < 4; j++) {
            short8 b = *(const short8*)(&Bs[(j * 16 + ln) * PJ_STR + ks * 32 + q * 8]);
            acc[0][j] = __builtin_amdgcn_mfma_f32_16x16x32_bf16(b, a0, acc[0][j], 0, 0, 0);
            acc[1][j] = __builtin_amdgcn_mfma_f32_16x16x32_bf16(b, a1, acc[1][j], 0, 0, 0);
        }
    }
#pragma unroll
    for (int rt = 0; rt < 2; rt++) {
        int n = n0 + wr + rt * 16 + ln;
#pragma unroll
        for (int j = 0; j < 4; j++) {
            int d = j * 16 + q * 4;
            float4 v;
            v.x = acc[rt][j][0]; v.y = acc[rt][j][1];
            v.z = acc[rt][j][2]; v.w = acc[rt][j][3];
            if (k == 0) {
                float4 bv = *(const float4*)(&pb[d]);
                v.x += bv.x; v.y += bv.y; v.z += bv.z; v.w += bv.w;
            }
            *(float4*)(&out[(size_t)n * 1600 + k * 64 + d]) = v;
        }
    }
}

extern "C" void kernel_launch(void* const* d_in, const int* in_sizes, int n_in,
                              void* d_out, int out_size, void* d_ws, size_t ws_size,
                              hipStream_t stream) {
    const float* nf      = (const float*)d_in[0];
    const int* species   = (const int*)d_in[1];
    const float* dist    = (const float*)d_in[2];
    const int* snd       = (const int*)d_in[3];
    const int* rcv       = (const int*)d_in[4];
    const float* wig     = (const float*)d_in[5];
    const float* semb    = (const float*)d_in[6];
    const float* remb    = (const float*)d_in[7];
    const float* rad_w1  = (const float*)d_in[8];
    const float* rad_b1  = (const float*)d_in[9];
    const float* rad_g1  = (const float*)d_in[10];
    const float* rad_be1 = (const float*)d_in[11];
    const float* rad_w2  = (const float*)d_in[12];
    const float* rad_b2  = (const float*)d_in[13];
    const float* rad_g2  = (const float*)d_in[14];
    const float* rad_be2 = (const float*)d_in[15];
    const float* rad_w3  = (const float*)d_in[16];
    const float* rad_b3  = (const float*)d_in[17];
    const float* c1_w0   = (const float*)d_in[18];
    const float* c1_b0   = (const float*)d_in[19];
    const float* c1_wm1  = (const float*)d_in[20];
    const float* c1_wm2  = (const float*)d_in[21];
    const float* aln_g   = (const float*)d_in[22];
    const float* aln_b   = (const float*)d_in[23];
    const float* adot    = (const float*)d_in[24];
    const float* to_grid = (const float*)d_in[25];
    const float* from_grid=(const float*)d_in[26];
    const float* c2_w0   = (const float*)d_in[27];
    const float* c2_b0   = (const float*)d_in[28];
    const float* c2_wm1  = (const float*)d_in[29];
    const float* c2_wm2  = (const float*)d_in[30];
    const float* proj_w  = (const float*)d_in[31];
    const float* proj_b  = (const float*)d_in[32];

    char* ws = (char*)d_ws;
    size_t off = 0;
    auto take = [&](size_t bytes) -> char* {
        char* p = ws + off;
        off += (bytes + 255) & ~(size_t)255;
        return p;
    };
    // fixed section
    u16* w_rad1T  = (u16*)take(64 * 192 * 2);
    u16* w_rad2T  = (u16*)take(64 * 64 * 2);
    u16* w_rad3T  = (u16*)take(1536 * 64 * 2);
    u16* w_c1w0T  = (u16*)take(640 * 640 * 2);
    u16* w_c1m1T  = (u16*)take((size_t)512 * 1024 * 2);
    u16* w_c1m2T  = (u16*)take((size_t)384 * 768 * 2);
    u16* w_c2w0T  = (u16*)take((size_t)640 * 320 * 2);
    u16* w_c2m1T  = (u16*)take((size_t)1024 * 512 * 2);
    u16* w_c2m2T  = (u16*)take((size_t)768 * 384 * 2);
    u16* w_tgP    = (u16*)take(112 * 32 * 2);
    u16* w_fgP    = (u16*)take(32 * 128 * 2);
    u16* w_pwT    = (u16*)take(5 * 8192 * 2);
    float* logits = (float*)take((size_t)E_EDGES * 8 * 4);
    float* ealpha = (float*)take((size_t)E_EDGES * 8 * 4);
    u32* nmax     = (u32*)take((size_t)N_NODES_C * 8 * 4);
    float* nsum   = (float*)take((size_t)N_NODES_C * 8 * 4);
    float* node   = (float*)take((size_t)N_NODES_C * 3200 * 4);
    u16* a_h2     = (u16*)take((size_t)E_EDGES * 64 * 2);
    u32* c_deg    = (u32*)take((size_t)N_NODES_C * 4);
    u32* c_row    = (u32*)take((size_t)N_NODES_C * 4);
    u32* c_cur    = (u32*)take((size_t)N_NODES_C * 4);
    int* c_elist  = (int*)take((size_t)E_EDGES * 4);
    // arena — aliased by phase
    char* arena   = take(173015040);
    if (off > ws_size) {  // diagnostic: paint output so the failure mode is identifiable
        k_diag<<<(out_size + 255) / 256, 256, 0, stream>>>((float*)d_out, out_size);
        return;
    }

    u16* a_ee   = (u16*)(arena + 0);           // radial phase
    u16* a_xe   = (u16*)(arena + 0);           // per-chunk (EC,1536); ee dead after radmlp
    u16* a_A1   = (u16*)(arena + 37748736);    // per-chunk (EC,2432)
    u16* a_Y0   = (u16*)(arena + 97517568);    // full (E,640)
    u16* a_Y1   = (u16*)(arena + 128974848);   // full (E,512)
    u16* a_Y2   = (u16*)(arena + 154140672);   // full (E,384) -> arena end
    u16* a_A2   = (u16*)(arena + 0);           // full (E,1216); xe/A1 dead
    u16* a_Z0   = (u16*)(arena + 59768832);    // per-chunk (EC,640)
    u16* a_Z1   = (u16*)(arena + 75497472);    // per-chunk (EC,1024)
    u16* a_Z2   = (u16*)(arena + 100663296);   // per-chunk (EC,768); overlaps dead Y0 region

    // ---- fused prep (weights + init + deg-zero + edge embeds): 1 launch ----
    PrepArgs pa;
    pa.rad_w1 = rad_w1; pa.rad_w2 = rad_w2; pa.rad_w3 = rad_w3;
    pa.c1_w0 = c1_w0; pa.c2_w0 = c2_w0;
    pa.c1_wm1 = c1_wm1; pa.c1_wm2 = c1_wm2; pa.c2_wm1 = c2_wm1; pa.c2_wm2 = c2_wm2;
    pa.to_grid = to_grid; pa.from_grid = from_grid; pa.proj_w = proj_w;
    pa.w_rad1T = w_rad1T; pa.w_rad2T = w_rad2T; pa.w_rad3T = w_rad3T;
    pa.w_c1w0T = w_c1w0T; pa.w_c2w0T = w_c2w0T;
    pa.w_c1m1T = w_c1m1T; pa.w_c1m2T = w_c1m2T; pa.w_c2m1T = w_c2m1T; pa.w_c2m2T = w_c2m2T;
    pa.w_tgP = w_tgP; pa.w_fgP = w_fgP; pa.w_pwT = w_pwT;
    pa.nmax = nmax; pa.nsum = nsum; pa.c_deg = c_deg;
    pa.dist = dist; pa.species = species; pa.snd = snd; pa.rcv = rcv;
    pa.semb = semb; pa.remb = remb; pa.ee = a_ee;
    k_prep<<<PREP_BLOCKS, 256, 0, stream>>>(pa);

    // ---- CSR build ----
    k_deg<<<96, 256, 0, stream>>>(rcv, c_deg);
    k_pfx<<<1, 256, 0, stream>>>(c_deg, c_row, c_cur);
    k_fill<<<96, 256, 0, stream>>>(rcv, c_cur, c_elist);

    // ---- fused radial MLP: 1 launch ----
    k_radmlp<<<192, 256, 0, stream>>>(a_ee, w_rad1T, w_rad2T,
                                      rad_b1, rad_g1, rad_be1,
                                      rad_b2, rad_g2, rad_be2, a_h2);

    // ---- chunked: x_edge gemm -> rotate -> conv1 (3 gemms fused) ----
    for (int c = 0; c < 2; c++) {
        int e0 = c * EC;
        k_gemm<<<dim3(96, 12), 256, 0, stream>>>(a_h2 + (size_t)e0 * 64, 64, w_rad3T, 64,
                                                 a_xe, 1536, 1536, 64, rad_b3);
        k_rotate<<<EC / 2, 256, 0, stream>>>(nf, wig, snd, rcv, a_xe, a_A1, e0);
        Gemm3 g1;
        g1.d[0] = { a_A1,        w_c1w0T, a_Y0 + (size_t)e0 * 640, c1_b0,   2432, 640,  640, 640, 640 };
        g1.d[1] = { a_A1 + 640,  w_c1m1T, a_Y1 + (size_t)e0 * 512, nullptr, 2432, 1024, 512, 512, 1024 };
        g1.d[2] = { a_A1 + 1664, w_c1m2T, a_Y2 + (size_t)e0 * 384, nullptr, 2432, 768,  384, 384, 768 };
        g1.cut0 = 5; g1.cut1 = 9; g1.nY = 12;
        g1.logits = nullptr; g1.rcv = nullptr; g1.nmax = nullptr; g1.ealpha = nullptr; g1.nsum = nullptr;
        k_gemm3<<<dim3(96, 12), 256, 0, stream>>>(g1);
    }

    // ---- grid nonlinearity + attention logits (fused; logits 8 edges/block) ----
    k_grid_logits<<<E_EDGES / 2 + E_EDGES / 8, 256, 0, stream>>>(
        a_Y0, a_Y1, a_Y2, w_tgP, w_fgP, a_A2,
        rcv, aln_g, aln_b, adot, logits, nmax);

    // ---- chunked: conv2 (3 gemms fused; chunk0 carries the expsum plane) -> gather ----
    for (int c = 0; c < 2; c++) {
        int e0 = c * EC;
        Gemm3 g2;
        g2.d[0] = { a_A2 + (size_t)e0 * 1216,       w_c2w0T, a_Z0, c2_b0,   1216, 320, 640,  640,  320 };
        g2.d[1] = { a_A2 + (size_t)e0 * 1216 + 320, w_c2m1T, a_Z1, nullptr, 1216, 512, 1024, 1024, 512 };
        g2.d[2] = { a_A2 + (size_t)e0 * 1216 + 832, w_c2m2T, a_Z2, nullptr, 1216, 384, 768,  768,  384 };
        g2.cut0 = 5; g2.cut1 = 13; g2.nY = 19;
        g2.logits = logits; g2.rcv = rcv; g2.nmax = nmax; g2.ealpha = ealpha; g2.nsum = nsum;
        int gy = (c == 0) ? 20 : 19;        // chunk0 carries the expsum plane (deps: logits done)
        k_gemm3<<<dim3(96, gy), 256, 0, stream>>>(g2);
        k_gather<<<N_NODES_C / 4, 256, 0, stream>>>(a_Z0, a_Z1, a_Z2, wig, ealpha, nsum,
                                                    c_row, c_deg, c_elist, node, e0, c);
    }

    // ---- output projection (MFMA) ----
    k_proj_mfma<<<dim3(32, 25), 256, 0, stream>>>(node, w_pwT, proj_b, (float*)d_out);
}

// Round 11
// 892.677 us; speedup vs baseline: 1.2285x; 1.0058x over previous
//
#include <hip/hip_runtime.h>

typedef unsigned short u16;
typedef unsigned int u32;
typedef __attribute__((ext_vector_type(8))) short short8;
typedef __attribute__((ext_vector_type(4))) float floatx4;

#define E_EDGES 24576
#define EC 12288            // edge chunk
#define N_NODES_C 4096

__device__ __forceinline__ float bf2f(u16 u) {
    union { u32 i; float f; } v; v.i = ((u32)u) << 16; return v.f;
}
__device__ __forceinline__ u16 f2bf(float f) {
    union { float f; u32 i; } v; v.f = f;
    u32 x = v.i;
    u32 r = (x + 0x7fffu + ((x >> 16) & 1u)) >> 16;
    return (u16)r;
}
// packed f32x2 -> bf16x2 in one VALU inst (RNE), no builtin on gfx950 -> inline asm
__device__ __forceinline__ u32 pk_bf16(float a, float b) {
    u32 r;
    asm("v_cvt_pk_bf16_f32 %0, %1, %2" : "=v"(r) : "v"(a), "v"(b));
    return r;
}
__device__ __forceinline__ u32 encf(float f) {
    union { float f; u32 i; } v; v.f = f;
    return (v.i & 0x80000000u) ? ~v.i : (v.i | 0x80000000u);
}
__device__ __forceinline__ float decf(u32 u) {
    union { u32 i; float f; } v;
    v.i = (u & 0x80000000u) ? (u ^ 0x80000000u) : ~u;
    return v.f;
}
// fast transcendentals: v_exp_f32 + v_rcp_f32
__device__ __forceinline__ float sigmoidf_(float x) { return __fdividef(1.f, 1.f + __expf(-x)); }
__device__ __forceinline__ float siluf_(float x) { return x * __fdividef(1.f, 1.f + __expf(-x)); }

// async global->LDS, 16B per lane; LDS dest must be wave-uniform base + lane*16
__device__ __forceinline__ void gld16(const u16* g, u16* l) {
    __builtin_amdgcn_global_load_lds((const __attribute__((address_space(1))) unsigned int*)g,
                                     (__attribute__((address_space(3))) unsigned int*)l, 16, 0, 0);
}

// diagnostic: ws too small -> paint output with 1000 (f32)
__global__ void k_diag(float* __restrict__ out, int n) {
    int i = blockIdx.x * 256 + threadIdx.x;
    if (i < n) out[i] = 1000.0f;
}

// ================= fused prep: all weight prep + init + deg-zero + edge embeds =================
struct PrepArgs {
    const float *rad_w1, *rad_w2, *rad_w3, *c1_w0, *c2_w0;
    const float *c1_wm1, *c1_wm2, *c2_wm1, *c2_wm2;
    const float *to_grid, *from_grid, *proj_w;
    u16 *w_rad1T, *w_rad2T, *w_rad3T, *w_c1w0T, *w_c2w0T;
    u16 *w_c1m1T, *w_c1m2T, *w_c2m1T, *w_c2m2T;
    u16 *w_tgP, *w_fgP, *w_pwT;
    u32 *nmax; float *nsum; u32 *c_deg;
    const float *dist; const int *species, *snd, *rcv;
    const float *semb, *remb; u16 *ee;
};

__device__ __forceinline__ void prep_transpose(const float* __restrict__ src, u16* __restrict__ dst,
                                               int K, int N, int idx) {
    if (idx >= K * N) return;
    int k = idx / N, n = idx % N;
    dst[n * K + k] = f2bf(src[idx]);
}
__device__ __forceinline__ void prep_combine(const float* __restrict__ src, u16* __restrict__ dst,
                                             int K, int H, int idx) {
    if (idx >= 4 * K * H) return;
    int n = idx / (2 * K), k = idx % (2 * K);
    float v;
    if (k < K) v = src[k * 2 * H + n];
    else {
        int kk = k - K;
        if (n < H) v = -src[kk * 2 * H + H + n];
        else       v = src[kk * 2 * H + (n - H)];
    }
    dst[idx] = f2bf(v);
}

#define PB0 48
#define PB1 16
#define PB2 384
#define PB3 1600
#define PB4 800
#define PB5 2048
#define PB6 1152
#define PB7 2048
#define PB8 1152
#define PB9 30
#define PB10 160
#define PB11 128
#define PB12 16
#define PB13 18432
#define PREP_BLOCKS (PB0+PB1+PB2+PB3+PB4+PB5+PB6+PB7+PB8+PB9+PB10+PB11+PB12+PB13)

__global__ __launch_bounds__(256) void k_prep(PrepArgs a) {
    int bid = blockIdx.x;
    int tid = threadIdx.x;
    if (bid < PB0) { prep_transpose(a.rad_w1, a.w_rad1T, 192, 64, bid * 256 + tid); return; }
    bid -= PB0;
    if (bid < PB1) { prep_transpose(a.rad_w2, a.w_rad2T, 64, 64, bid * 256 + tid); return; }
    bid -= PB1;
    if (bid < PB2) { prep_transpose(a.rad_w3, a.w_rad3T, 64, 1536, bid * 256 + tid); return; }
    bid -= PB2;
    if (bid < PB3) { prep_transpose(a.c1_w0, a.w_c1w0T, 640, 640, bid * 256 + tid); return; }
    bid -= PB3;
    if (bid < PB4) { prep_transpose(a.c2_w0, a.w_c2w0T, 320, 640, bid * 256 + tid); return; }
    bid -= PB4;
    if (bid < PB5) { prep_combine(a.c1_wm1, a.w_c1m1T, 512, 256, bid * 256 + tid); return; }
    bid -= PB5;
    if (bid < PB6) { prep_combine(a.c1_wm2, a.w_c1m2T, 384, 192, bid * 256 + tid); return; }
    bid -= PB6;
    if (bid < PB7) { prep_combine(a.c2_wm1, a.w_c2m1T, 256, 512, bid * 256 + tid); return; }
    bid -= PB7;
    if (bid < PB8) { prep_combine(a.c2_wm2, a.w_c2m2T, 192, 384, bid * 256 + tid); return; }
    bid -= PB8;
    if (bid < PB9) {
        int idx = bid * 256 + tid;
        if (idx < 112 * 32) {
            int p = idx >> 5, m = idx & 31;
            a.w_tgP[idx] = (p < 100 && m < 19) ? f2bf(a.to_grid[p * 19 + m]) : (u16)0;
        }
        int j = idx - 112 * 32;
        if (j >= 0 && j < 32 * 128) {
            int m = j >> 7, k = j & 127;
            a.w_fgP[j] = (m < 19 && k < 100) ? f2bf(a.from_grid[m * 100 + k]) : (u16)0;
        }
        return;
    }
    bid -= PB9;
    if (bid < PB10) {
        int idx = bid * 256 + tid;
        int l = idx >> 13, rem = idx & 8191;
        prep_transpose(a.proj_w + (size_t)l * 8192, a.w_pwT + (size_t)l * 8192, 128, 64, rem);
        return;
    }
    bid -= PB10;
    if (bid < PB11) {
        int idx = bid * 256 + tid;
        if (idx < N_NODES_C * 8) { a.nmax[idx] = 0x007FFFFFu; a.nsum[idx] = 0.f; }
        return;
    }
    bid -= PB11;
    if (bid < PB12) {
        int idx = bid * 256 + tid;
        if (idx < N_NODES_C) a.c_deg[idx] = 0u;
        return;
    }
    bid -= PB12;
    {
        int idx = bid * 256 + tid;
        if (idx >= E_EDGES * 192) return;
        int e = idx / 192, c = idx % 192;
        float v;
        if (c < 64)       v = a.dist[e * 64 + c];
        else if (c < 128) v = a.semb[a.species[a.snd[e]] * 64 + (c - 64)];
        else              v = a.remb[a.species[a.rcv[e]] * 64 + (c - 128)];
        a.ee[idx] = f2bf(v);
    }
}

// ---------------- CSR build over receivers (static per launch) ----------------
__global__ void k_deg(const int* __restrict__ rcv, u32* __restrict__ deg) {
    int e = blockIdx.x * 256 + threadIdx.x;
    if (e < E_EDGES) atomicAdd(&deg[rcv[e]], 1u);
}
__global__ __launch_bounds__(256) void k_pfx(const u32* __restrict__ deg,
                                             u32* __restrict__ rowstart, u32* __restrict__ cur) {
    __shared__ u32 ps[256];
    int t = threadIdx.x;
    u32 loc[16]; u32 s = 0;
#pragma unroll
    for (int i = 0; i < 16; i++) { loc[i] = s; s += deg[t * 16 + i]; }
    ps[t] = s;
    __syncthreads();
    for (int o = 1; o < 256; o <<= 1) {
        u32 v = (t >= o) ? ps[t - o] : 0u;
        __syncthreads();
        ps[t] += v;
        __syncthreads();
    }
    u32 base = (t == 0) ? 0u : ps[t - 1];
#pragma unroll
    for (int i = 0; i < 16; i++) { u32 v = base + loc[i]; rowstart[t * 16 + i] = v; cur[t * 16 + i] = v; }
}
__global__ void k_fill(const int* __restrict__ rcv, u32* __restrict__ cur, int* __restrict__ elist) {
    int e = blockIdx.x * 256 + threadIdx.x;
    if (e < E_EDGES) { u32 p = atomicAdd(&cur[rcv[e]], 1u); elist[p] = e; }
}

// ---------------- fused radial MLP: silu(LN(ee@W1+b1)) -> silu(LN(.@W2+b2)) -> h2 ----------------
__global__ __launch_bounds__(256) void k_radmlp(
    const u16* __restrict__ ee, const u16* __restrict__ w1T, const u16* __restrict__ w2T,
    const float* __restrict__ b1, const float* __restrict__ g1, const float* __restrict__ be1,
    const float* __restrict__ b2, const float* __restrict__ g2, const float* __restrict__ be2,
    u16* __restrict__ h2) {
    __shared__ u16 Y1s[128 * 72];
    int tid = threadIdx.x;
    int wave = tid >> 6, lane = tid & 63;
    int ln = lane & 15, q = lane >> 4;
    int wm = wave * 32;
    int e0 = blockIdx.x * 128;

    floatx4 acc[2][4];
#pragma unroll
    for (int i = 0; i < 2; i++)
#pragma unroll
        for (int j = 0; j < 4; j++) acc[i][j] = floatx4{0.f, 0.f, 0.f, 0.f};
    // GEMM1: K=192
#pragma unroll
    for (int ks = 0; ks < 6; ks++) {
        short8 a0 = *(const short8*)(&ee[(size_t)(e0 + wm + ln) * 192 + ks * 32 + q * 8]);
        short8 a1 = *(const short8*)(&ee[(size_t)(e0 + wm + 16 + ln) * 192 + ks * 32 + q * 8]);
#pragma unroll
        for (int j = 0; j < 4; j++) {
            short8 b = *(const short8*)(&w1T[(size_t)(j * 16 + ln) * 192 + ks * 32 + q * 8]);
            acc[0][j] = __builtin_amdgcn_mfma_f32_16x16x32_bf16(b, a0, acc[0][j], 0, 0, 0);
            acc[1][j] = __builtin_amdgcn_mfma_f32_16x16x32_bf16(b, a1, acc[1][j], 0, 0, 0);
        }
    }
    // LN1 + silu -> Y1s
#pragma unroll
    for (int i = 0; i < 2; i++) {
        float s = 0.f, s2 = 0.f;
#pragma unroll
        for (int j = 0; j < 4; j++) {
            int cb = j * 16 + q * 4;
            float4 bv = *(const float4*)(&b1[cb]);
            float vb[4] = {bv.x, bv.y, bv.z, bv.w};
#pragma unroll
            for (int r = 0; r < 4; r++) {
                float v = acc[i][j][r] + vb[r];
                acc[i][j][r] = v;
                s += v; s2 += v * v;
            }
        }
        s += __shfl_xor(s, 16); s += __shfl_xor(s, 32);
        s2 += __shfl_xor(s2, 16); s2 += __shfl_xor(s2, 32);
        float mu = s * (1.f / 64.f);
        float var = s2 * (1.f / 64.f) - mu * mu;
        float rs = rsqrtf(var + 1e-5f);
        int row = wm + i * 16 + ln;
#pragma unroll
        for (int j = 0; j < 4; j++) {
            int cb = j * 16 + q * 4;
            float4 gv = *(const float4*)(&g1[cb]);
            float4 ev = *(const float4*)(&be1[cb]);
            float y0 = (acc[i][j][0] - mu) * rs * gv.x + ev.x;
            float y1 = (acc[i][j][1] - mu) * rs * gv.y + ev.y;
            float y2 = (acc[i][j][2] - mu) * rs * gv.z + ev.z;
            float y3 = (acc[i][j][3] - mu) * rs * gv.w + ev.w;
            uint2 pv;
            pv.x = pk_bf16(siluf_(y0), siluf_(y1));
            pv.y = pk_bf16(siluf_(y2), siluf_(y3));
            *(uint2*)(&Y1s[row * 72 + cb]) = pv;
        }
    }
    __syncthreads();
    // GEMM2: K=64
#pragma unroll
    for (int i = 0; i < 2; i++)
#pragma unroll
        for (int j = 0; j < 4; j++) acc[i][j] = floatx4{0.f, 0.f, 0.f, 0.f};
#pragma unroll
    for (int ks = 0; ks < 2; ks++) {
        short8 a0 = *(const short8*)(&Y1s[(wm + ln) * 72 + ks * 32 + q * 8]);
        short8 a1 = *(const short8*)(&Y1s[(wm + 16 + ln) * 72 + ks * 32 + q * 8]);
#pragma unroll
        for (int j = 0; j < 4; j++) {
            short8 b = *(const short8*)(&w2T[(size_t)(j * 16 + ln) * 64 + ks * 32 + q * 8]);
            acc[0][j] = __builtin_amdgcn_mfma_f32_16x16x32_bf16(b, a0, acc[0][j], 0, 0, 0);
            acc[1][j] = __builtin_amdgcn_mfma_f32_16x16x32_bf16(b, a1, acc[1][j], 0, 0, 0);
        }
    }
    // LN2 + silu -> h2 (global, uint2 stores)
#pragma unroll
    for (int i = 0; i < 2; i++) {
        float s = 0.f, s2 = 0.f;
#pragma unroll
        for (int j = 0; j < 4; j++) {
            int cb = j * 16 + q * 4;
            float4 bv = *(const float4*)(&b2[cb]);
            float vb[4] = {bv.x, bv.y, bv.z, bv.w};
#pragma unroll
            for (int r = 0; r < 4; r++) {
                float v = acc[i][j][r] + vb[r];
                acc[i][j][r] = v;
                s += v; s2 += v * v;
            }
        }
        s += __shfl_xor(s, 16); s += __shfl_xor(s, 32);
        s2 += __shfl_xor(s2, 16); s2 += __shfl_xor(s2, 32);
        float mu = s * (1.f / 64.f);
        float var = s2 * (1.f / 64.f) - mu * mu;
        float rs = rsqrtf(var + 1e-5f);
        int row = e0 + wm + i * 16 + ln;
#pragma unroll
        for (int j = 0; j < 4; j++) {
            int cb = j * 16 + q * 4;
            float4 gv = *(const float4*)(&g2[cb]);
            float4 ev = *(const float4*)(&be2[cb]);
            float y0 = (acc[i][j][0] - mu) * rs * gv.x + ev.x;
            float y1 = (acc[i][j][1] - mu) * rs * gv.y + ev.y;
            float y2 = (acc[i][j][2] - mu) * rs * gv.z + ev.z;
            float y3 = (acc[i][j][3] - mu) * rs * gv.w + ev.w;
            uint2 pv;
            pv.x = pk_bf16(siluf_(y0), siluf_(y1));
            pv.y = pk_bf16(siluf_(y2), siluf_(y3));
            *(uint2*)(&h2[(size_t)row * 64 + cb]) = pv;
        }
    }
}

// ---------------- GEMM: A (M,K) bf16 rm, BT (N,K) bf16 rm, C (M,N) bf16 ----------------
__global__ __launch_bounds__(256) void k_gemm(
    const u16* __restrict__ A, int lda,
    const u16* __restrict__ BT, int ldb,
    u16* __restrict__ C, int ldc,
    int N, int K,
    const float* __restrict__ bias) {
    __shared__ u16 As[2][128 * 32];
    __shared__ u16 Bs[2][128 * 32];
    int tid = threadIdx.x;
    int bm0 = blockIdx.x * 128;
    int bn0 = blockIdx.y * 128;
    int wave = tid >> 6, lane = tid & 63;
    int wm = (wave >> 1) * 64, wn = (wave & 1) * 64;
    int lrow = lane & 15, lk = (lane >> 4) * 8;

    int srow = (wave << 4) + (lane >> 2);
    int schunk = (lane & 3) << 3;
    const u16* Arow0 = A + (size_t)(bm0 + srow) * lda + schunk;
    const u16* Arow1 = A + (size_t)(bm0 + srow + 64) * lda + schunk;
    int n0 = bn0 + srow;      if (n0 >= N) n0 = N - 1;
    int n1 = bn0 + srow + 64; if (n1 >= N) n1 = N - 1;
    const u16* Brow0 = BT + (size_t)n0 * ldb + schunk;
    const u16* Brow1 = BT + (size_t)n1 * ldb + schunk;

    auto stage = [&](int buf, int k0) {
        gld16(Arow0 + k0, &As[buf][srow * 32 + schunk]);
        gld16(Arow1 + k0, &As[buf][(srow + 64) * 32 + schunk]);
        gld16(Brow0 + k0, &Bs[buf][srow * 32 + schunk]);
        gld16(Brow1 + k0, &Bs[buf][(srow + 64) * 32 + schunk]);
    };

    floatx4 acc[4][4];
#pragma unroll
    for (int i = 0; i < 4; i++)
#pragma unroll
        for (int j = 0; j < 4; j++) acc[i][j] = floatx4{0.f, 0.f, 0.f, 0.f};

    int NT = K >> 5;
    stage(0, 0);
    for (int kt = 0; kt < NT; kt++) {
        int cur = kt & 1;
        if (kt + 1 < NT) {
            stage(cur ^ 1, (kt + 1) << 5);
            asm volatile("s_waitcnt vmcnt(4)" ::: "memory");
        } else {
            asm volatile("s_waitcnt vmcnt(0)" ::: "memory");
        }
        __syncthreads();
        short8 a[4], b[4];
#pragma unroll
        for (int i = 0; i < 4; i++) a[i] = *(const short8*)(&As[cur][(wm + i * 16 + lrow) * 32 + lk]);
#pragma unroll
        for (int j = 0; j < 4; j++) b[j] = *(const short8*)(&Bs[cur][(wn + j * 16 + lrow) * 32 + lk]);
#pragma unroll
        for (int i = 0; i < 4; i++)
#pragma unroll
            for (int j = 0; j < 4; j++)
                acc[i][j] = __builtin_amdgcn_mfma_f32_16x16x32_bf16(b[j], a[i], acc[i][j], 0, 0, 0);
        __syncthreads();
    }

    int q = lane >> 4;
#pragma unroll
    for (int i = 0; i < 4; i++) {
        int row = bm0 + wm + i * 16 + lrow;
#pragma unroll
        for (int j = 0; j < 4; j++) {
            int col = bn0 + wn + j * 16 + q * 4;
            if (col < N) {
                float4 bv = bias ? *(const float4*)(&bias[col]) : float4{0.f, 0.f, 0.f, 0.f};
                uint2 pv;
                pv.x = pk_bf16(acc[i][j][0] + bv.x, acc[i][j][1] + bv.y);
                pv.y = pk_bf16(acc[i][j][2] + bv.z, acc[i][j][3] + bv.w);
                *(uint2*)(&C[(size_t)row * ldc + col]) = pv;
            }
        }
    }
}

// ---------------- batched 3-way GEMM + optional fused expsum plane ----------------
struct GemmDesc {
    const u16* A; const u16* BT; u16* C;
    const float* bias;
    int lda, ldb, ldc, N, K;
};
struct Gemm3 {
    GemmDesc d[3];
    int cut0, cut1, nY;     // blocks with blockIdx.y >= nY run the expsum plane
    const float* logits; const int* rcv; const u32* nmax;
    float* ealpha; float* nsum;
};
__global__ __launch_bounds__(256) void k_gemm3(Gemm3 g) {
    int y = blockIdx.y;
    if (y >= g.nY) {
        // fused expsum: 96 x-blocks * 256 threads * 8 iters = E*8 exactly
        int base = blockIdx.x * 256 + threadIdx.x;
#pragma unroll
        for (int it = 0; it < 8; it++) {
            int idx = it * 24576 + base;
            int e = idx >> 3, h = idx & 7;
            int r = g.rcv[e];
            float amax = decf(g.nmax[r * 8 + h]);
            if (!(amax > -1e38f && amax < 1e38f)) amax = 0.f;
            float v = __expf(g.logits[idx] - amax);
            g.ealpha[idx] = v;
            atomicAdd(&g.nsum[r * 8 + h], v);
        }
        return;
    }
    GemmDesc d;
    int ytile;
    if (y < g.cut0)      { d = g.d[0]; ytile = y; }
    else if (y < g.cut1) { d = g.d[1]; ytile = y - g.cut0; }
    else                 { d = g.d[2]; ytile = y - g.cut1; }

    __shared__ u16 As[2][128 * 32];
    __shared__ u16 Bs[2][128 * 32];
    int tid = threadIdx.x;
    int bm0 = blockIdx.x * 128;
    int bn0 = ytile * 128;
    int wave = tid >> 6, lane = tid & 63;
    int wm = (wave >> 1) * 64, wn = (wave & 1) * 64;
    int lrow = lane & 15, lk = (lane >> 4) * 8;

    int srow = (wave << 4) + (lane >> 2);
    int schunk = (lane & 3) << 3;
    const u16* Arow0 = d.A + (size_t)(bm0 + srow) * d.lda + schunk;
    const u16* Arow1 = d.A + (size_t)(bm0 + srow + 64) * d.lda + schunk;
    int n0 = bn0 + srow;      if (n0 >= d.N) n0 = d.N - 1;
    int n1 = bn0 + srow + 64; if (n1 >= d.N) n1 = d.N - 1;
    const u16* Brow0 = d.BT + (size_t)n0 * d.ldb + schunk;
    const u16* Brow1 = d.BT + (size_t)n1 * d.ldb + schunk;

    auto stage = [&](int buf, int k0) {
        gld16(Arow0 + k0, &As[buf][srow * 32 + schunk]);
        gld16(Arow1 + k0, &As[buf][(srow + 64) * 32 + schunk]);
        gld16(Brow0 + k0, &Bs[buf][srow * 32 + schunk]);
        gld16(Brow1 + k0, &Bs[buf][(srow + 64) * 32 + schunk]);
    };

    floatx4 acc[4][4];
#pragma unroll
    for (int i = 0; i < 4; i++)
#pragma unroll
        for (int j = 0; j < 4; j++) acc[i][j] = floatx4{0.f, 0.f, 0.f, 0.f};

    int NT = d.K >> 5;
    stage(0, 0);
    for (int kt = 0; kt < NT; kt++) {
        int cur = kt & 1;
        if (kt + 1 < NT) {
            stage(cur ^ 1, (kt + 1) << 5);
            asm volatile("s_waitcnt vmcnt(4)" ::: "memory");
        } else {
            asm volatile("s_waitcnt vmcnt(0)" ::: "memory");
        }
        __syncthreads();
        short8 a[4], b[4];
#pragma unroll
        for (int i = 0; i < 4; i++) a[i] = *(const short8*)(&As[cur][(wm + i * 16 + lrow) * 32 + lk]);
#pragma unroll
        for (int j = 0; j < 4; j++) b[j] = *(const short8*)(&Bs[cur][(wn + j * 16 + lrow) * 32 + lk]);
#pragma unroll
        for (int i = 0; i < 4; i++)
#pragma unroll
            for (int j = 0; j < 4; j++)
                acc[i][j] = __builtin_amdgcn_mfma_f32_16x16x32_bf16(b[j], a[i], acc[i][j], 0, 0, 0);
        __syncthreads();
    }

    int q = lane >> 4;
#pragma unroll
    for (int i = 0; i < 4; i++) {
        int row = bm0 + wm + i * 16 + lrow;
#pragma unroll
        for (int j = 0; j < 4; j++) {
            int col = bn0 + wn + j * 16 + q * 4;
            if (col < d.N) {
                float4 bv = d.bias ? *(const float4*)(&d.bias[col]) : float4{0.f, 0.f, 0.f, 0.f};
                uint2 pv;
                pv.x = pk_bf16(acc[i][j][0] + bv.x, acc[i][j][1] + bv.y);
                pv.y = pk_bf16(acc[i][j][2] + bv.z, acc[i][j][3] + bv.w);
                *(uint2*)(&d.C[(size_t)row * d.ldc + col]) = pv;
            }
        }
    }
}

// ---------------- rotate: wigner @ concat(nf[snd],nf[rcv]); scale by x_edge; pack A1 (chunked) ----------------
__global__ __launch_bounds__(256) void k_rotate(const float* __restrict__ nf, const float* __restrict__ wig,
                                                const int* __restrict__ snd, const int* __restrict__ rcv,
                                                const u16* __restrict__ xe, u16* __restrict__ A1, int e0) {
    __shared__ float wl[2][475];
    int tid = threadIdx.x;
    for (int i = tid; i < 950; i += 256) {
        int ee = e0 + blockIdx.x * 2 + (i / 475);
        wl[i / 475][i % 475] = wig[(size_t)ee * 475 + (i % 475)];
    }
    __syncthreads();
    int le = tid >> 7, c = tid & 127;
    int el = blockIdx.x * 2 + le;       // chunk-local
    int e = e0 + el;                    // global
    int nd = (c < 64) ? snd[e] : rcv[e];
    int cc = c & 63;
    float msg[25];
#pragma unroll
    for (int k = 0; k < 25; k++) msg[k] = nf[(size_t)nd * 1600 + k * 64 + cc];
    const float* w = wl[le];
    size_t ebase = (size_t)el * 2432;
    size_t xbase = (size_t)el * 1536;
#pragma unroll
    for (int m = 0; m < 19; m++) {
        float r = 0.f;
#pragma unroll
        for (int k = 0; k < 25; k++) r += w[m * 25 + k] * msg[k];
        int a1c, xc;
        if (m < 5)       { a1c = m * 128;               xc = m * 128; }
        else if (m < 9)  { a1c = 640 + (m - 5) * 128;   xc = 640 + (m - 5) * 128; }
        else if (m < 13) { a1c = 1152 + (m - 9) * 128;  xc = 640 + (m - 9) * 128; }
        else if (m < 16) { a1c = 1664 + (m - 13) * 128; xc = 1152 + (m - 13) * 128; }
        else             { a1c = 2048 + (m - 16) * 128; xc = 1152 + (m - 16) * 128; }
        float sc = bf2f(xe[xbase + xc + c]);
        A1[ebase + a1c + c] = f2bf(r * sc);
    }
}

// ---------------- attention logits + segment max (standalone; zero LDS, high occupancy) ----------------
// R10 lesson: fusing this into the 34.8KB-LDS grid kernel cost ~23us (occupancy-capped
// block-scheduling waves) vs ~3us launch saving. Keep separate.
__global__ __launch_bounds__(256) void k_logits(const u16* __restrict__ Y0, const int* __restrict__ rcv,
                                                const float* __restrict__ g, const float* __restrict__ b,
                                                const float* __restrict__ adot,
                                                float* __restrict__ logits, u32* __restrict__ nmax) {
    int e = blockIdx.x;
    int tid = threadIdx.x;
    int h = tid >> 5, c = tid & 31;
    float x = bf2f(Y0[(size_t)e * 640 + 320 + h * 32 + c]);
    float s = x, s2 = x * x;
#pragma unroll
    for (int o = 16; o; o >>= 1) { s += __shfl_xor(s, o); s2 += __shfl_xor(s2, o); }
    float mu = s * (1.f / 32.f);
    float var = s2 * (1.f / 32.f) - mu * mu;
    float rs = rsqrtf(var + 1e-5f);
    float a = (x - mu) * rs * g[c] + b[c];
    float f = 0.6f * a + 0.4f * a * (2.f * sigmoidf_(a) - 1.f);
    float l = f * adot[h * 32 + c];
#pragma unroll
    for (int o = 16; o; o >>= 1) l += __shfl_xor(l, o);
    if (c == 0) {
        logits[e * 8 + h] = l;
        atomicMax(&nmax[rcv[e] * 8 + h], encf(l));
    }
}

// ---------------- grid round-trip via MFMA (pure; logits un-fused per R10 post-mortem) ----------------
#define GR_XS_STR 40
#define GR_T1_STR 136
__global__ __launch_bounds__(256) void k_grid_mfma(
    const u16* __restrict__ Y0, const u16* __restrict__ Y1, const u16* __restrict__ Y2,
    const u16* __restrict__ tgP, const u16* __restrict__ fgP, u16* __restrict__ A2) {
    __shared__ u16 T1s[128 * GR_T1_STR];
    u16* Xs = T1s;                       // alias: Xs consumed before T1s written
    int tid = threadIdx.x;
    int e0 = blockIdx.x * 2;
    {
        int mp = tid & 15;
        int c0 = ((tid >> 4) & 7) << 3;
        int le = tid >> 7;
        int e = e0 + le;
        int m0 = 2 * mp, m1 = m0 + 1;
        uint4 va = {0, 0, 0, 0}, vb = {0, 0, 0, 0};
        if (m0 < 5)       va = *(const uint4*)(&Y0[(size_t)e * 640 + m0 * 64 + c0]);
        else if (m0 < 13) va = *(const uint4*)(&Y1[(size_t)e * 512 + (m0 - 5) * 64 + c0]);
        else if (m0 < 19) va = *(const uint4*)(&Y2[(size_t)e * 384 + (m0 - 13) * 64 + c0]);
        if (m1 < 5)       vb = *(const uint4*)(&Y0[(size_t)e * 640 + m1 * 64 + c0]);
        else if (m1 < 13) vb = *(const uint4*)(&Y1[(size_t)e * 512 + (m1 - 5) * 64 + c0]);
        else if (m1 < 19) vb = *(const uint4*)(&Y2[(size_t)e * 384 + (m1 - 13) * 64 + c0]);
        const u16* pa = (const u16*)&va;
        const u16* pb = (const u16*)&vb;
        int rbase = le * 64 + c0;
#pragma unroll
        for (int j = 0; j < 8; j++) {
            u32 w = (u32)pa[j] | ((u32)pb[j] << 16);
            *(u32*)(&Xs[(rbase + j) * GR_XS_STR + 2 * mp]) = w;
        }
    }
    __syncthreads();
    int wave = tid >> 6, lane = tid & 63;
    int wn = wave << 5;
    int ln = lane & 15, q = lane >> 4;
    short8 bx0 = *(const short8*)(&Xs[(wn + ln) * GR_XS_STR + q * 8]);
    short8 bx1 = *(const short8*)(&Xs[(wn + 16 + ln) * GR_XS_STR + q * 8]);
    floatx4 acc1[2][7];
#pragma unroll
    for (int pt = 0; pt < 7; pt++) {
        short8 a = *(const short8*)(&tgP[(size_t)(pt * 16 + ln) * 32 + q * 8]);
        acc1[0][pt] = __builtin_amdgcn_mfma_f32_16x16x32_bf16(a, bx0, floatx4{0.f, 0.f, 0.f, 0.f}, 0, 0, 0);
        acc1[1][pt] = __builtin_amdgcn_mfma_f32_16x16x32_bf16(a, bx1, floatx4{0.f, 0.f, 0.f, 0.f}, 0, 0, 0);
    }
    __syncthreads();    // all Xs reads complete -> safe to overwrite (alias)
    {
        int row = tid >> 1;
        uint4 z = {0, 0, 0, 0};
        *(uint4*)(&T1s[row * GR_T1_STR + 112 + (tid & 1) * 8]) = z;
    }
#pragma unroll
    for (int i = 0; i < 2; i++) {
        u16* dst = &T1s[(wn + i * 16 + ln) * GR_T1_STR + q * 4];
#pragma unroll
        for (int pt = 0; pt < 7; pt++) {
            uint2 pv;
            pv.x = pk_bf16(siluf_(acc1[i][pt][0]), siluf_(acc1[i][pt][1]));
            pv.y = pk_bf16(siluf_(acc1[i][pt][2]), siluf_(acc1[i][pt][3]));
            *(uint2*)(dst + pt * 16) = pv;
        }
    }
    __syncthreads();
    floatx4 acc2[2][2];
    acc2[0][0] = floatx4{0.f, 0.f, 0.f, 0.f}; acc2[0][1] = floatx4{0.f, 0.f, 0.f, 0.f};
    acc2[1][0] = floatx4{0.f, 0.f, 0.f, 0.f}; acc2[1][1] = floatx4{0.f, 0.f, 0.f, 0.f};
#pragma unroll
    for (int ks = 0; ks < 4; ks++) {
        short8 c0 = *(const short8*)(&T1s[(wn + ln) * GR_T1_STR + ks * 32 + q * 8]);
        short8 c1 = *(const short8*)(&T1s[(wn + 16 + ln) * GR_T1_STR + ks * 32 + q * 8]);
#pragma unroll
        for (int ct = 0; ct < 2; ct++) {
            short8 b = *(const short8*)(&fgP[(size_t)(ct * 16 + ln) * 128 + ks * 32 + q * 8]);
            acc2[0][ct] = __builtin_amdgcn_mfma_f32_16x16x32_bf16(c0, b, acc2[0][ct], 0, 0, 0);
            acc2[1][ct] = __builtin_amdgcn_mfma_f32_16x16x32_bf16(c1, b, acc2[1][ct], 0, 0, 0);
        }
    }
#pragma unroll
    for (int rt = 0; rt < 2; rt++) {
        int row = wn + rt * 16 + q * 4;
        int e = e0 + (row >> 6), c = row & 63;
#pragma unroll
        for (int ct = 0; ct < 2; ct++) {
            int mp = ct * 16 + ln;
            if (mp >= 1 && mp < 19) {
                uint2 pv;
                pv.x = pk_bf16(acc2[rt][ct][0], acc2[rt][ct][1]);
                pv.y = pk_bf16(acc2[rt][ct][2], acc2[rt][ct][3]);
                *(uint2*)(&A2[(size_t)e * 1216 + mp * 64 + c]) = pv;
            }
        }
    }
    if (tid < 128) {
        int e = e0 + (tid >> 6), c = tid & 63;
        float gate = bf2f(Y0[(size_t)e * 640 + 576 + c]);
        A2[(size_t)e * 1216 + c] = f2bf(siluf_(gate));
    }
}

// ---------------- gather: attention scale + wigner^T + segment-sum (no atomics) ----------------
__global__ __launch_bounds__(256) void k_gather(
    const u16* __restrict__ Z0, const u16* __restrict__ Z1, const u16* __restrict__ Z2,
    const float* __restrict__ wig, const float* __restrict__ ealpha, const float* __restrict__ nsum,
    const u32* __restrict__ rowstart, const u32* __restrict__ deg, const int* __restrict__ elist,
    float* __restrict__ node, int e0, int accum) {
    int n = blockIdx.x * 4 + (threadIdx.x >> 6);
    int lane = threadIdx.x & 63;
    int h = lane >> 3;
    float sden = __fdividef(1.f, nsum[n * 8 + h] + 1e-16f);
    float a0[25], a1[25];
#pragma unroll
    for (int k = 0; k < 25; k++) { a0[k] = 0.f; a1[k] = 0.f; }
    u32 lo = rowstart[n], cnt = deg[n];
    bool did = false;
    for (u32 i = 0; i < cnt; i++) {
        int e = __builtin_amdgcn_readfirstlane(elist[lo + i]);
        int el = e - e0;
        if ((u32)el >= (u32)EC) continue;       // wave-uniform
        did = true;
        float al = ealpha[e * 8 + h] * sden;
        u32 zp[19];
        const u16* z0 = Z0 + (size_t)el * 640 + 2 * lane;
        const u16* z1 = Z1 + (size_t)el * 1024 + 2 * lane;
        const u16* z2 = Z2 + (size_t)el * 768 + 2 * lane;
#pragma unroll
        for (int m = 0; m < 5; m++) zp[m] = *(const u32*)(z0 + m * 128);
#pragma unroll
        for (int m = 0; m < 8; m++) zp[5 + m] = *(const u32*)(z1 + m * 128);
#pragma unroll
        for (int m = 0; m < 6; m++) zp[13 + m] = *(const u32*)(z2 + m * 128);
        const float* __restrict__ w = wig + (size_t)e * 475;
#pragma unroll
        for (int m = 0; m < 19; m++) {
            float s0 = bf2f((u16)(zp[m] & 0xffffu)) * al;
            float s1 = bf2f((u16)(zp[m] >> 16)) * al;
#pragma unroll
            for (int k = 0; k < 25; k++) {
                float wv = w[m * 25 + k];
                a0[k] = fmaf(wv, s0, a0[k]);
                a1[k] = fmaf(wv, s1, a1[k]);
            }
        }
    }
    float* nb = node + (size_t)n * 3200 + 2 * lane;
    if (accum) {
        if (!did) return;
#pragma unroll
        for (int k = 0; k < 25; k++) {
            float2 v = *(float2*)(&nb[k * 128]);
            v.x += a0[k]; v.y += a1[k];
            *(float2*)(&nb[k * 128]) = v;
        }
    } else {
#pragma unroll
        for (int k = 0; k < 25; k++) {
            float2 v; v.x = a0[k]; v.y = a1[k];
            *(float2*)(&nb[k * 128]) = v;
        }
    }
}

// ---------------- final projection via MFMA ----------------
#define PJ_STR 136
__global__ __launch_bounds__(256) void k_proj_mfma(
    const float* __restrict__ node, const u16* __restrict__ pwTb,
    const float* __restrict__ pb, float* __restrict__ out) {
    __shared__ u16 As[128 * PJ_STR];
    __shared__ u16 Bs[64 * PJ_STR];
    int tid = threadIdx.x;
    int n0 = blockIdx.x * 128;
    int k = blockIdx.y;
    int l = (int)sqrtf((float)k + 0.5f);
#pragma unroll
    for (int it = 0; it < 16; it++) {
        int i = tid + it * 256;
        int row = i >> 5;
        int c0 = (i & 31) << 2;
        float4 v = *(const float4*)(&node[(size_t)(n0 + row) * 3200 + k * 128 + c0]);
        uint2 pv;
        pv.x = pk_bf16(v.x, v.y);
        pv.y = pk_bf16(v.z, v.w);
        *(uint2*)(&As[row * PJ_STR + c0]) = pv;
    }
    const u16* pw = pwTb + (size_t)l * 8192;
#pragma unroll
    for (int jt = 0; jt < 4; jt++) {
        int j = tid + jt * 256;
        int d = j >> 4;
        int c0 = (j & 15) << 3;
        *(uint4*)(&Bs[d * PJ_STR + c0]) = *(const uint4*)(&pw[d * 128 + c0]);
    }
    __syncthreads();
    int wave = tid >> 6, lane = tid & 63;
    int wr = wave * 32;
    int ln = lane & 15, q = lane >> 4;
    floatx4 acc[2][4];
#pragma unroll
    for (int i = 0; i < 2; i++)
#pragma unroll
        for (int j = 0; j < 4; j++) acc[i][j] = floatx4{0.f, 0.f, 0.f, 0.f};
#pragma unroll
    for (int ks = 0; ks < 4; ks++) {
        short8 a0 = *(const short8*)(&As[(wr + ln) * PJ_STR + ks * 32 + q * 8]);
        short8 a1 = *(const short8*)(&As[(wr + 16 + ln) * PJ_STR + ks * 32 + q * 8]);
#pragma unroll
        for (int j = 0; j < 4; j++) {
            short8 b = *(const short8*)(&Bs[(j * 16 + ln) * PJ_STR + ks * 32 + q * 8]);
            acc[0][j] = __builtin_amdgcn_mfma_f32_16x16x32_bf16(b, a0, acc[0][j], 0, 0, 0);
            acc[1][j] = __builtin_amdgcn_mfma_f32_16x16x32_bf16(b, a1, acc[1][j], 0, 0, 0);
        }
    }
#pragma unroll
    for (int rt = 0; rt < 2; rt++) {
        int n = n0 + wr + rt * 16 + ln;
#pragma unroll
        for (int j = 0; j < 4; j++) {
            int d = j * 16 + q * 4;
            float4 v;
            v.x = acc[rt][j][0]; v.y = acc[rt][j][1];
            v.z = acc[rt][j][2]; v.w = acc[rt][j][3];
            if (k == 0) {
                float4 bv = *(const float4*)(&pb[d]);
                v.x += bv.x; v.y += bv.y; v.z += bv.z; v.w += bv.w;
            }
            *(float4*)(&out[(size_t)n * 1600 + k * 64 + d]) = v;
        }
    }
}

extern "C" void kernel_launch(void* const* d_in, const int* in_sizes, int n_in,
                              void* d_out, int out_size, void* d_ws, size_t ws_size,
                              hipStream_t stream) {
    const float* nf      = (const float*)d_in[0];
    const int* species   = (const int*)d_in[1];
    const float* dist    = (const float*)d_in[2];
    const int* snd       = (const int*)d_in[3];
    const int* rcv       = (const int*)d_in[4];
    const float* wig     = (const float*)d_in[5];
    const float* semb    = (const float*)d_in[6];
    const float* remb    = (const float*)d_in[7];
    const float* rad_w1  = (const float*)d_in[8];
    const float* rad_b1  = (const float*)d_in[9];
    const float* rad_g1  = (const float*)d_in[10];
    const float* rad_be1 = (const float*)d_in[11];
    const float* rad_w2  = (const float*)d_in[12];
    const float* rad_b2  = (const float*)d_in[13];
    const float* rad_g2  = (const float*)d_in[14];
    const float* rad_be2 = (const float*)d_in[15];
    const float* rad_w3  = (const float*)d_in[16];
    const float* rad_b3  = (const float*)d_in[17];
    const float* c1_w0   = (const float*)d_in[18];
    const float* c1_b0   = (const float*)d_in[19];
    const float* c1_wm1  = (const float*)d_in[20];
    const float* c1_wm2  = (const float*)d_in[21];
    const float* aln_g   = (const float*)d_in[22];
    const float* aln_b   = (const float*)d_in[23];
    const float* adot    = (const float*)d_in[24];
    const float* to_grid = (const float*)d_in[25];
    const float* from_grid=(const float*)d_in[26];
    const float* c2_w0   = (const float*)d_in[27];
    const float* c2_b0   = (const float*)d_in[28];
    const float* c2_wm1  = (const float*)d_in[29];
    const float* c2_wm2  = (const float*)d_in[30];
    const float* proj_w  = (const float*)d_in[31];
    const float* proj_b  = (const float*)d_in[32];

    char* ws = (char*)d_ws;
    size_t off = 0;
    auto take = [&](size_t bytes) -> char* {
        char* p = ws + off;
        off += (bytes + 255) & ~(size_t)255;
        return p;
    };
    // fixed section
    u16* w_rad1T  = (u16*)take(64 * 192 * 2);
    u16* w_rad2T  = (u16*)take(64 * 64 * 2);
    u16* w_rad3T  = (u16*)take(1536 * 64 * 2);
    u16* w_c1w0T  = (u16*)take(640 * 640 * 2);
    u16* w_c1m1T  = (u16*)take((size_t)512 * 1024 * 2);
    u16* w_c1m2T  = (u16*)take((size_t)384 * 768 * 2);
    u16* w_c2w0T  = (u16*)take((size_t)640 * 320 * 2);
    u16* w_c2m1T  = (u16*)take((size_t)1024 * 512 * 2);
    u16* w_c2m2T  = (u16*)take((size_t)768 * 384 * 2);
    u16* w_tgP    = (u16*)take(112 * 32 * 2);
    u16* w_fgP    = (u16*)take(32 * 128 * 2);
    u16* w_pwT    = (u16*)take(5 * 8192 * 2);
    float* logits = (float*)take((size_t)E_EDGES * 8 * 4);
    float* ealpha = (float*)take((size_t)E_EDGES * 8 * 4);
    u32* nmax     = (u32*)take((size_t)N_NODES_C * 8 * 4);
    float* nsum   = (float*)take((size_t)N_NODES_C * 8 * 4);
    float* node   = (float*)take((size_t)N_NODES_C * 3200 * 4);
    u16* a_h2     = (u16*)take((size_t)E_EDGES * 64 * 2);
    u32* c_deg    = (u32*)take((size_t)N_NODES_C * 4);
    u32* c_row    = (u32*)take((size_t)N_NODES_C * 4);
    u32* c_cur    = (u32*)take((size_t)N_NODES_C * 4);
    int* c_elist  = (int*)take((size_t)E_EDGES * 4);
    // arena — aliased by phase
    char* arena   = take(173015040);
    if (off > ws_size) {  // diagnostic: paint output so the failure mode is identifiable
        k_diag<<<(out_size + 255) / 256, 256, 0, stream>>>((float*)d_out, out_size);
        return;
    }

    u16* a_ee   = (u16*)(arena + 0);           // radial phase
    u16* a_xe   = (u16*)(arena + 0);           // per-chunk (EC,1536); ee dead after radmlp
    u16* a_A1   = (u16*)(arena + 37748736);    // per-chunk (EC,2432)
    u16* a_Y0   = (u16*)(arena + 97517568);    // full (E,640)
    u16* a_Y1   = (u16*)(arena + 128974848);   // full (E,512)
    u16* a_Y2   = (u16*)(arena + 154140672);   // full (E,384) -> arena end
    u16* a_A2   = (u16*)(arena + 0);           // full (E,1216); xe/A1 dead
    u16* a_Z0   = (u16*)(arena + 59768832);    // per-chunk (EC,640)
    u16* a_Z1   = (u16*)(arena + 75497472);    // per-chunk (EC,1024)
    u16* a_Z2   = (u16*)(arena + 100663296);   // per-chunk (EC,768); overlaps dead Y0 region

    // ---- fused prep (weights + init + deg-zero + edge embeds): 1 launch ----
    PrepArgs pa;
    pa.rad_w1 = rad_w1; pa.rad_w2 = rad_w2; pa.rad_w3 = rad_w3;
    pa.c1_w0 = c1_w0; pa.c2_w0 = c2_w0;
    pa.c1_wm1 = c1_wm1; pa.c1_wm2 = c1_wm2; pa.c2_wm1 = c2_wm1; pa.c2_wm2 = c2_wm2;
    pa.to_grid = to_grid; pa.from_grid = from_grid; pa.proj_w = proj_w;
    pa.w_rad1T = w_rad1T; pa.w_rad2T = w_rad2T; pa.w_rad3T = w_rad3T;
    pa.w_c1w0T = w_c1w0T; pa.w_c2w0T = w_c2w0T;
    pa.w_c1m1T = w_c1m1T; pa.w_c1m2T = w_c1m2T; pa.w_c2m1T = w_c2m1T; pa.w_c2m2T = w_c2m2T;
    pa.w_tgP = w_tgP; pa.w_fgP = w_fgP; pa.w_pwT = w_pwT;
    pa.nmax = nmax; pa.nsum = nsum; pa.c_deg = c_deg;
    pa.dist = dist; pa.species = species; pa.snd = snd; pa.rcv = rcv;
    pa.semb = semb; pa.remb = remb; pa.ee = a_ee;
    k_prep<<<PREP_BLOCKS, 256, 0, stream>>>(pa);

    // ---- CSR build ----
    k_deg<<<96, 256, 0, stream>>>(rcv, c_deg);
    k_pfx<<<1, 256, 0, stream>>>(c_deg, c_row, c_cur);
    k_fill<<<96, 256, 0, stream>>>(rcv, c_cur, c_elist);

    // ---- fused radial MLP: 1 launch ----
    k_radmlp<<<192, 256, 0, stream>>>(a_ee, w_rad1T, w_rad2T,
                                      rad_b1, rad_g1, rad_be1,
                                      rad_b2, rad_g2, rad_be2, a_h2);

    // ---- chunked: x_edge gemm -> rotate -> conv1 (3 gemms fused) ----
    for (int c = 0; c < 2; c++) {
        int e0 = c * EC;
        k_gemm<<<dim3(96, 12), 256, 0, stream>>>(a_h2 + (size_t)e0 * 64, 64, w_rad3T, 64,
                                                 a_xe, 1536, 1536, 64, rad_b3);
        k_rotate<<<EC / 2, 256, 0, stream>>>(nf, wig, snd, rcv, a_xe, a_A1, e0);
        Gemm3 g1;
        g1.d[0] = { a_A1,        w_c1w0T, a_Y0 + (size_t)e0 * 640, c1_b0,   2432, 640,  640, 640, 640 };
        g1.d[1] = { a_A1 + 640,  w_c1m1T, a_Y1 + (size_t)e0 * 512, nullptr, 2432, 1024, 512, 512, 1024 };
        g1.d[2] = { a_A1 + 1664, w_c1m2T, a_Y2 + (size_t)e0 * 384, nullptr, 2432, 768,  384, 384, 768 };
        g1.cut0 = 5; g1.cut1 = 9; g1.nY = 12;
        g1.logits = nullptr; g1.rcv = nullptr; g1.nmax = nullptr; g1.ealpha = nullptr; g1.nsum = nullptr;
        k_gemm3<<<dim3(96, 12), 256, 0, stream>>>(g1);
    }

    // ---- attention logits (standalone, zero LDS) then grid nonlinearity ----
    k_logits<<<E_EDGES, 256, 0, stream>>>(a_Y0, rcv, aln_g, aln_b, adot, logits, nmax);
    k_grid_mfma<<<E_EDGES / 2, 256, 0, stream>>>(a_Y0, a_Y1, a_Y2, w_tgP, w_fgP, a_A2);

    // ---- chunked: conv2 (3 gemms fused; chunk0 carries the expsum plane) -> gather ----
    for (int c = 0; c < 2; c++) {
        int e0 = c * EC;
        Gemm3 g2;
        g2.d[0] = { a_A2 + (size_t)e0 * 1216,       w_c2w0T, a_Z0, c2_b0,   1216, 320, 640,  640,  320 };
        g2.d[1] = { a_A2 + (size_t)e0 * 1216 + 320, w_c2m1T, a_Z1, nullptr, 1216, 512, 1024, 1024, 512 };
        g2.d[2] = { a_A2 + (size_t)e0 * 1216 + 832, w_c2m2T, a_Z2, nullptr, 1216, 384, 768,  768,  384 };
        g2.cut0 = 5; g2.cut1 = 13; g2.nY = 19;
        g2.logits = logits; g2.rcv = rcv; g2.nmax = nmax; g2.ealpha = ealpha; g2.nsum = nsum;
        int gy = (c == 0) ? 20 : 19;        // chunk0 carries the expsum plane (deps: logits done)
        k_gemm3<<<dim3(96, gy), 256, 0, stream>>>(g2);
        k_gather<<<N_NODES_C / 4, 256, 0, stream>>>(a_Z0, a_Z1, a_Z2, wig, ealpha, nsum,
                                                    c_row, c_deg, c_elist, node, e0, c);
    }

    // ---- output projection (MFMA) ----
    k_proj_mfma<<<dim3(32, 25), 256, 0, stream>>>(node, w_pwT, proj_b, (float*)d_out);
}